// Round 1
// baseline (1421.254 us; speedup 1.0000x reference)
//
#include <hip/hip_runtime.h>
#include <stdint.h>
#include <math.h>

// Problem constants
#define NTOK 4096   // B*S
#define H    1024
#define NHEAD 16
#define HD   64
#define SEQ  2048
#define NE   8
#define DDIM 1024

// ---------------- helpers ----------------

__device__ __forceinline__ int dot4(int a, int b, int c) {
#if __has_builtin(__builtin_amdgcn_sdot4)
  return __builtin_amdgcn_sdot4(a, b, c, false);
#else
  c += (int)(int8_t)(a)       * (int)(int8_t)(b);
  c += (int)(int8_t)(a >> 8)  * (int)(int8_t)(b >> 8);
  c += (int)(int8_t)(a >> 16) * (int)(int8_t)(b >> 16);
  c += (int)(int8_t)(a >> 24) * (int)(int8_t)(b >> 24);
  return c;
#endif
}

__device__ __forceinline__ float d4f(float4 a, float4 b, float acc) {
  acc = fmaf(a.x, b.x, acc); acc = fmaf(a.y, b.y, acc);
  acc = fmaf(a.z, b.z, acc); acc = fmaf(a.w, b.w, acc);
  return acc;
}

// 256-thread block reduce (double). op=0 sum, op=1 max. tmp: __shared__ double[4]
__device__ __forceinline__ double bredd(double v, int op, double* tmp) {
#pragma unroll
  for (int o = 32; o; o >>= 1) {
    double w = __shfl_xor(v, o);
    v = op ? fmax(v, w) : v + w;
  }
  int wid = threadIdx.x >> 6;
  if ((threadIdx.x & 63) == 0) tmp[wid] = v;
  __syncthreads();
  double r = op ? fmax(fmax(tmp[0], tmp[1]), fmax(tmp[2], tmp[3]))
                : (tmp[0] + tmp[1] + tmp[2] + tmp[3]);
  __syncthreads();
  return r;
}

// quantize 4 doubles to packed int8 with double scale (round-half-even like jnp.round)
__device__ __forceinline__ int qpackd(double n0, double n1, double n2, double n3, double s) {
  int a = (int)fmin(fmax(rint(n0 * s), -128.0), 127.0);
  int b = (int)fmin(fmax(rint(n1 * s), -128.0), 127.0);
  int c = (int)fmin(fmax(rint(n2 * s), -128.0), 127.0);
  int d = (int)fmin(fmax(rint(n3 * s), -128.0), 127.0);
  return (a & 255) | ((b & 255) << 8) | ((c & 255) << 16) | ((d & 255) << 24);
}

// map flat tensor id (0..27, each 1M elems) -> source pointer
__device__ __forceinline__ const float* wsrc(int tensor,
    const float* qw_, const float* kw_, const float* vw_, const float* ow_,
    const float* gw_, const float* uw_, const float* dw_) {
  if (tensor < 4) return tensor == 0 ? qw_ : tensor == 1 ? kw_ : tensor == 2 ? vw_ : ow_;
  if (tensor < 12) return gw_ + ((long long)(tensor - 4) << 20);
  if (tensor < 20) return uw_ + ((long long)(tensor - 12) << 20);
  return dw_ + ((long long)(tensor - 20) << 20);
}

// ---------------- weight quantization (fp64 scale, deterministic) ----------------

__global__ __launch_bounds__(256) void k_absum(
    const float* qw_, const float* kw_, const float* vw_, const float* ow_,
    const float* gw_, const float* uw_, const float* dw_, double* partial) {
  __shared__ double tmp[4];
  int tensor = blockIdx.x >> 10;
  int j = ((blockIdx.x & 1023) << 10) + threadIdx.x * 4;
  const float* src = wsrc(tensor, qw_, kw_, vw_, ow_, gw_, uw_, dw_);
  float4 w = *(const float4*)(src + j);
  double v = fabs((double)w.x) + fabs((double)w.y) + fabs((double)w.z) + fabs((double)w.w);
  v = bredd(v, 0, tmp);
  if (threadIdx.x == 0) partial[blockIdx.x] = v;
}

__global__ __launch_bounds__(256) void k_wscale(const double* partial, double* wsd) {
  __shared__ double tmp[4];
  int tensor = blockIdx.x;
  const double* p = partial + (tensor << 10);
  int i = threadIdx.x * 4;
  double v = p[i] + p[i + 1] + p[i + 2] + p[i + 3];
  v = bredd(v, 0, tmp);
  if (threadIdx.x == 0) wsd[tensor] = 1.0 / fmax(v * (1.0 / 1048576.0), 1e-5);
}

__global__ __launch_bounds__(256) void k_quantw(
    const float* qw_, const float* kw_, const float* vw_, const float* ow_,
    const float* gw_, const float* uw_, const float* dw_,
    const double* wsd, int8_t* qw) {
  int tensor = blockIdx.x >> 10;
  int j = ((blockIdx.x & 1023) << 10) + threadIdx.x * 4;
  const float* src = wsrc(tensor, qw_, kw_, vw_, ow_, gw_, uw_, dw_);
  double s = wsd[tensor];
  float4 w = *(const float4*)(src + j);
  int a = (int)fmin(fmax(rint((double)w.x * s), -1.0), 1.0);
  int b = (int)fmin(fmax(rint((double)w.y * s), -1.0), 1.0);
  int c = (int)fmin(fmax(rint((double)w.z * s), -1.0), 1.0);
  int d = (int)fmin(fmax(rint((double)w.w * s), -1.0), 1.0);
  ((int*)qw)[(tensor << 18) + (j >> 2)] =
      (a & 255) | ((b & 255) << 8) | ((c & 255) << 16) | ((d & 255) << 24);
}

// ---------------- rmsnorm + act_quant (attention input), fp64 decisions ----------------

__global__ __launch_bounds__(256) void k_rms1(const float* X, const float* lnw,
                                              int8_t* xq, double* xsd) {
  __shared__ double tmp[4];
  int t = blockIdx.x, tid = threadIdx.x;
  float4 xv = ((const float4*)(X + (long long)t * H))[tid];
  double x0 = xv.x, x1 = xv.y, x2 = xv.z, x3 = xv.w;
  double ss = x0 * x0 + x1 * x1 + x2 * x2 + x3 * x3;
  ss = bredd(ss, 0, tmp);
  double r = 1.0 / sqrt(ss * (1.0 / 1024.0) + 1e-5);
  float4 wv = ((const float4*)lnw)[tid];
  double n0 = x0 * r * wv.x, n1 = x1 * r * wv.y, n2 = x2 * r * wv.z, n3 = x3 * r * wv.w;
  double ma = fmax(fmax(fabs(n0), fabs(n1)), fmax(fabs(n2), fabs(n3)));
  ma = bredd(ma, 1, tmp);
  double s = 127.0 / fmax(ma, 1e-5);
  ((int*)xq)[t * 256 + tid] = qpackd(n0, n1, n2, n3, s);
  if (tid == 0) xsd[t] = s;
}

// act_quant only (rows of 1024 floats), fp64 decisions
__global__ __launch_bounds__(256) void k_actq(const float* X, int8_t* xq, double* xsd) {
  __shared__ double tmp[4];
  int t = blockIdx.x, tid = threadIdx.x;
  float4 xv = ((const float4*)(X + (long long)t * H))[tid];
  double x0 = xv.x, x1 = xv.y, x2 = xv.z, x3 = xv.w;
  double ma = fmax(fmax(fabs(x0), fabs(x1)), fmax(fabs(x2), fabs(x3)));
  ma = bredd(ma, 1, tmp);
  double s = 127.0 / fmax(ma, 1e-5);
  ((int*)xq)[t * 256 + tid] = qpackd(x0, x1, x2, x3, s);
  if (tid == 0) xsd[t] = s;
}

// ---------------- int8 GEMM: out[t,n] = res[t,n] + acc / (xs[t]*sw) ----------------

__global__ __launch_bounds__(256) void k_gemm(
    const int8_t* __restrict__ Xq, const double* __restrict__ xsd,
    const int8_t* __restrict__ W, const double* __restrict__ wsd, int widx,
    const float* __restrict__ residual, float* __restrict__ out) {
  __shared__ int Xs[32][65];
  __shared__ int Wt[32][65];
  int tid = threadIdx.x;
  int t0 = blockIdx.y * 64, n0 = blockIdx.x * 64;
  const int* Xg = (const int*)Xq;
  const int* Wg = (const int*)W;
  int acc[4][4] = {};
  int lr = tid >> 5, lc = tid & 31;
  int ty = tid >> 4, tx = tid & 15;
  for (int k0 = 0; k0 < 1024; k0 += 128) {
    int kc = k0 >> 2;
#pragma unroll
    for (int i = 0; i < 8; i++) {
      int rr = lr + i * 8;
      Xs[lc][rr] = Xg[(t0 + rr) * 256 + kc + lc];
      Wt[lc][rr] = Wg[(n0 + rr) * 256 + kc + lc];
    }
    __syncthreads();
#pragma unroll
    for (int kk = 0; kk < 32; kk++) {
      int4 a = *(const int4*)&Xs[kk][ty * 4];
      int4 b = *(const int4*)&Wt[kk][tx * 4];
      acc[0][0] = dot4(a.x, b.x, acc[0][0]); acc[0][1] = dot4(a.x, b.y, acc[0][1]);
      acc[0][2] = dot4(a.x, b.z, acc[0][2]); acc[0][3] = dot4(a.x, b.w, acc[0][3]);
      acc[1][0] = dot4(a.y, b.x, acc[1][0]); acc[1][1] = dot4(a.y, b.y, acc[1][1]);
      acc[1][2] = dot4(a.y, b.z, acc[1][2]); acc[1][3] = dot4(a.y, b.w, acc[1][3]);
      acc[2][0] = dot4(a.z, b.x, acc[2][0]); acc[2][1] = dot4(a.z, b.y, acc[2][1]);
      acc[2][2] = dot4(a.z, b.z, acc[2][2]); acc[2][3] = dot4(a.z, b.w, acc[2][3]);
      acc[3][0] = dot4(a.w, b.x, acc[3][0]); acc[3][1] = dot4(a.w, b.y, acc[3][1]);
      acc[3][2] = dot4(a.w, b.z, acc[3][2]); acc[3][3] = dot4(a.w, b.w, acc[3][3]);
    }
    __syncthreads();
  }
  double sw = wsd[widx];
#pragma unroll
  for (int i = 0; i < 4; i++) {
    int t = t0 + ty * 4 + i;
    double inv = 1.0 / (xsd[t] * sw);
#pragma unroll
    for (int j = 0; j < 4; j++) {
      int n = n0 + tx * 4 + j;
      double v = (double)acc[i][j] * inv;
      if (residual) v += (double)residual[(long long)t * H + n];
      out[(long long)t * H + n] = (float)v;
    }
  }
}

// ---------------- attention ----------------
// k_knorm: per-(b,head) max key L2-norm -> fixed softmax bound.

__global__ __launch_bounds__(256) void k_knorm(const float* __restrict__ K,
                                               float* __restrict__ Mk) {
  __shared__ float tmp[4];
  int bh = blockIdx.x;          // b*16 + head
  int b = bh >> 4, head = bh & 15;
  int tid = threadIdx.x;
  float mx = 0.f;
  for (int key = tid; key < SEQ; key += 256) {
    const float4* kr = (const float4*)(K + ((long long)(b * SEQ + key)) * H + head * HD);
    float s = 0.f;
#pragma unroll
    for (int i = 0; i < 16; i++) {
      float4 v = kr[i];
      s += v.x * v.x + v.y * v.y + v.z * v.z + v.w * v.w;
    }
    mx = fmaxf(mx, s);
  }
#pragma unroll
  for (int o = 32; o; o >>= 1) mx = fmaxf(mx, __shfl_xor(mx, o));
  if ((tid & 63) == 0) tmp[tid >> 6] = mx;
  __syncthreads();
  if (tid == 0)
    Mk[bh] = sqrtf(fmaxf(fmaxf(tmp[0], tmp[1]), fmaxf(tmp[2], tmp[3])));
}

// k_attn (R7 restructure): grid (32 qtiles reversed, 16 heads, 2 b), block 256 = 4 waves.
// NEW lane mapping: lane = qp*2 + dp; lane owns 2 queries (j = qp*2, qp*2+1) x 32 dims
// (d0 = dp*32). A wave covers ALL 64 queries of the block; the 4 waves split KEYS
// 4-ways in pairs (wave w: keys {8m+2w, 8m+2w+1}). This removes the per-key double
// shuffle (now ONE shfl_xor(.,1) per dot), processes 2 keys/iter for ILP (8 indep
// 16-deep QK chains), and raises FMA density to ~92% of inner-loop VALU ops.
// Key-split partials merge ONCE per block through LDS (waves 1..3 publish, wave 0
// sums + normalizes). Fixed-bound softmax (validated): wgt = exp(p - 0.125|q||k|max).
// LDS: stage K=smem[0], V=smem[1]; merge aliases smem[0..2] (both dead by then).
// __launch_bounds__(256,3): cap ~170 VGPR -> 3 blocks/CU (LDS 53KB/block fits 3x).

__global__ __launch_bounds__(256, 3) void k_attn(
    const float* __restrict__ Q, const float* __restrict__ K,
    const float* __restrict__ V, float* __restrict__ O,
    const float* __restrict__ Mk) {
  __shared__ float smem[3][64][68];
  __shared__ float lsh[4][64];
  int g = 31 - blockIdx.x;            // longest blocks dispatch first
  int head = blockIdx.y, b = blockIdx.z;
  int tid = threadIdx.x;
  int w = tid >> 6, lane = tid & 63;
  int dp = lane & 1;                  // dim half: 0 -> dims 0..31, 1 -> 32..63
  int qp = lane >> 1;                 // query pair 0..31
  int qlo = g * 64;
  int d0 = dp << 5;
  long long bh_base = ((long long)b * SEQ) * H + head * HD;

  float mkv = Mk[b * 16 + head];
  float4 q4[2][8];
  float4 acc[2][8];
  float mb[2], l[2] = {0.f, 0.f};
#pragma unroll
  for (int qq = 0; qq < 2; qq++)
#pragma unroll
    for (int c = 0; c < 8; c++) acc[qq][c] = make_float4(0.f, 0.f, 0.f, 0.f);

  // load 2 queries (32 dims each), fixed bound mb = 0.125*|q|*max|k|
#pragma unroll
  for (int qq = 0; qq < 2; qq++) {
    int j = qp * 2 + qq;
    const float4* qp_ = (const float4*)(Q + bh_base + (long long)(qlo + j) * H + d0);
    float ss = 0.f;
#pragma unroll
    for (int c = 0; c < 8; c++) {
      float4 t = qp_[c];
      ss += t.x * t.x + t.y * t.y + t.z * t.z + t.w * t.w;
      q4[qq][c] = make_float4(t.x * 0.125f, t.y * 0.125f, t.z * 0.125f, t.w * 0.125f);
    }
    ss += __shfl_xor(ss, 1);          // partner dim-half
    mb[qq] = 0.125f * sqrtf(ss) * mkv;
  }

  int srow = tid >> 2;                // staging: key row 0..63
  int sdc = (tid & 3) << 4;           // staging: d chunk 0/16/32/48

  for (int t = 0; t <= g; t++) {
    long long srowg = bh_base + (long long)(t * 64 + srow) * H + sdc;
    const float4* kg = (const float4*)(K + srowg);
    const float4* vg = (const float4*)(V + srowg);
    float4* ksd = (float4*)&smem[0][srow][sdc];
    float4* vsd = (float4*)&smem[1][srow][sdc];
#pragma unroll
    for (int i = 0; i < 4; i++) ksd[i] = kg[i];
#pragma unroll
    for (int i = 0; i < 4; i++) vsd[i] = vg[i];
    __syncthreads();

    bool diag = (t == g);
    int j0 = qp * 2, j1 = j0 + 1;
#pragma unroll 1
    for (int m = 0; m < 8; m++) {
      int ka = m * 8 + w * 2;         // this wave's key pair: ka, ka+1
      const float4* krA = (const float4*)&smem[0][ka][d0];
      const float4* krB = (const float4*)&smem[0][ka + 1][d0];
      // QK dots: 2 keys x 2 queries, each split into even/odd chains (8 chains)
      float pA0e = 0.f, pA0o = 0.f, pA1e = 0.f, pA1o = 0.f;
      float pB0e = 0.f, pB0o = 0.f, pB1e = 0.f, pB1o = 0.f;
#pragma unroll
      for (int c = 0; c < 8; c += 2) {
        float4 kAe = krA[c], kAo = krA[c + 1];
        float4 kBe = krB[c], kBo = krB[c + 1];
        pA0e = d4f(q4[0][c], kAe, pA0e); pA0o = d4f(q4[0][c + 1], kAo, pA0o);
        pA1e = d4f(q4[1][c], kAe, pA1e); pA1o = d4f(q4[1][c + 1], kAo, pA1o);
        pB0e = d4f(q4[0][c], kBe, pB0e); pB0o = d4f(q4[0][c + 1], kBo, pB0o);
        pB1e = d4f(q4[1][c], kBe, pB1e); pB1o = d4f(q4[1][c + 1], kBo, pB1o);
      }
      float pA0 = pA0e + pA0o, pA1 = pA1e + pA1o;
      float pB0 = pB0e + pB0o, pB1 = pB1e + pB1o;
      pA0 += __shfl_xor(pA0, 1);
      pA1 += __shfl_xor(pA1, 1);
      pB0 += __shfl_xor(pB0, 1);
      pB1 += __shfl_xor(pB1, 1);
      bool okA0 = !diag || (ka <= j0);
      bool okA1 = !diag || (ka <= j1);
      bool okB0 = !diag || (ka + 1 <= j0);
      bool okB1 = !diag || (ka + 1 <= j1);
      float wA0 = okA0 ? __expf(pA0 - mb[0]) : 0.f;
      float wA1 = okA1 ? __expf(pA1 - mb[1]) : 0.f;
      float wB0 = okB0 ? __expf(pB0 - mb[0]) : 0.f;
      float wB1 = okB1 ? __expf(pB1 - mb[1]) : 0.f;
      l[0] += wA0 + wB0;
      l[1] += wA1 + wB1;
      const float4* vrA = (const float4*)&smem[1][ka][d0];
      const float4* vrB = (const float4*)&smem[1][ka + 1][d0];
#pragma unroll
      for (int c = 0; c < 8; c++) {
        float4 vA = vrA[c], vB = vrB[c];
        acc[0][c].x = fmaf(wA0, vA.x, fmaf(wB0, vB.x, acc[0][c].x));
        acc[0][c].y = fmaf(wA0, vA.y, fmaf(wB0, vB.y, acc[0][c].y));
        acc[0][c].z = fmaf(wA0, vA.z, fmaf(wB0, vB.z, acc[0][c].z));
        acc[0][c].w = fmaf(wA0, vA.w, fmaf(wB0, vB.w, acc[0][c].w));
        acc[1][c].x = fmaf(wA1, vA.x, fmaf(wB1, vB.x, acc[1][c].x));
        acc[1][c].y = fmaf(wA1, vA.y, fmaf(wB1, vB.y, acc[1][c].y));
        acc[1][c].z = fmaf(wA1, vA.z, fmaf(wB1, vB.z, acc[1][c].z));
        acc[1][c].w = fmaf(wA1, vA.w, fmaf(wB1, vB.w, acc[1][c].w));
      }
    }
    __syncthreads();
  }

  // ---- merge key-split partials (fixed bound => plain sums).
  // K/V tiles are dead; waves 1..3 publish acc into smem[0..2], wave 0 sums.
  if (dp == 0) {
    lsh[w][qp * 2 + 0] = l[0];
    lsh[w][qp * 2 + 1] = l[1];
  }
  if (w > 0) {
#pragma unroll
    for (int qq = 0; qq < 2; qq++) {
      float4* dst = (float4*)&smem[w - 1][qp * 2 + qq][d0];
#pragma unroll
      for (int c = 0; c < 8; c++) dst[c] = acc[qq][c];
    }
  }
  __syncthreads();
  if (w == 0) {
#pragma unroll
    for (int qq = 0; qq < 2; qq++) {
      int j = qp * 2 + qq;
      float lt = lsh[0][j] + lsh[1][j] + lsh[2][j] + lsh[3][j];
      float inv = 1.f / lt;
      const float4* m0 = (const float4*)&smem[0][j][d0];
      const float4* m1 = (const float4*)&smem[1][j][d0];
      const float4* m2 = (const float4*)&smem[2][j][d0];
      float4* op = (float4*)(O + bh_base + (long long)(qlo + j) * H + d0);
#pragma unroll
      for (int c = 0; c < 8; c++) {
        float4 s0 = m0[c], s1 = m1[c], s2 = m2[c];
        op[c] = make_float4((acc[qq][c].x + s0.x + s1.x + s2.x) * inv,
                            (acc[qq][c].y + s0.y + s1.y + s2.y) * inv,
                            (acc[qq][c].z + s0.z + s1.z + s2.z) * inv,
                            (acc[qq][c].w + s0.w + s1.w + s2.w) * inv);
      }
    }
  }
}

// ---------------- rmsnorm2 + router (argmax, fp64) + act_quant ----------------

__global__ __launch_bounds__(256) void k_rms2_router(
    const float* X2, const float* lnw, const float* rw,
    int8_t* xq, double* xsd, int* eidx) {
  __shared__ double tmp[4];
  __shared__ double xn[1024];
  __shared__ double logits[8];
  int t = blockIdx.x, tid = threadIdx.x;
  float4 xv = ((const float4*)(X2 + (long long)t * H))[tid];
  double x0 = xv.x, x1 = xv.y, x2 = xv.z, x3 = xv.w;
  double ss = x0 * x0 + x1 * x1 + x2 * x2 + x3 * x3;
  ss = bredd(ss, 0, tmp);
  double r = 1.0 / sqrt(ss * (1.0 / 1024.0) + 1e-5);
  float4 wv = ((const float4*)lnw)[tid];
  double n0 = x0 * r * wv.x, n1 = x1 * r * wv.y, n2 = x2 * r * wv.z, n3 = x3 * r * wv.w;
  xn[tid * 4 + 0] = n0; xn[tid * 4 + 1] = n1;
  xn[tid * 4 + 2] = n2; xn[tid * 4 + 3] = n3;
  double ma = fmax(fmax(fabs(n0), fabs(n1)), fmax(fabs(n2), fabs(n3)));
  ma = bredd(ma, 1, tmp);  // contains syncthreads -> xn visible
  double s = 127.0 / fmax(ma, 1e-5);
  ((int*)xq)[t * 256 + tid] = qpackd(n0, n1, n2, n3, s);
  if (tid == 0) xsd[t] = s;
  if (tid < 64) {
    int e = tid >> 3, i = tid & 7;
    const float* wr = rw + e * 1024;
    double p = 0.0;
    for (int h = i; h < 1024; h += 8) p += xn[h] * (double)wr[h];
    p += __shfl_xor(p, 1);
    p += __shfl_xor(p, 2);
    p += __shfl_xor(p, 4);
    if (i == 0) logits[e] = p;
  }
  __syncthreads();
  if (tid == 0) {
    double best = logits[0];
    int bi = 0;
    for (int e = 1; e < 8; e++)
      if (logits[e] > best) { best = logits[e]; bi = e; }
    eidx[t] = bi;
  }
}

// ---------------- MoE routing: group tokens by expert into padded 64-slot tiles ----
// meta[0] = ntile; meta[1+i] = expert of tile i. tokidx[slot] = token or -1 (pad).

__global__ __launch_bounds__(256) void k_route(const int* __restrict__ eidx,
                                               int* __restrict__ meta,
                                               int* __restrict__ tokidx) {
  __shared__ int cnt[8], pb[9], cur[8];
  int tid = threadIdx.x;
  if (tid < 8) cnt[tid] = 0;
  __syncthreads();
  for (int t = tid; t < NTOK; t += 256) atomicAdd(&cnt[eidx[t]], 1);
  __syncthreads();
  if (tid == 0) {
    pb[0] = 0;
    int nt = 0;
    for (int e = 0; e < 8; e++) {
      int tiles = (cnt[e] + 63) >> 6;
      for (int i = 0; i < tiles; i++) meta[1 + nt + i] = e;
      nt += tiles;
      pb[e + 1] = pb[e] + tiles * 64;
      cur[e] = pb[e];
    }
    meta[0] = nt;
  }
  __syncthreads();
  for (int s = tid; s < 4608; s += 256) tokidx[s] = -1;
  __syncthreads();
  for (int t = tid; t < NTOK; t += 256) {
    int e = eidx[t];
    int s = atomicAdd(&cur[e], 1);
    tokidx[s] = t;
  }
}

// ---------------- MoE gate+up GEMM -> hh (fused relu(g)^2*u) ----------------
// grid (16 n-tiles, 71 slot-tiles). Gathered X rows; two W tiles per block.

__global__ __launch_bounds__(256) void k_moe_gu(
    const int8_t* __restrict__ Xq, const double* __restrict__ xsd,
    const int8_t* __restrict__ qw, const double* __restrict__ wsd,
    const int* __restrict__ meta, const int* __restrict__ tokidx,
    float* __restrict__ hhbuf) {
  __shared__ int Xs[32][65];
  __shared__ int Wg[32][65];
  __shared__ int Wu[32][65];
  int tile = blockIdx.y;
  if (tile >= meta[0]) return;
  int e = meta[1 + tile];
  int n0 = blockIdx.x * 64;
  int s0 = tile * 64;
  int tid = threadIdx.x;
  int lr = tid >> 5, lc = tid & 31;
  int ty = tid >> 4, tx = tid & 15;
  const int* Xg = (const int*)Xq;
  const int* Gg = (const int*)(qw + ((long long)(4 + e) << 20));
  const int* Ug = (const int*)(qw + ((long long)(12 + e) << 20));
  int toks[8];
#pragma unroll
  for (int i = 0; i < 8; i++) {
    int tk = tokidx[s0 + lr + i * 8];
    toks[i] = tk < 0 ? 0 : tk;
  }
  int accg[4][4] = {};
  int accu[4][4] = {};
  for (int k0 = 0; k0 < 1024; k0 += 128) {
    int kc = k0 >> 2;
#pragma unroll
    for (int i = 0; i < 8; i++) {
      int rr = lr + i * 8;
      Xs[lc][rr] = Xg[toks[i] * 256 + kc + lc];
      Wg[lc][rr] = Gg[(n0 + rr) * 256 + kc + lc];
      Wu[lc][rr] = Ug[(n0 + rr) * 256 + kc + lc];
    }
    __syncthreads();
#pragma unroll
    for (int kk = 0; kk < 32; kk++) {
      int4 a  = *(const int4*)&Xs[kk][ty * 4];
      int4 bg = *(const int4*)&Wg[kk][tx * 4];
      int4 bu = *(const int4*)&Wu[kk][tx * 4];
      accg[0][0] = dot4(a.x, bg.x, accg[0][0]); accg[0][1] = dot4(a.x, bg.y, accg[0][1]);
      accg[0][2] = dot4(a.x, bg.z, accg[0][2]); accg[0][3] = dot4(a.x, bg.w, accg[0][3]);
      accg[1][0] = dot4(a.y, bg.x, accg[1][0]); accg[1][1] = dot4(a.y, bg.y, accg[1][1]);
      accg[1][2] = dot4(a.y, bg.z, accg[1][2]); accg[1][3] = dot4(a.y, bg.w, accg[1][3]);
      accg[2][0] = dot4(a.z, bg.x, accg[2][0]); accg[2][1] = dot4(a.z, bg.y, accg[2][1]);
      accg[2][2] = dot4(a.z, bg.z, accg[2][2]); accg[2][3] = dot4(a.z, bg.w, accg[2][3]);
      accg[3][0] = dot4(a.w, bg.x, accg[3][0]); accg[3][1] = dot4(a.w, bg.y, accg[3][1]);
      accg[3][2] = dot4(a.w, bg.z, accg[3][2]); accg[3][3] = dot4(a.w, bg.w, accg[3][3]);
      accu[0][0] = dot4(a.x, bu.x, accu[0][0]); accu[0][1] = dot4(a.x, bu.y, accu[0][1]);
      accu[0][2] = dot4(a.x, bu.z, accu[0][2]); accu[0][3] = dot4(a.x, bu.w, accu[0][3]);
      accu[1][0] = dot4(a.y, bu.x, accu[1][0]); accu[1][1] = dot4(a.y, bu.y, accu[1][1]);
      accu[1][2] = dot4(a.y, bu.z, accu[1][2]); accu[1][3] = dot4(a.y, bu.w, accu[1][3]);
      accu[2][0] = dot4(a.z, bu.x, accu[2][0]); accu[2][1] = dot4(a.z, bu.y, accu[2][1]);
      accu[2][2] = dot4(a.z, bu.z, accu[2][2]); accu[2][3] = dot4(a.z, bu.w, accu[2][3]);
      accu[3][0] = dot4(a.w, bu.x, accu[3][0]); accu[3][1] = dot4(a.w, bu.y, accu[3][1]);
      accu[3][2] = dot4(a.w, bu.z, accu[3][2]); accu[3][3] = dot4(a.w, bu.w, accu[3][3]);
    }
    __syncthreads();
  }
  double swg = wsd[4 + e], swu = wsd[12 + e];
#pragma unroll
  for (int i = 0; i < 4; i++) {
    int s = s0 + ty * 4 + i;
    int tok = tokidx[s];
    if (tok < 0) continue;
    double ig = 1.0 / (xsd[tok] * swg);
    double iu = 1.0 / (xsd[tok] * swu);
#pragma unroll
    for (int j = 0; j < 4; j++) {
      int n = n0 + tx * 4 + j;
      double g = (double)accg[i][j] * ig;
      double u = (double)accu[i][j] * iu;
      double rg = fmax(g, 0.0);
      hhbuf[(long long)s * DDIM + n] = (float)(rg * rg * u);
    }
  }
}

// ---------------- act_quant over hh slot rows ----------------

__global__ __launch_bounds__(256) void k_hh_actq(
    const float* __restrict__ hhbuf, const int* __restrict__ meta,
    const int* __restrict__ tokidx, int8_t* __restrict__ hq,
    double* __restrict__ hsd) {
  __shared__ double tmp[4];
  int s = blockIdx.x;
  if (s >= meta[0] * 64) return;
  int tid = threadIdx.x;
  int tok = tokidx[s];
  if (tok < 0) {
    ((int*)hq)[s * 256 + tid] = 0;
    if (tid == 0) hsd[s] = 1.0;
    return;
  }
  float4 xv = ((const float4*)(hhbuf + (long long)s * DDIM))[tid];
  double x0 = xv.x, x1 = xv.y, x2 = xv.z, x3 = xv.w;
  double ma = fmax(fmax(fabs(x0), fabs(x1)), fmax(fabs(x2), fabs(x3)));
  ma = bredd(ma, 1, tmp);
  double sc = 127.0 / fmax(ma, 1e-5);
  ((int*)hq)[s * 256 + tid] = qpackd(x0, x1, x2, x3, sc);
  if (tid == 0) hsd[s] = sc;
}

// ---------------- MoE down GEMM + residual -> out (scatter) ----------------

__global__ __launch_bounds__(256) void k_moe_down(
    const int8_t* __restrict__ hq, const double* __restrict__ hsd,
    const int8_t* __restrict__ qw, const double* __restrict__ wsd,
    const int* __restrict__ meta, const int* __restrict__ tokidx,
    const float* __restrict__ x2, float* __restrict__ out) {
  __shared__ int Xs[32][65];
  __shared__ int Wt[32][65];
  int tile = blockIdx.y;
  if (tile >= meta[0]) return;
  int e = meta[1 + tile];
  int n0 = blockIdx.x * 64;
  int s0 = tile * 64;
  int tid = threadIdx.x;
  int lr = tid >> 5, lc = tid & 31;
  int ty = tid >> 4, tx = tid & 15;
  const int* Xg = (const int*)hq;
  const int* Wg = (const int*)(qw + ((long long)(20 + e) << 20));
  int acc[4][4] = {};
  for (int k0 = 0; k0 < 1024; k0 += 128) {
    int kc = k0 >> 2;
#pragma unroll
    for (int i = 0; i < 8; i++) {
      int rr = lr + i * 8;
      Xs[lc][rr] = Xg[(s0 + rr) * 256 + kc + lc];
      Wt[lc][rr] = Wg[(n0 + rr) * 256 + kc + lc];
    }
    __syncthreads();
#pragma unroll
    for (int kk = 0; kk < 32; kk++) {
      int4 a = *(const int4*)&Xs[kk][ty * 4];
      int4 b = *(const int4*)&Wt[kk][tx * 4];
      acc[0][0] = dot4(a.x, b.x, acc[0][0]); acc[0][1] = dot4(a.x, b.y, acc[0][1]);
      acc[0][2] = dot4(a.x, b.z, acc[0][2]); acc[0][3] = dot4(a.x, b.w, acc[0][3]);
      acc[1][0] = dot4(a.y, b.x, acc[1][0]); acc[1][1] = dot4(a.y, b.y, acc[1][1]);
      acc[1][2] = dot4(a.y, b.z, acc[1][2]); acc[1][3] = dot4(a.y, b.w, acc[1][3]);
      acc[2][0] = dot4(a.z, b.x, acc[2][0]); acc[2][1] = dot4(a.z, b.y, acc[2][1]);
      acc[2][2] = dot4(a.z, b.z, acc[2][2]); acc[2][3] = dot4(a.z, b.w, acc[2][3]);
      acc[3][0] = dot4(a.w, b.x, acc[3][0]); acc[3][1] = dot4(a.w, b.y, acc[3][1]);
      acc[3][2] = dot4(a.w, b.z, acc[3][2]); acc[3][3] = dot4(a.w, b.w, acc[3][3]);
    }
    __syncthreads();
  }
  double sw = wsd[20 + e];
#pragma unroll
  for (int i = 0; i < 4; i++) {
    int s = s0 + ty * 4 + i;
    int tok = tokidx[s];
    if (tok < 0) continue;
    double inv = 1.0 / (hsd[s] * sw);
#pragma unroll
    for (int j = 0; j < 4; j++) {
      int n = n0 + tx * 4 + j;
      out[(long long)tok * H + n] =
          (float)((double)x2[(long long)tok * H + n] + (double)acc[i][j] * inv);
    }
  }
}

// ---------------- launch ----------------
// ws layout (bytes):
//   0        partial double[28*1024] (224 KB)
//   229376   wsd double[28]
//   229600   xsd double[4096] (32 KB)
//   262368   eidx int[4096] (16 KB)
//   278752   Mk float[32]
//   278912   meta int[128]  (ntile + tile_e)
//   279424   tokidx int[4608] (18 KB)
//   297856   hsd double[4608] (36.9 KB)
//   1MB      qw int8: 28 x 1MB
//   29MB     xq int8 4MB
//   33MB     qbuf fp32 16MB (q -> attn out h); later hhbuf f32 [4544][1024] (18.6MB, 33..51.6)
//   49MB     kbuf fp32 16MB (k; dead after attn)
//   52MB     hq int8 [4544][1024] (4.65MB, 52..56.7)   <- inside dead kbuf region
//   65MB     vbuf fp32 16MB (v -> x2 residual)

extern "C" void kernel_launch(void* const* d_in, const int* in_sizes, int n_in,
                              void* d_out, int out_size, void* d_ws, size_t ws_size,
                              hipStream_t stream) {
  const float* x   = (const float*)d_in[0];
  const float* qw_ = (const float*)d_in[1];
  const float* kw_ = (const float*)d_in[2];
  const float* vw_ = (const float*)d_in[3];
  const float* ow_ = (const float*)d_in[4];
  const float* ln1 = (const float*)d_in[5];
  const float* ln2 = (const float*)d_in[6];
  const float* rw  = (const float*)d_in[7];
  const float* gw  = (const float*)d_in[8];
  const float* uw  = (const float*)d_in[9];
  const float* dw  = (const float*)d_in[10];
  float* out = (float*)d_out;

  uint8_t* ws = (uint8_t*)d_ws;
  double* partial = (double*)ws;
  double* wsd    = (double*)(ws + 229376);
  double* xsd    = (double*)(ws + 229600);
  int*    eidx   = (int*)(ws + 262368);
  float*  Mk     = (float*)(ws + 278752);
  int*    meta   = (int*)(ws + 278912);
  int*    tokidx = (int*)(ws + 279424);
  double* hsd    = (double*)(ws + 297856);
  int8_t* qw     = (int8_t*)(ws + (1ull << 20));
  int8_t* xq     = (int8_t*)(ws + (29ull << 20));
  float*  qbuf   = (float*)(ws + (33ull << 20));
  float*  hhbuf  = (float*)(ws + (33ull << 20));   // aliases qbuf (dead by then)
  float*  kbuf   = (float*)(ws + (49ull << 20));
  int8_t* hq     = (int8_t*)(ws + (52ull << 20));  // inside dead kbuf region
  float*  vbuf   = (float*)(ws + (65ull << 20));

  // weight quantization (deterministic fp64 scales)
  k_absum<<<28 * 1024, 256, 0, stream>>>(qw_, kw_, vw_, ow_, gw, uw, dw, partial);
  k_wscale<<<28, 256, 0, stream>>>(partial, wsd);
  k_quantw<<<28 * 1024, 256, 0, stream>>>(qw_, kw_, vw_, ow_, gw, uw, dw, wsd, qw);

  // attention input: rmsnorm + act_quant
  k_rms1<<<NTOK, 256, 0, stream>>>(x, ln1, xq, xsd);
  // q/k/v projections (exact int8 x ternary GEMM)
  k_gemm<<<dim3(16, 64), 256, 0, stream>>>(xq, xsd, qw,             wsd, 0, nullptr, qbuf);
  k_gemm<<<dim3(16, 64), 256, 0, stream>>>(xq, xsd, qw + (1 << 20), wsd, 1, nullptr, kbuf);
  k_gemm<<<dim3(16, 64), 256, 0, stream>>>(xq, xsd, qw + (2 << 20), wsd, 2, nullptr, vbuf);
  // causal flash attention (fixed-bound softmax, staged K/V, key-split waves)
  k_knorm<<<32, 256, 0, stream>>>(kbuf, Mk);
  k_attn<<<dim3(32, NHEAD, 2), 256, 0, stream>>>(qbuf, kbuf, vbuf, qbuf, Mk);
  // o projection with residual: x2 = x + bitlinear(h, o_w) -> vbuf
  k_actq<<<NTOK, 256, 0, stream>>>(qbuf, xq, xsd);
  k_gemm<<<dim3(16, 64), 256, 0, stream>>>(xq, xsd, qw + (3 << 20), wsd, 3, x, vbuf);
  // MoE: rmsnorm2 + router argmax + act_quant, then expert-gathered GEMMs
  k_rms2_router<<<NTOK, 256, 0, stream>>>(vbuf, ln2, rw, xq, xsd, eidx);
  k_route<<<1, 256, 0, stream>>>(eidx, meta, tokidx);
  k_moe_gu<<<dim3(16, 71), 256, 0, stream>>>(xq, xsd, qw, wsd, meta, tokidx, hhbuf);
  k_hh_actq<<<4544, 256, 0, stream>>>(hhbuf, meta, tokidx, hq, hsd);
  k_moe_down<<<dim3(16, 71), 256, 0, stream>>>(hq, hsd, qw, wsd, meta, tokidx, vbuf, out);
}

// Round 2
// 1012.736 us; speedup vs baseline: 1.4034x; 1.4034x over previous
//
#include <hip/hip_runtime.h>
#include <stdint.h>
#include <math.h>

// Problem constants
#define NTOK 4096   // B*S
#define H    1024
#define NHEAD 16
#define HD   64
#define SEQ  2048
#define NE   8
#define DDIM 1024

// ---------------- helpers ----------------

__device__ __forceinline__ int dot4(int a, int b, int c) {
#if __has_builtin(__builtin_amdgcn_sdot4)
  return __builtin_amdgcn_sdot4(a, b, c, false);
#else
  c += (int)(int8_t)(a)       * (int)(int8_t)(b);
  c += (int)(int8_t)(a >> 8)  * (int)(int8_t)(b >> 8);
  c += (int)(int8_t)(a >> 16) * (int)(int8_t)(b >> 16);
  c += (int)(int8_t)(a >> 24) * (int)(int8_t)(b >> 24);
  return c;
#endif
}

// 256-thread block reduce (double). op=0 sum, op=1 max. tmp: __shared__ double[4]
__device__ __forceinline__ double bredd(double v, int op, double* tmp) {
#pragma unroll
  for (int o = 32; o; o >>= 1) {
    double w = __shfl_xor(v, o);
    v = op ? fmax(v, w) : v + w;
  }
  int wid = threadIdx.x >> 6;
  if ((threadIdx.x & 63) == 0) tmp[wid] = v;
  __syncthreads();
  double r = op ? fmax(fmax(tmp[0], tmp[1]), fmax(tmp[2], tmp[3]))
                : (tmp[0] + tmp[1] + tmp[2] + tmp[3]);
  __syncthreads();
  return r;
}

// quantize 4 doubles to packed int8 with double scale (round-half-even like jnp.round)
__device__ __forceinline__ int qpackd(double n0, double n1, double n2, double n3, double s) {
  int a = (int)fmin(fmax(rint(n0 * s), -128.0), 127.0);
  int b = (int)fmin(fmax(rint(n1 * s), -128.0), 127.0);
  int c = (int)fmin(fmax(rint(n2 * s), -128.0), 127.0);
  int d = (int)fmin(fmax(rint(n3 * s), -128.0), 127.0);
  return (a & 255) | ((b & 255) << 8) | ((c & 255) << 16) | ((d & 255) << 24);
}

// map flat tensor id (0..27, each 1M elems) -> source pointer
__device__ __forceinline__ const float* wsrc(int tensor,
    const float* qw_, const float* kw_, const float* vw_, const float* ow_,
    const float* gw_, const float* uw_, const float* dw_) {
  if (tensor < 4) return tensor == 0 ? qw_ : tensor == 1 ? kw_ : tensor == 2 ? vw_ : ow_;
  if (tensor < 12) return gw_ + ((long long)(tensor - 4) << 20);
  if (tensor < 20) return uw_ + ((long long)(tensor - 12) << 20);
  return dw_ + ((long long)(tensor - 20) << 20);
}

// ---------------- weight quantization (fp64 scale, deterministic) ----------------

__global__ __launch_bounds__(256) void k_absum(
    const float* qw_, const float* kw_, const float* vw_, const float* ow_,
    const float* gw_, const float* uw_, const float* dw_, double* partial) {
  __shared__ double tmp[4];
  int tensor = blockIdx.x >> 10;
  int j = ((blockIdx.x & 1023) << 10) + threadIdx.x * 4;
  const float* src = wsrc(tensor, qw_, kw_, vw_, ow_, gw_, uw_, dw_);
  float4 w = *(const float4*)(src + j);
  double v = fabs((double)w.x) + fabs((double)w.y) + fabs((double)w.z) + fabs((double)w.w);
  v = bredd(v, 0, tmp);
  if (threadIdx.x == 0) partial[blockIdx.x] = v;
}

__global__ __launch_bounds__(256) void k_wscale(const double* partial, double* wsd) {
  __shared__ double tmp[4];
  int tensor = blockIdx.x;
  const double* p = partial + (tensor << 10);
  int i = threadIdx.x * 4;
  double v = p[i] + p[i + 1] + p[i + 2] + p[i + 3];
  v = bredd(v, 0, tmp);
  if (threadIdx.x == 0) wsd[tensor] = 1.0 / fmax(v * (1.0 / 1048576.0), 1e-5);
}

__global__ __launch_bounds__(256) void k_quantw(
    const float* qw_, const float* kw_, const float* vw_, const float* ow_,
    const float* gw_, const float* uw_, const float* dw_,
    const double* wsd, int8_t* qw) {
  int tensor = blockIdx.x >> 10;
  int j = ((blockIdx.x & 1023) << 10) + threadIdx.x * 4;
  const float* src = wsrc(tensor, qw_, kw_, vw_, ow_, gw_, uw_, dw_);
  double s = wsd[tensor];
  float4 w = *(const float4*)(src + j);
  int a = (int)fmin(fmax(rint((double)w.x * s), -1.0), 1.0);
  int b = (int)fmin(fmax(rint((double)w.y * s), -1.0), 1.0);
  int c = (int)fmin(fmax(rint((double)w.z * s), -1.0), 1.0);
  int d = (int)fmin(fmax(rint((double)w.w * s), -1.0), 1.0);
  ((int*)qw)[(tensor << 18) + (j >> 2)] =
      (a & 255) | ((b & 255) << 8) | ((c & 255) << 16) | ((d & 255) << 24);
}

// ---------------- rmsnorm + act_quant (attention input), fp64 decisions ----------------

__global__ __launch_bounds__(256) void k_rms1(const float* X, const float* lnw,
                                              int8_t* xq, double* xsd) {
  __shared__ double tmp[4];
  int t = blockIdx.x, tid = threadIdx.x;
  float4 xv = ((const float4*)(X + (long long)t * H))[tid];
  double x0 = xv.x, x1 = xv.y, x2 = xv.z, x3 = xv.w;
  double ss = x0 * x0 + x1 * x1 + x2 * x2 + x3 * x3;
  ss = bredd(ss, 0, tmp);
  double r = 1.0 / sqrt(ss * (1.0 / 1024.0) + 1e-5);
  float4 wv = ((const float4*)lnw)[tid];
  double n0 = x0 * r * wv.x, n1 = x1 * r * wv.y, n2 = x2 * r * wv.z, n3 = x3 * r * wv.w;
  double ma = fmax(fmax(fabs(n0), fabs(n1)), fmax(fabs(n2), fabs(n3)));
  ma = bredd(ma, 1, tmp);
  double s = 127.0 / fmax(ma, 1e-5);
  ((int*)xq)[t * 256 + tid] = qpackd(n0, n1, n2, n3, s);
  if (tid == 0) xsd[t] = s;
}

// act_quant only (rows of 1024 floats), fp64 decisions
__global__ __launch_bounds__(256) void k_actq(const float* X, int8_t* xq, double* xsd) {
  __shared__ double tmp[4];
  int t = blockIdx.x, tid = threadIdx.x;
  float4 xv = ((const float4*)(X + (long long)t * H))[tid];
  double x0 = xv.x, x1 = xv.y, x2 = xv.z, x3 = xv.w;
  double ma = fmax(fmax(fabs(x0), fabs(x1)), fmax(fabs(x2), fabs(x3)));
  ma = bredd(ma, 1, tmp);
  double s = 127.0 / fmax(ma, 1e-5);
  ((int*)xq)[t * 256 + tid] = qpackd(x0, x1, x2, x3, s);
  if (tid == 0) xsd[t] = s;
}

// ---------------- int8 GEMM: out[t,n] = res[t,n] + acc / (xs[t]*sw) ----------------

__global__ __launch_bounds__(256) void k_gemm(
    const int8_t* __restrict__ Xq, const double* __restrict__ xsd,
    const int8_t* __restrict__ W, const double* __restrict__ wsd, int widx,
    const float* __restrict__ residual, float* __restrict__ out) {
  __shared__ int Xs[32][65];
  __shared__ int Wt[32][65];
  int tid = threadIdx.x;
  int t0 = blockIdx.y * 64, n0 = blockIdx.x * 64;
  const int* Xg = (const int*)Xq;
  const int* Wg = (const int*)W;
  int acc[4][4] = {};
  int lr = tid >> 5, lc = tid & 31;
  int ty = tid >> 4, tx = tid & 15;
  for (int k0 = 0; k0 < 1024; k0 += 128) {
    int kc = k0 >> 2;
#pragma unroll
    for (int i = 0; i < 8; i++) {
      int rr = lr + i * 8;
      Xs[lc][rr] = Xg[(t0 + rr) * 256 + kc + lc];
      Wt[lc][rr] = Wg[(n0 + rr) * 256 + kc + lc];
    }
    __syncthreads();
#pragma unroll
    for (int kk = 0; kk < 32; kk++) {
      int4 a = *(const int4*)&Xs[kk][ty * 4];
      int4 b = *(const int4*)&Wt[kk][tx * 4];
      acc[0][0] = dot4(a.x, b.x, acc[0][0]); acc[0][1] = dot4(a.x, b.y, acc[0][1]);
      acc[0][2] = dot4(a.x, b.z, acc[0][2]); acc[0][3] = dot4(a.x, b.w, acc[0][3]);
      acc[1][0] = dot4(a.y, b.x, acc[1][0]); acc[1][1] = dot4(a.y, b.y, acc[1][1]);
      acc[1][2] = dot4(a.y, b.z, acc[1][2]); acc[1][3] = dot4(a.y, b.w, acc[1][3]);
      acc[2][0] = dot4(a.z, b.x, acc[2][0]); acc[2][1] = dot4(a.z, b.y, acc[2][1]);
      acc[2][2] = dot4(a.z, b.z, acc[2][2]); acc[2][3] = dot4(a.z, b.w, acc[2][3]);
      acc[3][0] = dot4(a.w, b.x, acc[3][0]); acc[3][1] = dot4(a.w, b.y, acc[3][1]);
      acc[3][2] = dot4(a.w, b.z, acc[3][2]); acc[3][3] = dot4(a.w, b.w, acc[3][3]);
    }
    __syncthreads();
  }
  double sw = wsd[widx];
#pragma unroll
  for (int i = 0; i < 4; i++) {
    int t = t0 + ty * 4 + i;
    double inv = 1.0 / (xsd[t] * sw);
#pragma unroll
    for (int j = 0; j < 4; j++) {
      int n = n0 + tx * 4 + j;
      double v = (double)acc[i][j] * inv;
      if (residual) v += (double)residual[(long long)t * H + n];
      out[(long long)t * H + n] = (float)v;
    }
  }
}

// ---------------- attention ----------------
// k_knorm: per-(b,head) max key L2-norm -> fixed softmax bound.

__global__ __launch_bounds__(256) void k_knorm(const float* __restrict__ K,
                                               float* __restrict__ Mk) {
  __shared__ float tmp[4];
  int bh = blockIdx.x;          // b*16 + head
  int b = bh >> 4, head = bh & 15;
  int tid = threadIdx.x;
  float mx = 0.f;
  for (int key = tid; key < SEQ; key += 256) {
    const float4* kr = (const float4*)(K + ((long long)(b * SEQ + key)) * H + head * HD);
    float s = 0.f;
#pragma unroll
    for (int i = 0; i < 16; i++) {
      float4 v = kr[i];
      s += v.x * v.x + v.y * v.y + v.z * v.z + v.w * v.w;
    }
    mx = fmaxf(mx, s);
  }
#pragma unroll
  for (int o = 32; o; o >>= 1) mx = fmaxf(mx, __shfl_xor(mx, o));
  if ((tid & 63) == 0) tmp[tid >> 6] = mx;
  __syncthreads();
  if (tid == 0)
    Mk[bh] = sqrtf(fmaxf(fmaxf(tmp[0], tmp[1]), fmaxf(tmp[2], tmp[3])));
}

// k_attn (R8): R5/R6 inner structure (655us version) + balanced block swizzle.
// Grid is FLAT 1024 blocks. HW round-robins consecutive blocks across 8 XCDs then
// CU slots, so blocks {i, i+256, i+512, i+768} share a CU. With the old (g=31-x)
// grid those four had the SAME causal depth g -> per-CU work spread 4..128 tiles
// (makespan = the g=31 CU, occupancy 13%). Decode i = r*256+c, g5=c>>3, hb3=c&7:
//   head/b  = hb3 | r<<3
//   g       = r0: g5, r1: 31-g5, r2: (g5+16)&31, r3: 31-((g5+16)&31)
// Bijective on (g, head, b); co-resident g's sum to 62 -> every CU gets exactly
// 66 tile-units. Bonus: XCD = i&7 = hb3, so each XCD L2 sees only 4 (b,head)
// K/V/Q sets (~4MB, fits 4MB L2).
// Block 256 = 4 waves, 64 q/block; K/V staged in LDS; wave w: query-half qh=w>>1,
// key parity ks=w&1. Fixed-bound softmax: wgt = exp(p - 0.125*|q|*maxk|k|);
// partials merge by plain sums reusing the dead K-tile LDS.

__global__ __launch_bounds__(256) void k_attn(
    const float* __restrict__ Q, const float* __restrict__ K,
    const float* __restrict__ V, float* __restrict__ O,
    const float* __restrict__ Mk) {
  __shared__ float smem[2][64][68];   // Ks=smem[0], Vs=smem[1]; merge aliases smem[0]
  __shared__ float lsh[4][32];
  int i = blockIdx.x;
  int r = i >> 8, c = i & 255;
  int g5 = c >> 3, hb3 = c & 7;
  int hb = hb3 | (r << 3);
  int head = hb & 15, b = hb >> 4;
  int gx = (r & 2) ? ((g5 + 16) & 31) : g5;
  int g = (r & 1) ? (31 - gx) : gx;
  int tid = threadIdx.x;
  int w = tid >> 6, lane = tid & 63;
  int qh = w >> 1, ks = w & 1;
  int quad = lane >> 2, dp = lane & 3;
  int qlo = g * 64;
  int d0 = dp << 4;
  long long bh_base = ((long long)b * SEQ) * H + head * HD;

  // load 2 queries (quad-local), compute fixed bound mb
  float4 q[2][4];
  float mb[2], l[2] = {0.f, 0.f};
  float acc[2][16];
#pragma unroll
  for (int qq = 0; qq < 2; qq++)
#pragma unroll
    for (int i2 = 0; i2 < 16; i2++) acc[qq][i2] = 0.f;
  float mkv = Mk[b * 16 + head];
#pragma unroll
  for (int qq = 0; qq < 2; qq++) {
    int j = qh * 32 + quad * 2 + qq;                  // local query 0..63
    const float4* qp = (const float4*)(Q + bh_base + (long long)(qlo + j) * H + d0);
    float ss = 0.f;
#pragma unroll
    for (int i2 = 0; i2 < 4; i2++) {
      float4 t = qp[i2];
      q[qq][i2] = make_float4(t.x * 0.125f, t.y * 0.125f, t.z * 0.125f, t.w * 0.125f);
      ss += t.x * t.x + t.y * t.y + t.z * t.z + t.w * t.w;
    }
    ss += __shfl_xor(ss, 1);
    ss += __shfl_xor(ss, 2);
    mb[qq] = 0.125f * sqrtf(ss) * mkv;
  }

  int srow = tid >> 2;               // staging: key row 0..63
  int sdc = (tid & 3) << 4;          // staging: d chunk 0/16/32/48

  for (int t = 0; t <= g; t++) {
    long long srowg = bh_base + (long long)(t * 64 + srow) * H + sdc;
    const float4* kg = (const float4*)(K + srowg);
    const float4* vg = (const float4*)(V + srowg);
    float4* ksd = (float4*)&smem[0][srow][sdc];
    float4* vsd = (float4*)&smem[1][srow][sdc];
#pragma unroll
    for (int i2 = 0; i2 < 4; i2++) ksd[i2] = kg[i2];
#pragma unroll
    for (int i2 = 0; i2 < 4; i2++) vsd[i2] = vg[i2];
    __syncthreads();

    int kend = (t < g) ? 64 : (qh * 32 + 32);   // diagonal: qh=0 waves skip keys>=32
    for (int kk = ks; kk < kend; kk += 2) {
      const float4* kr = (const float4*)&smem[0][kk][d0];
      float4 kv0 = kr[0], kv1 = kr[1], kv2 = kr[2], kv3 = kr[3];
      float p[2];
#pragma unroll
      for (int qq = 0; qq < 2; qq++) {
        float pa = 0.f, pb = 0.f;
        pa = fmaf(q[qq][0].x, kv0.x, pa); pb = fmaf(q[qq][0].y, kv0.y, pb);
        pa = fmaf(q[qq][0].z, kv0.z, pa); pb = fmaf(q[qq][0].w, kv0.w, pb);
        pa = fmaf(q[qq][1].x, kv1.x, pa); pb = fmaf(q[qq][1].y, kv1.y, pb);
        pa = fmaf(q[qq][1].z, kv1.z, pa); pb = fmaf(q[qq][1].w, kv1.w, pb);
        pa = fmaf(q[qq][2].x, kv2.x, pa); pb = fmaf(q[qq][2].y, kv2.y, pb);
        pa = fmaf(q[qq][2].z, kv2.z, pa); pb = fmaf(q[qq][2].w, kv2.w, pb);
        pa = fmaf(q[qq][3].x, kv3.x, pa); pb = fmaf(q[qq][3].y, kv3.y, pb);
        pa = fmaf(q[qq][3].z, kv3.z, pa); pb = fmaf(q[qq][3].w, kv3.w, pb);
        float pp = pa + pb;
        pp += __shfl_xor(pp, 1);
        pp += __shfl_xor(pp, 2);
        p[qq] = pp;
      }
      const float4* vr = (const float4*)&smem[1][kk][d0];
      float4 vv0 = vr[0], vv1 = vr[1], vv2 = vr[2], vv3 = vr[3];
#pragma unroll
      for (int qq = 0; qq < 2; qq++) {
        int j = qh * 32 + quad * 2 + qq;
        bool ok = (t < g) || (kk <= j);
        float wgt = ok ? __expf(p[qq] - mb[qq]) : 0.f;
        l[qq] += wgt;
        acc[qq][0]  = fmaf(wgt, vv0.x, acc[qq][0]);
        acc[qq][1]  = fmaf(wgt, vv0.y, acc[qq][1]);
        acc[qq][2]  = fmaf(wgt, vv0.z, acc[qq][2]);
        acc[qq][3]  = fmaf(wgt, vv0.w, acc[qq][3]);
        acc[qq][4]  = fmaf(wgt, vv1.x, acc[qq][4]);
        acc[qq][5]  = fmaf(wgt, vv1.y, acc[qq][5]);
        acc[qq][6]  = fmaf(wgt, vv1.z, acc[qq][6]);
        acc[qq][7]  = fmaf(wgt, vv1.w, acc[qq][7]);
        acc[qq][8]  = fmaf(wgt, vv2.x, acc[qq][8]);
        acc[qq][9]  = fmaf(wgt, vv2.y, acc[qq][9]);
        acc[qq][10] = fmaf(wgt, vv2.z, acc[qq][10]);
        acc[qq][11] = fmaf(wgt, vv2.w, acc[qq][11]);
        acc[qq][12] = fmaf(wgt, vv3.x, acc[qq][12]);
        acc[qq][13] = fmaf(wgt, vv3.y, acc[qq][13]);
        acc[qq][14] = fmaf(wgt, vv3.z, acc[qq][14]);
        acc[qq][15] = fmaf(wgt, vv3.w, acc[qq][15]);
      }
    }
    __syncthreads();
  }

  // ---- merge (fixed bound => plain sums). smem[0] (K tile) is dead; alias it.
  float (*mrg)[68] = smem[0];        // 64 rows: rows 0..31 <- wave1, 32..63 <- wave3
  if (dp == 0) {
    lsh[w][quad * 2 + 0] = l[0];
    lsh[w][quad * 2 + 1] = l[1];
  }
  if (ks == 1) {                     // waves 1,3 publish partial acc
#pragma unroll
    for (int qq = 0; qq < 2; qq++) {
      int row = qh * 32 + quad * 2 + qq;
      float4* dst = (float4*)&mrg[row][d0];
#pragma unroll
      for (int i2 = 0; i2 < 4; i2++)
        dst[i2] = make_float4(acc[qq][4*i2], acc[qq][4*i2+1], acc[qq][4*i2+2], acc[qq][4*i2+3]);
    }
  }
  __syncthreads();
  if (ks == 0) {                     // waves 0,2: sum, normalize, store
#pragma unroll
    for (int qq = 0; qq < 2; qq++) {
      int jl = quad * 2 + qq;        // 0..31 within half
      int row = qh * 32 + jl;
      float lt = lsh[w][jl] + lsh[w + 1][jl];
      float inv = 1.f / lt;
      const float4* src = (const float4*)&mrg[row][d0];
      float4* op = (float4*)(O + bh_base + (long long)(qlo + row) * H + d0);
#pragma unroll
      for (int i2 = 0; i2 < 4; i2++) {
        float4 s = src[i2];
        op[i2] = make_float4((acc[qq][4*i2+0] + s.x) * inv, (acc[qq][4*i2+1] + s.y) * inv,
                             (acc[qq][4*i2+2] + s.z) * inv, (acc[qq][4*i2+3] + s.w) * inv);
      }
    }
  }
}

// ---------------- rmsnorm2 + router (argmax, fp64) + act_quant ----------------

__global__ __launch_bounds__(256) void k_rms2_router(
    const float* X2, const float* lnw, const float* rw,
    int8_t* xq, double* xsd, int* eidx) {
  __shared__ double tmp[4];
  __shared__ double xn[1024];
  __shared__ double logits[8];
  int t = blockIdx.x, tid = threadIdx.x;
  float4 xv = ((const float4*)(X2 + (long long)t * H))[tid];
  double x0 = xv.x, x1 = xv.y, x2 = xv.z, x3 = xv.w;
  double ss = x0 * x0 + x1 * x1 + x2 * x2 + x3 * x3;
  ss = bredd(ss, 0, tmp);
  double r = 1.0 / sqrt(ss * (1.0 / 1024.0) + 1e-5);
  float4 wv = ((const float4*)lnw)[tid];
  double n0 = x0 * r * wv.x, n1 = x1 * r * wv.y, n2 = x2 * r * wv.z, n3 = x3 * r * wv.w;
  xn[tid * 4 + 0] = n0; xn[tid * 4 + 1] = n1;
  xn[tid * 4 + 2] = n2; xn[tid * 4 + 3] = n3;
  double ma = fmax(fmax(fabs(n0), fabs(n1)), fmax(fabs(n2), fabs(n3)));
  ma = bredd(ma, 1, tmp);  // contains syncthreads -> xn visible
  double s = 127.0 / fmax(ma, 1e-5);
  ((int*)xq)[t * 256 + tid] = qpackd(n0, n1, n2, n3, s);
  if (tid == 0) xsd[t] = s;
  if (tid < 64) {
    int e = tid >> 3, i = tid & 7;
    const float* wr = rw + e * 1024;
    double p = 0.0;
    for (int h = i; h < 1024; h += 8) p += xn[h] * (double)wr[h];
    p += __shfl_xor(p, 1);
    p += __shfl_xor(p, 2);
    p += __shfl_xor(p, 4);
    if (i == 0) logits[e] = p;
  }
  __syncthreads();
  if (tid == 0) {
    double best = logits[0];
    int bi = 0;
    for (int e = 1; e < 8; e++)
      if (logits[e] > best) { best = logits[e]; bi = e; }
    eidx[t] = bi;
  }
}

// ---------------- MoE routing: group tokens by expert into padded 64-slot tiles ----
// meta[0] = ntile; meta[1+i] = expert of tile i. tokidx[slot] = token or -1 (pad).

__global__ __launch_bounds__(256) void k_route(const int* __restrict__ eidx,
                                               int* __restrict__ meta,
                                               int* __restrict__ tokidx) {
  __shared__ int cnt[8], pb[9], cur[8];
  int tid = threadIdx.x;
  if (tid < 8) cnt[tid] = 0;
  __syncthreads();
  for (int t = tid; t < NTOK; t += 256) atomicAdd(&cnt[eidx[t]], 1);
  __syncthreads();
  if (tid == 0) {
    pb[0] = 0;
    int nt = 0;
    for (int e = 0; e < 8; e++) {
      int tiles = (cnt[e] + 63) >> 6;
      for (int i = 0; i < tiles; i++) meta[1 + nt + i] = e;
      nt += tiles;
      pb[e + 1] = pb[e] + tiles * 64;
      cur[e] = pb[e];
    }
    meta[0] = nt;
  }
  __syncthreads();
  for (int s = tid; s < 4608; s += 256) tokidx[s] = -1;
  __syncthreads();
  for (int t = tid; t < NTOK; t += 256) {
    int e = eidx[t];
    int s = atomicAdd(&cur[e], 1);
    tokidx[s] = t;
  }
}

// ---------------- MoE gate+up GEMM -> hh (fused relu(g)^2*u) ----------------
// grid (16 n-tiles, 71 slot-tiles). Gathered X rows; two W tiles per block.

__global__ __launch_bounds__(256) void k_moe_gu(
    const int8_t* __restrict__ Xq, const double* __restrict__ xsd,
    const int8_t* __restrict__ qw, const double* __restrict__ wsd,
    const int* __restrict__ meta, const int* __restrict__ tokidx,
    float* __restrict__ hhbuf) {
  __shared__ int Xs[32][65];
  __shared__ int Wg[32][65];
  __shared__ int Wu[32][65];
  int tile = blockIdx.y;
  if (tile >= meta[0]) return;
  int e = meta[1 + tile];
  int n0 = blockIdx.x * 64;
  int s0 = tile * 64;
  int tid = threadIdx.x;
  int lr = tid >> 5, lc = tid & 31;
  int ty = tid >> 4, tx = tid & 15;
  const int* Xg = (const int*)Xq;
  const int* Gg = (const int*)(qw + ((long long)(4 + e) << 20));
  const int* Ug = (const int*)(qw + ((long long)(12 + e) << 20));
  int toks[8];
#pragma unroll
  for (int i = 0; i < 8; i++) {
    int tk = tokidx[s0 + lr + i * 8];
    toks[i] = tk < 0 ? 0 : tk;
  }
  int accg[4][4] = {};
  int accu[4][4] = {};
  for (int k0 = 0; k0 < 1024; k0 += 128) {
    int kc = k0 >> 2;
#pragma unroll
    for (int i = 0; i < 8; i++) {
      int rr = lr + i * 8;
      Xs[lc][rr] = Xg[toks[i] * 256 + kc + lc];
      Wg[lc][rr] = Gg[(n0 + rr) * 256 + kc + lc];
      Wu[lc][rr] = Ug[(n0 + rr) * 256 + kc + lc];
    }
    __syncthreads();
#pragma unroll
    for (int kk = 0; kk < 32; kk++) {
      int4 a  = *(const int4*)&Xs[kk][ty * 4];
      int4 bg = *(const int4*)&Wg[kk][tx * 4];
      int4 bu = *(const int4*)&Wu[kk][tx * 4];
      accg[0][0] = dot4(a.x, bg.x, accg[0][0]); accg[0][1] = dot4(a.x, bg.y, accg[0][1]);
      accg[0][2] = dot4(a.x, bg.z, accg[0][2]); accg[0][3] = dot4(a.x, bg.w, accg[0][3]);
      accg[1][0] = dot4(a.y, bg.x, accg[1][0]); accg[1][1] = dot4(a.y, bg.y, accg[1][1]);
      accg[1][2] = dot4(a.y, bg.z, accg[1][2]); accg[1][3] = dot4(a.y, bg.w, accg[1][3]);
      accg[2][0] = dot4(a.z, bg.x, accg[2][0]); accg[2][1] = dot4(a.z, bg.y, accg[2][1]);
      accg[2][2] = dot4(a.z, bg.z, accg[2][2]); accg[2][3] = dot4(a.z, bg.w, accg[2][3]);
      accg[3][0] = dot4(a.w, bg.x, accg[3][0]); accg[3][1] = dot4(a.w, bg.y, accg[3][1]);
      accg[3][2] = dot4(a.w, bg.z, accg[3][2]); accg[3][3] = dot4(a.w, bg.w, accg[3][3]);
      accu[0][0] = dot4(a.x, bu.x, accu[0][0]); accu[0][1] = dot4(a.x, bu.y, accu[0][1]);
      accu[0][2] = dot4(a.x, bu.z, accu[0][2]); accu[0][3] = dot4(a.x, bu.w, accu[0][3]);
      accu[1][0] = dot4(a.y, bu.x, accu[1][0]); accu[1][1] = dot4(a.y, bu.y, accu[1][1]);
      accu[1][2] = dot4(a.y, bu.z, accu[1][2]); accu[1][3] = dot4(a.y, bu.w, accu[1][3]);
      accu[2][0] = dot4(a.z, bu.x, accu[2][0]); accu[2][1] = dot4(a.z, bu.y, accu[2][1]);
      accu[2][2] = dot4(a.z, bu.z, accu[2][2]); accu[2][3] = dot4(a.z, bu.w, accu[2][3]);
      accu[3][0] = dot4(a.w, bu.x, accu[3][0]); accu[3][1] = dot4(a.w, bu.y, accu[3][1]);
      accu[3][2] = dot4(a.w, bu.z, accu[3][2]); accu[3][3] = dot4(a.w, bu.w, accu[3][3]);
    }
    __syncthreads();
  }
  double swg = wsd[4 + e], swu = wsd[12 + e];
#pragma unroll
  for (int i = 0; i < 4; i++) {
    int s = s0 + ty * 4 + i;
    int tok = tokidx[s];
    if (tok < 0) continue;
    double ig = 1.0 / (xsd[tok] * swg);
    double iu = 1.0 / (xsd[tok] * swu);
#pragma unroll
    for (int j = 0; j < 4; j++) {
      int n = n0 + tx * 4 + j;
      double g = (double)accg[i][j] * ig;
      double u = (double)accu[i][j] * iu;
      double rg = fmax(g, 0.0);
      hhbuf[(long long)s * DDIM + n] = (float)(rg * rg * u);
    }
  }
}

// ---------------- act_quant over hh slot rows ----------------

__global__ __launch_bounds__(256) void k_hh_actq(
    const float* __restrict__ hhbuf, const int* __restrict__ meta,
    const int* __restrict__ tokidx, int8_t* __restrict__ hq,
    double* __restrict__ hsd) {
  __shared__ double tmp[4];
  int s = blockIdx.x;
  if (s >= meta[0] * 64) return;
  int tid = threadIdx.x;
  int tok = tokidx[s];
  if (tok < 0) {
    ((int*)hq)[s * 256 + tid] = 0;
    if (tid == 0) hsd[s] = 1.0;
    return;
  }
  float4 xv = ((const float4*)(hhbuf + (long long)s * DDIM))[tid];
  double x0 = xv.x, x1 = xv.y, x2 = xv.z, x3 = xv.w;
  double ma = fmax(fmax(fabs(x0), fabs(x1)), fmax(fabs(x2), fabs(x3)));
  ma = bredd(ma, 1, tmp);
  double sc = 127.0 / fmax(ma, 1e-5);
  ((int*)hq)[s * 256 + tid] = qpackd(x0, x1, x2, x3, sc);
  if (tid == 0) hsd[s] = sc;
}

// ---------------- MoE down GEMM + residual -> out (scatter) ----------------

__global__ __launch_bounds__(256) void k_moe_down(
    const int8_t* __restrict__ hq, const double* __restrict__ hsd,
    const int8_t* __restrict__ qw, const double* __restrict__ wsd,
    const int* __restrict__ meta, const int* __restrict__ tokidx,
    const float* __restrict__ x2, float* __restrict__ out) {
  __shared__ int Xs[32][65];
  __shared__ int Wt[32][65];
  int tile = blockIdx.y;
  if (tile >= meta[0]) return;
  int e = meta[1 + tile];
  int n0 = blockIdx.x * 64;
  int s0 = tile * 64;
  int tid = threadIdx.x;
  int lr = tid >> 5, lc = tid & 31;
  int ty = tid >> 4, tx = tid & 15;
  const int* Xg = (const int*)hq;
  const int* Wg = (const int*)(qw + ((long long)(20 + e) << 20));
  int acc[4][4] = {};
  for (int k0 = 0; k0 < 1024; k0 += 128) {
    int kc = k0 >> 2;
#pragma unroll
    for (int i = 0; i < 8; i++) {
      int rr = lr + i * 8;
      Xs[lc][rr] = Xg[(s0 + rr) * 256 + kc + lc];
      Wt[lc][rr] = Wg[(n0 + rr) * 256 + kc + lc];
    }
    __syncthreads();
#pragma unroll
    for (int kk = 0; kk < 32; kk++) {
      int4 a = *(const int4*)&Xs[kk][ty * 4];
      int4 b = *(const int4*)&Wt[kk][tx * 4];
      acc[0][0] = dot4(a.x, b.x, acc[0][0]); acc[0][1] = dot4(a.x, b.y, acc[0][1]);
      acc[0][2] = dot4(a.x, b.z, acc[0][2]); acc[0][3] = dot4(a.x, b.w, acc[0][3]);
      acc[1][0] = dot4(a.y, b.x, acc[1][0]); acc[1][1] = dot4(a.y, b.y, acc[1][1]);
      acc[1][2] = dot4(a.y, b.z, acc[1][2]); acc[1][3] = dot4(a.y, b.w, acc[1][3]);
      acc[2][0] = dot4(a.z, b.x, acc[2][0]); acc[2][1] = dot4(a.z, b.y, acc[2][1]);
      acc[2][2] = dot4(a.z, b.z, acc[2][2]); acc[2][3] = dot4(a.z, b.w, acc[2][3]);
      acc[3][0] = dot4(a.w, b.x, acc[3][0]); acc[3][1] = dot4(a.w, b.y, acc[3][1]);
      acc[3][2] = dot4(a.w, b.z, acc[3][2]); acc[3][3] = dot4(a.w, b.w, acc[3][3]);
    }
    __syncthreads();
  }
  double sw = wsd[20 + e];
#pragma unroll
  for (int i = 0; i < 4; i++) {
    int s = s0 + ty * 4 + i;
    int tok = tokidx[s];
    if (tok < 0) continue;
    double inv = 1.0 / (hsd[s] * sw);
#pragma unroll
    for (int j = 0; j < 4; j++) {
      int n = n0 + tx * 4 + j;
      out[(long long)tok * H + n] =
          (float)((double)x2[(long long)tok * H + n] + (double)acc[i][j] * inv);
    }
  }
}

// ---------------- launch ----------------
// ws layout (bytes):
//   0        partial double[28*1024] (224 KB)
//   229376   wsd double[28]
//   229600   xsd double[4096] (32 KB)
//   262368   eidx int[4096] (16 KB)
//   278752   Mk float[32]
//   278912   meta int[128]  (ntile + tile_e)
//   279424   tokidx int[4608] (18 KB)
//   297856   hsd double[4608] (36.9 KB)
//   1MB      qw int8: 28 x 1MB
//   29MB     xq int8 4MB
//   33MB     qbuf fp32 16MB (q -> attn out h); later hhbuf f32 [4544][1024] (18.6MB, 33..51.6)
//   49MB     kbuf fp32 16MB (k; dead after attn)
//   52MB     hq int8 [4544][1024] (4.65MB, 52..56.7)   <- inside dead kbuf region
//   65MB     vbuf fp32 16MB (v -> x2 residual)

extern "C" void kernel_launch(void* const* d_in, const int* in_sizes, int n_in,
                              void* d_out, int out_size, void* d_ws, size_t ws_size,
                              hipStream_t stream) {
  const float* x   = (const float*)d_in[0];
  const float* qw_ = (const float*)d_in[1];
  const float* kw_ = (const float*)d_in[2];
  const float* vw_ = (const float*)d_in[3];
  const float* ow_ = (const float*)d_in[4];
  const float* ln1 = (const float*)d_in[5];
  const float* ln2 = (const float*)d_in[6];
  const float* rw  = (const float*)d_in[7];
  const float* gw  = (const float*)d_in[8];
  const float* uw  = (const float*)d_in[9];
  const float* dw  = (const float*)d_in[10];
  float* out = (float*)d_out;

  uint8_t* ws = (uint8_t*)d_ws;
  double* partial = (double*)ws;
  double* wsd    = (double*)(ws + 229376);
  double* xsd    = (double*)(ws + 229600);
  int*    eidx   = (int*)(ws + 262368);
  float*  Mk     = (float*)(ws + 278752);
  int*    meta   = (int*)(ws + 278912);
  int*    tokidx = (int*)(ws + 279424);
  double* hsd    = (double*)(ws + 297856);
  int8_t* qw     = (int8_t*)(ws + (1ull << 20));
  int8_t* xq     = (int8_t*)(ws + (29ull << 20));
  float*  qbuf   = (float*)(ws + (33ull << 20));
  float*  hhbuf  = (float*)(ws + (33ull << 20));   // aliases qbuf (dead by then)
  float*  kbuf   = (float*)(ws + (49ull << 20));
  int8_t* hq     = (int8_t*)(ws + (52ull << 20));  // inside dead kbuf region
  float*  vbuf   = (float*)(ws + (65ull << 20));

  // weight quantization (deterministic fp64 scales)
  k_absum<<<28 * 1024, 256, 0, stream>>>(qw_, kw_, vw_, ow_, gw, uw, dw, partial);
  k_wscale<<<28, 256, 0, stream>>>(partial, wsd);
  k_quantw<<<28 * 1024, 256, 0, stream>>>(qw_, kw_, vw_, ow_, gw, uw, dw, wsd, qw);

  // attention input: rmsnorm + act_quant
  k_rms1<<<NTOK, 256, 0, stream>>>(x, ln1, xq, xsd);
  // q/k/v projections (exact int8 x ternary GEMM)
  k_gemm<<<dim3(16, 64), 256, 0, stream>>>(xq, xsd, qw,             wsd, 0, nullptr, qbuf);
  k_gemm<<<dim3(16, 64), 256, 0, stream>>>(xq, xsd, qw + (1 << 20), wsd, 1, nullptr, kbuf);
  k_gemm<<<dim3(16, 64), 256, 0, stream>>>(xq, xsd, qw + (2 << 20), wsd, 2, nullptr, vbuf);
  // causal flash attention (fixed-bound softmax, staged K/V, key-split waves)
  k_knorm<<<32, 256, 0, stream>>>(kbuf, Mk);
  k_attn<<<dim3(1024), 256, 0, stream>>>(qbuf, kbuf, vbuf, qbuf, Mk);
  // o projection with residual: x2 = x + bitlinear(h, o_w) -> vbuf
  k_actq<<<NTOK, 256, 0, stream>>>(qbuf, xq, xsd);
  k_gemm<<<dim3(16, 64), 256, 0, stream>>>(xq, xsd, qw + (3 << 20), wsd, 3, x, vbuf);
  // MoE: rmsnorm2 + router argmax + act_quant, then expert-gathered GEMMs
  k_rms2_router<<<NTOK, 256, 0, stream>>>(vbuf, ln2, rw, xq, xsd, eidx);
  k_route<<<1, 256, 0, stream>>>(eidx, meta, tokidx);
  k_moe_gu<<<dim3(16, 71), 256, 0, stream>>>(xq, xsd, qw, wsd, meta, tokidx, hhbuf);
  k_hh_actq<<<4544, 256, 0, stream>>>(hhbuf, meta, tokidx, hq, hsd);
  k_moe_down<<<dim3(16, 71), 256, 0, stream>>>(hq, hsd, qw, wsd, meta, tokidx, vbuf, out);
}

// Round 3
// 922.034 us; speedup vs baseline: 1.5414x; 1.0984x over previous
//
#include <hip/hip_runtime.h>
#include <stdint.h>
#include <math.h>

// Problem constants
#define NTOK 4096   // B*S
#define H    1024
#define NHEAD 16
#define HD   64
#define SEQ  2048
#define NE   8
#define DDIM 1024

// ---------------- helpers ----------------

__device__ __forceinline__ int dot4(int a, int b, int c) {
#if __has_builtin(__builtin_amdgcn_sdot4)
  return __builtin_amdgcn_sdot4(a, b, c, false);
#else
  c += (int)(int8_t)(a)       * (int)(int8_t)(b);
  c += (int)(int8_t)(a >> 8)  * (int)(int8_t)(b >> 8);
  c += (int)(int8_t)(a >> 16) * (int)(int8_t)(b >> 16);
  c += (int)(int8_t)(a >> 24) * (int)(int8_t)(b >> 24);
  return c;
#endif
}

// 256-thread block reduce (double). op=0 sum, op=1 max. tmp: __shared__ double[4]
__device__ __forceinline__ double bredd(double v, int op, double* tmp) {
#pragma unroll
  for (int o = 32; o; o >>= 1) {
    double w = __shfl_xor(v, o);
    v = op ? fmax(v, w) : v + w;
  }
  int wid = threadIdx.x >> 6;
  if ((threadIdx.x & 63) == 0) tmp[wid] = v;
  __syncthreads();
  double r = op ? fmax(fmax(tmp[0], tmp[1]), fmax(tmp[2], tmp[3]))
                : (tmp[0] + tmp[1] + tmp[2] + tmp[3]);
  __syncthreads();
  return r;
}

// quantize 4 doubles to packed int8 with double scale (round-half-even like jnp.round)
__device__ __forceinline__ int qpackd(double n0, double n1, double n2, double n3, double s) {
  int a = (int)fmin(fmax(rint(n0 * s), -128.0), 127.0);
  int b = (int)fmin(fmax(rint(n1 * s), -128.0), 127.0);
  int c = (int)fmin(fmax(rint(n2 * s), -128.0), 127.0);
  int d = (int)fmin(fmax(rint(n3 * s), -128.0), 127.0);
  return (a & 255) | ((b & 255) << 8) | ((c & 255) << 16) | ((d & 255) << 24);
}

// map flat tensor id (0..27, each 1M elems) -> source pointer
__device__ __forceinline__ const float* wsrc(int tensor,
    const float* qw_, const float* kw_, const float* vw_, const float* ow_,
    const float* gw_, const float* uw_, const float* dw_) {
  if (tensor < 4) return tensor == 0 ? qw_ : tensor == 1 ? kw_ : tensor == 2 ? vw_ : ow_;
  if (tensor < 12) return gw_ + ((long long)(tensor - 4) << 20);
  if (tensor < 20) return uw_ + ((long long)(tensor - 12) << 20);
  return dw_ + ((long long)(tensor - 20) << 20);
}

// ---------------- weight quantization (fp64 scale, deterministic) ----------------

__global__ __launch_bounds__(256) void k_absum(
    const float* qw_, const float* kw_, const float* vw_, const float* ow_,
    const float* gw_, const float* uw_, const float* dw_, double* partial) {
  __shared__ double tmp[4];
  int tensor = blockIdx.x >> 10;
  int j = ((blockIdx.x & 1023) << 10) + threadIdx.x * 4;
  const float* src = wsrc(tensor, qw_, kw_, vw_, ow_, gw_, uw_, dw_);
  float4 w = *(const float4*)(src + j);
  double v = fabs((double)w.x) + fabs((double)w.y) + fabs((double)w.z) + fabs((double)w.w);
  v = bredd(v, 0, tmp);
  if (threadIdx.x == 0) partial[blockIdx.x] = v;
}

__global__ __launch_bounds__(256) void k_wscale(const double* partial, double* wsd) {
  __shared__ double tmp[4];
  int tensor = blockIdx.x;
  const double* p = partial + (tensor << 10);
  int i = threadIdx.x * 4;
  double v = p[i] + p[i + 1] + p[i + 2] + p[i + 3];
  v = bredd(v, 0, tmp);
  if (threadIdx.x == 0) wsd[tensor] = 1.0 / fmax(v * (1.0 / 1048576.0), 1e-5);
}

__global__ __launch_bounds__(256) void k_quantw(
    const float* qw_, const float* kw_, const float* vw_, const float* ow_,
    const float* gw_, const float* uw_, const float* dw_,
    const double* wsd, int8_t* qw) {
  int tensor = blockIdx.x >> 10;
  int j = ((blockIdx.x & 1023) << 10) + threadIdx.x * 4;
  const float* src = wsrc(tensor, qw_, kw_, vw_, ow_, gw_, uw_, dw_);
  double s = wsd[tensor];
  float4 w = *(const float4*)(src + j);
  int a = (int)fmin(fmax(rint((double)w.x * s), -1.0), 1.0);
  int b = (int)fmin(fmax(rint((double)w.y * s), -1.0), 1.0);
  int c = (int)fmin(fmax(rint((double)w.z * s), -1.0), 1.0);
  int d = (int)fmin(fmax(rint((double)w.w * s), -1.0), 1.0);
  ((int*)qw)[(tensor << 18) + (j >> 2)] =
      (a & 255) | ((b & 255) << 8) | ((c & 255) << 16) | ((d & 255) << 24);
}

// ---------------- rmsnorm + act_quant (attention input), fp64 decisions ----------------

__global__ __launch_bounds__(256) void k_rms1(const float* X, const float* lnw,
                                              int8_t* xq, double* xsd) {
  __shared__ double tmp[4];
  int t = blockIdx.x, tid = threadIdx.x;
  float4 xv = ((const float4*)(X + (long long)t * H))[tid];
  double x0 = xv.x, x1 = xv.y, x2 = xv.z, x3 = xv.w;
  double ss = x0 * x0 + x1 * x1 + x2 * x2 + x3 * x3;
  ss = bredd(ss, 0, tmp);
  double r = 1.0 / sqrt(ss * (1.0 / 1024.0) + 1e-5);
  float4 wv = ((const float4*)lnw)[tid];
  double n0 = x0 * r * wv.x, n1 = x1 * r * wv.y, n2 = x2 * r * wv.z, n3 = x3 * r * wv.w;
  double ma = fmax(fmax(fabs(n0), fabs(n1)), fmax(fabs(n2), fabs(n3)));
  ma = bredd(ma, 1, tmp);
  double s = 127.0 / fmax(ma, 1e-5);
  ((int*)xq)[t * 256 + tid] = qpackd(n0, n1, n2, n3, s);
  if (tid == 0) xsd[t] = s;
}

// act_quant only (rows of 1024 floats), fp64 decisions
__global__ __launch_bounds__(256) void k_actq(const float* X, int8_t* xq, double* xsd) {
  __shared__ double tmp[4];
  int t = blockIdx.x, tid = threadIdx.x;
  float4 xv = ((const float4*)(X + (long long)t * H))[tid];
  double x0 = xv.x, x1 = xv.y, x2 = xv.z, x3 = xv.w;
  double ma = fmax(fmax(fabs(x0), fabs(x1)), fmax(fabs(x2), fabs(x3)));
  ma = bredd(ma, 1, tmp);
  double s = 127.0 / fmax(ma, 1e-5);
  ((int*)xq)[t * 256 + tid] = qpackd(x0, x1, x2, x3, s);
  if (tid == 0) xsd[t] = s;
}

// ---------------- int8 GEMM: out[t,n] = res[t,n] + acc / (xs[t]*sw) ----------------

__global__ __launch_bounds__(256) void k_gemm(
    const int8_t* __restrict__ Xq, const double* __restrict__ xsd,
    const int8_t* __restrict__ W, const double* __restrict__ wsd, int widx,
    const float* __restrict__ residual, float* __restrict__ out) {
  __shared__ int Xs[32][65];
  __shared__ int Wt[32][65];
  int tid = threadIdx.x;
  int t0 = blockIdx.y * 64, n0 = blockIdx.x * 64;
  const int* Xg = (const int*)Xq;
  const int* Wg = (const int*)W;
  int acc[4][4] = {};
  int lr = tid >> 5, lc = tid & 31;
  int ty = tid >> 4, tx = tid & 15;
  for (int k0 = 0; k0 < 1024; k0 += 128) {
    int kc = k0 >> 2;
#pragma unroll
    for (int i = 0; i < 8; i++) {
      int rr = lr + i * 8;
      Xs[lc][rr] = Xg[(t0 + rr) * 256 + kc + lc];
      Wt[lc][rr] = Wg[(n0 + rr) * 256 + kc + lc];
    }
    __syncthreads();
#pragma unroll
    for (int kk = 0; kk < 32; kk++) {
      int4 a = *(const int4*)&Xs[kk][ty * 4];
      int4 b = *(const int4*)&Wt[kk][tx * 4];
      acc[0][0] = dot4(a.x, b.x, acc[0][0]); acc[0][1] = dot4(a.x, b.y, acc[0][1]);
      acc[0][2] = dot4(a.x, b.z, acc[0][2]); acc[0][3] = dot4(a.x, b.w, acc[0][3]);
      acc[1][0] = dot4(a.y, b.x, acc[1][0]); acc[1][1] = dot4(a.y, b.y, acc[1][1]);
      acc[1][2] = dot4(a.y, b.z, acc[1][2]); acc[1][3] = dot4(a.y, b.w, acc[1][3]);
      acc[2][0] = dot4(a.z, b.x, acc[2][0]); acc[2][1] = dot4(a.z, b.y, acc[2][1]);
      acc[2][2] = dot4(a.z, b.z, acc[2][2]); acc[2][3] = dot4(a.z, b.w, acc[2][3]);
      acc[3][0] = dot4(a.w, b.x, acc[3][0]); acc[3][1] = dot4(a.w, b.y, acc[3][1]);
      acc[3][2] = dot4(a.w, b.z, acc[3][2]); acc[3][3] = dot4(a.w, b.w, acc[3][3]);
    }
    __syncthreads();
  }
  double sw = wsd[widx];
#pragma unroll
  for (int i = 0; i < 4; i++) {
    int t = t0 + ty * 4 + i;
    double inv = 1.0 / (xsd[t] * sw);
#pragma unroll
    for (int j = 0; j < 4; j++) {
      int n = n0 + tx * 4 + j;
      double v = (double)acc[i][j] * inv;
      if (residual) v += (double)residual[(long long)t * H + n];
      out[(long long)t * H + n] = (float)v;
    }
  }
}

// ---------------- attention ----------------
// k_knorm: per-(b,head) max key L2-norm -> fixed softmax bound.

__global__ __launch_bounds__(256) void k_knorm(const float* __restrict__ K,
                                               float* __restrict__ Mk) {
  __shared__ float tmp[4];
  int bh = blockIdx.x;          // b*16 + head
  int b = bh >> 4, head = bh & 15;
  int tid = threadIdx.x;
  float mx = 0.f;
  for (int key = tid; key < SEQ; key += 256) {
    const float4* kr = (const float4*)(K + ((long long)(b * SEQ + key)) * H + head * HD);
    float s = 0.f;
#pragma unroll
    for (int i = 0; i < 16; i++) {
      float4 v = kr[i];
      s += v.x * v.x + v.y * v.y + v.z * v.z + v.w * v.w;
    }
    mx = fmaxf(mx, s);
  }
#pragma unroll
  for (int o = 32; o; o >>= 1) mx = fmaxf(mx, __shfl_xor(mx, o));
  if ((tid & 63) == 0) tmp[tid >> 6] = mx;
  __syncthreads();
  if (tid == 0)
    Mk[bh] = sqrtf(fmaxf(fmaxf(tmp[0], tmp[1]), fmaxf(tmp[2], tmp[3])));
}

// k_attn (R9): uniform-duration blocks. 512 blocks x 512 threads (8 waves).
// Each block processes TWO q-tiles sequentially: g = p and g = 31-p, so every
// block does exactly (p+1)+(32-p) = 33 tile-units -> all blocks finish together
// (R8's tail: co-resident blocks had unequal g, occupancy decayed 4->1 blocks/CU).
// 512 blocks = 2/CU x 8 waves = 4 waves/SIMD, constant for the whole kernel.
// Decode i: [0:2]=hb3 (XCD id -> (head,b) L2 locality), [3:4]=hb hi, [5:8]=p.
// Per q-tile: 8 waves = qh (2 query-halves) x ks (4-way key split, stride-4 keys).
// Lane = quad*4+dp: quad owns 2 queries, dp owns 16 dims. Fixed-bound softmax
// (validated): wgt = exp(p - 0.125*|q|*maxk|k|); partials merge by plain sums.
// Merge tree: ks2->smem[0], ks3->smem[1] publish; ks1 folds smem[1], republishes;
// ks0 folds smem[0]+smem[1], normalizes, stores.

__global__ __launch_bounds__(512) void k_attn(
    const float* __restrict__ Q, const float* __restrict__ K,
    const float* __restrict__ V, float* __restrict__ O,
    const float* __restrict__ Mk) {
  __shared__ float smem[2][64][68];   // Ks=smem[0], Vs=smem[1]; merge aliases both
  __shared__ float lsh[8][32];
  int i = blockIdx.x;
  int hb = (i & 7) | (((i >> 3) & 3) << 3);
  int p  = ((i >> 5) & 7) | (((i >> 8) & 1) << 3);
  int head = hb & 15, b = hb >> 4;
  int tid = threadIdx.x;
  int w = tid >> 6, lane = tid & 63;
  int qh = w >> 2, ks = w & 3;
  int quad = lane >> 2, dp = lane & 3;
  int d0 = dp << 4;
  long long bh_base = ((long long)b * SEQ) * H + head * HD;
  float mkv = Mk[b * 16 + head];

  int srow = tid >> 3;               // staging: key row 0..63
  int sc8 = (tid & 7) << 3;          // staging: float offset 0,8,..,56 (2 float4s)

  for (int ph = 0; ph < 2; ph++) {
    int g = ph ? (31 - p) : p;
    int qlo = g * 64;

    float4 q[2][4];
    float mb[2], l[2] = {0.f, 0.f};
    float acc[2][16];
#pragma unroll
    for (int qq = 0; qq < 2; qq++)
#pragma unroll
      for (int i2 = 0; i2 < 16; i2++) acc[qq][i2] = 0.f;

    // load 2 queries (quad-local), compute fixed bound mb
#pragma unroll
    for (int qq = 0; qq < 2; qq++) {
      int j = qh * 32 + quad * 2 + qq;                // local query 0..63
      const float4* qp_ = (const float4*)(Q + bh_base + (long long)(qlo + j) * H + d0);
      float ss = 0.f;
#pragma unroll
      for (int i2 = 0; i2 < 4; i2++) {
        float4 t = qp_[i2];
        q[qq][i2] = make_float4(t.x * 0.125f, t.y * 0.125f, t.z * 0.125f, t.w * 0.125f);
        ss += t.x * t.x + t.y * t.y + t.z * t.z + t.w * t.w;
      }
      ss += __shfl_xor(ss, 1);
      ss += __shfl_xor(ss, 2);
      mb[qq] = 0.125f * sqrtf(ss) * mkv;
    }

    for (int t = 0; t <= g; t++) {
      long long srowg = bh_base + (long long)(t * 64 + srow) * H + sc8;
      const float4* kg = (const float4*)(K + srowg);
      const float4* vg = (const float4*)(V + srowg);
      float4* ksd = (float4*)&smem[0][srow][sc8];
      float4* vsd = (float4*)&smem[1][srow][sc8];
      ksd[0] = kg[0]; ksd[1] = kg[1];
      vsd[0] = vg[0]; vsd[1] = vg[1];
      __syncthreads();

      int kend = (t < g) ? 64 : (qh * 32 + 32);   // diagonal: qh=0 waves skip keys>=32
      for (int kk = ks; kk < kend; kk += 4) {
        const float4* kr = (const float4*)&smem[0][kk][d0];
        float4 kv0 = kr[0], kv1 = kr[1], kv2 = kr[2], kv3 = kr[3];
        float pr[2];
#pragma unroll
        for (int qq = 0; qq < 2; qq++) {
          float pa = 0.f, pb = 0.f;
          pa = fmaf(q[qq][0].x, kv0.x, pa); pb = fmaf(q[qq][0].y, kv0.y, pb);
          pa = fmaf(q[qq][0].z, kv0.z, pa); pb = fmaf(q[qq][0].w, kv0.w, pb);
          pa = fmaf(q[qq][1].x, kv1.x, pa); pb = fmaf(q[qq][1].y, kv1.y, pb);
          pa = fmaf(q[qq][1].z, kv1.z, pa); pb = fmaf(q[qq][1].w, kv1.w, pb);
          pa = fmaf(q[qq][2].x, kv2.x, pa); pb = fmaf(q[qq][2].y, kv2.y, pb);
          pa = fmaf(q[qq][2].z, kv2.z, pa); pb = fmaf(q[qq][2].w, kv2.w, pb);
          pa = fmaf(q[qq][3].x, kv3.x, pa); pb = fmaf(q[qq][3].y, kv3.y, pb);
          pa = fmaf(q[qq][3].w, kv3.w, pa); pb = fmaf(q[qq][3].z, kv3.z, pb);
          float pp = pa + pb;
          pp += __shfl_xor(pp, 1);
          pp += __shfl_xor(pp, 2);
          pr[qq] = pp;
        }
        const float4* vr = (const float4*)&smem[1][kk][d0];
        float4 vv0 = vr[0], vv1 = vr[1], vv2 = vr[2], vv3 = vr[3];
#pragma unroll
        for (int qq = 0; qq < 2; qq++) {
          int j = qh * 32 + quad * 2 + qq;
          bool ok = (t < g) || (kk <= j);
          float wgt = ok ? __expf(pr[qq] - mb[qq]) : 0.f;
          l[qq] += wgt;
          acc[qq][0]  = fmaf(wgt, vv0.x, acc[qq][0]);
          acc[qq][1]  = fmaf(wgt, vv0.y, acc[qq][1]);
          acc[qq][2]  = fmaf(wgt, vv0.z, acc[qq][2]);
          acc[qq][3]  = fmaf(wgt, vv0.w, acc[qq][3]);
          acc[qq][4]  = fmaf(wgt, vv1.x, acc[qq][4]);
          acc[qq][5]  = fmaf(wgt, vv1.y, acc[qq][5]);
          acc[qq][6]  = fmaf(wgt, vv1.z, acc[qq][6]);
          acc[qq][7]  = fmaf(wgt, vv1.w, acc[qq][7]);
          acc[qq][8]  = fmaf(wgt, vv2.x, acc[qq][8]);
          acc[qq][9]  = fmaf(wgt, vv2.y, acc[qq][9]);
          acc[qq][10] = fmaf(wgt, vv2.z, acc[qq][10]);
          acc[qq][11] = fmaf(wgt, vv2.w, acc[qq][11]);
          acc[qq][12] = fmaf(wgt, vv3.x, acc[qq][12]);
          acc[qq][13] = fmaf(wgt, vv3.y, acc[qq][13]);
          acc[qq][14] = fmaf(wgt, vv3.z, acc[qq][14]);
          acc[qq][15] = fmaf(wgt, vv3.w, acc[qq][15]);
        }
      }
      __syncthreads();
    }

    // ---- 4-way merge (fixed bound => plain sums). K/V tiles are dead; alias.
    if (dp == 0) {
      lsh[w][quad * 2 + 0] = l[0];
      lsh[w][quad * 2 + 1] = l[1];
    }
    if (ks >= 2) {                   // ks2 -> smem[0], ks3 -> smem[1]
      float (*mrg)[68] = smem[ks - 2];
#pragma unroll
      for (int qq = 0; qq < 2; qq++) {
        int row = qh * 32 + quad * 2 + qq;
        float4* dst = (float4*)&mrg[row][d0];
#pragma unroll
        for (int i2 = 0; i2 < 4; i2++)
          dst[i2] = make_float4(acc[qq][4*i2], acc[qq][4*i2+1], acc[qq][4*i2+2], acc[qq][4*i2+3]);
      }
    }
    __syncthreads();
    if (ks == 0) {                   // fold ks2 partial
#pragma unroll
      for (int qq = 0; qq < 2; qq++) {
        int row = qh * 32 + quad * 2 + qq;
        const float4* src = (const float4*)&smem[0][row][d0];
#pragma unroll
        for (int i2 = 0; i2 < 4; i2++) {
          float4 s = src[i2];
          acc[qq][4*i2+0] += s.x; acc[qq][4*i2+1] += s.y;
          acc[qq][4*i2+2] += s.z; acc[qq][4*i2+3] += s.w;
        }
      }
    }
    if (ks == 1) {                   // fold ks3 partial, republish to smem[1]
#pragma unroll
      for (int qq = 0; qq < 2; qq++) {
        int row = qh * 32 + quad * 2 + qq;
        float4* sp = (float4*)&smem[1][row][d0];
#pragma unroll
        for (int i2 = 0; i2 < 4; i2++) {
          float4 s = sp[i2];
          sp[i2] = make_float4(acc[qq][4*i2+0] + s.x, acc[qq][4*i2+1] + s.y,
                               acc[qq][4*i2+2] + s.z, acc[qq][4*i2+3] + s.w);
        }
      }
    }
    __syncthreads();
    if (ks == 0) {                   // final fold + normalize + store
#pragma unroll
      for (int qq = 0; qq < 2; qq++) {
        int jl = quad * 2 + qq;
        int row = qh * 32 + jl;
        float lt = lsh[qh * 4 + 0][jl] + lsh[qh * 4 + 1][jl] +
                   lsh[qh * 4 + 2][jl] + lsh[qh * 4 + 3][jl];
        float inv = 1.f / lt;
        const float4* src = (const float4*)&smem[1][row][d0];
        float4* op = (float4*)(O + bh_base + (long long)(qlo + row) * H + d0);
#pragma unroll
        for (int i2 = 0; i2 < 4; i2++) {
          float4 s = src[i2];
          op[i2] = make_float4((acc[qq][4*i2+0] + s.x) * inv, (acc[qq][4*i2+1] + s.y) * inv,
                               (acc[qq][4*i2+2] + s.z) * inv, (acc[qq][4*i2+3] + s.w) * inv);
        }
      }
    }
    __syncthreads();                 // smem/lsh reuse safe for next phase
  }
}

// ---------------- rmsnorm2 + router (argmax, fp64) + act_quant ----------------

__global__ __launch_bounds__(256) void k_rms2_router(
    const float* X2, const float* lnw, const float* rw,
    int8_t* xq, double* xsd, int* eidx) {
  __shared__ double tmp[4];
  __shared__ double xn[1024];
  __shared__ double logits[8];
  int t = blockIdx.x, tid = threadIdx.x;
  float4 xv = ((const float4*)(X2 + (long long)t * H))[tid];
  double x0 = xv.x, x1 = xv.y, x2 = xv.z, x3 = xv.w;
  double ss = x0 * x0 + x1 * x1 + x2 * x2 + x3 * x3;
  ss = bredd(ss, 0, tmp);
  double r = 1.0 / sqrt(ss * (1.0 / 1024.0) + 1e-5);
  float4 wv = ((const float4*)lnw)[tid];
  double n0 = x0 * r * wv.x, n1 = x1 * r * wv.y, n2 = x2 * r * wv.z, n3 = x3 * r * wv.w;
  xn[tid * 4 + 0] = n0; xn[tid * 4 + 1] = n1;
  xn[tid * 4 + 2] = n2; xn[tid * 4 + 3] = n3;
  double ma = fmax(fmax(fabs(n0), fabs(n1)), fmax(fabs(n2), fabs(n3)));
  ma = bredd(ma, 1, tmp);  // contains syncthreads -> xn visible
  double s = 127.0 / fmax(ma, 1e-5);
  ((int*)xq)[t * 256 + tid] = qpackd(n0, n1, n2, n3, s);
  if (tid == 0) xsd[t] = s;
  if (tid < 64) {
    int e = tid >> 3, i = tid & 7;
    const float* wr = rw + e * 1024;
    double p = 0.0;
    for (int h = i; h < 1024; h += 8) p += xn[h] * (double)wr[h];
    p += __shfl_xor(p, 1);
    p += __shfl_xor(p, 2);
    p += __shfl_xor(p, 4);
    if (i == 0) logits[e] = p;
  }
  __syncthreads();
  if (tid == 0) {
    double best = logits[0];
    int bi = 0;
    for (int e = 1; e < 8; e++)
      if (logits[e] > best) { best = logits[e]; bi = e; }
    eidx[t] = bi;
  }
}

// ---------------- MoE routing: group tokens by expert into padded 64-slot tiles ----
// meta[0] = ntile; meta[1+i] = expert of tile i. tokidx[slot] = token or -1 (pad).

__global__ __launch_bounds__(256) void k_route(const int* __restrict__ eidx,
                                               int* __restrict__ meta,
                                               int* __restrict__ tokidx) {
  __shared__ int cnt[8], pb[9], cur[8];
  int tid = threadIdx.x;
  if (tid < 8) cnt[tid] = 0;
  __syncthreads();
  for (int t = tid; t < NTOK; t += 256) atomicAdd(&cnt[eidx[t]], 1);
  __syncthreads();
  if (tid == 0) {
    pb[0] = 0;
    int nt = 0;
    for (int e = 0; e < 8; e++) {
      int tiles = (cnt[e] + 63) >> 6;
      for (int i = 0; i < tiles; i++) meta[1 + nt + i] = e;
      nt += tiles;
      pb[e + 1] = pb[e] + tiles * 64;
      cur[e] = pb[e];
    }
    meta[0] = nt;
  }
  __syncthreads();
  for (int s = tid; s < 4608; s += 256) tokidx[s] = -1;
  __syncthreads();
  for (int t = tid; t < NTOK; t += 256) {
    int e = eidx[t];
    int s = atomicAdd(&cur[e], 1);
    tokidx[s] = t;
  }
}

// ---------------- MoE gate+up GEMM -> hh (fused relu(g)^2*u) ----------------
// grid (16 n-tiles, 71 slot-tiles). Gathered X rows; two W tiles per block.

__global__ __launch_bounds__(256) void k_moe_gu(
    const int8_t* __restrict__ Xq, const double* __restrict__ xsd,
    const int8_t* __restrict__ qw, const double* __restrict__ wsd,
    const int* __restrict__ meta, const int* __restrict__ tokidx,
    float* __restrict__ hhbuf) {
  __shared__ int Xs[32][65];
  __shared__ int Wg[32][65];
  __shared__ int Wu[32][65];
  int tile = blockIdx.y;
  if (tile >= meta[0]) return;
  int e = meta[1 + tile];
  int n0 = blockIdx.x * 64;
  int s0 = tile * 64;
  int tid = threadIdx.x;
  int lr = tid >> 5, lc = tid & 31;
  int ty = tid >> 4, tx = tid & 15;
  const int* Xg = (const int*)Xq;
  const int* Gg = (const int*)(qw + ((long long)(4 + e) << 20));
  const int* Ug = (const int*)(qw + ((long long)(12 + e) << 20));
  int toks[8];
#pragma unroll
  for (int i = 0; i < 8; i++) {
    int tk = tokidx[s0 + lr + i * 8];
    toks[i] = tk < 0 ? 0 : tk;
  }
  int accg[4][4] = {};
  int accu[4][4] = {};
  for (int k0 = 0; k0 < 1024; k0 += 128) {
    int kc = k0 >> 2;
#pragma unroll
    for (int i = 0; i < 8; i++) {
      int rr = lr + i * 8;
      Xs[lc][rr] = Xg[toks[i] * 256 + kc + lc];
      Wg[lc][rr] = Gg[(n0 + rr) * 256 + kc + lc];
      Wu[lc][rr] = Ug[(n0 + rr) * 256 + kc + lc];
    }
    __syncthreads();
#pragma unroll
    for (int kk = 0; kk < 32; kk++) {
      int4 a  = *(const int4*)&Xs[kk][ty * 4];
      int4 bg = *(const int4*)&Wg[kk][tx * 4];
      int4 bu = *(const int4*)&Wu[kk][tx * 4];
      accg[0][0] = dot4(a.x, bg.x, accg[0][0]); accg[0][1] = dot4(a.x, bg.y, accg[0][1]);
      accg[0][2] = dot4(a.x, bg.z, accg[0][2]); accg[0][3] = dot4(a.x, bg.w, accg[0][3]);
      accg[1][0] = dot4(a.y, bg.x, accg[1][0]); accg[1][1] = dot4(a.y, bg.y, accg[1][1]);
      accg[1][2] = dot4(a.y, bg.z, accg[1][2]); accg[1][3] = dot4(a.y, bg.w, accg[1][3]);
      accg[2][0] = dot4(a.z, bg.x, accg[2][0]); accg[2][1] = dot4(a.z, bg.y, accg[2][1]);
      accg[2][2] = dot4(a.z, bg.z, accg[2][2]); accg[2][3] = dot4(a.z, bg.w, accg[2][3]);
      accg[3][0] = dot4(a.w, bg.x, accg[3][0]); accg[3][1] = dot4(a.w, bg.y, accg[3][1]);
      accg[3][2] = dot4(a.w, bg.z, accg[3][2]); accg[3][3] = dot4(a.w, bg.w, accg[3][3]);
      accu[0][0] = dot4(a.x, bu.x, accu[0][0]); accu[0][1] = dot4(a.x, bu.y, accu[0][1]);
      accu[0][2] = dot4(a.x, bu.z, accu[0][2]); accu[0][3] = dot4(a.x, bu.w, accu[0][3]);
      accu[1][0] = dot4(a.y, bu.x, accu[1][0]); accu[1][1] = dot4(a.y, bu.y, accu[1][1]);
      accu[1][2] = dot4(a.y, bu.z, accu[1][2]); accu[1][3] = dot4(a.y, bu.w, accu[1][3]);
      accu[2][0] = dot4(a.z, bu.x, accu[2][0]); accu[2][1] = dot4(a.z, bu.y, accu[2][1]);
      accu[2][2] = dot4(a.z, bu.z, accu[2][2]); accu[2][3] = dot4(a.z, bu.w, accu[2][3]);
      accu[3][0] = dot4(a.w, bu.x, accu[3][0]); accu[3][1] = dot4(a.w, bu.y, accu[3][1]);
      accu[3][2] = dot4(a.w, bu.z, accu[3][2]); accu[3][3] = dot4(a.w, bu.w, accu[3][3]);
    }
    __syncthreads();
  }
  double swg = wsd[4 + e], swu = wsd[12 + e];
#pragma unroll
  for (int i = 0; i < 4; i++) {
    int s = s0 + ty * 4 + i;
    int tok = tokidx[s];
    if (tok < 0) continue;
    double ig = 1.0 / (xsd[tok] * swg);
    double iu = 1.0 / (xsd[tok] * swu);
#pragma unroll
    for (int j = 0; j < 4; j++) {
      int n = n0 + tx * 4 + j;
      double g = (double)accg[i][j] * ig;
      double u = (double)accu[i][j] * iu;
      double rg = fmax(g, 0.0);
      hhbuf[(long long)s * DDIM + n] = (float)(rg * rg * u);
    }
  }
}

// ---------------- act_quant over hh slot rows ----------------

__global__ __launch_bounds__(256) void k_hh_actq(
    const float* __restrict__ hhbuf, const int* __restrict__ meta,
    const int* __restrict__ tokidx, int8_t* __restrict__ hq,
    double* __restrict__ hsd) {
  __shared__ double tmp[4];
  int s = blockIdx.x;
  if (s >= meta[0] * 64) return;
  int tid = threadIdx.x;
  int tok = tokidx[s];
  if (tok < 0) {
    ((int*)hq)[s * 256 + tid] = 0;
    if (tid == 0) hsd[s] = 1.0;
    return;
  }
  float4 xv = ((const float4*)(hhbuf + (long long)s * DDIM))[tid];
  double x0 = xv.x, x1 = xv.y, x2 = xv.z, x3 = xv.w;
  double ma = fmax(fmax(fabs(x0), fabs(x1)), fmax(fabs(x2), fabs(x3)));
  ma = bredd(ma, 1, tmp);
  double sc = 127.0 / fmax(ma, 1e-5);
  ((int*)hq)[s * 256 + tid] = qpackd(x0, x1, x2, x3, sc);
  if (tid == 0) hsd[s] = sc;
}

// ---------------- MoE down GEMM + residual -> out (scatter) ----------------

__global__ __launch_bounds__(256) void k_moe_down(
    const int8_t* __restrict__ hq, const double* __restrict__ hsd,
    const int8_t* __restrict__ qw, const double* __restrict__ wsd,
    const int* __restrict__ meta, const int* __restrict__ tokidx,
    const float* __restrict__ x2, float* __restrict__ out) {
  __shared__ int Xs[32][65];
  __shared__ int Wt[32][65];
  int tile = blockIdx.y;
  if (tile >= meta[0]) return;
  int e = meta[1 + tile];
  int n0 = blockIdx.x * 64;
  int s0 = tile * 64;
  int tid = threadIdx.x;
  int lr = tid >> 5, lc = tid & 31;
  int ty = tid >> 4, tx = tid & 15;
  const int* Xg = (const int*)hq;
  const int* Wg = (const int*)(qw + ((long long)(20 + e) << 20));
  int acc[4][4] = {};
  for (int k0 = 0; k0 < 1024; k0 += 128) {
    int kc = k0 >> 2;
#pragma unroll
    for (int i = 0; i < 8; i++) {
      int rr = lr + i * 8;
      Xs[lc][rr] = Xg[(s0 + rr) * 256 + kc + lc];
      Wt[lc][rr] = Wg[(n0 + rr) * 256 + kc + lc];
    }
    __syncthreads();
#pragma unroll
    for (int kk = 0; kk < 32; kk++) {
      int4 a = *(const int4*)&Xs[kk][ty * 4];
      int4 b = *(const int4*)&Wt[kk][tx * 4];
      acc[0][0] = dot4(a.x, b.x, acc[0][0]); acc[0][1] = dot4(a.x, b.y, acc[0][1]);
      acc[0][2] = dot4(a.x, b.z, acc[0][2]); acc[0][3] = dot4(a.x, b.w, acc[0][3]);
      acc[1][0] = dot4(a.y, b.x, acc[1][0]); acc[1][1] = dot4(a.y, b.y, acc[1][1]);
      acc[1][2] = dot4(a.y, b.z, acc[1][2]); acc[1][3] = dot4(a.y, b.w, acc[1][3]);
      acc[2][0] = dot4(a.z, b.x, acc[2][0]); acc[2][1] = dot4(a.z, b.y, acc[2][1]);
      acc[2][2] = dot4(a.z, b.z, acc[2][2]); acc[2][3] = dot4(a.z, b.w, acc[2][3]);
      acc[3][0] = dot4(a.w, b.x, acc[3][0]); acc[3][1] = dot4(a.w, b.y, acc[3][1]);
      acc[3][2] = dot4(a.w, b.z, acc[3][2]); acc[3][3] = dot4(a.w, b.w, acc[3][3]);
    }
    __syncthreads();
  }
  double sw = wsd[20 + e];
#pragma unroll
  for (int i = 0; i < 4; i++) {
    int s = s0 + ty * 4 + i;
    int tok = tokidx[s];
    if (tok < 0) continue;
    double inv = 1.0 / (hsd[s] * sw);
#pragma unroll
    for (int j = 0; j < 4; j++) {
      int n = n0 + tx * 4 + j;
      out[(long long)tok * H + n] =
          (float)((double)x2[(long long)tok * H + n] + (double)acc[i][j] * inv);
    }
  }
}

// ---------------- launch ----------------
// ws layout (bytes):
//   0        partial double[28*1024] (224 KB)
//   229376   wsd double[28]
//   229600   xsd double[4096] (32 KB)
//   262368   eidx int[4096] (16 KB)
//   278752   Mk float[32]
//   278912   meta int[128]  (ntile + tile_e)
//   279424   tokidx int[4608] (18 KB)
//   297856   hsd double[4608] (36.9 KB)
//   1MB      qw int8: 28 x 1MB
//   29MB     xq int8 4MB
//   33MB     qbuf fp32 16MB (q -> attn out h); later hhbuf f32 [4544][1024] (18.6MB, 33..51.6)
//   49MB     kbuf fp32 16MB (k; dead after attn)
//   52MB     hq int8 [4544][1024] (4.65MB, 52..56.7)   <- inside dead kbuf region
//   65MB     vbuf fp32 16MB (v -> x2 residual)

extern "C" void kernel_launch(void* const* d_in, const int* in_sizes, int n_in,
                              void* d_out, int out_size, void* d_ws, size_t ws_size,
                              hipStream_t stream) {
  const float* x   = (const float*)d_in[0];
  const float* qw_ = (const float*)d_in[1];
  const float* kw_ = (const float*)d_in[2];
  const float* vw_ = (const float*)d_in[3];
  const float* ow_ = (const float*)d_in[4];
  const float* ln1 = (const float*)d_in[5];
  const float* ln2 = (const float*)d_in[6];
  const float* rw  = (const float*)d_in[7];
  const float* gw  = (const float*)d_in[8];
  const float* uw  = (const float*)d_in[9];
  const float* dw  = (const float*)d_in[10];
  float* out = (float*)d_out;

  uint8_t* ws = (uint8_t*)d_ws;
  double* partial = (double*)ws;
  double* wsd    = (double*)(ws + 229376);
  double* xsd    = (double*)(ws + 229600);
  int*    eidx   = (int*)(ws + 262368);
  float*  Mk     = (float*)(ws + 278752);
  int*    meta   = (int*)(ws + 278912);
  int*    tokidx = (int*)(ws + 279424);
  double* hsd    = (double*)(ws + 297856);
  int8_t* qw     = (int8_t*)(ws + (1ull << 20));
  int8_t* xq     = (int8_t*)(ws + (29ull << 20));
  float*  qbuf   = (float*)(ws + (33ull << 20));
  float*  hhbuf  = (float*)(ws + (33ull << 20));   // aliases qbuf (dead by then)
  float*  kbuf   = (float*)(ws + (49ull << 20));
  int8_t* hq     = (int8_t*)(ws + (52ull << 20));  // inside dead kbuf region
  float*  vbuf   = (float*)(ws + (65ull << 20));

  // weight quantization (deterministic fp64 scales)
  k_absum<<<28 * 1024, 256, 0, stream>>>(qw_, kw_, vw_, ow_, gw, uw, dw, partial);
  k_wscale<<<28, 256, 0, stream>>>(partial, wsd);
  k_quantw<<<28 * 1024, 256, 0, stream>>>(qw_, kw_, vw_, ow_, gw, uw, dw, wsd, qw);

  // attention input: rmsnorm + act_quant
  k_rms1<<<NTOK, 256, 0, stream>>>(x, ln1, xq, xsd);
  // q/k/v projections (exact int8 x ternary GEMM)
  k_gemm<<<dim3(16, 64), 256, 0, stream>>>(xq, xsd, qw,             wsd, 0, nullptr, qbuf);
  k_gemm<<<dim3(16, 64), 256, 0, stream>>>(xq, xsd, qw + (1 << 20), wsd, 1, nullptr, kbuf);
  k_gemm<<<dim3(16, 64), 256, 0, stream>>>(xq, xsd, qw + (2 << 20), wsd, 2, nullptr, vbuf);
  // causal flash attention (fixed-bound softmax, staged K/V, uniform 33-tile blocks)
  k_knorm<<<32, 256, 0, stream>>>(kbuf, Mk);
  k_attn<<<dim3(512), 512, 0, stream>>>(qbuf, kbuf, vbuf, qbuf, Mk);
  // o projection with residual: x2 = x + bitlinear(h, o_w) -> vbuf
  k_actq<<<NTOK, 256, 0, stream>>>(qbuf, xq, xsd);
  k_gemm<<<dim3(16, 64), 256, 0, stream>>>(xq, xsd, qw + (3 << 20), wsd, 3, x, vbuf);
  // MoE: rmsnorm2 + router argmax + act_quant, then expert-gathered GEMMs
  k_rms2_router<<<NTOK, 256, 0, stream>>>(vbuf, ln2, rw, xq, xsd, eidx);
  k_route<<<1, 256, 0, stream>>>(eidx, meta, tokidx);
  k_moe_gu<<<dim3(16, 71), 256, 0, stream>>>(xq, xsd, qw, wsd, meta, tokidx, hhbuf);
  k_hh_actq<<<4544, 256, 0, stream>>>(hhbuf, meta, tokidx, hq, hsd);
  k_moe_down<<<dim3(16, 71), 256, 0, stream>>>(hq, hsd, qw, wsd, meta, tokidx, vbuf, out);
}

// Round 4
// 716.474 us; speedup vs baseline: 1.9837x; 1.2869x over previous
//
#include <hip/hip_runtime.h>
#include <stdint.h>
#include <math.h>

// Problem constants
#define NTOK 4096   // B*S
#define H    1024
#define NHEAD 16
#define HD   64
#define SEQ  2048
#define NE   8
#define DDIM 1024

typedef __attribute__((ext_vector_type(4)))  int i32x4;
typedef __attribute__((ext_vector_type(16))) int i32x16;

// ---------------- helpers ----------------

__device__ __forceinline__ i32x16 mfma_i8(i32x4 a, i32x4 b, i32x16 c) {
  return __builtin_amdgcn_mfma_i32_32x32x32_i8(a, b, c, 0, 0, 0);
}

// 256-thread block reduce (double). op=0 sum, op=1 max. tmp: __shared__ double[4]
__device__ __forceinline__ double bredd(double v, int op, double* tmp) {
#pragma unroll
  for (int o = 32; o; o >>= 1) {
    double w = __shfl_xor(v, o);
    v = op ? fmax(v, w) : v + w;
  }
  int wid = threadIdx.x >> 6;
  if ((threadIdx.x & 63) == 0) tmp[wid] = v;
  __syncthreads();
  double r = op ? fmax(fmax(tmp[0], tmp[1]), fmax(tmp[2], tmp[3]))
                : (tmp[0] + tmp[1] + tmp[2] + tmp[3]);
  __syncthreads();
  return r;
}

// quantize 4 doubles to packed int8 with double scale (round-half-even like jnp.round)
__device__ __forceinline__ int qpackd(double n0, double n1, double n2, double n3, double s) {
  int a = (int)fmin(fmax(rint(n0 * s), -128.0), 127.0);
  int b = (int)fmin(fmax(rint(n1 * s), -128.0), 127.0);
  int c = (int)fmin(fmax(rint(n2 * s), -128.0), 127.0);
  int d = (int)fmin(fmax(rint(n3 * s), -128.0), 127.0);
  return (a & 255) | ((b & 255) << 8) | ((c & 255) << 16) | ((d & 255) << 24);
}

// map flat tensor id (0..27, each 1M elems) -> source pointer
__device__ __forceinline__ const float* wsrc(int tensor,
    const float* qw_, const float* kw_, const float* vw_, const float* ow_,
    const float* gw_, const float* uw_, const float* dw_) {
  if (tensor < 4) return tensor == 0 ? qw_ : tensor == 1 ? kw_ : tensor == 2 ? vw_ : ow_;
  if (tensor < 12) return gw_ + ((long long)(tensor - 4) << 20);
  if (tensor < 20) return uw_ + ((long long)(tensor - 12) << 20);
  return dw_ + ((long long)(tensor - 20) << 20);
}

// ---------------- weight quantization (fp64 scale, deterministic) ----------------

__global__ __launch_bounds__(256) void k_absum(
    const float* qw_, const float* kw_, const float* vw_, const float* ow_,
    const float* gw_, const float* uw_, const float* dw_, double* partial) {
  __shared__ double tmp[4];
  int tensor = blockIdx.x >> 10;
  int j = ((blockIdx.x & 1023) << 10) + threadIdx.x * 4;
  const float* src = wsrc(tensor, qw_, kw_, vw_, ow_, gw_, uw_, dw_);
  float4 w = *(const float4*)(src + j);
  double v = fabs((double)w.x) + fabs((double)w.y) + fabs((double)w.z) + fabs((double)w.w);
  v = bredd(v, 0, tmp);
  if (threadIdx.x == 0) partial[blockIdx.x] = v;
}

__global__ __launch_bounds__(256) void k_wscale(const double* partial, double* wsd) {
  __shared__ double tmp[4];
  int tensor = blockIdx.x;
  const double* p = partial + (tensor << 10);
  int i = threadIdx.x * 4;
  double v = p[i] + p[i + 1] + p[i + 2] + p[i + 3];
  v = bredd(v, 0, tmp);
  if (threadIdx.x == 0) wsd[tensor] = 1.0 / fmax(v * (1.0 / 1048576.0), 1e-5);
}

__global__ __launch_bounds__(256) void k_quantw(
    const float* qw_, const float* kw_, const float* vw_, const float* ow_,
    const float* gw_, const float* uw_, const float* dw_,
    const double* wsd, int8_t* qw) {
  int tensor = blockIdx.x >> 10;
  int j = ((blockIdx.x & 1023) << 10) + threadIdx.x * 4;
  const float* src = wsrc(tensor, qw_, kw_, vw_, ow_, gw_, uw_, dw_);
  double s = wsd[tensor];
  float4 w = *(const float4*)(src + j);
  int a = (int)fmin(fmax(rint((double)w.x * s), -1.0), 1.0);
  int b = (int)fmin(fmax(rint((double)w.y * s), -1.0), 1.0);
  int c = (int)fmin(fmax(rint((double)w.z * s), -1.0), 1.0);
  int d = (int)fmin(fmax(rint((double)w.w * s), -1.0), 1.0);
  ((int*)qw)[(tensor << 18) + (j >> 2)] =
      (a & 255) | ((b & 255) << 8) | ((c & 255) << 16) | ((d & 255) << 24);
}

// ---------------- rmsnorm + act_quant (attention input), fp64 decisions ----------------

__global__ __launch_bounds__(256) void k_rms1(const float* X, const float* lnw,
                                              int8_t* xq, double* xsd) {
  __shared__ double tmp[4];
  int t = blockIdx.x, tid = threadIdx.x;
  float4 xv = ((const float4*)(X + (long long)t * H))[tid];
  double x0 = xv.x, x1 = xv.y, x2 = xv.z, x3 = xv.w;
  double ss = x0 * x0 + x1 * x1 + x2 * x2 + x3 * x3;
  ss = bredd(ss, 0, tmp);
  double r = 1.0 / sqrt(ss * (1.0 / 1024.0) + 1e-5);
  float4 wv = ((const float4*)lnw)[tid];
  double n0 = x0 * r * wv.x, n1 = x1 * r * wv.y, n2 = x2 * r * wv.z, n3 = x3 * r * wv.w;
  double ma = fmax(fmax(fabs(n0), fabs(n1)), fmax(fabs(n2), fabs(n3)));
  ma = bredd(ma, 1, tmp);
  double s = 127.0 / fmax(ma, 1e-5);
  ((int*)xq)[t * 256 + tid] = qpackd(n0, n1, n2, n3, s);
  if (tid == 0) xsd[t] = s;
}

// act_quant only (rows of 1024 floats), fp64 decisions
__global__ __launch_bounds__(256) void k_actq(const float* X, int8_t* xq, double* xsd) {
  __shared__ double tmp[4];
  int t = blockIdx.x, tid = threadIdx.x;
  float4 xv = ((const float4*)(X + (long long)t * H))[tid];
  double x0 = xv.x, x1 = xv.y, x2 = xv.z, x3 = xv.w;
  double ma = fmax(fmax(fabs(x0), fabs(x1)), fmax(fabs(x2), fabs(x3)));
  ma = bredd(ma, 1, tmp);
  double s = 127.0 / fmax(ma, 1e-5);
  ((int*)xq)[t * 256 + tid] = qpackd(x0, x1, x2, x3, s);
  if (tid == 0) xsd[t] = s;
}

// ---------------- int8 GEMM via MFMA: out[t,n] = res[t,n] + acc/(xs[t]*sw) -------
// BM=128 BN=128 BK=64. 4 waves 2x2; wave tile 64x64 = 2x2 mfma_i32_32x32x32_i8.
// LDS K-major [kc(16B)][row]: frag read = two contiguous 512B runs (optimal).
// i32 accumulation is exact -> output bit-identical to the dot4 version.
// A-frag: lane=(row=l&31, kchunk=l>>5); C/D: col=lane&31, row=(r&3)+8*(r>>2)+4*(l>>5).

__global__ __launch_bounds__(256) void k_gemm(
    const int8_t* __restrict__ Xq, const double* __restrict__ xsd,
    const int8_t* __restrict__ W, const double* __restrict__ wsd, int widx,
    const float* __restrict__ residual, float* __restrict__ out) {
  __shared__ i32x4 Xs[4][128];
  __shared__ i32x4 Ws[4][128];
  int tid = threadIdx.x;
  int t0 = blockIdx.y * 128, n0 = blockIdx.x * 128;
  int w = tid >> 6, lane = tid & 63;
  int wm = w >> 1, wn = w & 1;
  int lrow = lane & 31, lk = lane >> 5;
  i32x16 acc[2][2];
#pragma unroll
  for (int i = 0; i < 2; i++)
#pragma unroll
    for (int j = 0; j < 2; j++)
#pragma unroll
      for (int r = 0; r < 16; r++) acc[i][j][r] = 0;

  for (int k0 = 0; k0 < 1024; k0 += 64) {
#pragma unroll
    for (int i = 0; i < 2; i++) {
      int u = tid * 2 + i;                 // 0..511
      int row = u >> 2, kc = u & 3;
      Xs[kc][row] = *(const i32x4*)(Xq + (long long)(t0 + row) * 1024 + k0 + kc * 16);
      Ws[kc][row] = *(const i32x4*)(W  + (long long)(n0 + row) * 1024 + k0 + kc * 16);
    }
    __syncthreads();
#pragma unroll
    for (int ks = 0; ks < 2; ks++) {
      i32x4 a0 = Xs[ks * 2 + lk][wm * 64 + lrow];
      i32x4 a1 = Xs[ks * 2 + lk][wm * 64 + 32 + lrow];
      i32x4 b0 = Ws[ks * 2 + lk][wn * 64 + lrow];
      i32x4 b1 = Ws[ks * 2 + lk][wn * 64 + 32 + lrow];
      acc[0][0] = mfma_i8(a0, b0, acc[0][0]);
      acc[0][1] = mfma_i8(a0, b1, acc[0][1]);
      acc[1][0] = mfma_i8(a1, b0, acc[1][0]);
      acc[1][1] = mfma_i8(a1, b1, acc[1][1]);
    }
    __syncthreads();
  }

  double sw = wsd[widx];
#pragma unroll
  for (int i = 0; i < 2; i++) {
#pragma unroll
    for (int r = 0; r < 16; r++) {
      int trow = t0 + wm * 64 + i * 32 + (r & 3) + 8 * (r >> 2) + 4 * lk;
      double inv = 1.0 / (xsd[trow] * sw);
#pragma unroll
      for (int j = 0; j < 2; j++) {
        int n = n0 + wn * 64 + j * 32 + lrow;
        double v = (double)acc[i][j][r] * inv;
        if (residual) v += (double)residual[(long long)trow * H + n];
        out[(long long)trow * H + n] = (float)v;
      }
    }
  }
}

// ---------------- attention ----------------
// k_knorm: per-(b,head) max key L2-norm -> fixed softmax bound.

__global__ __launch_bounds__(256) void k_knorm(const float* __restrict__ K,
                                               float* __restrict__ Mk) {
  __shared__ float tmp[4];
  int bh = blockIdx.x;          // b*16 + head
  int b = bh >> 4, head = bh & 15;
  int tid = threadIdx.x;
  float mx = 0.f;
  for (int key = tid; key < SEQ; key += 256) {
    const float4* kr = (const float4*)(K + ((long long)(b * SEQ + key)) * H + head * HD);
    float s = 0.f;
#pragma unroll
    for (int i = 0; i < 16; i++) {
      float4 v = kr[i];
      s += v.x * v.x + v.y * v.y + v.z * v.z + v.w * v.w;
    }
    mx = fmaxf(mx, s);
  }
#pragma unroll
  for (int o = 32; o; o >>= 1) mx = fmaxf(mx, __shfl_xor(mx, o));
  if ((tid & 63) == 0) tmp[tid >> 6] = mx;
  __syncthreads();
  if (tid == 0)
    Mk[bh] = sqrtf(fmaxf(fmaxf(tmp[0], tmp[1]), fmaxf(tmp[2], tmp[3])));
}

// k_attn (R9, unchanged): uniform-duration blocks. 512 blocks x 512 threads.
// Each block does q-tiles g=p and g=31-p (33 tile-units every block, no tail).

__global__ __launch_bounds__(512) void k_attn(
    const float* __restrict__ Q, const float* __restrict__ K,
    const float* __restrict__ V, float* __restrict__ O,
    const float* __restrict__ Mk) {
  __shared__ float smem[2][64][68];   // Ks=smem[0], Vs=smem[1]; merge aliases both
  __shared__ float lsh[8][32];
  int i = blockIdx.x;
  int hb = (i & 7) | (((i >> 3) & 3) << 3);
  int p  = ((i >> 5) & 7) | (((i >> 8) & 1) << 3);
  int head = hb & 15, b = hb >> 4;
  int tid = threadIdx.x;
  int w = tid >> 6, lane = tid & 63;
  int qh = w >> 2, ks = w & 3;
  int quad = lane >> 2, dp = lane & 3;
  int d0 = dp << 4;
  long long bh_base = ((long long)b * SEQ) * H + head * HD;
  float mkv = Mk[b * 16 + head];

  int srow = tid >> 3;               // staging: key row 0..63
  int sc8 = (tid & 7) << 3;          // staging: float offset 0,8,..,56 (2 float4s)

  for (int ph = 0; ph < 2; ph++) {
    int g = ph ? (31 - p) : p;
    int qlo = g * 64;

    float4 q[2][4];
    float mb[2], l[2] = {0.f, 0.f};
    float acc[2][16];
#pragma unroll
    for (int qq = 0; qq < 2; qq++)
#pragma unroll
      for (int i2 = 0; i2 < 16; i2++) acc[qq][i2] = 0.f;

    // load 2 queries (quad-local), compute fixed bound mb
#pragma unroll
    for (int qq = 0; qq < 2; qq++) {
      int j = qh * 32 + quad * 2 + qq;                // local query 0..63
      const float4* qp_ = (const float4*)(Q + bh_base + (long long)(qlo + j) * H + d0);
      float ss = 0.f;
#pragma unroll
      for (int i2 = 0; i2 < 4; i2++) {
        float4 t = qp_[i2];
        q[qq][i2] = make_float4(t.x * 0.125f, t.y * 0.125f, t.z * 0.125f, t.w * 0.125f);
        ss += t.x * t.x + t.y * t.y + t.z * t.z + t.w * t.w;
      }
      ss += __shfl_xor(ss, 1);
      ss += __shfl_xor(ss, 2);
      mb[qq] = 0.125f * sqrtf(ss) * mkv;
    }

    for (int t = 0; t <= g; t++) {
      long long srowg = bh_base + (long long)(t * 64 + srow) * H + sc8;
      const float4* kg = (const float4*)(K + srowg);
      const float4* vg = (const float4*)(V + srowg);
      float4* ksd = (float4*)&smem[0][srow][sc8];
      float4* vsd = (float4*)&smem[1][srow][sc8];
      ksd[0] = kg[0]; ksd[1] = kg[1];
      vsd[0] = vg[0]; vsd[1] = vg[1];
      __syncthreads();

      int kend = (t < g) ? 64 : (qh * 32 + 32);   // diagonal: qh=0 waves skip keys>=32
      for (int kk = ks; kk < kend; kk += 4) {
        const float4* kr = (const float4*)&smem[0][kk][d0];
        float4 kv0 = kr[0], kv1 = kr[1], kv2 = kr[2], kv3 = kr[3];
        float pr[2];
#pragma unroll
        for (int qq = 0; qq < 2; qq++) {
          float pa = 0.f, pb = 0.f;
          pa = fmaf(q[qq][0].x, kv0.x, pa); pb = fmaf(q[qq][0].y, kv0.y, pb);
          pa = fmaf(q[qq][0].z, kv0.z, pa); pb = fmaf(q[qq][0].w, kv0.w, pb);
          pa = fmaf(q[qq][1].x, kv1.x, pa); pb = fmaf(q[qq][1].y, kv1.y, pb);
          pa = fmaf(q[qq][1].z, kv1.z, pa); pb = fmaf(q[qq][1].w, kv1.w, pb);
          pa = fmaf(q[qq][2].x, kv2.x, pa); pb = fmaf(q[qq][2].y, kv2.y, pb);
          pa = fmaf(q[qq][2].z, kv2.z, pa); pb = fmaf(q[qq][2].w, kv2.w, pb);
          pa = fmaf(q[qq][3].x, kv3.x, pa); pb = fmaf(q[qq][3].y, kv3.y, pb);
          pa = fmaf(q[qq][3].w, kv3.w, pa); pb = fmaf(q[qq][3].z, kv3.z, pb);
          float pp = pa + pb;
          pp += __shfl_xor(pp, 1);
          pp += __shfl_xor(pp, 2);
          pr[qq] = pp;
        }
        const float4* vr = (const float4*)&smem[1][kk][d0];
        float4 vv0 = vr[0], vv1 = vr[1], vv2 = vr[2], vv3 = vr[3];
#pragma unroll
        for (int qq = 0; qq < 2; qq++) {
          int j = qh * 32 + quad * 2 + qq;
          bool ok = (t < g) || (kk <= j);
          float wgt = ok ? __expf(pr[qq] - mb[qq]) : 0.f;
          l[qq] += wgt;
          acc[qq][0]  = fmaf(wgt, vv0.x, acc[qq][0]);
          acc[qq][1]  = fmaf(wgt, vv0.y, acc[qq][1]);
          acc[qq][2]  = fmaf(wgt, vv0.z, acc[qq][2]);
          acc[qq][3]  = fmaf(wgt, vv0.w, acc[qq][3]);
          acc[qq][4]  = fmaf(wgt, vv1.x, acc[qq][4]);
          acc[qq][5]  = fmaf(wgt, vv1.y, acc[qq][5]);
          acc[qq][6]  = fmaf(wgt, vv1.z, acc[qq][6]);
          acc[qq][7]  = fmaf(wgt, vv1.w, acc[qq][7]);
          acc[qq][8]  = fmaf(wgt, vv2.x, acc[qq][8]);
          acc[qq][9]  = fmaf(wgt, vv2.y, acc[qq][9]);
          acc[qq][10] = fmaf(wgt, vv2.z, acc[qq][10]);
          acc[qq][11] = fmaf(wgt, vv2.w, acc[qq][11]);
          acc[qq][12] = fmaf(wgt, vv3.x, acc[qq][12]);
          acc[qq][13] = fmaf(wgt, vv3.y, acc[qq][13]);
          acc[qq][14] = fmaf(wgt, vv3.z, acc[qq][14]);
          acc[qq][15] = fmaf(wgt, vv3.w, acc[qq][15]);
        }
      }
      __syncthreads();
    }

    // ---- 4-way merge (fixed bound => plain sums). K/V tiles are dead; alias.
    if (dp == 0) {
      lsh[w][quad * 2 + 0] = l[0];
      lsh[w][quad * 2 + 1] = l[1];
    }
    if (ks >= 2) {                   // ks2 -> smem[0], ks3 -> smem[1]
      float (*mrg)[68] = smem[ks - 2];
#pragma unroll
      for (int qq = 0; qq < 2; qq++) {
        int row = qh * 32 + quad * 2 + qq;
        float4* dst = (float4*)&mrg[row][d0];
#pragma unroll
        for (int i2 = 0; i2 < 4; i2++)
          dst[i2] = make_float4(acc[qq][4*i2], acc[qq][4*i2+1], acc[qq][4*i2+2], acc[qq][4*i2+3]);
      }
    }
    __syncthreads();
    if (ks == 0) {                   // fold ks2 partial
#pragma unroll
      for (int qq = 0; qq < 2; qq++) {
        int row = qh * 32 + quad * 2 + qq;
        const float4* src = (const float4*)&smem[0][row][d0];
#pragma unroll
        for (int i2 = 0; i2 < 4; i2++) {
          float4 s = src[i2];
          acc[qq][4*i2+0] += s.x; acc[qq][4*i2+1] += s.y;
          acc[qq][4*i2+2] += s.z; acc[qq][4*i2+3] += s.w;
        }
      }
    }
    if (ks == 1) {                   // fold ks3 partial, republish to smem[1]
#pragma unroll
      for (int qq = 0; qq < 2; qq++) {
        int row = qh * 32 + quad * 2 + qq;
        float4* sp = (float4*)&smem[1][row][d0];
#pragma unroll
        for (int i2 = 0; i2 < 4; i2++) {
          float4 s = sp[i2];
          sp[i2] = make_float4(acc[qq][4*i2+0] + s.x, acc[qq][4*i2+1] + s.y,
                               acc[qq][4*i2+2] + s.z, acc[qq][4*i2+3] + s.w);
        }
      }
    }
    __syncthreads();
    if (ks == 0) {                   // final fold + normalize + store
#pragma unroll
      for (int qq = 0; qq < 2; qq++) {
        int jl = quad * 2 + qq;
        int row = qh * 32 + jl;
        float lt = lsh[qh * 4 + 0][jl] + lsh[qh * 4 + 1][jl] +
                   lsh[qh * 4 + 2][jl] + lsh[qh * 4 + 3][jl];
        float inv = 1.f / lt;
        const float4* src = (const float4*)&smem[1][row][d0];
        float4* op = (float4*)(O + bh_base + (long long)(qlo + row) * H + d0);
#pragma unroll
        for (int i2 = 0; i2 < 4; i2++) {
          float4 s = src[i2];
          op[i2] = make_float4((acc[qq][4*i2+0] + s.x) * inv, (acc[qq][4*i2+1] + s.y) * inv,
                               (acc[qq][4*i2+2] + s.z) * inv, (acc[qq][4*i2+3] + s.w) * inv);
        }
      }
    }
    __syncthreads();                 // smem/lsh reuse safe for next phase
  }
}

// ---------------- rmsnorm2 + router (argmax, fp64) + act_quant ----------------

__global__ __launch_bounds__(256) void k_rms2_router(
    const float* X2, const float* lnw, const float* rw,
    int8_t* xq, double* xsd, int* eidx) {
  __shared__ double tmp[4];
  __shared__ double xn[1024];
  __shared__ double logits[8];
  int t = blockIdx.x, tid = threadIdx.x;
  float4 xv = ((const float4*)(X2 + (long long)t * H))[tid];
  double x0 = xv.x, x1 = xv.y, x2 = xv.z, x3 = xv.w;
  double ss = x0 * x0 + x1 * x1 + x2 * x2 + x3 * x3;
  ss = bredd(ss, 0, tmp);
  double r = 1.0 / sqrt(ss * (1.0 / 1024.0) + 1e-5);
  float4 wv = ((const float4*)lnw)[tid];
  double n0 = x0 * r * wv.x, n1 = x1 * r * wv.y, n2 = x2 * r * wv.z, n3 = x3 * r * wv.w;
  xn[tid * 4 + 0] = n0; xn[tid * 4 + 1] = n1;
  xn[tid * 4 + 2] = n2; xn[tid * 4 + 3] = n3;
  double ma = fmax(fmax(fabs(n0), fabs(n1)), fmax(fabs(n2), fabs(n3)));
  ma = bredd(ma, 1, tmp);  // contains syncthreads -> xn visible
  double s = 127.0 / fmax(ma, 1e-5);
  ((int*)xq)[t * 256 + tid] = qpackd(n0, n1, n2, n3, s);
  if (tid == 0) xsd[t] = s;
  if (tid < 64) {
    int e = tid >> 3, i = tid & 7;
    const float* wr = rw + e * 1024;
    double p = 0.0;
    for (int h = i; h < 1024; h += 8) p += xn[h] * (double)wr[h];
    p += __shfl_xor(p, 1);
    p += __shfl_xor(p, 2);
    p += __shfl_xor(p, 4);
    if (i == 0) logits[e] = p;
  }
  __syncthreads();
  if (tid == 0) {
    double best = logits[0];
    int bi = 0;
    for (int e = 1; e < 8; e++)
      if (logits[e] > best) { best = logits[e]; bi = e; }
    eidx[t] = bi;
  }
}

// ---------------- MoE routing: group tokens by expert into padded 64-slot tiles ----
// meta[0] = ntile; meta[1+i] = expert of tile i. tokidx[slot] = token or -1 (pad).

__global__ __launch_bounds__(256) void k_route(const int* __restrict__ eidx,
                                               int* __restrict__ meta,
                                               int* __restrict__ tokidx) {
  __shared__ int cnt[8], pb[9], cur[8];
  int tid = threadIdx.x;
  if (tid < 8) cnt[tid] = 0;
  __syncthreads();
  for (int t = tid; t < NTOK; t += 256) atomicAdd(&cnt[eidx[t]], 1);
  __syncthreads();
  if (tid == 0) {
    pb[0] = 0;
    int nt = 0;
    for (int e = 0; e < 8; e++) {
      int tiles = (cnt[e] + 63) >> 6;
      for (int i = 0; i < tiles; i++) meta[1 + nt + i] = e;
      nt += tiles;
      pb[e + 1] = pb[e] + tiles * 64;
      cur[e] = pb[e];
    }
    meta[0] = nt;
  }
  __syncthreads();
  for (int s = tid; s < 4608; s += 256) tokidx[s] = -1;
  __syncthreads();
  for (int t = tid; t < NTOK; t += 256) {
    int e = eidx[t];
    int s = atomicAdd(&cur[e], 1);
    tokidx[s] = t;
  }
}

// ---------------- MoE gate+up GEMM via MFMA -> hh (fused relu(g)^2*u) ----------
// BM=64 (one expert slot-tile) BN=128 BK=64; 4 waves, wave = 64t x 32n x {gate,up}.
// Gathered X rows via tokidx; grid (8 n-tiles, 71 slot-tiles).

__global__ __launch_bounds__(256) void k_moe_gu(
    const int8_t* __restrict__ Xq, const double* __restrict__ xsd,
    const int8_t* __restrict__ qw, const double* __restrict__ wsd,
    const int* __restrict__ meta, const int* __restrict__ tokidx,
    float* __restrict__ hhbuf) {
  __shared__ i32x4 Xs[4][64];
  __shared__ i32x4 Wg[4][128];
  __shared__ i32x4 Wu[4][128];
  int tile = blockIdx.y;
  if (tile >= meta[0]) return;
  int e = meta[1 + tile];
  int n0 = blockIdx.x * 128;
  int s0 = tile * 64;
  int tid = threadIdx.x;
  int w = tid >> 6, lane = tid & 63;
  int lrow = lane & 31, lk = lane >> 5;
  const int8_t* Gg = qw + ((long long)(4 + e) << 20);
  const int8_t* Ug = qw + ((long long)(12 + e) << 20);
  // X staging gather: thread owns unit (row=tid>>2, kc=tid&3)
  int xrow = tid >> 2, xkc = tid & 3;
  int tokr = tokidx[s0 + xrow];
  if (tokr < 0) tokr = 0;
  i32x16 accg[2], accu[2];
#pragma unroll
  for (int i = 0; i < 2; i++)
#pragma unroll
    for (int r = 0; r < 16; r++) { accg[i][r] = 0; accu[i][r] = 0; }

  for (int k0 = 0; k0 < 1024; k0 += 64) {
    Xs[xkc][xrow] = *(const i32x4*)(Xq + (long long)tokr * 1024 + k0 + xkc * 16);
#pragma unroll
    for (int i = 0; i < 2; i++) {
      int u = tid * 2 + i;                 // 0..511
      int row = u >> 2, kc = u & 3;
      Wg[kc][row] = *(const i32x4*)(Gg + (long long)(n0 + row) * 1024 + k0 + kc * 16);
      Wu[kc][row] = *(const i32x4*)(Ug + (long long)(n0 + row) * 1024 + k0 + kc * 16);
    }
    __syncthreads();
#pragma unroll
    for (int ks = 0; ks < 2; ks++) {
      i32x4 a0 = Xs[ks * 2 + lk][lrow];
      i32x4 a1 = Xs[ks * 2 + lk][32 + lrow];
      i32x4 bg = Wg[ks * 2 + lk][w * 32 + lrow];
      i32x4 bu = Wu[ks * 2 + lk][w * 32 + lrow];
      accg[0] = mfma_i8(a0, bg, accg[0]);
      accg[1] = mfma_i8(a1, bg, accg[1]);
      accu[0] = mfma_i8(a0, bu, accu[0]);
      accu[1] = mfma_i8(a1, bu, accu[1]);
    }
    __syncthreads();
  }

  double swg = wsd[4 + e], swu = wsd[12 + e];
  int n = n0 + w * 32 + lrow;
#pragma unroll
  for (int i = 0; i < 2; i++) {
#pragma unroll
    for (int r = 0; r < 16; r++) {
      int s = s0 + i * 32 + (r & 3) + 8 * (r >> 2) + 4 * lk;
      int tok = tokidx[s];
      if (tok < 0) continue;
      double ig = 1.0 / (xsd[tok] * swg);
      double iu = 1.0 / (xsd[tok] * swu);
      double g = (double)accg[i][r] * ig;
      double uu = (double)accu[i][r] * iu;
      double rg = fmax(g, 0.0);
      hhbuf[(long long)s * DDIM + n] = (float)(rg * rg * uu);
    }
  }
}

// ---------------- act_quant over hh slot rows ----------------

__global__ __launch_bounds__(256) void k_hh_actq(
    const float* __restrict__ hhbuf, const int* __restrict__ meta,
    const int* __restrict__ tokidx, int8_t* __restrict__ hq,
    double* __restrict__ hsd) {
  __shared__ double tmp[4];
  int s = blockIdx.x;
  if (s >= meta[0] * 64) return;
  int tid = threadIdx.x;
  int tok = tokidx[s];
  if (tok < 0) {
    ((int*)hq)[s * 256 + tid] = 0;
    if (tid == 0) hsd[s] = 1.0;
    return;
  }
  float4 xv = ((const float4*)(hhbuf + (long long)s * DDIM))[tid];
  double x0 = xv.x, x1 = xv.y, x2 = xv.z, x3 = xv.w;
  double ma = fmax(fmax(fabs(x0), fabs(x1)), fmax(fabs(x2), fabs(x3)));
  ma = bredd(ma, 1, tmp);
  double sc = 127.0 / fmax(ma, 1e-5);
  ((int*)hq)[s * 256 + tid] = qpackd(x0, x1, x2, x3, sc);
  if (tid == 0) hsd[s] = sc;
}

// ---------------- MoE down GEMM via MFMA + residual -> out (scatter) ------------
// BM=64 slots BN=128 BK=64; 4 waves, wave = 64t x 32n. X = hq (slot-major, no gather).

__global__ __launch_bounds__(256) void k_moe_down(
    const int8_t* __restrict__ hq, const double* __restrict__ hsd,
    const int8_t* __restrict__ qw, const double* __restrict__ wsd,
    const int* __restrict__ meta, const int* __restrict__ tokidx,
    const float* __restrict__ x2, float* __restrict__ out) {
  __shared__ i32x4 Xs[4][64];
  __shared__ i32x4 Ws[4][128];
  int tile = blockIdx.y;
  if (tile >= meta[0]) return;
  int e = meta[1 + tile];
  int n0 = blockIdx.x * 128;
  int s0 = tile * 64;
  int tid = threadIdx.x;
  int w = tid >> 6, lane = tid & 63;
  int lrow = lane & 31, lk = lane >> 5;
  const int8_t* Wp = qw + ((long long)(20 + e) << 20);
  int xrow = tid >> 2, xkc = tid & 3;
  i32x16 acc[2];
#pragma unroll
  for (int i = 0; i < 2; i++)
#pragma unroll
    for (int r = 0; r < 16; r++) acc[i][r] = 0;

  for (int k0 = 0; k0 < 1024; k0 += 64) {
    Xs[xkc][xrow] = *(const i32x4*)(hq + (long long)(s0 + xrow) * 1024 + k0 + xkc * 16);
#pragma unroll
    for (int i = 0; i < 2; i++) {
      int u = tid * 2 + i;
      int row = u >> 2, kc = u & 3;
      Ws[kc][row] = *(const i32x4*)(Wp + (long long)(n0 + row) * 1024 + k0 + kc * 16);
    }
    __syncthreads();
#pragma unroll
    for (int ks = 0; ks < 2; ks++) {
      i32x4 a0 = Xs[ks * 2 + lk][lrow];
      i32x4 a1 = Xs[ks * 2 + lk][32 + lrow];
      i32x4 b  = Ws[ks * 2 + lk][w * 32 + lrow];
      acc[0] = mfma_i8(a0, b, acc[0]);
      acc[1] = mfma_i8(a1, b, acc[1]);
    }
    __syncthreads();
  }

  double sw = wsd[20 + e];
  int n = n0 + w * 32 + lrow;
#pragma unroll
  for (int i = 0; i < 2; i++) {
#pragma unroll
    for (int r = 0; r < 16; r++) {
      int s = s0 + i * 32 + (r & 3) + 8 * (r >> 2) + 4 * lk;
      int tok = tokidx[s];
      if (tok < 0) continue;
      double inv = 1.0 / (hsd[s] * sw);
      out[(long long)tok * H + n] =
          (float)((double)x2[(long long)tok * H + n] + (double)acc[i][r] * inv);
    }
  }
}

// ---------------- launch ----------------
// ws layout (bytes):
//   0        partial double[28*1024] (224 KB)
//   229376   wsd double[28]
//   229600   xsd double[4096] (32 KB)
//   262368   eidx int[4096] (16 KB)
//   278752   Mk float[32]
//   278912   meta int[128]  (ntile + tile_e)
//   279424   tokidx int[4608] (18 KB)
//   297856   hsd double[4608] (36.9 KB)
//   1MB      qw int8: 28 x 1MB
//   29MB     xq int8 4MB
//   33MB     qbuf fp32 16MB (q -> attn out h); later hhbuf f32 [4544][1024] (18.6MB, 33..51.6)
//   49MB     kbuf fp32 16MB (k; dead after attn)
//   52MB     hq int8 [4544][1024] (4.65MB, 52..56.7)   <- inside dead kbuf region
//   65MB     vbuf fp32 16MB (v -> x2 residual)

extern "C" void kernel_launch(void* const* d_in, const int* in_sizes, int n_in,
                              void* d_out, int out_size, void* d_ws, size_t ws_size,
                              hipStream_t stream) {
  const float* x   = (const float*)d_in[0];
  const float* qw_ = (const float*)d_in[1];
  const float* kw_ = (const float*)d_in[2];
  const float* vw_ = (const float*)d_in[3];
  const float* ow_ = (const float*)d_in[4];
  const float* ln1 = (const float*)d_in[5];
  const float* ln2 = (const float*)d_in[6];
  const float* rw  = (const float*)d_in[7];
  const float* gw  = (const float*)d_in[8];
  const float* uw  = (const float*)d_in[9];
  const float* dw  = (const float*)d_in[10];
  float* out = (float*)d_out;

  uint8_t* ws = (uint8_t*)d_ws;
  double* partial = (double*)ws;
  double* wsd    = (double*)(ws + 229376);
  double* xsd    = (double*)(ws + 229600);
  int*    eidx   = (int*)(ws + 262368);
  float*  Mk     = (float*)(ws + 278752);
  int*    meta   = (int*)(ws + 278912);
  int*    tokidx = (int*)(ws + 279424);
  double* hsd    = (double*)(ws + 297856);
  int8_t* qw     = (int8_t*)(ws + (1ull << 20));
  int8_t* xq     = (int8_t*)(ws + (29ull << 20));
  float*  qbuf   = (float*)(ws + (33ull << 20));
  float*  hhbuf  = (float*)(ws + (33ull << 20));   // aliases qbuf (dead by then)
  float*  kbuf   = (float*)(ws + (49ull << 20));
  int8_t* hq     = (int8_t*)(ws + (52ull << 20));  // inside dead kbuf region
  float*  vbuf   = (float*)(ws + (65ull << 20));

  // weight quantization (deterministic fp64 scales)
  k_absum<<<28 * 1024, 256, 0, stream>>>(qw_, kw_, vw_, ow_, gw, uw, dw, partial);
  k_wscale<<<28, 256, 0, stream>>>(partial, wsd);
  k_quantw<<<28 * 1024, 256, 0, stream>>>(qw_, kw_, vw_, ow_, gw, uw, dw, wsd, qw);

  // attention input: rmsnorm + act_quant
  k_rms1<<<NTOK, 256, 0, stream>>>(x, ln1, xq, xsd);
  // q/k/v projections (exact int8 x ternary GEMM on MFMA)
  k_gemm<<<dim3(8, 32), 256, 0, stream>>>(xq, xsd, qw,             wsd, 0, nullptr, qbuf);
  k_gemm<<<dim3(8, 32), 256, 0, stream>>>(xq, xsd, qw + (1 << 20), wsd, 1, nullptr, kbuf);
  k_gemm<<<dim3(8, 32), 256, 0, stream>>>(xq, xsd, qw + (2 << 20), wsd, 2, nullptr, vbuf);
  // causal flash attention (fixed-bound softmax, staged K/V, uniform 33-tile blocks)
  k_knorm<<<32, 256, 0, stream>>>(kbuf, Mk);
  k_attn<<<dim3(512), 512, 0, stream>>>(qbuf, kbuf, vbuf, qbuf, Mk);
  // o projection with residual: x2 = x + bitlinear(h, o_w) -> vbuf
  k_actq<<<NTOK, 256, 0, stream>>>(qbuf, xq, xsd);
  k_gemm<<<dim3(8, 32), 256, 0, stream>>>(xq, xsd, qw + (3 << 20), wsd, 3, x, vbuf);
  // MoE: rmsnorm2 + router argmax + act_quant, then expert-gathered GEMMs
  k_rms2_router<<<NTOK, 256, 0, stream>>>(vbuf, ln2, rw, xq, xsd, eidx);
  k_route<<<1, 256, 0, stream>>>(eidx, meta, tokidx);
  k_moe_gu<<<dim3(8, 71), 256, 0, stream>>>(xq, xsd, qw, wsd, meta, tokidx, hhbuf);
  k_hh_actq<<<4544, 256, 0, stream>>>(hhbuf, meta, tokidx, hq, hsd);
  k_moe_down<<<dim3(8, 71), 256, 0, stream>>>(hq, hsd, qw, wsd, meta, tokidx, vbuf, out);
}

// Round 6
// 648.281 us; speedup vs baseline: 2.1923x; 1.1052x over previous
//
#include <hip/hip_runtime.h>
#include <stdint.h>
#include <math.h>

// Problem constants
#define NTOK 4096   // B*S
#define H    1024
#define NHEAD 16
#define HD   64
#define SEQ  2048
#define NE   8
#define DDIM 1024

typedef __attribute__((ext_vector_type(4)))  int i32x4;
typedef __attribute__((ext_vector_type(16))) int i32x16;
typedef __attribute__((ext_vector_type(8)))  short bf16x8;
typedef __attribute__((ext_vector_type(4)))  float f32x4;

// ---------------- helpers ----------------

__device__ __forceinline__ i32x16 mfma_i8(i32x4 a, i32x4 b, i32x16 c) {
  return __builtin_amdgcn_mfma_i32_32x32x32_i8(a, b, c, 0, 0, 0);
}

// float -> bf16 round-to-nearest-even (finite inputs)
__device__ __forceinline__ unsigned int f2bf(float f) {
  unsigned int u = __float_as_uint(f);
  return (u + 0x7fffu + ((u >> 16) & 1u)) >> 16;
}
__device__ __forceinline__ float bf2f(unsigned int b) {
  return __uint_as_float(b << 16);
}
// pack hi-parts of (a,b) into return, lo-parts (residual bf16) into lo
__device__ __forceinline__ unsigned int f2bf2hl(float a, float b, unsigned int& lo) {
  unsigned int ha = f2bf(a), hb = f2bf(b);
  lo = f2bf(a - bf2f(ha)) | (f2bf(b - bf2f(hb)) << 16);
  return ha | (hb << 16);
}

// 256-thread block reduce (double). op=0 sum, op=1 max. tmp: __shared__ double[4]
__device__ __forceinline__ double bredd(double v, int op, double* tmp) {
#pragma unroll
  for (int o = 32; o; o >>= 1) {
    double w = __shfl_xor(v, o);
    v = op ? fmax(v, w) : v + w;
  }
  int wid = threadIdx.x >> 6;
  if ((threadIdx.x & 63) == 0) tmp[wid] = v;
  __syncthreads();
  double r = op ? fmax(fmax(tmp[0], tmp[1]), fmax(tmp[2], tmp[3]))
                : (tmp[0] + tmp[1] + tmp[2] + tmp[3]);
  __syncthreads();
  return r;
}

// quantize 4 doubles to packed int8 with double scale (round-half-even like jnp.round)
__device__ __forceinline__ int qpackd(double n0, double n1, double n2, double n3, double s) {
  int a = (int)fmin(fmax(rint(n0 * s), -128.0), 127.0);
  int b = (int)fmin(fmax(rint(n1 * s), -128.0), 127.0);
  int c = (int)fmin(fmax(rint(n2 * s), -128.0), 127.0);
  int d = (int)fmin(fmax(rint(n3 * s), -128.0), 127.0);
  return (a & 255) | ((b & 255) << 8) | ((c & 255) << 16) | ((d & 255) << 24);
}

// map flat tensor id (0..27, each 1M elems) -> source pointer
__device__ __forceinline__ const float* wsrc(int tensor,
    const float* qw_, const float* kw_, const float* vw_, const float* ow_,
    const float* gw_, const float* uw_, const float* dw_) {
  if (tensor < 4) return tensor == 0 ? qw_ : tensor == 1 ? kw_ : tensor == 2 ? vw_ : ow_;
  if (tensor < 12) return gw_ + ((long long)(tensor - 4) << 20);
  if (tensor < 20) return uw_ + ((long long)(tensor - 12) << 20);
  return dw_ + ((long long)(tensor - 20) << 20);
}

// ---------------- weight quantization (fp64 scale, deterministic) ----------------

__global__ __launch_bounds__(256) void k_absum(
    const float* qw_, const float* kw_, const float* vw_, const float* ow_,
    const float* gw_, const float* uw_, const float* dw_, double* partial) {
  __shared__ double tmp[4];
  int tensor = blockIdx.x >> 10;
  int j = ((blockIdx.x & 1023) << 10) + threadIdx.x * 4;
  const float* src = wsrc(tensor, qw_, kw_, vw_, ow_, gw_, uw_, dw_);
  float4 w = *(const float4*)(src + j);
  double v = fabs((double)w.x) + fabs((double)w.y) + fabs((double)w.z) + fabs((double)w.w);
  v = bredd(v, 0, tmp);
  if (threadIdx.x == 0) partial[blockIdx.x] = v;
}

__global__ __launch_bounds__(256) void k_wscale(const double* partial, double* wsd) {
  __shared__ double tmp[4];
  int tensor = blockIdx.x;
  const double* p = partial + (tensor << 10);
  int i = threadIdx.x * 4;
  double v = p[i] + p[i + 1] + p[i + 2] + p[i + 3];
  v = bredd(v, 0, tmp);
  if (threadIdx.x == 0) wsd[tensor] = 1.0 / fmax(v * (1.0 / 1048576.0), 1e-5);
}

__global__ __launch_bounds__(256) void k_quantw(
    const float* qw_, const float* kw_, const float* vw_, const float* ow_,
    const float* gw_, const float* uw_, const float* dw_,
    const double* wsd, int8_t* qw) {
  int tensor = blockIdx.x >> 10;
  int j = ((blockIdx.x & 1023) << 10) + threadIdx.x * 4;
  const float* src = wsrc(tensor, qw_, kw_, vw_, ow_, gw_, uw_, dw_);
  double s = wsd[tensor];
  float4 w = *(const float4*)(src + j);
  int a = (int)fmin(fmax(rint((double)w.x * s), -1.0), 1.0);
  int b = (int)fmin(fmax(rint((double)w.y * s), -1.0), 1.0);
  int c = (int)fmin(fmax(rint((double)w.z * s), -1.0), 1.0);
  int d = (int)fmin(fmax(rint((double)w.w * s), -1.0), 1.0);
  ((int*)qw)[(tensor << 18) + (j >> 2)] =
      (a & 255) | ((b & 255) << 8) | ((c & 255) << 16) | ((d & 255) << 24);
}

// ---------------- rmsnorm + act_quant (attention input), fp64 decisions ----------------

__global__ __launch_bounds__(256) void k_rms1(const float* X, const float* lnw,
                                              int8_t* xq, double* xsd) {
  __shared__ double tmp[4];
  int t = blockIdx.x, tid = threadIdx.x;
  float4 xv = ((const float4*)(X + (long long)t * H))[tid];
  double x0 = xv.x, x1 = xv.y, x2 = xv.z, x3 = xv.w;
  double ss = x0 * x0 + x1 * x1 + x2 * x2 + x3 * x3;
  ss = bredd(ss, 0, tmp);
  double r = 1.0 / sqrt(ss * (1.0 / 1024.0) + 1e-5);
  float4 wv = ((const float4*)lnw)[tid];
  double n0 = x0 * r * wv.x, n1 = x1 * r * wv.y, n2 = x2 * r * wv.z, n3 = x3 * r * wv.w;
  double ma = fmax(fmax(fabs(n0), fabs(n1)), fmax(fabs(n2), fabs(n3)));
  ma = bredd(ma, 1, tmp);
  double s = 127.0 / fmax(ma, 1e-5);
  ((int*)xq)[t * 256 + tid] = qpackd(n0, n1, n2, n3, s);
  if (tid == 0) xsd[t] = s;
}

// act_quant only (rows of 1024 floats), fp64 decisions
__global__ __launch_bounds__(256) void k_actq(const float* X, int8_t* xq, double* xsd) {
  __shared__ double tmp[4];
  int t = blockIdx.x, tid = threadIdx.x;
  float4 xv = ((const float4*)(X + (long long)t * H))[tid];
  double x0 = xv.x, x1 = xv.y, x2 = xv.z, x3 = xv.w;
  double ma = fmax(fmax(fabs(x0), fabs(x1)), fmax(fabs(x2), fabs(x3)));
  ma = bredd(ma, 1, tmp);
  double s = 127.0 / fmax(ma, 1e-5);
  ((int*)xq)[t * 256 + tid] = qpackd(x0, x1, x2, x3, s);
  if (tid == 0) xsd[t] = s;
}

// ---------------- int8 GEMM via MFMA: out[t,n] = res[t,n] + acc/(xs[t]*sw) -------
// BM=128 BN=128 BK=64. 4 waves 2x2; wave tile 64x64 = 2x2 mfma_i32_32x32x32_i8.

__global__ __launch_bounds__(256) void k_gemm(
    const int8_t* __restrict__ Xq, const double* __restrict__ xsd,
    const int8_t* __restrict__ W, const double* __restrict__ wsd, int widx,
    const float* __restrict__ residual, float* __restrict__ out) {
  __shared__ i32x4 Xs[4][128];
  __shared__ i32x4 Ws[4][128];
  int tid = threadIdx.x;
  int t0 = blockIdx.y * 128, n0 = blockIdx.x * 128;
  int w = tid >> 6, lane = tid & 63;
  int wm = w >> 1, wn = w & 1;
  int lrow = lane & 31, lk = lane >> 5;
  i32x16 acc[2][2];
#pragma unroll
  for (int i = 0; i < 2; i++)
#pragma unroll
    for (int j = 0; j < 2; j++)
#pragma unroll
      for (int r = 0; r < 16; r++) acc[i][j][r] = 0;

  for (int k0 = 0; k0 < 1024; k0 += 64) {
#pragma unroll
    for (int i = 0; i < 2; i++) {
      int u = tid * 2 + i;                 // 0..511
      int row = u >> 2, kc = u & 3;
      Xs[kc][row] = *(const i32x4*)(Xq + (long long)(t0 + row) * 1024 + k0 + kc * 16);
      Ws[kc][row] = *(const i32x4*)(W  + (long long)(n0 + row) * 1024 + k0 + kc * 16);
    }
    __syncthreads();
#pragma unroll
    for (int ks = 0; ks < 2; ks++) {
      i32x4 a0 = Xs[ks * 2 + lk][wm * 64 + lrow];
      i32x4 a1 = Xs[ks * 2 + lk][wm * 64 + 32 + lrow];
      i32x4 b0 = Ws[ks * 2 + lk][wn * 64 + lrow];
      i32x4 b1 = Ws[ks * 2 + lk][wn * 64 + 32 + lrow];
      acc[0][0] = mfma_i8(a0, b0, acc[0][0]);
      acc[0][1] = mfma_i8(a0, b1, acc[0][1]);
      acc[1][0] = mfma_i8(a1, b0, acc[1][0]);
      acc[1][1] = mfma_i8(a1, b1, acc[1][1]);
    }
    __syncthreads();
  }

  double sw = wsd[widx];
#pragma unroll
  for (int i = 0; i < 2; i++) {
#pragma unroll
    for (int r = 0; r < 16; r++) {
      int trow = t0 + wm * 64 + i * 32 + (r & 3) + 8 * (r >> 2) + 4 * lk;
      double inv = 1.0 / (xsd[trow] * sw);
#pragma unroll
      for (int j = 0; j < 2; j++) {
        int n = n0 + wn * 64 + j * 32 + lrow;
        double v = (double)acc[i][j][r] * inv;
        if (residual) v += (double)residual[(long long)trow * H + n];
        out[(long long)trow * H + n] = (float)v;
      }
    }
  }
}

// ---------------- attention ----------------
// k_knorm: per-(b,head) max key L2-norm -> fixed softmax bound.

__global__ __launch_bounds__(256) void k_knorm(const float* __restrict__ K,
                                               float* __restrict__ Mk) {
  __shared__ float tmp[4];
  int bh = blockIdx.x;          // b*16 + head
  int b = bh >> 4, head = bh & 15;
  int tid = threadIdx.x;
  float mx = 0.f;
  for (int key = tid; key < SEQ; key += 256) {
    const float4* kr = (const float4*)(K + ((long long)(b * SEQ + key)) * H + head * HD);
    float s = 0.f;
#pragma unroll
    for (int i = 0; i < 16; i++) {
      float4 v = kr[i];
      s += v.x * v.x + v.y * v.y + v.z * v.z + v.w * v.w;
    }
    mx = fmaxf(mx, s);
  }
#pragma unroll
  for (int o = 32; o; o >>= 1) mx = fmaxf(mx, __shfl_xor(mx, o));
  if ((tid & 63) == 0) tmp[tid >> 6] = mx;
  __syncthreads();
  if (tid == 0)
    Mk[bh] = sqrtf(fmaxf(fmaxf(tmp[0], tmp[1]), fmaxf(tmp[2], tmp[3])));
}

// k_attn (R12): R11 structure + DOUBLE-BF16 QK^T (R11's single-bf16 failed at
// absmax 0.17: logit rounding 2^-9*|q||k| is ~0.1-0.2). Split x = hi + lo
// (hi=bf16(x), lo=bf16(x-hi), ~17 mantissa bits combined); logit =
// Qlo*Khi + Qhi*Klo + Qhi*Khi via 3 MFMAs (lo*lo dropped, ~2^-18 rel).
// Logit error ~2e-4 -> fp32-grade. Everything else identical to R11:
// 512 uniform blocks (g=p & 31-p), 8 waves, 4-way key split, MFMA tile
// C layout col=lane&15=key / row=(lane>>4)*4+r=q (m89-verified), VALU
// softmax+PV reading broadcast logits from Plds, fixed-bound softmax,
// merge aliasing Plds/Vs. LDS 72.7KB -> 2 blocks/CU (same as R11).

__global__ __launch_bounds__(512) void k_attn(
    const float* __restrict__ Q, const float* __restrict__ K,
    const float* __restrict__ V, float* __restrict__ O,
    const float* __restrict__ Mk) {
  __shared__ float Plds[64][68];            // logits; merge publish buf A
  __shared__ float Vs[64][68];              // V tile fp32; merge publish buf B
  __shared__ unsigned short Kb[64][72];     // K tile bf16 hi
  __shared__ unsigned short Kl[64][72];     // K tile bf16 lo
  __shared__ unsigned short Qb[64][72];     // Q tile bf16 hi (x0.125)
  __shared__ unsigned short Ql[64][72];     // Q tile bf16 lo
  __shared__ float lsh[8][32];
  int i = blockIdx.x;
  int hb = (i & 7) | (((i >> 3) & 3) << 3);
  int p  = ((i >> 5) & 7) | (((i >> 8) & 1) << 3);
  int head = hb & 15, b = hb >> 4;
  int tid = threadIdx.x;
  int w = tid >> 6, lane = tid & 63;
  int qh = w >> 2, ks = w & 3;
  int quad = lane >> 2, dp = lane & 3;
  int d0 = dp << 4;
  int l15 = lane & 15, lhi = lane >> 4;
  long long bh_base = ((long long)b * SEQ) * H + head * HD;
  float mkv = Mk[b * 16 + head];

  int srow = tid >> 3;               // staging: row 0..63
  int sd = (tid & 7) << 3;           // staging: elem offset 0,8,..,56

  for (int ph = 0; ph < 2; ph++) {
    int g = ph ? (31 - p) : p;
    int qlo = g * 64;

    // stage Q tile as double-bf16 (x0.125), once per phase
    {
      const float* qg = Q + bh_base + (long long)(qlo + srow) * H + sd;
      float4 a = *(const float4*)qg;
      float4 c = *(const float4*)(qg + 4);
      uint4 phh, pll;
      phh.x = f2bf2hl(a.x * 0.125f, a.y * 0.125f, pll.x);
      phh.y = f2bf2hl(a.z * 0.125f, a.w * 0.125f, pll.y);
      phh.z = f2bf2hl(c.x * 0.125f, c.y * 0.125f, pll.z);
      phh.w = f2bf2hl(c.z * 0.125f, c.w * 0.125f, pll.w);
      *(uint4*)&Qb[srow][sd] = phh;
      *(uint4*)&Ql[srow][sd] = pll;
    }

    float mb[2], l[2] = {0.f, 0.f};
    float acc[2][16];
#pragma unroll
    for (int qq = 0; qq < 2; qq++)
#pragma unroll
      for (int i2 = 0; i2 < 16; i2++) acc[qq][i2] = 0.f;

    // fixed bound mb = 0.125*|q|*max|k| (fp32 norms, quad-local reduce)
    int j0 = qh * 32 + quad * 2, j1 = j0 + 1;
#pragma unroll
    for (int qq = 0; qq < 2; qq++) {
      int j = qh * 32 + quad * 2 + qq;
      const float4* qp_ = (const float4*)(Q + bh_base + (long long)(qlo + j) * H + d0);
      float ss = 0.f;
#pragma unroll
      for (int i2 = 0; i2 < 4; i2++) {
        float4 t = qp_[i2];
        ss += t.x * t.x + t.y * t.y + t.z * t.z + t.w * t.w;
      }
      ss += __shfl_xor(ss, 1);
      ss += __shfl_xor(ss, 2);
      mb[qq] = 0.125f * sqrtf(ss) * mkv;
    }

    for (int t = 0; t <= g; t++) {
      // ---- stage K (double-bf16) and V (fp32)
      {
        const float* kg = K + bh_base + (long long)(t * 64 + srow) * H + sd;
        const float* vg = V + bh_base + (long long)(t * 64 + srow) * H + sd;
        float4 ka = *(const float4*)kg;
        float4 kc = *(const float4*)(kg + 4);
        uint4 phh, pll;
        phh.x = f2bf2hl(ka.x, ka.y, pll.x);
        phh.y = f2bf2hl(ka.z, ka.w, pll.y);
        phh.z = f2bf2hl(kc.x, kc.y, pll.z);
        phh.w = f2bf2hl(kc.z, kc.w, pll.w);
        *(uint4*)&Kb[srow][sd] = phh;
        *(uint4*)&Kl[srow][sd] = pll;
        float4 va = *(const float4*)vg;
        float4 vc = *(const float4*)(vg + 4);
        *(float4*)&Vs[srow][sd] = va;
        *(float4*)&Vs[srow][sd + 4] = vc;
      }
      __syncthreads();

      // ---- MFMA QK^T -> Plds (3-term double-bf16). wave w: q-block w>>1,
      //      k-blocks (w&1)*2 + {0,1}
      {
        int qb = w >> 1;
#pragma unroll
        for (int kb2 = 0; kb2 < 2; kb2++) {
          int kb = (w & 1) * 2 + kb2;
          f32x4 c = {0.f, 0.f, 0.f, 0.f};
#pragma unroll
          for (int ks2 = 0; ks2 < 2; ks2++) {
            bf16x8 ah = *(const bf16x8*)&Qb[qb * 16 + l15][ks2 * 32 + lhi * 8];
            bf16x8 al = *(const bf16x8*)&Ql[qb * 16 + l15][ks2 * 32 + lhi * 8];
            bf16x8 bh = *(const bf16x8*)&Kb[kb * 16 + l15][ks2 * 32 + lhi * 8];
            bf16x8 bl = *(const bf16x8*)&Kl[kb * 16 + l15][ks2 * 32 + lhi * 8];
            c = __builtin_amdgcn_mfma_f32_16x16x32_bf16(al, bh, c, 0, 0, 0);
            c = __builtin_amdgcn_mfma_f32_16x16x32_bf16(ah, bl, c, 0, 0, 0);
            c = __builtin_amdgcn_mfma_f32_16x16x32_bf16(ah, bh, c, 0, 0, 0);
          }
#pragma unroll
          for (int r = 0; r < 4; r++)
            Plds[qb * 16 + lhi * 4 + r][kb * 16 + l15] = c[r];
        }
      }
      __syncthreads();

      // ---- VALU softmax + PV (reads logits from Plds)
      int kend = (t < g) ? 64 : (qh * 32 + 32);   // diagonal: qh=0 waves skip keys>=32
      for (int kk = ks; kk < kend; kk += 4) {
        float p0 = Plds[j0][kk];
        float p1 = Plds[j1][kk];
        const float4* vr = (const float4*)&Vs[kk][d0];
        float4 vv0 = vr[0], vv1 = vr[1], vv2 = vr[2], vv3 = vr[3];
        bool ok0 = (t < g) || (kk <= j0);
        bool ok1 = (t < g) || (kk <= j1);
        float wgt0 = ok0 ? __expf(p0 - mb[0]) : 0.f;
        float wgt1 = ok1 ? __expf(p1 - mb[1]) : 0.f;
        l[0] += wgt0;
        l[1] += wgt1;
        acc[0][0]  = fmaf(wgt0, vv0.x, acc[0][0]);
        acc[0][1]  = fmaf(wgt0, vv0.y, acc[0][1]);
        acc[0][2]  = fmaf(wgt0, vv0.z, acc[0][2]);
        acc[0][3]  = fmaf(wgt0, vv0.w, acc[0][3]);
        acc[0][4]  = fmaf(wgt0, vv1.x, acc[0][4]);
        acc[0][5]  = fmaf(wgt0, vv1.y, acc[0][5]);
        acc[0][6]  = fmaf(wgt0, vv1.z, acc[0][6]);
        acc[0][7]  = fmaf(wgt0, vv1.w, acc[0][7]);
        acc[0][8]  = fmaf(wgt0, vv2.x, acc[0][8]);
        acc[0][9]  = fmaf(wgt0, vv2.y, acc[0][9]);
        acc[0][10] = fmaf(wgt0, vv2.z, acc[0][10]);
        acc[0][11] = fmaf(wgt0, vv2.w, acc[0][11]);
        acc[0][12] = fmaf(wgt0, vv3.x, acc[0][12]);
        acc[0][13] = fmaf(wgt0, vv3.y, acc[0][13]);
        acc[0][14] = fmaf(wgt0, vv3.z, acc[0][14]);
        acc[0][15] = fmaf(wgt0, vv3.w, acc[0][15]);
        acc[1][0]  = fmaf(wgt1, vv0.x, acc[1][0]);
        acc[1][1]  = fmaf(wgt1, vv0.y, acc[1][1]);
        acc[1][2]  = fmaf(wgt1, vv0.z, acc[1][2]);
        acc[1][3]  = fmaf(wgt1, vv0.w, acc[1][3]);
        acc[1][4]  = fmaf(wgt1, vv1.x, acc[1][4]);
        acc[1][5]  = fmaf(wgt1, vv1.y, acc[1][5]);
        acc[1][6]  = fmaf(wgt1, vv1.z, acc[1][6]);
        acc[1][7]  = fmaf(wgt1, vv1.w, acc[1][7]);
        acc[1][8]  = fmaf(wgt1, vv2.x, acc[1][8]);
        acc[1][9]  = fmaf(wgt1, vv2.y, acc[1][9]);
        acc[1][10] = fmaf(wgt1, vv2.z, acc[1][10]);
        acc[1][11] = fmaf(wgt1, vv2.w, acc[1][11]);
        acc[1][12] = fmaf(wgt1, vv3.x, acc[1][12]);
        acc[1][13] = fmaf(wgt1, vv3.y, acc[1][13]);
        acc[1][14] = fmaf(wgt1, vv3.z, acc[1][14]);
        acc[1][15] = fmaf(wgt1, vv3.w, acc[1][15]);
      }
      __syncthreads();
    }

    // ---- 4-way merge (fixed bound => plain sums). Plds/Vs are dead; alias.
    if (dp == 0) {
      lsh[w][quad * 2 + 0] = l[0];
      lsh[w][quad * 2 + 1] = l[1];
    }
    if (ks >= 2) {                   // ks2 -> Plds, ks3 -> Vs
      float (*mrg)[68] = (ks == 2) ? Plds : Vs;
#pragma unroll
      for (int qq = 0; qq < 2; qq++) {
        int row = qh * 32 + quad * 2 + qq;
        float4* dst = (float4*)&mrg[row][d0];
#pragma unroll
        for (int i2 = 0; i2 < 4; i2++)
          dst[i2] = make_float4(acc[qq][4*i2], acc[qq][4*i2+1], acc[qq][4*i2+2], acc[qq][4*i2+3]);
      }
    }
    __syncthreads();
    if (ks == 0) {                   // fold ks2 partial
#pragma unroll
      for (int qq = 0; qq < 2; qq++) {
        int row = qh * 32 + quad * 2 + qq;
        const float4* src = (const float4*)&Plds[row][d0];
#pragma unroll
        for (int i2 = 0; i2 < 4; i2++) {
          float4 s = src[i2];
          acc[qq][4*i2+0] += s.x; acc[qq][4*i2+1] += s.y;
          acc[qq][4*i2+2] += s.z; acc[qq][4*i2+3] += s.w;
        }
      }
    }
    if (ks == 1) {                   // fold ks3 partial, republish to Vs
#pragma unroll
      for (int qq = 0; qq < 2; qq++) {
        int row = qh * 32 + quad * 2 + qq;
        float4* sp = (float4*)&Vs[row][d0];
#pragma unroll
        for (int i2 = 0; i2 < 4; i2++) {
          float4 s = sp[i2];
          sp[i2] = make_float4(acc[qq][4*i2+0] + s.x, acc[qq][4*i2+1] + s.y,
                               acc[qq][4*i2+2] + s.z, acc[qq][4*i2+3] + s.w);
        }
      }
    }
    __syncthreads();
    if (ks == 0) {                   // final fold + normalize + store
#pragma unroll
      for (int qq = 0; qq < 2; qq++) {
        int jl = quad * 2 + qq;
        int row = qh * 32 + jl;
        float lt = lsh[qh * 4 + 0][jl] + lsh[qh * 4 + 1][jl] +
                   lsh[qh * 4 + 2][jl] + lsh[qh * 4 + 3][jl];
        float inv = 1.f / lt;
        const float4* src = (const float4*)&Vs[row][d0];
        float4* op = (float4*)(O + bh_base + (long long)(qlo + row) * H + d0);
#pragma unroll
        for (int i2 = 0; i2 < 4; i2++) {
          float4 s = src[i2];
          op[i2] = make_float4((acc[qq][4*i2+0] + s.x) * inv, (acc[qq][4*i2+1] + s.y) * inv,
                               (acc[qq][4*i2+2] + s.z) * inv, (acc[qq][4*i2+3] + s.w) * inv);
        }
      }
    }
    __syncthreads();                 // smem/lsh reuse safe for next phase
  }
}

// ---------------- rmsnorm2 + router (argmax, fp64) + act_quant ----------------

__global__ __launch_bounds__(256) void k_rms2_router(
    const float* X2, const float* lnw, const float* rw,
    int8_t* xq, double* xsd, int* eidx) {
  __shared__ double tmp[4];
  __shared__ double xn[1024];
  __shared__ double logits[8];
  int t = blockIdx.x, tid = threadIdx.x;
  float4 xv = ((const float4*)(X2 + (long long)t * H))[tid];
  double x0 = xv.x, x1 = xv.y, x2 = xv.z, x3 = xv.w;
  double ss = x0 * x0 + x1 * x1 + x2 * x2 + x3 * x3;
  ss = bredd(ss, 0, tmp);
  double r = 1.0 / sqrt(ss * (1.0 / 1024.0) + 1e-5);
  float4 wv = ((const float4*)lnw)[tid];
  double n0 = x0 * r * wv.x, n1 = x1 * r * wv.y, n2 = x2 * r * wv.z, n3 = x3 * r * wv.w;
  xn[tid * 4 + 0] = n0; xn[tid * 4 + 1] = n1;
  xn[tid * 4 + 2] = n2; xn[tid * 4 + 3] = n3;
  double ma = fmax(fmax(fabs(n0), fabs(n1)), fmax(fabs(n2), fabs(n3)));
  ma = bredd(ma, 1, tmp);  // contains syncthreads -> xn visible
  double s = 127.0 / fmax(ma, 1e-5);
  ((int*)xq)[t * 256 + tid] = qpackd(n0, n1, n2, n3, s);
  if (tid == 0) xsd[t] = s;
  if (tid < 64) {
    int e = tid >> 3, i = tid & 7;
    const float* wr = rw + e * 1024;
    double p = 0.0;
    for (int h = i; h < 1024; h += 8) p += xn[h] * (double)wr[h];
    p += __shfl_xor(p, 1);
    p += __shfl_xor(p, 2);
    p += __shfl_xor(p, 4);
    if (i == 0) logits[e] = p;
  }
  __syncthreads();
  if (tid == 0) {
    double best = logits[0];
    int bi = 0;
    for (int e = 1; e < 8; e++)
      if (logits[e] > best) { best = logits[e]; bi = e; }
    eidx[t] = bi;
  }
}

// ---------------- MoE routing: group tokens by expert into padded 64-slot tiles ----
// meta[0] = ntile; meta[1+i] = expert of tile i. tokidx[slot] = token or -1 (pad).

__global__ __launch_bounds__(256) void k_route(const int* __restrict__ eidx,
                                               int* __restrict__ meta,
                                               int* __restrict__ tokidx) {
  __shared__ int cnt[8], pb[9], cur[8];
  int tid = threadIdx.x;
  if (tid < 8) cnt[tid] = 0;
  __syncthreads();
  for (int t = tid; t < NTOK; t += 256) atomicAdd(&cnt[eidx[t]], 1);
  __syncthreads();
  if (tid == 0) {
    pb[0] = 0;
    int nt = 0;
    for (int e = 0; e < 8; e++) {
      int tiles = (cnt[e] + 63) >> 6;
      for (int i = 0; i < tiles; i++) meta[1 + nt + i] = e;
      nt += tiles;
      pb[e + 1] = pb[e] + tiles * 64;
      cur[e] = pb[e];
    }
    meta[0] = nt;
  }
  __syncthreads();
  for (int s = tid; s < 4608; s += 256) tokidx[s] = -1;
  __syncthreads();
  for (int t = tid; t < NTOK; t += 256) {
    int e = eidx[t];
    int s = atomicAdd(&cur[e], 1);
    tokidx[s] = t;
  }
}

// ---------------- MoE gate+up GEMM via MFMA -> hh (fused relu(g)^2*u) ----------

__global__ __launch_bounds__(256) void k_moe_gu(
    const int8_t* __restrict__ Xq, const double* __restrict__ xsd,
    const int8_t* __restrict__ qw, const double* __restrict__ wsd,
    const int* __restrict__ meta, const int* __restrict__ tokidx,
    float* __restrict__ hhbuf) {
  __shared__ i32x4 Xs[4][64];
  __shared__ i32x4 Wg[4][128];
  __shared__ i32x4 Wu[4][128];
  int tile = blockIdx.y;
  if (tile >= meta[0]) return;
  int e = meta[1 + tile];
  int n0 = blockIdx.x * 128;
  int s0 = tile * 64;
  int tid = threadIdx.x;
  int w = tid >> 6, lane = tid & 63;
  int lrow = lane & 31, lk = lane >> 5;
  const int8_t* Gg = qw + ((long long)(4 + e) << 20);
  const int8_t* Ug = qw + ((long long)(12 + e) << 20);
  int xrow = tid >> 2, xkc = tid & 3;
  int tokr = tokidx[s0 + xrow];
  if (tokr < 0) tokr = 0;
  i32x16 accg[2], accu[2];
#pragma unroll
  for (int i = 0; i < 2; i++)
#pragma unroll
    for (int r = 0; r < 16; r++) { accg[i][r] = 0; accu[i][r] = 0; }

  for (int k0 = 0; k0 < 1024; k0 += 64) {
    Xs[xkc][xrow] = *(const i32x4*)(Xq + (long long)tokr * 1024 + k0 + xkc * 16);
#pragma unroll
    for (int i = 0; i < 2; i++) {
      int u = tid * 2 + i;                 // 0..511
      int row = u >> 2, kc = u & 3;
      Wg[kc][row] = *(const i32x4*)(Gg + (long long)(n0 + row) * 1024 + k0 + kc * 16);
      Wu[kc][row] = *(const i32x4*)(Ug + (long long)(n0 + row) * 1024 + k0 + kc * 16);
    }
    __syncthreads();
#pragma unroll
    for (int ks = 0; ks < 2; ks++) {
      i32x4 a0 = Xs[ks * 2 + lk][lrow];
      i32x4 a1 = Xs[ks * 2 + lk][32 + lrow];
      i32x4 bg = Wg[ks * 2 + lk][w * 32 + lrow];
      i32x4 bu = Wu[ks * 2 + lk][w * 32 + lrow];
      accg[0] = mfma_i8(a0, bg, accg[0]);
      accg[1] = mfma_i8(a1, bg, accg[1]);
      accu[0] = mfma_i8(a0, bu, accu[0]);
      accu[1] = mfma_i8(a1, bu, accu[1]);
    }
    __syncthreads();
  }

  double swg = wsd[4 + e], swu = wsd[12 + e];
  int n = n0 + w * 32 + lrow;
#pragma unroll
  for (int i = 0; i < 2; i++) {
#pragma unroll
    for (int r = 0; r < 16; r++) {
      int s = s0 + i * 32 + (r & 3) + 8 * (r >> 2) + 4 * lk;
      int tok = tokidx[s];
      if (tok < 0) continue;
      double ig = 1.0 / (xsd[tok] * swg);
      double iu = 1.0 / (xsd[tok] * swu);
      double g = (double)accg[i][r] * ig;
      double uu = (double)accu[i][r] * iu;
      double rg = fmax(g, 0.0);
      hhbuf[(long long)s * DDIM + n] = (float)(rg * rg * uu);
    }
  }
}

// ---------------- act_quant over hh slot rows ----------------

__global__ __launch_bounds__(256) void k_hh_actq(
    const float* __restrict__ hhbuf, const int* __restrict__ meta,
    const int* __restrict__ tokidx, int8_t* __restrict__ hq,
    double* __restrict__ hsd) {
  __shared__ double tmp[4];
  int s = blockIdx.x;
  if (s >= meta[0] * 64) return;
  int tid = threadIdx.x;
  int tok = tokidx[s];
  if (tok < 0) {
    ((int*)hq)[s * 256 + tid] = 0;
    if (tid == 0) hsd[s] = 1.0;
    return;
  }
  float4 xv = ((const float4*)(hhbuf + (long long)s * DDIM))[tid];
  double x0 = xv.x, x1 = xv.y, x2 = xv.z, x3 = xv.w;
  double ma = fmax(fmax(fabs(x0), fabs(x1)), fmax(fabs(x2), fabs(x3)));
  ma = bredd(ma, 1, tmp);
  double sc = 127.0 / fmax(ma, 1e-5);
  ((int*)hq)[s * 256 + tid] = qpackd(x0, x1, x2, x3, sc);
  if (tid == 0) hsd[s] = sc;
}

// ---------------- MoE down GEMM via MFMA + residual -> out (scatter) ------------

__global__ __launch_bounds__(256) void k_moe_down(
    const int8_t* __restrict__ hq, const double* __restrict__ hsd,
    const int8_t* __restrict__ qw, const double* __restrict__ wsd,
    const int* __restrict__ meta, const int* __restrict__ tokidx,
    const float* __restrict__ x2, float* __restrict__ out) {
  __shared__ i32x4 Xs[4][64];
  __shared__ i32x4 Ws[4][128];
  int tile = blockIdx.y;
  if (tile >= meta[0]) return;
  int e = meta[1 + tile];
  int n0 = blockIdx.x * 128;
  int s0 = tile * 64;
  int tid = threadIdx.x;
  int w = tid >> 6, lane = tid & 63;
  int lrow = lane & 31, lk = lane >> 5;
  const int8_t* Wp = qw + ((long long)(20 + e) << 20);
  int xrow = tid >> 2, xkc = tid & 3;
  i32x16 acc[2];
#pragma unroll
  for (int i = 0; i < 2; i++)
#pragma unroll
    for (int r = 0; r < 16; r++) acc[i][r] = 0;

  for (int k0 = 0; k0 < 1024; k0 += 64) {
    Xs[xkc][xrow] = *(const i32x4*)(hq + (long long)(s0 + xrow) * 1024 + k0 + xkc * 16);
#pragma unroll
    for (int i = 0; i < 2; i++) {
      int u = tid * 2 + i;
      int row = u >> 2, kc = u & 3;
      Ws[kc][row] = *(const i32x4*)(Wp + (long long)(n0 + row) * 1024 + k0 + kc * 16);
    }
    __syncthreads();
#pragma unroll
    for (int ks = 0; ks < 2; ks++) {
      i32x4 a0 = Xs[ks * 2 + lk][lrow];
      i32x4 a1 = Xs[ks * 2 + lk][32 + lrow];
      i32x4 b  = Ws[ks * 2 + lk][w * 32 + lrow];
      acc[0] = mfma_i8(a0, b, acc[0]);
      acc[1] = mfma_i8(a1, b, acc[1]);
    }
    __syncthreads();
  }

  double sw = wsd[20 + e];
  int n = n0 + w * 32 + lrow;
#pragma unroll
  for (int i = 0; i < 2; i++) {
#pragma unroll
    for (int r = 0; r < 16; r++) {
      int s = s0 + i * 32 + (r & 3) + 8 * (r >> 2) + 4 * lk;
      int tok = tokidx[s];
      if (tok < 0) continue;
      double inv = 1.0 / (hsd[s] * sw);
      out[(long long)tok * H + n] =
          (float)((double)x2[(long long)tok * H + n] + (double)acc[i][r] * inv);
    }
  }
}

// ---------------- launch ----------------
// ws layout (bytes):
//   0        partial double[28*1024] (224 KB)
//   229376   wsd double[28]
//   229600   xsd double[4096] (32 KB)
//   262368   eidx int[4096] (16 KB)
//   278752   Mk float[32]
//   278912   meta int[128]  (ntile + tile_e)
//   279424   tokidx int[4608] (18 KB)
//   297856   hsd double[4608] (36.9 KB)
//   1MB      qw int8: 28 x 1MB
//   29MB     xq int8 4MB
//   33MB     qbuf fp32 16MB (q -> attn out h); later hhbuf f32 [4544][1024] (18.6MB, 33..51.6)
//   49MB     kbuf fp32 16MB (k; dead after attn)
//   52MB     hq int8 [4544][1024] (4.65MB, 52..56.7)   <- inside dead kbuf region
//   65MB     vbuf fp32 16MB (v -> x2 residual)

extern "C" void kernel_launch(void* const* d_in, const int* in_sizes, int n_in,
                              void* d_out, int out_size, void* d_ws, size_t ws_size,
                              hipStream_t stream) {
  const float* x   = (const float*)d_in[0];
  const float* qw_ = (const float*)d_in[1];
  const float* kw_ = (const float*)d_in[2];
  const float* vw_ = (const float*)d_in[3];
  const float* ow_ = (const float*)d_in[4];
  const float* ln1 = (const float*)d_in[5];
  const float* ln2 = (const float*)d_in[6];
  const float* rw  = (const float*)d_in[7];
  const float* gw  = (const float*)d_in[8];
  const float* uw  = (const float*)d_in[9];
  const float* dw  = (const float*)d_in[10];
  float* out = (float*)d_out;

  uint8_t* ws = (uint8_t*)d_ws;
  double* partial = (double*)ws;
  double* wsd    = (double*)(ws + 229376);
  double* xsd    = (double*)(ws + 229600);
  int*    eidx   = (int*)(ws + 262368);
  float*  Mk     = (float*)(ws + 278752);
  int*    meta   = (int*)(ws + 278912);
  int*    tokidx = (int*)(ws + 279424);
  double* hsd    = (double*)(ws + 297856);
  int8_t* qw     = (int8_t*)(ws + (1ull << 20));
  int8_t* xq     = (int8_t*)(ws + (29ull << 20));
  float*  qbuf   = (float*)(ws + (33ull << 20));
  float*  hhbuf  = (float*)(ws + (33ull << 20));   // aliases qbuf (dead by then)
  float*  kbuf   = (float*)(ws + (49ull << 20));
  int8_t* hq     = (int8_t*)(ws + (52ull << 20));  // inside dead kbuf region
  float*  vbuf   = (float*)(ws + (65ull << 20));

  // weight quantization (deterministic fp64 scales)
  k_absum<<<28 * 1024, 256, 0, stream>>>(qw_, kw_, vw_, ow_, gw, uw, dw, partial);
  k_wscale<<<28, 256, 0, stream>>>(partial, wsd);
  k_quantw<<<28 * 1024, 256, 0, stream>>>(qw_, kw_, vw_, ow_, gw, uw, dw, wsd, qw);

  // attention input: rmsnorm + act_quant
  k_rms1<<<NTOK, 256, 0, stream>>>(x, ln1, xq, xsd);
  // q/k/v projections (exact int8 x ternary GEMM on MFMA)
  k_gemm<<<dim3(8, 32), 256, 0, stream>>>(xq, xsd, qw,             wsd, 0, nullptr, qbuf);
  k_gemm<<<dim3(8, 32), 256, 0, stream>>>(xq, xsd, qw + (1 << 20), wsd, 1, nullptr, kbuf);
  k_gemm<<<dim3(8, 32), 256, 0, stream>>>(xq, xsd, qw + (2 << 20), wsd, 2, nullptr, vbuf);
  // causal flash attention (double-bf16 MFMA QK^T + fixed-bound softmax)
  k_knorm<<<32, 256, 0, stream>>>(kbuf, Mk);
  k_attn<<<dim3(512), 512, 0, stream>>>(qbuf, kbuf, vbuf, qbuf, Mk);
  // o projection with residual: x2 = x + bitlinear(h, o_w) -> vbuf
  k_actq<<<NTOK, 256, 0, stream>>>(qbuf, xq, xsd);
  k_gemm<<<dim3(8, 32), 256, 0, stream>>>(xq, xsd, qw + (3 << 20), wsd, 3, x, vbuf);
  // MoE: rmsnorm2 + router argmax + act_quant, then expert-gathered GEMMs
  k_rms2_router<<<NTOK, 256, 0, stream>>>(vbuf, ln2, rw, xq, xsd, eidx);
  k_route<<<1, 256, 0, stream>>>(eidx, meta, tokidx);
  k_moe_gu<<<dim3(8, 71), 256, 0, stream>>>(xq, xsd, qw, wsd, meta, tokidx, hhbuf);
  k_hh_actq<<<4544, 256, 0, stream>>>(hhbuf, meta, tokidx, hq, hsd);
  k_moe_down<<<dim3(8, 71), 256, 0, stream>>>(hq, hsd, qw, wsd, meta, tokidx, vbuf, out);
}

// Round 7
// 572.565 us; speedup vs baseline: 2.4823x; 1.1322x over previous
//
#include <hip/hip_runtime.h>
#include <stdint.h>
#include <math.h>

// Problem constants
#define NTOK 4096   // B*S
#define H    1024
#define NHEAD 16
#define HD   64
#define SEQ  2048
#define NE   8
#define DDIM 1024

typedef __attribute__((ext_vector_type(4)))  int i32x4;
typedef __attribute__((ext_vector_type(16))) int i32x16;
typedef __attribute__((ext_vector_type(8)))  short bf16x8;
typedef __attribute__((ext_vector_type(4)))  float f32x4;

// ---------------- helpers ----------------

__device__ __forceinline__ i32x16 mfma_i8(i32x4 a, i32x4 b, i32x16 c) {
  return __builtin_amdgcn_mfma_i32_32x32x32_i8(a, b, c, 0, 0, 0);
}

// float -> bf16 round-to-nearest-even (finite inputs)
__device__ __forceinline__ unsigned int f2bf(float f) {
  unsigned int u = __float_as_uint(f);
  return (u + 0x7fffu + ((u >> 16) & 1u)) >> 16;
}
__device__ __forceinline__ float bf2f(unsigned int b) {
  return __uint_as_float(b << 16);
}
// pack hi-parts of (a,b) into return, lo-parts (residual bf16) into lo
__device__ __forceinline__ unsigned int f2bf2hl(float a, float b, unsigned int& lo) {
  unsigned int ha = f2bf(a), hb = f2bf(b);
  lo = f2bf(a - bf2f(ha)) | (f2bf(b - bf2f(hb)) << 16);
  return ha | (hb << 16);
}
// pack double-bf16 pair of one float: low ushort = hi, high ushort = lo
__device__ __forceinline__ unsigned int fpair(float a) {
  unsigned int hi = f2bf(a);
  unsigned int lo = f2bf(a - bf2f(hi));
  return hi | (lo << 16);
}
__device__ __forceinline__ unsigned int ror16(unsigned int x) {
  return (x >> 16) | (x << 16);
}

// 256-thread block reduce (double). op=0 sum, op=1 max. tmp: __shared__ double[4]
__device__ __forceinline__ double bredd(double v, int op, double* tmp) {
#pragma unroll
  for (int o = 32; o; o >>= 1) {
    double w = __shfl_xor(v, o);
    v = op ? fmax(v, w) : v + w;
  }
  int wid = threadIdx.x >> 6;
  if ((threadIdx.x & 63) == 0) tmp[wid] = v;
  __syncthreads();
  double r = op ? fmax(fmax(tmp[0], tmp[1]), fmax(tmp[2], tmp[3]))
                : (tmp[0] + tmp[1] + tmp[2] + tmp[3]);
  __syncthreads();
  return r;
}

// quantize 4 doubles to packed int8 with double scale (round-half-even like jnp.round)
__device__ __forceinline__ int qpackd(double n0, double n1, double n2, double n3, double s) {
  int a = (int)fmin(fmax(rint(n0 * s), -128.0), 127.0);
  int b = (int)fmin(fmax(rint(n1 * s), -128.0), 127.0);
  int c = (int)fmin(fmax(rint(n2 * s), -128.0), 127.0);
  int d = (int)fmin(fmax(rint(n3 * s), -128.0), 127.0);
  return (a & 255) | ((b & 255) << 8) | ((c & 255) << 16) | ((d & 255) << 24);
}

// map flat tensor id (0..27, each 1M elems) -> source pointer
__device__ __forceinline__ const float* wsrc(int tensor,
    const float* qw_, const float* kw_, const float* vw_, const float* ow_,
    const float* gw_, const float* uw_, const float* dw_) {
  if (tensor < 4) return tensor == 0 ? qw_ : tensor == 1 ? kw_ : tensor == 2 ? vw_ : ow_;
  if (tensor < 12) return gw_ + ((long long)(tensor - 4) << 20);
  if (tensor < 20) return uw_ + ((long long)(tensor - 12) << 20);
  return dw_ + ((long long)(tensor - 20) << 20);
}

// ---------------- weight quantization (fp64 scale, deterministic) ----------------

__global__ __launch_bounds__(256) void k_absum(
    const float* qw_, const float* kw_, const float* vw_, const float* ow_,
    const float* gw_, const float* uw_, const float* dw_, double* partial) {
  __shared__ double tmp[4];
  int tensor = blockIdx.x >> 10;
  int j = ((blockIdx.x & 1023) << 10) + threadIdx.x * 4;
  const float* src = wsrc(tensor, qw_, kw_, vw_, ow_, gw_, uw_, dw_);
  float4 w = *(const float4*)(src + j);
  double v = fabs((double)w.x) + fabs((double)w.y) + fabs((double)w.z) + fabs((double)w.w);
  v = bredd(v, 0, tmp);
  if (threadIdx.x == 0) partial[blockIdx.x] = v;
}

__global__ __launch_bounds__(256) void k_wscale(const double* partial, double* wsd) {
  __shared__ double tmp[4];
  int tensor = blockIdx.x;
  const double* p = partial + (tensor << 10);
  int i = threadIdx.x * 4;
  double v = p[i] + p[i + 1] + p[i + 2] + p[i + 3];
  v = bredd(v, 0, tmp);
  if (threadIdx.x == 0) wsd[tensor] = 1.0 / fmax(v * (1.0 / 1048576.0), 1e-5);
}

__global__ __launch_bounds__(256) void k_quantw(
    const float* qw_, const float* kw_, const float* vw_, const float* ow_,
    const float* gw_, const float* uw_, const float* dw_,
    const double* wsd, int8_t* qw) {
  int tensor = blockIdx.x >> 10;
  int j = ((blockIdx.x & 1023) << 10) + threadIdx.x * 4;
  const float* src = wsrc(tensor, qw_, kw_, vw_, ow_, gw_, uw_, dw_);
  double s = wsd[tensor];
  float4 w = *(const float4*)(src + j);
  int a = (int)fmin(fmax(rint((double)w.x * s), -1.0), 1.0);
  int b = (int)fmin(fmax(rint((double)w.y * s), -1.0), 1.0);
  int c = (int)fmin(fmax(rint((double)w.z * s), -1.0), 1.0);
  int d = (int)fmin(fmax(rint((double)w.w * s), -1.0), 1.0);
  ((int*)qw)[(tensor << 18) + (j >> 2)] =
      (a & 255) | ((b & 255) << 8) | ((c & 255) << 16) | ((d & 255) << 24);
}

// ---------------- rmsnorm + act_quant (attention input), fp64 decisions ----------------

__global__ __launch_bounds__(256) void k_rms1(const float* X, const float* lnw,
                                              int8_t* xq, double* xsd) {
  __shared__ double tmp[4];
  int t = blockIdx.x, tid = threadIdx.x;
  float4 xv = ((const float4*)(X + (long long)t * H))[tid];
  double x0 = xv.x, x1 = xv.y, x2 = xv.z, x3 = xv.w;
  double ss = x0 * x0 + x1 * x1 + x2 * x2 + x3 * x3;
  ss = bredd(ss, 0, tmp);
  double r = 1.0 / sqrt(ss * (1.0 / 1024.0) + 1e-5);
  float4 wv = ((const float4*)lnw)[tid];
  double n0 = x0 * r * wv.x, n1 = x1 * r * wv.y, n2 = x2 * r * wv.z, n3 = x3 * r * wv.w;
  double ma = fmax(fmax(fabs(n0), fabs(n1)), fmax(fabs(n2), fabs(n3)));
  ma = bredd(ma, 1, tmp);
  double s = 127.0 / fmax(ma, 1e-5);
  ((int*)xq)[t * 256 + tid] = qpackd(n0, n1, n2, n3, s);
  if (tid == 0) xsd[t] = s;
}

// act_quant only (rows of 1024 floats), fp64 decisions
__global__ __launch_bounds__(256) void k_actq(const float* X, int8_t* xq, double* xsd) {
  __shared__ double tmp[4];
  int t = blockIdx.x, tid = threadIdx.x;
  float4 xv = ((const float4*)(X + (long long)t * H))[tid];
  double x0 = xv.x, x1 = xv.y, x2 = xv.z, x3 = xv.w;
  double ma = fmax(fmax(fabs(x0), fabs(x1)), fmax(fabs(x2), fabs(x3)));
  ma = bredd(ma, 1, tmp);
  double s = 127.0 / fmax(ma, 1e-5);
  ((int*)xq)[t * 256 + tid] = qpackd(x0, x1, x2, x3, s);
  if (tid == 0) xsd[t] = s;
}

// ---------------- int8 GEMM via MFMA: out[t,n] = res[t,n] + acc/(xs[t]*sw) -------
// BM=128 BN=128 BK=64. 4 waves 2x2; wave tile 64x64 = 2x2 mfma_i32_32x32x32_i8.

__global__ __launch_bounds__(256) void k_gemm(
    const int8_t* __restrict__ Xq, const double* __restrict__ xsd,
    const int8_t* __restrict__ W, const double* __restrict__ wsd, int widx,
    const float* __restrict__ residual, float* __restrict__ out) {
  __shared__ i32x4 Xs[4][128];
  __shared__ i32x4 Ws[4][128];
  int tid = threadIdx.x;
  int t0 = blockIdx.y * 128, n0 = blockIdx.x * 128;
  int w = tid >> 6, lane = tid & 63;
  int wm = w >> 1, wn = w & 1;
  int lrow = lane & 31, lk = lane >> 5;
  i32x16 acc[2][2];
#pragma unroll
  for (int i = 0; i < 2; i++)
#pragma unroll
    for (int j = 0; j < 2; j++)
#pragma unroll
      for (int r = 0; r < 16; r++) acc[i][j][r] = 0;

  for (int k0 = 0; k0 < 1024; k0 += 64) {
#pragma unroll
    for (int i = 0; i < 2; i++) {
      int u = tid * 2 + i;                 // 0..511
      int row = u >> 2, kc = u & 3;
      Xs[kc][row] = *(const i32x4*)(Xq + (long long)(t0 + row) * 1024 + k0 + kc * 16);
      Ws[kc][row] = *(const i32x4*)(W  + (long long)(n0 + row) * 1024 + k0 + kc * 16);
    }
    __syncthreads();
#pragma unroll
    for (int ks = 0; ks < 2; ks++) {
      i32x4 a0 = Xs[ks * 2 + lk][wm * 64 + lrow];
      i32x4 a1 = Xs[ks * 2 + lk][wm * 64 + 32 + lrow];
      i32x4 b0 = Ws[ks * 2 + lk][wn * 64 + lrow];
      i32x4 b1 = Ws[ks * 2 + lk][wn * 64 + 32 + lrow];
      acc[0][0] = mfma_i8(a0, b0, acc[0][0]);
      acc[0][1] = mfma_i8(a0, b1, acc[0][1]);
      acc[1][0] = mfma_i8(a1, b0, acc[1][0]);
      acc[1][1] = mfma_i8(a1, b1, acc[1][1]);
    }
    __syncthreads();
  }

  double sw = wsd[widx];
#pragma unroll
  for (int i = 0; i < 2; i++) {
#pragma unroll
    for (int r = 0; r < 16; r++) {
      int trow = t0 + wm * 64 + i * 32 + (r & 3) + 8 * (r >> 2) + 4 * lk;
      double inv = 1.0 / (xsd[trow] * sw);
#pragma unroll
      for (int j = 0; j < 2; j++) {
        int n = n0 + wn * 64 + j * 32 + lrow;
        double v = (double)acc[i][j][r] * inv;
        if (residual) v += (double)residual[(long long)trow * H + n];
        out[(long long)trow * H + n] = (float)v;
      }
    }
  }
}

// ---------------- attention ----------------
// k_knorm: per-(b,head) max key L2-norm -> fixed softmax bound.

__global__ __launch_bounds__(256) void k_knorm(const float* __restrict__ K,
                                               float* __restrict__ Mk) {
  __shared__ float tmp[4];
  int bh = blockIdx.x;          // b*16 + head
  int b = bh >> 4, head = bh & 15;
  int tid = threadIdx.x;
  float mx = 0.f;
  for (int key = tid; key < SEQ; key += 256) {
    const float4* kr = (const float4*)(K + ((long long)(b * SEQ + key)) * H + head * HD);
    float s = 0.f;
#pragma unroll
    for (int i = 0; i < 16; i++) {
      float4 v = kr[i];
      s += v.x * v.x + v.y * v.y + v.z * v.z + v.w * v.w;
    }
    mx = fmaxf(mx, s);
  }
#pragma unroll
  for (int o = 32; o; o >>= 1) mx = fmaxf(mx, __shfl_xor(mx, o));
  if ((tid & 63) == 0) tmp[tid >> 6] = mx;
  __syncthreads();
  if (tid == 0)
    Mk[bh] = sqrtf(fmaxf(fmaxf(tmp[0], tmp[1]), fmaxf(tmp[2], tmp[3])));
}

// k_attn (R13): full-MFMA attention. 512 uniform blocks (g=p & 31-p), 8 waves.
// QK^T: double-bf16 3-term MFMA (R12, verified) -> logits in Pw (f32 words).
// Weight pass: 512 threads x 8 logits each (no redundancy): w = exp(p - mb[row]),
// lsum += w, then IN-PLACE repack each logit word as an interleaved double-bf16
// pair (hi | lo<<16) at the SAME word -> no extra barrier (per-thread word-private).
// PV: interleaved-pair MFMA trick: P word k = (Ph,Pl), V word k = (Vh,Vl):
//   mfma(P_int, V_int)        = sum Ph*Vh + Pl*Vl
//   mfma(P_int, ror16(V_int)) = sum Ph*Vl + Pl*Vh
// together the exact (Ph+Pl)(Vh+Vl) product (~2^-17 rel), fp32-accumulated into
// per-wave O frags held across tiles (no key split, no merge tree). V staged
// transposed as pairs VA[d][key] (B-operand needs [d][k]); stride 76 words keeps
// b128 frag reads aligned. l: register running sums, 3-shfl reduce at the end.
// C/D layouts all from the m89-verified mapping (same as QK in R12).

__global__ __launch_bounds__(512, 4) void k_attn(
    const float* __restrict__ Q, const float* __restrict__ K,
    const float* __restrict__ V, float* __restrict__ O,
    const float* __restrict__ Mk) {
  __shared__ unsigned short Qb[64][72];     // Q bf16 hi (x0.125)
  __shared__ unsigned short Ql[64][72];     // Q bf16 lo
  __shared__ unsigned short Kb[64][72];     // K bf16 hi
  __shared__ unsigned short Kl[64][72];     // K bf16 lo
  __shared__ unsigned int   VA[64][76];     // V^T pairs: VA[d][key] = Vh | Vl<<16
  __shared__ unsigned int   Pw[64][76];     // logits f32, then weight pairs (in-place)
  __shared__ float mbs[64];
  __shared__ float lred[64];
  int i = blockIdx.x;
  int hb = (i & 7) | (((i >> 3) & 3) << 3);
  int p  = ((i >> 5) & 7) | (((i >> 8) & 1) << 3);
  int head = hb & 15, b = hb >> 4;
  int tid = threadIdx.x;
  int w = tid >> 6, lane = tid & 63;
  int quad = lane >> 2, dp = lane & 3;
  int d0 = dp << 4;
  int l15 = lane & 15, lhi = lane >> 4;
  int qh = w >> 2, ks = w & 3;
  long long bh_base = ((long long)b * SEQ) * H + head * HD;
  float mkv = Mk[b * 16 + head];

  int srow = tid >> 3;               // staging / weight row 0..63
  int sd = (tid & 7) << 3;           // staging elem offset 0,8,..,56
  int wc = tid & 7;                  // weight chunk 0..7

  for (int ph = 0; ph < 2; ph++) {
    int g = ph ? (31 - p) : p;
    int qlo = g * 64;

    // stage Q tile as double-bf16 (x0.125), once per phase
    {
      const float* qg = Q + bh_base + (long long)(qlo + srow) * H + sd;
      float4 a = *(const float4*)qg;
      float4 c = *(const float4*)(qg + 4);
      uint4 phh, pll;
      phh.x = f2bf2hl(a.x * 0.125f, a.y * 0.125f, pll.x);
      phh.y = f2bf2hl(a.z * 0.125f, a.w * 0.125f, pll.y);
      phh.z = f2bf2hl(c.x * 0.125f, c.y * 0.125f, pll.z);
      phh.w = f2bf2hl(c.z * 0.125f, c.w * 0.125f, pll.w);
      *(uint4*)&Qb[srow][sd] = phh;
      *(uint4*)&Ql[srow][sd] = pll;
    }

    // fixed bound mb = 0.125*|q|*max|k| into mbs[] (ks==0 waves cover all rows)
    if (ks == 0) {
      int j0 = qh * 32 + quad * 2;
#pragma unroll
      for (int qq = 0; qq < 2; qq++) {
        int j = j0 + qq;
        const float4* qp_ = (const float4*)(Q + bh_base + (long long)(qlo + j) * H + d0);
        float ss = 0.f;
#pragma unroll
        for (int i2 = 0; i2 < 4; i2++) {
          float4 t = qp_[i2];
          ss += t.x * t.x + t.y * t.y + t.z * t.z + t.w * t.w;
        }
        ss += __shfl_xor(ss, 1);
        ss += __shfl_xor(ss, 2);
        if (dp == 0) mbs[j] = 0.125f * sqrtf(ss) * mkv;
      }
    }

    float lsum = 0.f;
    f32x4 oacc[2];
#pragma unroll
    for (int fi = 0; fi < 2; fi++)
#pragma unroll
      for (int r = 0; r < 4; r++) oacc[fi][r] = 0.f;

    __syncthreads();   // Qb/Ql/mbs visible

    for (int t = 0; t <= g; t++) {
      // ---- stage K (double-bf16) and V (transposed interleaved pairs)
      {
        const float* kg = K + bh_base + (long long)(t * 64 + srow) * H + sd;
        const float* vg = V + bh_base + (long long)(t * 64 + srow) * H + sd;
        float4 ka = *(const float4*)kg;
        float4 kc = *(const float4*)(kg + 4);
        uint4 phh, pll;
        phh.x = f2bf2hl(ka.x, ka.y, pll.x);
        phh.y = f2bf2hl(ka.z, ka.w, pll.y);
        phh.z = f2bf2hl(kc.x, kc.y, pll.z);
        phh.w = f2bf2hl(kc.z, kc.w, pll.w);
        *(uint4*)&Kb[srow][sd] = phh;
        *(uint4*)&Kl[srow][sd] = pll;
        float4 va = *(const float4*)vg;
        float4 vc = *(const float4*)(vg + 4);
        VA[sd + 0][srow] = fpair(va.x);
        VA[sd + 1][srow] = fpair(va.y);
        VA[sd + 2][srow] = fpair(va.z);
        VA[sd + 3][srow] = fpair(va.w);
        VA[sd + 4][srow] = fpair(vc.x);
        VA[sd + 5][srow] = fpair(vc.y);
        VA[sd + 6][srow] = fpair(vc.z);
        VA[sd + 7][srow] = fpair(vc.w);
      }
      __syncthreads();

      // ---- QK^T MFMA (3-term double-bf16) -> Pw (f32 logits)
      {
        int qb = w >> 1;
#pragma unroll
        for (int kb2 = 0; kb2 < 2; kb2++) {
          int kb = (w & 1) * 2 + kb2;
          f32x4 c = {0.f, 0.f, 0.f, 0.f};
#pragma unroll
          for (int ks2 = 0; ks2 < 2; ks2++) {
            bf16x8 ah = *(const bf16x8*)&Qb[qb * 16 + l15][ks2 * 32 + lhi * 8];
            bf16x8 al = *(const bf16x8*)&Ql[qb * 16 + l15][ks2 * 32 + lhi * 8];
            bf16x8 bh = *(const bf16x8*)&Kb[kb * 16 + l15][ks2 * 32 + lhi * 8];
            bf16x8 bl = *(const bf16x8*)&Kl[kb * 16 + l15][ks2 * 32 + lhi * 8];
            c = __builtin_amdgcn_mfma_f32_16x16x32_bf16(al, bh, c, 0, 0, 0);
            c = __builtin_amdgcn_mfma_f32_16x16x32_bf16(ah, bl, c, 0, 0, 0);
            c = __builtin_amdgcn_mfma_f32_16x16x32_bf16(ah, bh, c, 0, 0, 0);
          }
#pragma unroll
          for (int r = 0; r < 4; r++)
            Pw[qb * 16 + lhi * 4 + r][kb * 16 + l15] = __float_as_uint(c[r]);
        }
      }
      __syncthreads();

      // ---- weight pass: thread (srow, wc): 8 logits -> weights, in-place pairs
      {
        float mbr = mbs[srow];
        uint4 pa = *(const uint4*)&Pw[srow][wc * 8];
        uint4 pb = *(const uint4*)&Pw[srow][wc * 8 + 4];
        float pv0 = __uint_as_float(pa.x), pv1 = __uint_as_float(pa.y);
        float pv2 = __uint_as_float(pa.z), pv3 = __uint_as_float(pa.w);
        float pv4 = __uint_as_float(pb.x), pv5 = __uint_as_float(pb.y);
        float pv6 = __uint_as_float(pb.z), pv7 = __uint_as_float(pb.w);
        int kbase = wc * 8;
        bool dg = (t == g);
        float w0 = (dg && kbase + 0 > srow) ? 0.f : __expf(pv0 - mbr);
        float w1 = (dg && kbase + 1 > srow) ? 0.f : __expf(pv1 - mbr);
        float w2 = (dg && kbase + 2 > srow) ? 0.f : __expf(pv2 - mbr);
        float w3 = (dg && kbase + 3 > srow) ? 0.f : __expf(pv3 - mbr);
        float w4 = (dg && kbase + 4 > srow) ? 0.f : __expf(pv4 - mbr);
        float w5 = (dg && kbase + 5 > srow) ? 0.f : __expf(pv5 - mbr);
        float w6 = (dg && kbase + 6 > srow) ? 0.f : __expf(pv6 - mbr);
        float w7 = (dg && kbase + 7 > srow) ? 0.f : __expf(pv7 - mbr);
        lsum += ((w0 + w1) + (w2 + w3)) + ((w4 + w5) + (w6 + w7));
        uint4 oa, ob;
        oa.x = fpair(w0); oa.y = fpair(w1); oa.z = fpair(w2); oa.w = fpair(w3);
        ob.x = fpair(w4); ob.y = fpair(w5); ob.z = fpair(w6); ob.w = fpair(w7);
        *(uint4*)&Pw[srow][wc * 8] = oa;
        *(uint4*)&Pw[srow][wc * 8 + 4] = ob;
      }
      __syncthreads();

      // ---- PV MFMA: frag f = w*2+fi: q-block f>>2, d-block f&3
#pragma unroll
      for (int fi = 0; fi < 2; fi++) {
        int f = w * 2 + fi;
        int q4 = f >> 2, d4 = f & 3;
#pragma unroll
        for (int c4 = 0; c4 < 4; c4++) {
          bf16x8 af = *(const bf16x8*)&Pw[q4 * 16 + l15][c4 * 16 + lhi * 4];
          union { unsigned int u[4]; bf16x8 v; } bb, bs;
#pragma unroll
          for (int j = 0; j < 4; j++)
            bb.u[j] = VA[d4 * 16 + l15][c4 * 16 + lhi * 4 + j];
          oacc[fi] = __builtin_amdgcn_mfma_f32_16x16x32_bf16(af, bb.v, oacc[fi], 0, 0, 0);
#pragma unroll
          for (int j = 0; j < 4; j++)
            bs.u[j] = ror16(bb.u[j]);
          oacc[fi] = __builtin_amdgcn_mfma_f32_16x16x32_bf16(af, bs.v, oacc[fi], 0, 0, 0);
        }
      }
      __syncthreads();
    }

    // ---- l reduce (over wc chunks) and O epilogue
    lsum += __shfl_xor(lsum, 1);
    lsum += __shfl_xor(lsum, 2);
    lsum += __shfl_xor(lsum, 4);
    if ((lane & 7) == 0) lred[srow] = lsum;
    __syncthreads();
#pragma unroll
    for (int fi = 0; fi < 2; fi++) {
      int f = w * 2 + fi;
      int q4 = f >> 2, d4 = f & 3;
#pragma unroll
      for (int r = 0; r < 4; r++) {
        int qrow = q4 * 16 + lhi * 4 + r;
        float inv = 1.f / lred[qrow];
        O[bh_base + (long long)(qlo + qrow) * H + d4 * 16 + l15] = oacc[fi][r] * inv;
      }
    }
    __syncthreads();                 // LDS reuse safe for next phase
  }
}

// ---------------- rmsnorm2 + router (argmax, fp64) + act_quant ----------------

__global__ __launch_bounds__(256) void k_rms2_router(
    const float* X2, const float* lnw, const float* rw,
    int8_t* xq, double* xsd, int* eidx) {
  __shared__ double tmp[4];
  __shared__ double xn[1024];
  __shared__ double logits[8];
  int t = blockIdx.x, tid = threadIdx.x;
  float4 xv = ((const float4*)(X2 + (long long)t * H))[tid];
  double x0 = xv.x, x1 = xv.y, x2 = xv.z, x3 = xv.w;
  double ss = x0 * x0 + x1 * x1 + x2 * x2 + x3 * x3;
  ss = bredd(ss, 0, tmp);
  double r = 1.0 / sqrt(ss * (1.0 / 1024.0) + 1e-5);
  float4 wv = ((const float4*)lnw)[tid];
  double n0 = x0 * r * wv.x, n1 = x1 * r * wv.y, n2 = x2 * r * wv.z, n3 = x3 * r * wv.w;
  xn[tid * 4 + 0] = n0; xn[tid * 4 + 1] = n1;
  xn[tid * 4 + 2] = n2; xn[tid * 4 + 3] = n3;
  double ma = fmax(fmax(fabs(n0), fabs(n1)), fmax(fabs(n2), fabs(n3)));
  ma = bredd(ma, 1, tmp);  // contains syncthreads -> xn visible
  double s = 127.0 / fmax(ma, 1e-5);
  ((int*)xq)[t * 256 + tid] = qpackd(n0, n1, n2, n3, s);
  if (tid == 0) xsd[t] = s;
  if (tid < 64) {
    int e = tid >> 3, i = tid & 7;
    const float* wr = rw + e * 1024;
    double p = 0.0;
    for (int h = i; h < 1024; h += 8) p += xn[h] * (double)wr[h];
    p += __shfl_xor(p, 1);
    p += __shfl_xor(p, 2);
    p += __shfl_xor(p, 4);
    if (i == 0) logits[e] = p;
  }
  __syncthreads();
  if (tid == 0) {
    double best = logits[0];
    int bi = 0;
    for (int e = 1; e < 8; e++)
      if (logits[e] > best) { best = logits[e]; bi = e; }
    eidx[t] = bi;
  }
}

// ---------------- MoE routing: group tokens by expert into padded 64-slot tiles ----
// meta[0] = ntile; meta[1+i] = expert of tile i. tokidx[slot] = token or -1 (pad).

__global__ __launch_bounds__(256) void k_route(const int* __restrict__ eidx,
                                               int* __restrict__ meta,
                                               int* __restrict__ tokidx) {
  __shared__ int cnt[8], pb[9], cur[8];
  int tid = threadIdx.x;
  if (tid < 8) cnt[tid] = 0;
  __syncthreads();
  for (int t = tid; t < NTOK; t += 256) atomicAdd(&cnt[eidx[t]], 1);
  __syncthreads();
  if (tid == 0) {
    pb[0] = 0;
    int nt = 0;
    for (int e = 0; e < 8; e++) {
      int tiles = (cnt[e] + 63) >> 6;
      for (int i = 0; i < tiles; i++) meta[1 + nt + i] = e;
      nt += tiles;
      pb[e + 1] = pb[e] + tiles * 64;
      cur[e] = pb[e];
    }
    meta[0] = nt;
  }
  __syncthreads();
  for (int s = tid; s < 4608; s += 256) tokidx[s] = -1;
  __syncthreads();
  for (int t = tid; t < NTOK; t += 256) {
    int e = eidx[t];
    int s = atomicAdd(&cur[e], 1);
    tokidx[s] = t;
  }
}

// ---------------- MoE gate+up GEMM via MFMA -> hh (fused relu(g)^2*u) ----------

__global__ __launch_bounds__(256) void k_moe_gu(
    const int8_t* __restrict__ Xq, const double* __restrict__ xsd,
    const int8_t* __restrict__ qw, const double* __restrict__ wsd,
    const int* __restrict__ meta, const int* __restrict__ tokidx,
    float* __restrict__ hhbuf) {
  __shared__ i32x4 Xs[4][64];
  __shared__ i32x4 Wg[4][128];
  __shared__ i32x4 Wu[4][128];
  int tile = blockIdx.y;
  if (tile >= meta[0]) return;
  int e = meta[1 + tile];
  int n0 = blockIdx.x * 128;
  int s0 = tile * 64;
  int tid = threadIdx.x;
  int w = tid >> 6, lane = tid & 63;
  int lrow = lane & 31, lk = lane >> 5;
  const int8_t* Gg = qw + ((long long)(4 + e) << 20);
  const int8_t* Ug = qw + ((long long)(12 + e) << 20);
  int xrow = tid >> 2, xkc = tid & 3;
  int tokr = tokidx[s0 + xrow];
  if (tokr < 0) tokr = 0;
  i32x16 accg[2], accu[2];
#pragma unroll
  for (int i = 0; i < 2; i++)
#pragma unroll
    for (int r = 0; r < 16; r++) { accg[i][r] = 0; accu[i][r] = 0; }

  for (int k0 = 0; k0 < 1024; k0 += 64) {
    Xs[xkc][xrow] = *(const i32x4*)(Xq + (long long)tokr * 1024 + k0 + xkc * 16);
#pragma unroll
    for (int i = 0; i < 2; i++) {
      int u = tid * 2 + i;                 // 0..511
      int row = u >> 2, kc = u & 3;
      Wg[kc][row] = *(const i32x4*)(Gg + (long long)(n0 + row) * 1024 + k0 + kc * 16);
      Wu[kc][row] = *(const i32x4*)(Ug + (long long)(n0 + row) * 1024 + k0 + kc * 16);
    }
    __syncthreads();
#pragma unroll
    for (int ks = 0; ks < 2; ks++) {
      i32x4 a0 = Xs[ks * 2 + lk][lrow];
      i32x4 a1 = Xs[ks * 2 + lk][32 + lrow];
      i32x4 bg = Wg[ks * 2 + lk][w * 32 + lrow];
      i32x4 bu = Wu[ks * 2 + lk][w * 32 + lrow];
      accg[0] = mfma_i8(a0, bg, accg[0]);
      accg[1] = mfma_i8(a1, bg, accg[1]);
      accu[0] = mfma_i8(a0, bu, accu[0]);
      accu[1] = mfma_i8(a1, bu, accu[1]);
    }
    __syncthreads();
  }

  double swg = wsd[4 + e], swu = wsd[12 + e];
  int n = n0 + w * 32 + lrow;
#pragma unroll
  for (int i = 0; i < 2; i++) {
#pragma unroll
    for (int r = 0; r < 16; r++) {
      int s = s0 + i * 32 + (r & 3) + 8 * (r >> 2) + 4 * lk;
      int tok = tokidx[s];
      if (tok < 0) continue;
      double ig = 1.0 / (xsd[tok] * swg);
      double iu = 1.0 / (xsd[tok] * swu);
      double g = (double)accg[i][r] * ig;
      double uu = (double)accu[i][r] * iu;
      double rg = fmax(g, 0.0);
      hhbuf[(long long)s * DDIM + n] = (float)(rg * rg * uu);
    }
  }
}

// ---------------- act_quant over hh slot rows ----------------

__global__ __launch_bounds__(256) void k_hh_actq(
    const float* __restrict__ hhbuf, const int* __restrict__ meta,
    const int* __restrict__ tokidx, int8_t* __restrict__ hq,
    double* __restrict__ hsd) {
  __shared__ double tmp[4];
  int s = blockIdx.x;
  if (s >= meta[0] * 64) return;
  int tid = threadIdx.x;
  int tok = tokidx[s];
  if (tok < 0) {
    ((int*)hq)[s * 256 + tid] = 0;
    if (tid == 0) hsd[s] = 1.0;
    return;
  }
  float4 xv = ((const float4*)(hhbuf + (long long)s * DDIM))[tid];
  double x0 = xv.x, x1 = xv.y, x2 = xv.z, x3 = xv.w;
  double ma = fmax(fmax(fabs(x0), fabs(x1)), fmax(fabs(x2), fabs(x3)));
  ma = bredd(ma, 1, tmp);
  double sc = 127.0 / fmax(ma, 1e-5);
  ((int*)hq)[s * 256 + tid] = qpackd(x0, x1, x2, x3, sc);
  if (tid == 0) hsd[s] = sc;
}

// ---------------- MoE down GEMM via MFMA + residual -> out (scatter) ------------

__global__ __launch_bounds__(256) void k_moe_down(
    const int8_t* __restrict__ hq, const double* __restrict__ hsd,
    const int8_t* __restrict__ qw, const double* __restrict__ wsd,
    const int* __restrict__ meta, const int* __restrict__ tokidx,
    const float* __restrict__ x2, float* __restrict__ out) {
  __shared__ i32x4 Xs[4][64];
  __shared__ i32x4 Ws[4][128];
  int tile = blockIdx.y;
  if (tile >= meta[0]) return;
  int e = meta[1 + tile];
  int n0 = blockIdx.x * 128;
  int s0 = tile * 64;
  int tid = threadIdx.x;
  int w = tid >> 6, lane = tid & 63;
  int lrow = lane & 31, lk = lane >> 5;
  const int8_t* Wp = qw + ((long long)(20 + e) << 20);
  int xrow = tid >> 2, xkc = tid & 3;
  i32x16 acc[2];
#pragma unroll
  for (int i = 0; i < 2; i++)
#pragma unroll
    for (int r = 0; r < 16; r++) acc[i][r] = 0;

  for (int k0 = 0; k0 < 1024; k0 += 64) {
    Xs[xkc][xrow] = *(const i32x4*)(hq + (long long)(s0 + xrow) * 1024 + k0 + xkc * 16);
#pragma unroll
    for (int i = 0; i < 2; i++) {
      int u = tid * 2 + i;
      int row = u >> 2, kc = u & 3;
      Ws[kc][row] = *(const i32x4*)(Wp + (long long)(n0 + row) * 1024 + k0 + kc * 16);
    }
    __syncthreads();
#pragma unroll
    for (int ks = 0; ks < 2; ks++) {
      i32x4 a0 = Xs[ks * 2 + lk][lrow];
      i32x4 a1 = Xs[ks * 2 + lk][32 + lrow];
      i32x4 b  = Ws[ks * 2 + lk][w * 32 + lrow];
      acc[0] = mfma_i8(a0, b, acc[0]);
      acc[1] = mfma_i8(a1, b, acc[1]);
    }
    __syncthreads();
  }

  double sw = wsd[20 + e];
  int n = n0 + w * 32 + lrow;
#pragma unroll
  for (int i = 0; i < 2; i++) {
#pragma unroll
    for (int r = 0; r < 16; r++) {
      int s = s0 + i * 32 + (r & 3) + 8 * (r >> 2) + 4 * lk;
      int tok = tokidx[s];
      if (tok < 0) continue;
      double inv = 1.0 / (hsd[s] * sw);
      out[(long long)tok * H + n] =
          (float)((double)x2[(long long)tok * H + n] + (double)acc[i][r] * inv);
    }
  }
}

// ---------------- launch ----------------
// ws layout (bytes):
//   0        partial double[28*1024] (224 KB)
//   229376   wsd double[28]
//   229600   xsd double[4096] (32 KB)
//   262368   eidx int[4096] (16 KB)
//   278752   Mk float[32]
//   278912   meta int[128]  (ntile + tile_e)
//   279424   tokidx int[4608] (18 KB)
//   297856   hsd double[4608] (36.9 KB)
//   1MB      qw int8: 28 x 1MB
//   29MB     xq int8 4MB
//   33MB     qbuf fp32 16MB (q -> attn out h); later hhbuf f32 [4544][1024] (18.6MB, 33..51.6)
//   49MB     kbuf fp32 16MB (k; dead after attn)
//   52MB     hq int8 [4544][1024] (4.65MB, 52..56.7)   <- inside dead kbuf region
//   65MB     vbuf fp32 16MB (v -> x2 residual)

extern "C" void kernel_launch(void* const* d_in, const int* in_sizes, int n_in,
                              void* d_out, int out_size, void* d_ws, size_t ws_size,
                              hipStream_t stream) {
  const float* x   = (const float*)d_in[0];
  const float* qw_ = (const float*)d_in[1];
  const float* kw_ = (const float*)d_in[2];
  const float* vw_ = (const float*)d_in[3];
  const float* ow_ = (const float*)d_in[4];
  const float* ln1 = (const float*)d_in[5];
  const float* ln2 = (const float*)d_in[6];
  const float* rw  = (const float*)d_in[7];
  const float* gw  = (const float*)d_in[8];
  const float* uw  = (const float*)d_in[9];
  const float* dw  = (const float*)d_in[10];
  float* out = (float*)d_out;

  uint8_t* ws = (uint8_t*)d_ws;
  double* partial = (double*)ws;
  double* wsd    = (double*)(ws + 229376);
  double* xsd    = (double*)(ws + 229600);
  int*    eidx   = (int*)(ws + 262368);
  float*  Mk     = (float*)(ws + 278752);
  int*    meta   = (int*)(ws + 278912);
  int*    tokidx = (int*)(ws + 279424);
  double* hsd    = (double*)(ws + 297856);
  int8_t* qw     = (int8_t*)(ws + (1ull << 20));
  int8_t* xq     = (int8_t*)(ws + (29ull << 20));
  float*  qbuf   = (float*)(ws + (33ull << 20));
  float*  hhbuf  = (float*)(ws + (33ull << 20));   // aliases qbuf (dead by then)
  float*  kbuf   = (float*)(ws + (49ull << 20));
  int8_t* hq     = (int8_t*)(ws + (52ull << 20));  // inside dead kbuf region
  float*  vbuf   = (float*)(ws + (65ull << 20));

  // weight quantization (deterministic fp64 scales)
  k_absum<<<28 * 1024, 256, 0, stream>>>(qw_, kw_, vw_, ow_, gw, uw, dw, partial);
  k_wscale<<<28, 256, 0, stream>>>(partial, wsd);
  k_quantw<<<28 * 1024, 256, 0, stream>>>(qw_, kw_, vw_, ow_, gw, uw, dw, wsd, qw);

  // attention input: rmsnorm + act_quant
  k_rms1<<<NTOK, 256, 0, stream>>>(x, ln1, xq, xsd);
  // q/k/v projections (exact int8 x ternary GEMM on MFMA)
  k_gemm<<<dim3(8, 32), 256, 0, stream>>>(xq, xsd, qw,             wsd, 0, nullptr, qbuf);
  k_gemm<<<dim3(8, 32), 256, 0, stream>>>(xq, xsd, qw + (1 << 20), wsd, 1, nullptr, kbuf);
  k_gemm<<<dim3(8, 32), 256, 0, stream>>>(xq, xsd, qw + (2 << 20), wsd, 2, nullptr, vbuf);
  // causal flash attention (full-MFMA: double-bf16 QK^T + interleaved-pair PV)
  k_knorm<<<32, 256, 0, stream>>>(kbuf, Mk);
  k_attn<<<dim3(512), 512, 0, stream>>>(qbuf, kbuf, vbuf, qbuf, Mk);
  // o projection with residual: x2 = x + bitlinear(h, o_w) -> vbuf
  k_actq<<<NTOK, 256, 0, stream>>>(qbuf, xq, xsd);
  k_gemm<<<dim3(8, 32), 256, 0, stream>>>(xq, xsd, qw + (3 << 20), wsd, 3, x, vbuf);
  // MoE: rmsnorm2 + router argmax + act_quant, then expert-gathered GEMMs
  k_rms2_router<<<NTOK, 256, 0, stream>>>(vbuf, ln2, rw, xq, xsd, eidx);
  k_route<<<1, 256, 0, stream>>>(eidx, meta, tokidx);
  k_moe_gu<<<dim3(8, 71), 256, 0, stream>>>(xq, xsd, qw, wsd, meta, tokidx, hhbuf);
  k_hh_actq<<<4544, 256, 0, stream>>>(hhbuf, meta, tokidx, hq, hsd);
  k_moe_down<<<dim3(8, 71), 256, 0, stream>>>(hq, hsd, qw, wsd, meta, tokidx, vbuf, out);
}

// Round 9
// 529.728 us; speedup vs baseline: 2.6830x; 1.0809x over previous
//
#include <hip/hip_runtime.h>
#include <stdint.h>
#include <math.h>

// Problem constants
#define NTOK 4096   // B*S
#define H    1024
#define NHEAD 16
#define HD   64
#define SEQ  2048
#define NE   8
#define DDIM 1024

typedef __attribute__((ext_vector_type(4)))  int i32x4;
typedef __attribute__((ext_vector_type(16))) int i32x16;
typedef __attribute__((ext_vector_type(8)))  short bf16x8;
typedef __attribute__((ext_vector_type(4)))  float f32x4;

// ---------------- helpers ----------------

__device__ __forceinline__ i32x16 mfma_i8(i32x4 a, i32x4 b, i32x16 c) {
  return __builtin_amdgcn_mfma_i32_32x32x32_i8(a, b, c, 0, 0, 0);
}

// float -> bf16 round-to-nearest-even (finite inputs)
__device__ __forceinline__ unsigned int f2bf(float f) {
  unsigned int u = __float_as_uint(f);
  return (u + 0x7fffu + ((u >> 16) & 1u)) >> 16;
}
__device__ __forceinline__ float bf2f(unsigned int b) {
  return __uint_as_float(b << 16);
}
// pack hi-parts of (a,b) into return, lo-parts (residual bf16) into lo
__device__ __forceinline__ unsigned int f2bf2hl(float a, float b, unsigned int& lo) {
  unsigned int ha = f2bf(a), hb = f2bf(b);
  lo = f2bf(a - bf2f(ha)) | (f2bf(b - bf2f(hb)) << 16);
  return ha | (hb << 16);
}
// pack double-bf16 pair of one float: low ushort = hi, high ushort = lo
__device__ __forceinline__ unsigned int fpair(float a) {
  unsigned int hi = f2bf(a);
  unsigned int lo = f2bf(a - bf2f(hi));
  return hi | (lo << 16);
}
__device__ __forceinline__ unsigned int ror16(unsigned int x) {
  return (x >> 16) | (x << 16);
}

// 256-thread block reduce (double). op=0 sum, op=1 max. tmp: __shared__ double[4]
__device__ __forceinline__ double bredd(double v, int op, double* tmp) {
#pragma unroll
  for (int o = 32; o; o >>= 1) {
    double w = __shfl_xor(v, o);
    v = op ? fmax(v, w) : v + w;
  }
  int wid = threadIdx.x >> 6;
  if ((threadIdx.x & 63) == 0) tmp[wid] = v;
  __syncthreads();
  double r = op ? fmax(fmax(tmp[0], tmp[1]), fmax(tmp[2], tmp[3]))
                : (tmp[0] + tmp[1] + tmp[2] + tmp[3]);
  __syncthreads();
  return r;
}

// quantize 4 doubles to packed int8 with double scale (round-half-even like jnp.round)
__device__ __forceinline__ int qpackd(double n0, double n1, double n2, double n3, double s) {
  int a = (int)fmin(fmax(rint(n0 * s), -128.0), 127.0);
  int b = (int)fmin(fmax(rint(n1 * s), -128.0), 127.0);
  int c = (int)fmin(fmax(rint(n2 * s), -128.0), 127.0);
  int d = (int)fmin(fmax(rint(n3 * s), -128.0), 127.0);
  return (a & 255) | ((b & 255) << 8) | ((c & 255) << 16) | ((d & 255) << 24);
}

// map flat tensor id (0..27, each 1M elems) -> source pointer
__device__ __forceinline__ const float* wsrc(int tensor,
    const float* qw_, const float* kw_, const float* vw_, const float* ow_,
    const float* gw_, const float* uw_, const float* dw_) {
  if (tensor < 4) return tensor == 0 ? qw_ : tensor == 1 ? kw_ : tensor == 2 ? vw_ : ow_;
  if (tensor < 12) return gw_ + ((long long)(tensor - 4) << 20);
  if (tensor < 20) return uw_ + ((long long)(tensor - 12) << 20);
  return dw_ + ((long long)(tensor - 20) << 20);
}

// ---------------- weight quantization (fp64 scale, deterministic) ----------------

__global__ __launch_bounds__(256) void k_absum(
    const float* qw_, const float* kw_, const float* vw_, const float* ow_,
    const float* gw_, const float* uw_, const float* dw_, double* partial) {
  __shared__ double tmp[4];
  int tensor = blockIdx.x >> 10;
  int j = ((blockIdx.x & 1023) << 10) + threadIdx.x * 4;
  const float* src = wsrc(tensor, qw_, kw_, vw_, ow_, gw_, uw_, dw_);
  float4 w = *(const float4*)(src + j);
  double v = fabs((double)w.x) + fabs((double)w.y) + fabs((double)w.z) + fabs((double)w.w);
  v = bredd(v, 0, tmp);
  if (threadIdx.x == 0) partial[blockIdx.x] = v;
}

__global__ __launch_bounds__(256) void k_wscale(const double* partial, double* wsd) {
  __shared__ double tmp[4];
  int tensor = blockIdx.x;
  const double* p = partial + (tensor << 10);
  int i = threadIdx.x * 4;
  double v = p[i] + p[i + 1] + p[i + 2] + p[i + 3];
  v = bredd(v, 0, tmp);
  if (threadIdx.x == 0) wsd[tensor] = 1.0 / fmax(v * (1.0 / 1048576.0), 1e-5);
}

__global__ __launch_bounds__(256) void k_quantw(
    const float* qw_, const float* kw_, const float* vw_, const float* ow_,
    const float* gw_, const float* uw_, const float* dw_,
    const double* wsd, int8_t* qw) {
  int tensor = blockIdx.x >> 10;
  int j = ((blockIdx.x & 1023) << 10) + threadIdx.x * 4;
  const float* src = wsrc(tensor, qw_, kw_, vw_, ow_, gw_, uw_, dw_);
  double s = wsd[tensor];
  float4 w = *(const float4*)(src + j);
  int a = (int)fmin(fmax(rint((double)w.x * s), -1.0), 1.0);
  int b = (int)fmin(fmax(rint((double)w.y * s), -1.0), 1.0);
  int c = (int)fmin(fmax(rint((double)w.z * s), -1.0), 1.0);
  int d = (int)fmin(fmax(rint((double)w.w * s), -1.0), 1.0);
  ((int*)qw)[(tensor << 18) + (j >> 2)] =
      (a & 255) | ((b & 255) << 8) | ((c & 255) << 16) | ((d & 255) << 24);
}

// ---------------- rmsnorm + act_quant (attention input), fp64 decisions ----------------

__global__ __launch_bounds__(256) void k_rms1(const float* X, const float* lnw,
                                              int8_t* xq, double* xsd) {
  __shared__ double tmp[4];
  int t = blockIdx.x, tid = threadIdx.x;
  float4 xv = ((const float4*)(X + (long long)t * H))[tid];
  double x0 = xv.x, x1 = xv.y, x2 = xv.z, x3 = xv.w;
  double ss = x0 * x0 + x1 * x1 + x2 * x2 + x3 * x3;
  ss = bredd(ss, 0, tmp);
  double r = 1.0 / sqrt(ss * (1.0 / 1024.0) + 1e-5);
  float4 wv = ((const float4*)lnw)[tid];
  double n0 = x0 * r * wv.x, n1 = x1 * r * wv.y, n2 = x2 * r * wv.z, n3 = x3 * r * wv.w;
  double ma = fmax(fmax(fabs(n0), fabs(n1)), fmax(fabs(n2), fabs(n3)));
  ma = bredd(ma, 1, tmp);
  double s = 127.0 / fmax(ma, 1e-5);
  ((int*)xq)[t * 256 + tid] = qpackd(n0, n1, n2, n3, s);
  if (tid == 0) xsd[t] = s;
}

// act_quant only (rows of 1024 floats), fp64 decisions
__global__ __launch_bounds__(256) void k_actq(const float* X, int8_t* xq, double* xsd) {
  __shared__ double tmp[4];
  int t = blockIdx.x, tid = threadIdx.x;
  float4 xv = ((const float4*)(X + (long long)t * H))[tid];
  double x0 = xv.x, x1 = xv.y, x2 = xv.z, x3 = xv.w;
  double ma = fmax(fmax(fabs(x0), fabs(x1)), fmax(fabs(x2), fabs(x3)));
  ma = bredd(ma, 1, tmp);
  double s = 127.0 / fmax(ma, 1e-5);
  ((int*)xq)[t * 256 + tid] = qpackd(x0, x1, x2, x3, s);
  if (tid == 0) xsd[t] = s;
}

// ---------------- int8 GEMM via MFMA: out[t,n] = res[t,n] + acc/(xs[t]*sw) -------
// BM=128 BN=128 BK=64. 4 waves 2x2; wave tile 64x64 = 2x2 mfma_i32_32x32x32_i8.

__global__ __launch_bounds__(256) void k_gemm(
    const int8_t* __restrict__ Xq, const double* __restrict__ xsd,
    const int8_t* __restrict__ W, const double* __restrict__ wsd, int widx,
    const float* __restrict__ residual, float* __restrict__ out) {
  __shared__ i32x4 Xs[4][128];
  __shared__ i32x4 Ws[4][128];
  int tid = threadIdx.x;
  int t0 = blockIdx.y * 128, n0 = blockIdx.x * 128;
  int w = tid >> 6, lane = tid & 63;
  int wm = w >> 1, wn = w & 1;
  int lrow = lane & 31, lk = lane >> 5;
  i32x16 acc[2][2];
#pragma unroll
  for (int i = 0; i < 2; i++)
#pragma unroll
    for (int j = 0; j < 2; j++)
#pragma unroll
      for (int r = 0; r < 16; r++) acc[i][j][r] = 0;

  for (int k0 = 0; k0 < 1024; k0 += 64) {
#pragma unroll
    for (int i = 0; i < 2; i++) {
      int u = tid * 2 + i;                 // 0..511
      int row = u >> 2, kc = u & 3;
      Xs[kc][row] = *(const i32x4*)(Xq + (long long)(t0 + row) * 1024 + k0 + kc * 16);
      Ws[kc][row] = *(const i32x4*)(W  + (long long)(n0 + row) * 1024 + k0 + kc * 16);
    }
    __syncthreads();
#pragma unroll
    for (int ks = 0; ks < 2; ks++) {
      i32x4 a0 = Xs[ks * 2 + lk][wm * 64 + lrow];
      i32x4 a1 = Xs[ks * 2 + lk][wm * 64 + 32 + lrow];
      i32x4 b0 = Ws[ks * 2 + lk][wn * 64 + lrow];
      i32x4 b1 = Ws[ks * 2 + lk][wn * 64 + 32 + lrow];
      acc[0][0] = mfma_i8(a0, b0, acc[0][0]);
      acc[0][1] = mfma_i8(a0, b1, acc[0][1]);
      acc[1][0] = mfma_i8(a1, b0, acc[1][0]);
      acc[1][1] = mfma_i8(a1, b1, acc[1][1]);
    }
    __syncthreads();
  }

  double sw = wsd[widx];
#pragma unroll
  for (int i = 0; i < 2; i++) {
#pragma unroll
    for (int r = 0; r < 16; r++) {
      int trow = t0 + wm * 64 + i * 32 + (r & 3) + 8 * (r >> 2) + 4 * lk;
      double inv = 1.0 / (xsd[trow] * sw);
#pragma unroll
      for (int j = 0; j < 2; j++) {
        int n = n0 + wn * 64 + j * 32 + lrow;
        double v = (double)acc[i][j][r] * inv;
        if (residual) v += (double)residual[(long long)trow * H + n];
        out[(long long)trow * H + n] = (float)v;
      }
    }
  }
}

// k_gemm3: fused q/k/v projections. blockIdx.z selects weight tensor + output.
// Same body as k_gemm (no residual). 768 blocks = 3/CU -> staging of one block
// overlaps MFMA of another. Integer-exact (identical results to 3x k_gemm).

__global__ __launch_bounds__(256) void k_gemm3(
    const int8_t* __restrict__ Xq, const double* __restrict__ xsd,
    const int8_t* __restrict__ qw, const double* __restrict__ wsd,
    float* __restrict__ outq, float* __restrict__ outk, float* __restrict__ outv) {
  __shared__ i32x4 Xs[4][128];
  __shared__ i32x4 Ws[4][128];
  int z = blockIdx.z;
  const int8_t* W = qw + ((long long)z << 20);
  float* out = z == 0 ? outq : z == 1 ? outk : outv;
  int tid = threadIdx.x;
  int t0 = blockIdx.y * 128, n0 = blockIdx.x * 128;
  int w = tid >> 6, lane = tid & 63;
  int wm = w >> 1, wn = w & 1;
  int lrow = lane & 31, lk = lane >> 5;
  i32x16 acc[2][2];
#pragma unroll
  for (int i = 0; i < 2; i++)
#pragma unroll
    for (int j = 0; j < 2; j++)
#pragma unroll
      for (int r = 0; r < 16; r++) acc[i][j][r] = 0;

  for (int k0 = 0; k0 < 1024; k0 += 64) {
#pragma unroll
    for (int i = 0; i < 2; i++) {
      int u = tid * 2 + i;
      int row = u >> 2, kc = u & 3;
      Xs[kc][row] = *(const i32x4*)(Xq + (long long)(t0 + row) * 1024 + k0 + kc * 16);
      Ws[kc][row] = *(const i32x4*)(W  + (long long)(n0 + row) * 1024 + k0 + kc * 16);
    }
    __syncthreads();
#pragma unroll
    for (int ks = 0; ks < 2; ks++) {
      i32x4 a0 = Xs[ks * 2 + lk][wm * 64 + lrow];
      i32x4 a1 = Xs[ks * 2 + lk][wm * 64 + 32 + lrow];
      i32x4 b0 = Ws[ks * 2 + lk][wn * 64 + lrow];
      i32x4 b1 = Ws[ks * 2 + lk][wn * 64 + 32 + lrow];
      acc[0][0] = mfma_i8(a0, b0, acc[0][0]);
      acc[0][1] = mfma_i8(a0, b1, acc[0][1]);
      acc[1][0] = mfma_i8(a1, b0, acc[1][0]);
      acc[1][1] = mfma_i8(a1, b1, acc[1][1]);
    }
    __syncthreads();
  }

  double sw = wsd[z];
#pragma unroll
  for (int i = 0; i < 2; i++) {
#pragma unroll
    for (int r = 0; r < 16; r++) {
      int trow = t0 + wm * 64 + i * 32 + (r & 3) + 8 * (r >> 2) + 4 * lk;
      double inv = 1.0 / (xsd[trow] * sw);
#pragma unroll
      for (int j = 0; j < 2; j++) {
        int n = n0 + wn * 64 + j * 32 + lrow;
        out[(long long)trow * H + n] = (float)((double)acc[i][j][r] * inv);
      }
    }
  }
}

// ---------------- attention ----------------
// k_knorm: per-(b,head) max key L2-norm -> fixed softmax bound.

__global__ __launch_bounds__(256) void k_knorm(const float* __restrict__ K,
                                               float* __restrict__ Mk) {
  __shared__ float tmp[4];
  int bh = blockIdx.x;          // b*16 + head
  int b = bh >> 4, head = bh & 15;
  int tid = threadIdx.x;
  float mx = 0.f;
  for (int key = tid; key < SEQ; key += 256) {
    const float4* kr = (const float4*)(K + ((long long)(b * SEQ + key)) * H + head * HD);
    float s = 0.f;
#pragma unroll
    for (int i = 0; i < 16; i++) {
      float4 v = kr[i];
      s += v.x * v.x + v.y * v.y + v.z * v.z + v.w * v.w;
    }
    mx = fmaxf(mx, s);
  }
#pragma unroll
  for (int o = 32; o; o >>= 1) mx = fmaxf(mx, __shfl_xor(mx, o));
  if ((tid & 63) == 0) tmp[tid >> 6] = mx;
  __syncthreads();
  if (tid == 0)
    Mk[bh] = sqrtf(fmaxf(fmaxf(tmp[0], tmp[1]), fmaxf(tmp[2], tmp[3])));
}

// k_attn (R15): R13 pair-exact full-MFMA attention (passed, absmax 0.03125) with
// ONE addressing fix: VA columns XOR-swizzled by ((d>>3)&7)<<2.
//  - staging writes VA[d][key^swz]: swz = (lane&7)<<2 varies per lane ->
//    bank = srow ^ swz + const = 2 lanes/bank (free), vs 8-way before (the
//    3.14e7 conflicts: sd*76 = (lane&7)*608 = 0 mod 32 collapsed 64 lanes
//    onto 8 banks).
//  - b128 frag reads at col^swz: XOR is 4-word aligned -> groups stay
//    contiguous+aligned; window = (3*l15 + 4c4 + (lhi^sw)) mod 8 uniform ->
//    conflict-free. Bijective (bits 2-4 of 6-bit col index).
// PV exactness unchanged: P word = (Ph|Pl<<16), V word = (Vh|Vl<<16);
// mfma(P,V) + mfma(P,ror16(V)) = exact (Ph+Pl)(Vh+Vl), fp32 accum (~2^-17).
// R14's single-bf16 PV failed (0.164): downstream discrete decisions (router
// argmax, int8 roundings) need the ~2^-17 class, not 2^-9.

__global__ __launch_bounds__(512, 4) void k_attn(
    const float* __restrict__ Q, const float* __restrict__ K,
    const float* __restrict__ V, float* __restrict__ O,
    const float* __restrict__ Mk) {
  __shared__ unsigned short Qb[64][72];     // Q bf16 hi (x0.125)
  __shared__ unsigned short Ql[64][72];     // Q bf16 lo
  __shared__ unsigned short Kb[64][72];     // K bf16 hi
  __shared__ unsigned short Kl[64][72];     // K bf16 lo
  __shared__ unsigned int   VA[64][76];     // V^T pairs, col-swizzled
  __shared__ unsigned int   Pw[64][76];     // logits f32, then weight pairs (in-place)
  __shared__ float mbs[64];
  __shared__ float lred[64];
  int i = blockIdx.x;
  int hb = (i & 7) | (((i >> 3) & 3) << 3);
  int p  = ((i >> 5) & 7) | (((i >> 8) & 1) << 3);
  int head = hb & 15, b = hb >> 4;
  int tid = threadIdx.x;
  int w = tid >> 6, lane = tid & 63;
  int quad = lane >> 2, dp = lane & 3;
  int d0 = dp << 4;
  int l15 = lane & 15, lhi = lane >> 4;
  int qh = w >> 2, ks = w & 3;
  long long bh_base = ((long long)b * SEQ) * H + head * HD;
  float mkv = Mk[b * 16 + head];

  int srow = tid >> 3;               // staging / weight row 0..63
  int sd = (tid & 7) << 3;           // staging elem offset 0,8,..,56
  int wc = tid & 7;                  // weight chunk 0..7
  int vswz = (tid & 7) << 2;         // V^T staging column swizzle (= (d>>3)<<2)

  for (int ph = 0; ph < 2; ph++) {
    int g = ph ? (31 - p) : p;
    int qlo = g * 64;

    // stage Q tile as double-bf16 (x0.125), once per phase
    {
      const float* qg = Q + bh_base + (long long)(qlo + srow) * H + sd;
      float4 a = *(const float4*)qg;
      float4 c = *(const float4*)(qg + 4);
      uint4 phh, pll;
      phh.x = f2bf2hl(a.x * 0.125f, a.y * 0.125f, pll.x);
      phh.y = f2bf2hl(a.z * 0.125f, a.w * 0.125f, pll.y);
      phh.z = f2bf2hl(c.x * 0.125f, c.y * 0.125f, pll.z);
      phh.w = f2bf2hl(c.z * 0.125f, c.w * 0.125f, pll.w);
      *(uint4*)&Qb[srow][sd] = phh;
      *(uint4*)&Ql[srow][sd] = pll;
    }

    // fixed bound mb = 0.125*|q|*max|k| into mbs[] (ks==0 waves cover all rows)
    if (ks == 0) {
      int j0 = qh * 32 + quad * 2;
#pragma unroll
      for (int qq = 0; qq < 2; qq++) {
        int j = j0 + qq;
        const float4* qp_ = (const float4*)(Q + bh_base + (long long)(qlo + j) * H + d0);
        float ss = 0.f;
#pragma unroll
        for (int i2 = 0; i2 < 4; i2++) {
          float4 t = qp_[i2];
          ss += t.x * t.x + t.y * t.y + t.z * t.z + t.w * t.w;
        }
        ss += __shfl_xor(ss, 1);
        ss += __shfl_xor(ss, 2);
        if (dp == 0) mbs[j] = 0.125f * sqrtf(ss) * mkv;
      }
    }

    float lsum = 0.f;
    f32x4 oacc[2];
#pragma unroll
    for (int fi = 0; fi < 2; fi++)
#pragma unroll
      for (int r = 0; r < 4; r++) oacc[fi][r] = 0.f;

    __syncthreads();   // Qb/Ql/mbs visible

    for (int t = 0; t <= g; t++) {
      // ---- stage K (double-bf16) and V^T (interleaved pairs, swizzled col)
      {
        const float* kg = K + bh_base + (long long)(t * 64 + srow) * H + sd;
        const float* vg = V + bh_base + (long long)(t * 64 + srow) * H + sd;
        float4 ka = *(const float4*)kg;
        float4 kc = *(const float4*)(kg + 4);
        uint4 phh, pll;
        phh.x = f2bf2hl(ka.x, ka.y, pll.x);
        phh.y = f2bf2hl(ka.z, ka.w, pll.y);
        phh.z = f2bf2hl(kc.x, kc.y, pll.z);
        phh.w = f2bf2hl(kc.z, kc.w, pll.w);
        *(uint4*)&Kb[srow][sd] = phh;
        *(uint4*)&Kl[srow][sd] = pll;
        float4 va = *(const float4*)vg;
        float4 vc = *(const float4*)(vg + 4);
        int col = srow ^ vswz;           // swz = ((d>>3)&7)<<2, d = sd+j
        VA[sd + 0][col] = fpair(va.x);
        VA[sd + 1][col] = fpair(va.y);
        VA[sd + 2][col] = fpair(va.z);
        VA[sd + 3][col] = fpair(va.w);
        VA[sd + 4][col] = fpair(vc.x);
        VA[sd + 5][col] = fpair(vc.y);
        VA[sd + 6][col] = fpair(vc.z);
        VA[sd + 7][col] = fpair(vc.w);
      }
      __syncthreads();

      // ---- QK^T MFMA (3-term double-bf16) -> Pw (f32 logits)
      {
        int qb = w >> 1;
#pragma unroll
        for (int kb2 = 0; kb2 < 2; kb2++) {
          int kb = (w & 1) * 2 + kb2;
          f32x4 c = {0.f, 0.f, 0.f, 0.f};
#pragma unroll
          for (int ks2 = 0; ks2 < 2; ks2++) {
            bf16x8 ah = *(const bf16x8*)&Qb[qb * 16 + l15][ks2 * 32 + lhi * 8];
            bf16x8 al = *(const bf16x8*)&Ql[qb * 16 + l15][ks2 * 32 + lhi * 8];
            bf16x8 bh = *(const bf16x8*)&Kb[kb * 16 + l15][ks2 * 32 + lhi * 8];
            bf16x8 bl = *(const bf16x8*)&Kl[kb * 16 + l15][ks2 * 32 + lhi * 8];
            c = __builtin_amdgcn_mfma_f32_16x16x32_bf16(al, bh, c, 0, 0, 0);
            c = __builtin_amdgcn_mfma_f32_16x16x32_bf16(ah, bl, c, 0, 0, 0);
            c = __builtin_amdgcn_mfma_f32_16x16x32_bf16(ah, bh, c, 0, 0, 0);
          }
#pragma unroll
          for (int r = 0; r < 4; r++)
            Pw[qb * 16 + lhi * 4 + r][kb * 16 + l15] = __float_as_uint(c[r]);
        }
      }
      __syncthreads();

      // ---- weight pass: thread (srow, wc): 8 logits -> weights, in-place pairs
      {
        float mbr = mbs[srow];
        uint4 pa = *(const uint4*)&Pw[srow][wc * 8];
        uint4 pb = *(const uint4*)&Pw[srow][wc * 8 + 4];
        float pv0 = __uint_as_float(pa.x), pv1 = __uint_as_float(pa.y);
        float pv2 = __uint_as_float(pa.z), pv3 = __uint_as_float(pa.w);
        float pv4 = __uint_as_float(pb.x), pv5 = __uint_as_float(pb.y);
        float pv6 = __uint_as_float(pb.z), pv7 = __uint_as_float(pb.w);
        int kbase = wc * 8;
        bool dg = (t == g);
        float w0 = (dg && kbase + 0 > srow) ? 0.f : __expf(pv0 - mbr);
        float w1 = (dg && kbase + 1 > srow) ? 0.f : __expf(pv1 - mbr);
        float w2 = (dg && kbase + 2 > srow) ? 0.f : __expf(pv2 - mbr);
        float w3 = (dg && kbase + 3 > srow) ? 0.f : __expf(pv3 - mbr);
        float w4 = (dg && kbase + 4 > srow) ? 0.f : __expf(pv4 - mbr);
        float w5 = (dg && kbase + 5 > srow) ? 0.f : __expf(pv5 - mbr);
        float w6 = (dg && kbase + 6 > srow) ? 0.f : __expf(pv6 - mbr);
        float w7 = (dg && kbase + 7 > srow) ? 0.f : __expf(pv7 - mbr);
        lsum += ((w0 + w1) + (w2 + w3)) + ((w4 + w5) + (w6 + w7));
        uint4 oa, ob;
        oa.x = fpair(w0); oa.y = fpair(w1); oa.z = fpair(w2); oa.w = fpair(w3);
        ob.x = fpair(w4); ob.y = fpair(w5); ob.z = fpair(w6); ob.w = fpair(w7);
        *(uint4*)&Pw[srow][wc * 8] = oa;
        *(uint4*)&Pw[srow][wc * 8 + 4] = ob;
      }
      __syncthreads();

      // ---- PV MFMA: frag f = w*2+fi: q-block f>>2, d-block f&3
#pragma unroll
      for (int fi = 0; fi < 2; fi++) {
        int f = w * 2 + fi;
        int q4 = f >> 2, d4 = f & 3;
#pragma unroll
        for (int c4 = 0; c4 < 4; c4++) {
          bf16x8 af = *(const bf16x8*)&Pw[q4 * 16 + l15][c4 * 16 + lhi * 4];
          int row = d4 * 16 + l15;
          int rswz = ((row >> 3) & 7) << 2;
          union { uint4 q; unsigned int u[4]; bf16x8 v; } bb, bs;
          bb.q = *(const uint4*)&VA[row][(c4 * 16 + lhi * 4) ^ rswz];
          oacc[fi] = __builtin_amdgcn_mfma_f32_16x16x32_bf16(af, bb.v, oacc[fi], 0, 0, 0);
#pragma unroll
          for (int j = 0; j < 4; j++)
            bs.u[j] = ror16(bb.u[j]);
          oacc[fi] = __builtin_amdgcn_mfma_f32_16x16x32_bf16(af, bs.v, oacc[fi], 0, 0, 0);
        }
      }
      __syncthreads();
    }

    // ---- l reduce (over wc chunks) and O epilogue
    lsum += __shfl_xor(lsum, 1);
    lsum += __shfl_xor(lsum, 2);
    lsum += __shfl_xor(lsum, 4);
    if ((lane & 7) == 0) lred[srow] = lsum;
    __syncthreads();
#pragma unroll
    for (int fi = 0; fi < 2; fi++) {
      int f = w * 2 + fi;
      int q4 = f >> 2, d4 = f & 3;
#pragma unroll
      for (int r = 0; r < 4; r++) {
        int qrow = q4 * 16 + lhi * 4 + r;
        float inv = 1.f / lred[qrow];
        O[bh_base + (long long)(qlo + qrow) * H + d4 * 16 + l15] = oacc[fi][r] * inv;
      }
    }
    __syncthreads();                 // LDS reuse safe for next phase
  }
}

// ---------------- rmsnorm2 + router (argmax, fp64) + act_quant ----------------

__global__ __launch_bounds__(256) void k_rms2_router(
    const float* X2, const float* lnw, const float* rw,
    int8_t* xq, double* xsd, int* eidx) {
  __shared__ double tmp[4];
  __shared__ double xn[1024];
  __shared__ double logits[8];
  int t = blockIdx.x, tid = threadIdx.x;
  float4 xv = ((const float4*)(X2 + (long long)t * H))[tid];
  double x0 = xv.x, x1 = xv.y, x2 = xv.z, x3 = xv.w;
  double ss = x0 * x0 + x1 * x1 + x2 * x2 + x3 * x3;
  ss = bredd(ss, 0, tmp);
  double r = 1.0 / sqrt(ss * (1.0 / 1024.0) + 1e-5);
  float4 wv = ((const float4*)lnw)[tid];
  double n0 = x0 * r * wv.x, n1 = x1 * r * wv.y, n2 = x2 * r * wv.z, n3 = x3 * r * wv.w;
  xn[tid * 4 + 0] = n0; xn[tid * 4 + 1] = n1;
  xn[tid * 4 + 2] = n2; xn[tid * 4 + 3] = n3;
  double ma = fmax(fmax(fabs(n0), fabs(n1)), fmax(fabs(n2), fabs(n3)));
  ma = bredd(ma, 1, tmp);  // contains syncthreads -> xn visible
  double s = 127.0 / fmax(ma, 1e-5);
  ((int*)xq)[t * 256 + tid] = qpackd(n0, n1, n2, n3, s);
  if (tid == 0) xsd[t] = s;
  if (tid < 64) {
    int e = tid >> 3, i = tid & 7;
    const float* wr = rw + e * 1024;
    double p = 0.0;
    for (int h = i; h < 1024; h += 8) p += xn[h] * (double)wr[h];
    p += __shfl_xor(p, 1);
    p += __shfl_xor(p, 2);
    p += __shfl_xor(p, 4);
    if (i == 0) logits[e] = p;
  }
  __syncthreads();
  if (tid == 0) {
    double best = logits[0];
    int bi = 0;
    for (int e = 1; e < 8; e++)
      if (logits[e] > best) { best = logits[e]; bi = e; }
    eidx[t] = bi;
  }
}

// ---------------- MoE routing: group tokens by expert into padded 64-slot tiles ----
// meta[0] = ntile; meta[1+i] = expert of tile i. tokidx[slot] = token or -1 (pad).

__global__ __launch_bounds__(256) void k_route(const int* __restrict__ eidx,
                                               int* __restrict__ meta,
                                               int* __restrict__ tokidx) {
  __shared__ int cnt[8], pb[9], cur[8];
  int tid = threadIdx.x;
  if (tid < 8) cnt[tid] = 0;
  __syncthreads();
  for (int t = tid; t < NTOK; t += 256) atomicAdd(&cnt[eidx[t]], 1);
  __syncthreads();
  if (tid == 0) {
    pb[0] = 0;
    int nt = 0;
    for (int e = 0; e < 8; e++) {
      int tiles = (cnt[e] + 63) >> 6;
      for (int i = 0; i < tiles; i++) meta[1 + nt + i] = e;
      nt += tiles;
      pb[e + 1] = pb[e] + tiles * 64;
      cur[e] = pb[e];
    }
    meta[0] = nt;
  }
  __syncthreads();
  for (int s = tid; s < 4608; s += 256) tokidx[s] = -1;
  __syncthreads();
  for (int t = tid; t < NTOK; t += 256) {
    int e = eidx[t];
    int s = atomicAdd(&cur[e], 1);
    tokidx[s] = t;
  }
}

// ---------------- MoE gate+up GEMM via MFMA -> hh (fused relu(g)^2*u) ----------

__global__ __launch_bounds__(256) void k_moe_gu(
    const int8_t* __restrict__ Xq, const double* __restrict__ xsd,
    const int8_t* __restrict__ qw, const double* __restrict__ wsd,
    const int* __restrict__ meta, const int* __restrict__ tokidx,
    float* __restrict__ hhbuf) {
  __shared__ i32x4 Xs[4][64];
  __shared__ i32x4 Wg[4][128];
  __shared__ i32x4 Wu[4][128];
  int tile = blockIdx.y;
  if (tile >= meta[0]) return;
  int e = meta[1 + tile];
  int n0 = blockIdx.x * 128;
  int s0 = tile * 64;
  int tid = threadIdx.x;
  int w = tid >> 6, lane = tid & 63;
  int lrow = lane & 31, lk = lane >> 5;
  const int8_t* Gg = qw + ((long long)(4 + e) << 20);
  const int8_t* Ug = qw + ((long long)(12 + e) << 20);
  int xrow = tid >> 2, xkc = tid & 3;
  int tokr = tokidx[s0 + xrow];
  if (tokr < 0) tokr = 0;
  i32x16 accg[2], accu[2];
#pragma unroll
  for (int i = 0; i < 2; i++)
#pragma unroll
    for (int r = 0; r < 16; r++) { accg[i][r] = 0; accu[i][r] = 0; }

  for (int k0 = 0; k0 < 1024; k0 += 64) {
    Xs[xkc][xrow] = *(const i32x4*)(Xq + (long long)tokr * 1024 + k0 + xkc * 16);
#pragma unroll
    for (int i = 0; i < 2; i++) {
      int u = tid * 2 + i;                 // 0..511
      int row = u >> 2, kc = u & 3;
      Wg[kc][row] = *(const i32x4*)(Gg + (long long)(n0 + row) * 1024 + k0 + kc * 16);
      Wu[kc][row] = *(const i32x4*)(Ug + (long long)(n0 + row) * 1024 + k0 + kc * 16);
    }
    __syncthreads();
#pragma unroll
    for (int ks = 0; ks < 2; ks++) {
      i32x4 a0 = Xs[ks * 2 + lk][lrow];
      i32x4 a1 = Xs[ks * 2 + lk][32 + lrow];
      i32x4 bg = Wg[ks * 2 + lk][w * 32 + lrow];
      i32x4 bu = Wu[ks * 2 + lk][w * 32 + lrow];
      accg[0] = mfma_i8(a0, bg, accg[0]);
      accg[1] = mfma_i8(a1, bg, accg[1]);
      accu[0] = mfma_i8(a0, bu, accu[0]);
      accu[1] = mfma_i8(a1, bu, accu[1]);
    }
    __syncthreads();
  }

  double swg = wsd[4 + e], swu = wsd[12 + e];
  int n = n0 + w * 32 + lrow;
#pragma unroll
  for (int i = 0; i < 2; i++) {
#pragma unroll
    for (int r = 0; r < 16; r++) {
      int s = s0 + i * 32 + (r & 3) + 8 * (r >> 2) + 4 * lk;
      int tok = tokidx[s];
      if (tok < 0) continue;
      double ig = 1.0 / (xsd[tok] * swg);
      double iu = 1.0 / (xsd[tok] * swu);
      double g = (double)accg[i][r] * ig;
      double uu = (double)accu[i][r] * iu;
      double rg = fmax(g, 0.0);
      hhbuf[(long long)s * DDIM + n] = (float)(rg * rg * uu);
    }
  }
}

// ---------------- act_quant over hh slot rows ----------------

__global__ __launch_bounds__(256) void k_hh_actq(
    const float* __restrict__ hhbuf, const int* __restrict__ meta,
    const int* __restrict__ tokidx, int8_t* __restrict__ hq,
    double* __restrict__ hsd) {
  __shared__ double tmp[4];
  int s = blockIdx.x;
  if (s >= meta[0] * 64) return;
  int tid = threadIdx.x;
  int tok = tokidx[s];
  if (tok < 0) {
    ((int*)hq)[s * 256 + tid] = 0;
    if (tid == 0) hsd[s] = 1.0;
    return;
  }
  float4 xv = ((const float4*)(hhbuf + (long long)s * DDIM))[tid];
  double x0 = xv.x, x1 = xv.y, x2 = xv.z, x3 = xv.w;
  double ma = fmax(fmax(fabs(x0), fabs(x1)), fmax(fabs(x2), fabs(x3)));
  ma = bredd(ma, 1, tmp);
  double sc = 127.0 / fmax(ma, 1e-5);
  ((int*)hq)[s * 256 + tid] = qpackd(x0, x1, x2, x3, sc);
  if (tid == 0) hsd[s] = sc;
}

// ---------------- MoE down GEMM via MFMA + residual -> out (scatter) ------------

__global__ __launch_bounds__(256) void k_moe_down(
    const int8_t* __restrict__ hq, const double* __restrict__ hsd,
    const int8_t* __restrict__ qw, const double* __restrict__ wsd,
    const int* __restrict__ meta, const int* __restrict__ tokidx,
    const float* __restrict__ x2, float* __restrict__ out) {
  __shared__ i32x4 Xs[4][64];
  __shared__ i32x4 Ws[4][128];
  int tile = blockIdx.y;
  if (tile >= meta[0]) return;
  int e = meta[1 + tile];
  int n0 = blockIdx.x * 128;
  int s0 = tile * 64;
  int tid = threadIdx.x;
  int w = tid >> 6, lane = tid & 63;
  int lrow = lane & 31, lk = lane >> 5;
  const int8_t* Wp = qw + ((long long)(20 + e) << 20);
  int xrow = tid >> 2, xkc = tid & 3;
  i32x16 acc[2];
#pragma unroll
  for (int i = 0; i < 2; i++)
#pragma unroll
    for (int r = 0; r < 16; r++) acc[i][r] = 0;

  for (int k0 = 0; k0 < 1024; k0 += 64) {
    Xs[xkc][xrow] = *(const i32x4*)(hq + (long long)(s0 + xrow) * 1024 + k0 + xkc * 16);
#pragma unroll
    for (int i = 0; i < 2; i++) {
      int u = tid * 2 + i;
      int row = u >> 2, kc = u & 3;
      Ws[kc][row] = *(const i32x4*)(Wp + (long long)(n0 + row) * 1024 + k0 + kc * 16);
    }
    __syncthreads();
#pragma unroll
    for (int ks = 0; ks < 2; ks++) {
      i32x4 a0 = Xs[ks * 2 + lk][lrow];
      i32x4 a1 = Xs[ks * 2 + lk][32 + lrow];
      i32x4 b  = Ws[ks * 2 + lk][w * 32 + lrow];
      acc[0] = mfma_i8(a0, b, acc[0]);
      acc[1] = mfma_i8(a1, b, acc[1]);
    }
    __syncthreads();
  }

  double sw = wsd[20 + e];
  int n = n0 + w * 32 + lrow;
#pragma unroll
  for (int i = 0; i < 2; i++) {
#pragma unroll
    for (int r = 0; r < 16; r++) {
      int s = s0 + i * 32 + (r & 3) + 8 * (r >> 2) + 4 * lk;
      int tok = tokidx[s];
      if (tok < 0) continue;
      double inv = 1.0 / (hsd[s] * sw);
      out[(long long)tok * H + n] =
          (float)((double)x2[(long long)tok * H + n] + (double)acc[i][r] * inv);
    }
  }
}

// ---------------- launch ----------------
// ws layout (bytes):
//   0        partial double[28*1024] (224 KB)
//   229376   wsd double[28]
//   229600   xsd double[4096] (32 KB)
//   262368   eidx int[4096] (16 KB)
//   278752   Mk float[32]
//   278912   meta int[128]  (ntile + tile_e)
//   279424   tokidx int[4608] (18 KB)
//   297856   hsd double[4608] (36.9 KB)
//   1MB      qw int8: 28 x 1MB
//   29MB     xq int8 4MB
//   33MB     qbuf fp32 16MB (q -> attn out h); later hhbuf f32 [4544][1024] (18.6MB, 33..51.6)
//   49MB     kbuf fp32 16MB (k; dead after attn)
//   52MB     hq int8 [4544][1024] (4.65MB, 52..56.7)   <- inside dead kbuf region
//   65MB     vbuf fp32 16MB (v -> x2 residual)

extern "C" void kernel_launch(void* const* d_in, const int* in_sizes, int n_in,
                              void* d_out, int out_size, void* d_ws, size_t ws_size,
                              hipStream_t stream) {
  const float* x   = (const float*)d_in[0];
  const float* qw_ = (const float*)d_in[1];
  const float* kw_ = (const float*)d_in[2];
  const float* vw_ = (const float*)d_in[3];
  const float* ow_ = (const float*)d_in[4];
  const float* ln1 = (const float*)d_in[5];
  const float* ln2 = (const float*)d_in[6];
  const float* rw  = (const float*)d_in[7];
  const float* gw  = (const float*)d_in[8];
  const float* uw  = (const float*)d_in[9];
  const float* dw  = (const float*)d_in[10];
  float* out = (float*)d_out;

  uint8_t* ws = (uint8_t*)d_ws;
  double* partial = (double*)ws;
  double* wsd    = (double*)(ws + 229376);
  double* xsd    = (double*)(ws + 229600);
  int*    eidx   = (int*)(ws + 262368);
  float*  Mk     = (float*)(ws + 278752);
  int*    meta   = (int*)(ws + 278912);
  int*    tokidx = (int*)(ws + 279424);
  double* hsd    = (double*)(ws + 297856);
  int8_t* qw     = (int8_t*)(ws + (1ull << 20));
  int8_t* xq     = (int8_t*)(ws + (29ull << 20));
  float*  qbuf   = (float*)(ws + (33ull << 20));
  float*  hhbuf  = (float*)(ws + (33ull << 20));   // aliases qbuf (dead by then)
  float*  kbuf   = (float*)(ws + (49ull << 20));
  int8_t* hq     = (int8_t*)(ws + (52ull << 20));  // inside dead kbuf region
  float*  vbuf   = (float*)(ws + (65ull << 20));

  // weight quantization (deterministic fp64 scales)
  k_absum<<<28 * 1024, 256, 0, stream>>>(qw_, kw_, vw_, ow_, gw, uw, dw, partial);
  k_wscale<<<28, 256, 0, stream>>>(partial, wsd);
  k_quantw<<<28 * 1024, 256, 0, stream>>>(qw_, kw_, vw_, ow_, gw, uw, dw, wsd, qw);

  // attention input: rmsnorm + act_quant
  k_rms1<<<NTOK, 256, 0, stream>>>(x, ln1, xq, xsd);
  // q/k/v projections fused into one launch (3 blocks/CU -> latency hiding)
  k_gemm3<<<dim3(8, 32, 3), 256, 0, stream>>>(xq, xsd, qw, wsd, qbuf, kbuf, vbuf);
  // causal flash attention (pair-exact full-MFMA, VA swizzled)
  k_knorm<<<32, 256, 0, stream>>>(kbuf, Mk);
  k_attn<<<dim3(512), 512, 0, stream>>>(qbuf, kbuf, vbuf, qbuf, Mk);
  // o projection with residual: x2 = x + bitlinear(h, o_w) -> vbuf
  k_actq<<<NTOK, 256, 0, stream>>>(qbuf, xq, xsd);
  k_gemm<<<dim3(8, 32), 256, 0, stream>>>(xq, xsd, qw + (3 << 20), wsd, 3, x, vbuf);
  // MoE: rmsnorm2 + router argmax + act_quant, then expert-gathered GEMMs
  k_rms2_router<<<NTOK, 256, 0, stream>>>(vbuf, ln2, rw, xq, xsd, eidx);
  k_route<<<1, 256, 0, stream>>>(eidx, meta, tokidx);
  k_moe_gu<<<dim3(8, 71), 256, 0, stream>>>(xq, xsd, qw, wsd, meta, tokidx, hhbuf);
  k_hh_actq<<<4544, 256, 0, stream>>>(hhbuf, meta, tokidx, hq, hsd);
  k_moe_down<<<dim3(8, 71), 256, 0, stream>>>(hq, hsd, qw, wsd, meta, tokidx, vbuf, out);
}

// Round 10
// 497.685 us; speedup vs baseline: 2.8557x; 1.0644x over previous
//
#include <hip/hip_runtime.h>
#include <stdint.h>
#include <math.h>

// Problem constants
#define NTOK 4096   // B*S
#define H    1024
#define NHEAD 16
#define HD   64
#define SEQ  2048
#define NE   8
#define DDIM 1024

typedef __attribute__((ext_vector_type(4)))  int i32x4;
typedef __attribute__((ext_vector_type(16))) int i32x16;
typedef __attribute__((ext_vector_type(8)))  short bf16x8;
typedef __attribute__((ext_vector_type(4)))  float f32x4;

// ---------------- helpers ----------------

__device__ __forceinline__ i32x16 mfma_i8(i32x4 a, i32x4 b, i32x16 c) {
  return __builtin_amdgcn_mfma_i32_32x32x32_i8(a, b, c, 0, 0, 0);
}

// float -> bf16 round-to-nearest-even (finite inputs)
__device__ __forceinline__ unsigned int f2bf(float f) {
  unsigned int u = __float_as_uint(f);
  return (u + 0x7fffu + ((u >> 16) & 1u)) >> 16;
}
__device__ __forceinline__ float bf2f(unsigned int b) {
  return __uint_as_float(b << 16);
}
// pack hi-parts of (a,b) into return, lo-parts (residual bf16) into lo
__device__ __forceinline__ unsigned int f2bf2hl(float a, float b, unsigned int& lo) {
  unsigned int ha = f2bf(a), hb = f2bf(b);
  lo = f2bf(a - bf2f(ha)) | (f2bf(b - bf2f(hb)) << 16);
  return ha | (hb << 16);
}
// pack double-bf16 pair of one float: low ushort = hi, high ushort = lo
__device__ __forceinline__ unsigned int fpair(float a) {
  unsigned int hi = f2bf(a);
  unsigned int lo = f2bf(a - bf2f(hi));
  return hi | (lo << 16);
}
__device__ __forceinline__ unsigned int ror16(unsigned int x) {
  return (x >> 16) | (x << 16);
}

// 256-thread block reduce (double). op=0 sum, op=1 max. tmp: __shared__ double[4]
__device__ __forceinline__ double bredd(double v, int op, double* tmp) {
#pragma unroll
  for (int o = 32; o; o >>= 1) {
    double w = __shfl_xor(v, o);
    v = op ? fmax(v, w) : v + w;
  }
  int wid = threadIdx.x >> 6;
  if ((threadIdx.x & 63) == 0) tmp[wid] = v;
  __syncthreads();
  double r = op ? fmax(fmax(tmp[0], tmp[1]), fmax(tmp[2], tmp[3]))
                : (tmp[0] + tmp[1] + tmp[2] + tmp[3]);
  __syncthreads();
  return r;
}

// quantize 4 doubles to packed int8 with double scale (round-half-even like jnp.round)
__device__ __forceinline__ int qpackd(double n0, double n1, double n2, double n3, double s) {
  int a = (int)fmin(fmax(rint(n0 * s), -128.0), 127.0);
  int b = (int)fmin(fmax(rint(n1 * s), -128.0), 127.0);
  int c = (int)fmin(fmax(rint(n2 * s), -128.0), 127.0);
  int d = (int)fmin(fmax(rint(n3 * s), -128.0), 127.0);
  return (a & 255) | ((b & 255) << 8) | ((c & 255) << 16) | ((d & 255) << 24);
}

// map flat tensor id (0..27, each 1M elems) -> source pointer
__device__ __forceinline__ const float* wsrc(int tensor,
    const float* qw_, const float* kw_, const float* vw_, const float* ow_,
    const float* gw_, const float* uw_, const float* dw_) {
  if (tensor < 4) return tensor == 0 ? qw_ : tensor == 1 ? kw_ : tensor == 2 ? vw_ : ow_;
  if (tensor < 12) return gw_ + ((long long)(tensor - 4) << 20);
  if (tensor < 20) return uw_ + ((long long)(tensor - 12) << 20);
  return dw_ + ((long long)(tensor - 20) << 20);
}

// ---------------- weight quantization (fp64 scale, deterministic) ----------------

__global__ __launch_bounds__(256) void k_absum(
    const float* qw_, const float* kw_, const float* vw_, const float* ow_,
    const float* gw_, const float* uw_, const float* dw_, double* partial) {
  __shared__ double tmp[4];
  int tensor = blockIdx.x >> 10;
  int j = ((blockIdx.x & 1023) << 10) + threadIdx.x * 4;
  const float* src = wsrc(tensor, qw_, kw_, vw_, ow_, gw_, uw_, dw_);
  float4 w = *(const float4*)(src + j);
  double v = fabs((double)w.x) + fabs((double)w.y) + fabs((double)w.z) + fabs((double)w.w);
  v = bredd(v, 0, tmp);
  if (threadIdx.x == 0) partial[blockIdx.x] = v;
}

__global__ __launch_bounds__(256) void k_wscale(const double* partial, double* wsd) {
  __shared__ double tmp[4];
  int tensor = blockIdx.x;
  const double* p = partial + (tensor << 10);
  int i = threadIdx.x * 4;
  double v = p[i] + p[i + 1] + p[i + 2] + p[i + 3];
  v = bredd(v, 0, tmp);
  if (threadIdx.x == 0) wsd[tensor] = 1.0 / fmax(v * (1.0 / 1048576.0), 1e-5);
}

__global__ __launch_bounds__(256) void k_quantw(
    const float* qw_, const float* kw_, const float* vw_, const float* ow_,
    const float* gw_, const float* uw_, const float* dw_,
    const double* wsd, int8_t* qw) {
  int tensor = blockIdx.x >> 10;
  int j = ((blockIdx.x & 1023) << 10) + threadIdx.x * 4;
  const float* src = wsrc(tensor, qw_, kw_, vw_, ow_, gw_, uw_, dw_);
  double s = wsd[tensor];
  float4 w = *(const float4*)(src + j);
  int a = (int)fmin(fmax(rint((double)w.x * s), -1.0), 1.0);
  int b = (int)fmin(fmax(rint((double)w.y * s), -1.0), 1.0);
  int c = (int)fmin(fmax(rint((double)w.z * s), -1.0), 1.0);
  int d = (int)fmin(fmax(rint((double)w.w * s), -1.0), 1.0);
  ((int*)qw)[(tensor << 18) + (j >> 2)] =
      (a & 255) | ((b & 255) << 8) | ((c & 255) << 16) | ((d & 255) << 24);
}

// ---------------- rmsnorm + act_quant (attention input), fp64 decisions ----------------

__global__ __launch_bounds__(256) void k_rms1(const float* X, const float* lnw,
                                              int8_t* xq, double* xsd) {
  __shared__ double tmp[4];
  int t = blockIdx.x, tid = threadIdx.x;
  float4 xv = ((const float4*)(X + (long long)t * H))[tid];
  double x0 = xv.x, x1 = xv.y, x2 = xv.z, x3 = xv.w;
  double ss = x0 * x0 + x1 * x1 + x2 * x2 + x3 * x3;
  ss = bredd(ss, 0, tmp);
  double r = 1.0 / sqrt(ss * (1.0 / 1024.0) + 1e-5);
  float4 wv = ((const float4*)lnw)[tid];
  double n0 = x0 * r * wv.x, n1 = x1 * r * wv.y, n2 = x2 * r * wv.z, n3 = x3 * r * wv.w;
  double ma = fmax(fmax(fabs(n0), fabs(n1)), fmax(fabs(n2), fabs(n3)));
  ma = bredd(ma, 1, tmp);
  double s = 127.0 / fmax(ma, 1e-5);
  ((int*)xq)[t * 256 + tid] = qpackd(n0, n1, n2, n3, s);
  if (tid == 0) xsd[t] = s;
}

// act_quant only (rows of 1024 floats), fp64 decisions
__global__ __launch_bounds__(256) void k_actq(const float* X, int8_t* xq, double* xsd) {
  __shared__ double tmp[4];
  int t = blockIdx.x, tid = threadIdx.x;
  float4 xv = ((const float4*)(X + (long long)t * H))[tid];
  double x0 = xv.x, x1 = xv.y, x2 = xv.z, x3 = xv.w;
  double ma = fmax(fmax(fabs(x0), fabs(x1)), fmax(fabs(x2), fabs(x3)));
  ma = bredd(ma, 1, tmp);
  double s = 127.0 / fmax(ma, 1e-5);
  ((int*)xq)[t * 256 + tid] = qpackd(x0, x1, x2, x3, s);
  if (tid == 0) xsd[t] = s;
}

// ---------------- int8 GEMM via MFMA: out[t,n] = res[t,n] + acc/(xs[t]*sw) -------
// BM=128 BN=128 BK=64. 4 waves 2x2; wave tile 64x64 = 2x2 mfma_i32_32x32x32_i8.
// R16: per-row fp64 inv hoisted to LDS (128 divides/block vs 8192) - bit-identical.

__global__ __launch_bounds__(256) void k_gemm(
    const int8_t* __restrict__ Xq, const double* __restrict__ xsd,
    const int8_t* __restrict__ W, const double* __restrict__ wsd, int widx,
    const float* __restrict__ residual, float* __restrict__ out) {
  __shared__ i32x4 Xs[4][128];
  __shared__ i32x4 Ws[4][128];
  __shared__ double invs[128];
  int tid = threadIdx.x;
  int t0 = blockIdx.y * 128, n0 = blockIdx.x * 128;
  int w = tid >> 6, lane = tid & 63;
  int wm = w >> 1, wn = w & 1;
  int lrow = lane & 31, lk = lane >> 5;
  i32x16 acc[2][2];
#pragma unroll
  for (int i = 0; i < 2; i++)
#pragma unroll
    for (int j = 0; j < 2; j++)
#pragma unroll
      for (int r = 0; r < 16; r++) acc[i][j][r] = 0;

  for (int k0 = 0; k0 < 1024; k0 += 64) {
#pragma unroll
    for (int i = 0; i < 2; i++) {
      int u = tid * 2 + i;                 // 0..511
      int row = u >> 2, kc = u & 3;
      Xs[kc][row] = *(const i32x4*)(Xq + (long long)(t0 + row) * 1024 + k0 + kc * 16);
      Ws[kc][row] = *(const i32x4*)(W  + (long long)(n0 + row) * 1024 + k0 + kc * 16);
    }
    __syncthreads();
#pragma unroll
    for (int ks = 0; ks < 2; ks++) {
      i32x4 a0 = Xs[ks * 2 + lk][wm * 64 + lrow];
      i32x4 a1 = Xs[ks * 2 + lk][wm * 64 + 32 + lrow];
      i32x4 b0 = Ws[ks * 2 + lk][wn * 64 + lrow];
      i32x4 b1 = Ws[ks * 2 + lk][wn * 64 + 32 + lrow];
      acc[0][0] = mfma_i8(a0, b0, acc[0][0]);
      acc[0][1] = mfma_i8(a0, b1, acc[0][1]);
      acc[1][0] = mfma_i8(a1, b0, acc[1][0]);
      acc[1][1] = mfma_i8(a1, b1, acc[1][1]);
    }
    __syncthreads();
  }

  double sw = wsd[widx];
  if (tid < 128) invs[tid] = 1.0 / (xsd[t0 + tid] * sw);
  __syncthreads();
#pragma unroll
  for (int i = 0; i < 2; i++) {
#pragma unroll
    for (int r = 0; r < 16; r++) {
      int rloc = wm * 64 + i * 32 + (r & 3) + 8 * (r >> 2) + 4 * lk;
      int trow = t0 + rloc;
      double inv = invs[rloc];
#pragma unroll
      for (int j = 0; j < 2; j++) {
        int n = n0 + wn * 64 + j * 32 + lrow;
        double v = (double)acc[i][j][r] * inv;
        if (residual) v += (double)residual[(long long)trow * H + n];
        out[(long long)trow * H + n] = (float)v;
      }
    }
  }
}

// k_gemm3: fused q/k/v projections. blockIdx.z selects weight tensor + output.
// Same body as k_gemm (no residual). 768 blocks = 3/CU. Integer-exact.

__global__ __launch_bounds__(256) void k_gemm3(
    const int8_t* __restrict__ Xq, const double* __restrict__ xsd,
    const int8_t* __restrict__ qw, const double* __restrict__ wsd,
    float* __restrict__ outq, float* __restrict__ outk, float* __restrict__ outv) {
  __shared__ i32x4 Xs[4][128];
  __shared__ i32x4 Ws[4][128];
  __shared__ double invs[128];
  int z = blockIdx.z;
  const int8_t* W = qw + ((long long)z << 20);
  float* out = z == 0 ? outq : z == 1 ? outk : outv;
  int tid = threadIdx.x;
  int t0 = blockIdx.y * 128, n0 = blockIdx.x * 128;
  int w = tid >> 6, lane = tid & 63;
  int wm = w >> 1, wn = w & 1;
  int lrow = lane & 31, lk = lane >> 5;
  i32x16 acc[2][2];
#pragma unroll
  for (int i = 0; i < 2; i++)
#pragma unroll
    for (int j = 0; j < 2; j++)
#pragma unroll
      for (int r = 0; r < 16; r++) acc[i][j][r] = 0;

  for (int k0 = 0; k0 < 1024; k0 += 64) {
#pragma unroll
    for (int i = 0; i < 2; i++) {
      int u = tid * 2 + i;
      int row = u >> 2, kc = u & 3;
      Xs[kc][row] = *(const i32x4*)(Xq + (long long)(t0 + row) * 1024 + k0 + kc * 16);
      Ws[kc][row] = *(const i32x4*)(W  + (long long)(n0 + row) * 1024 + k0 + kc * 16);
    }
    __syncthreads();
#pragma unroll
    for (int ks = 0; ks < 2; ks++) {
      i32x4 a0 = Xs[ks * 2 + lk][wm * 64 + lrow];
      i32x4 a1 = Xs[ks * 2 + lk][wm * 64 + 32 + lrow];
      i32x4 b0 = Ws[ks * 2 + lk][wn * 64 + lrow];
      i32x4 b1 = Ws[ks * 2 + lk][wn * 64 + 32 + lrow];
      acc[0][0] = mfma_i8(a0, b0, acc[0][0]);
      acc[0][1] = mfma_i8(a0, b1, acc[0][1]);
      acc[1][0] = mfma_i8(a1, b0, acc[1][0]);
      acc[1][1] = mfma_i8(a1, b1, acc[1][1]);
    }
    __syncthreads();
  }

  double sw = wsd[z];
  if (tid < 128) invs[tid] = 1.0 / (xsd[t0 + tid] * sw);
  __syncthreads();
#pragma unroll
  for (int i = 0; i < 2; i++) {
#pragma unroll
    for (int r = 0; r < 16; r++) {
      int rloc = wm * 64 + i * 32 + (r & 3) + 8 * (r >> 2) + 4 * lk;
      int trow = t0 + rloc;
      double inv = invs[rloc];
#pragma unroll
      for (int j = 0; j < 2; j++) {
        int n = n0 + wn * 64 + j * 32 + lrow;
        out[(long long)trow * H + n] = (float)((double)acc[i][j][r] * inv);
      }
    }
  }
}

// ---------------- attention ----------------
// k_knorm: per-(b,head) max key L2-norm -> fixed softmax bound.

__global__ __launch_bounds__(256) void k_knorm(const float* __restrict__ K,
                                               float* __restrict__ Mk) {
  __shared__ float tmp[4];
  int bh = blockIdx.x;          // b*16 + head
  int b = bh >> 4, head = bh & 15;
  int tid = threadIdx.x;
  float mx = 0.f;
  for (int key = tid; key < SEQ; key += 256) {
    const float4* kr = (const float4*)(K + ((long long)(b * SEQ + key)) * H + head * HD);
    float s = 0.f;
#pragma unroll
    for (int i = 0; i < 16; i++) {
      float4 v = kr[i];
      s += v.x * v.x + v.y * v.y + v.z * v.z + v.w * v.w;
    }
    mx = fmaxf(mx, s);
  }
#pragma unroll
  for (int o = 32; o; o >>= 1) mx = fmaxf(mx, __shfl_xor(mx, o));
  if ((tid & 63) == 0) tmp[tid >> 6] = mx;
  __syncthreads();
  if (tid == 0)
    Mk[bh] = sqrtf(fmaxf(fmaxf(tmp[0], tmp[1]), fmaxf(tmp[2], tmp[3])));
}

// k_attn (R16): R15 + softmax fused into the QK C-dump. The C-frag owner lane
// (row=qb*16+lhi*4+r, col=kb*16+l15) already holds the logit in a register:
// apply causal mask + exp + fpair there and write the WEIGHT pair directly to
// Pw. Eliminates the separate weight-pass phase (its 96B/thread/tile LDS
// round-trip) and one barrier per tile (4 -> 3). Row-sum l: per-lane register
// partial lp[r] += wgt across all tiles (order-free sum), ONE 16-lane
// shfl-reduce per phase, published via lsh[8][16]; epilogue sums the two
// col-half waves. All weight values bit-identical to R15; only l's summation
// order changes (~1e-7). PV pair-exact MFMA + swizzled VA unchanged.

__global__ __launch_bounds__(512, 4) void k_attn(
    const float* __restrict__ Q, const float* __restrict__ K,
    const float* __restrict__ V, float* __restrict__ O,
    const float* __restrict__ Mk) {
  __shared__ unsigned short Qb[64][72];     // Q bf16 hi (x0.125)
  __shared__ unsigned short Ql[64][72];     // Q bf16 lo
  __shared__ unsigned short Kb[64][72];     // K bf16 hi
  __shared__ unsigned short Kl[64][72];     // K bf16 lo
  __shared__ unsigned int   VA[64][76];     // V^T pairs, col-swizzled
  __shared__ unsigned int   Pw[64][76];     // softmax weight pairs
  __shared__ float mbs[64];
  __shared__ float lsh[8][16];
  int i = blockIdx.x;
  int hb = (i & 7) | (((i >> 3) & 3) << 3);
  int p  = ((i >> 5) & 7) | (((i >> 8) & 1) << 3);
  int head = hb & 15, b = hb >> 4;
  int tid = threadIdx.x;
  int w = tid >> 6, lane = tid & 63;
  int quad = lane >> 2, dp = lane & 3;
  int d0 = dp << 4;
  int l15 = lane & 15, lhi = lane >> 4;
  int qh = w >> 2, ks = w & 3;
  long long bh_base = ((long long)b * SEQ) * H + head * HD;
  float mkv = Mk[b * 16 + head];

  int srow = tid >> 3;               // staging row 0..63
  int sd = (tid & 7) << 3;           // staging elem offset 0,8,..,56
  int vswz = (tid & 7) << 2;         // V^T staging column swizzle

  int qb = w >> 1;                   // wave's q-block (QK and PV epilogue)

  for (int ph = 0; ph < 2; ph++) {
    int g = ph ? (31 - p) : p;
    int qlo = g * 64;

    // stage Q tile as double-bf16 (x0.125), once per phase
    {
      const float* qg = Q + bh_base + (long long)(qlo + srow) * H + sd;
      float4 a = *(const float4*)qg;
      float4 c = *(const float4*)(qg + 4);
      uint4 phh, pll;
      phh.x = f2bf2hl(a.x * 0.125f, a.y * 0.125f, pll.x);
      phh.y = f2bf2hl(a.z * 0.125f, a.w * 0.125f, pll.y);
      phh.z = f2bf2hl(c.x * 0.125f, c.y * 0.125f, pll.z);
      phh.w = f2bf2hl(c.z * 0.125f, c.w * 0.125f, pll.w);
      *(uint4*)&Qb[srow][sd] = phh;
      *(uint4*)&Ql[srow][sd] = pll;
    }

    // fixed bound mb = 0.125*|q|*max|k| into mbs[] (ks==0 waves cover all rows)
    if (ks == 0) {
      int j0 = qh * 32 + quad * 2;
#pragma unroll
      for (int qq = 0; qq < 2; qq++) {
        int j = j0 + qq;
        const float4* qp_ = (const float4*)(Q + bh_base + (long long)(qlo + j) * H + d0);
        float ss = 0.f;
#pragma unroll
        for (int i2 = 0; i2 < 4; i2++) {
          float4 t = qp_[i2];
          ss += t.x * t.x + t.y * t.y + t.z * t.z + t.w * t.w;
        }
        ss += __shfl_xor(ss, 1);
        ss += __shfl_xor(ss, 2);
        if (dp == 0) mbs[j] = 0.125f * sqrtf(ss) * mkv;
      }
    }

    float lp[4] = {0.f, 0.f, 0.f, 0.f};
    f32x4 oacc[2];
#pragma unroll
    for (int fi = 0; fi < 2; fi++)
#pragma unroll
      for (int r = 0; r < 4; r++) oacc[fi][r] = 0.f;

    __syncthreads();   // Qb/Ql/mbs visible

    // hoist this lane's row bounds (invariant across tiles)
    float mbr4[4];
#pragma unroll
    for (int r = 0; r < 4; r++) mbr4[r] = mbs[qb * 16 + lhi * 4 + r];

    for (int t = 0; t <= g; t++) {
      // ---- stage K (double-bf16) and V^T (interleaved pairs, swizzled col)
      {
        const float* kg = K + bh_base + (long long)(t * 64 + srow) * H + sd;
        const float* vg = V + bh_base + (long long)(t * 64 + srow) * H + sd;
        float4 ka = *(const float4*)kg;
        float4 kc = *(const float4*)(kg + 4);
        uint4 phh, pll;
        phh.x = f2bf2hl(ka.x, ka.y, pll.x);
        phh.y = f2bf2hl(ka.z, ka.w, pll.y);
        phh.z = f2bf2hl(kc.x, kc.y, pll.z);
        phh.w = f2bf2hl(kc.z, kc.w, pll.w);
        *(uint4*)&Kb[srow][sd] = phh;
        *(uint4*)&Kl[srow][sd] = pll;
        float4 va = *(const float4*)vg;
        float4 vc = *(const float4*)(vg + 4);
        int col = srow ^ vswz;
        VA[sd + 0][col] = fpair(va.x);
        VA[sd + 1][col] = fpair(va.y);
        VA[sd + 2][col] = fpair(va.z);
        VA[sd + 3][col] = fpair(va.w);
        VA[sd + 4][col] = fpair(vc.x);
        VA[sd + 5][col] = fpair(vc.y);
        VA[sd + 6][col] = fpair(vc.z);
        VA[sd + 7][col] = fpair(vc.w);
      }
      __syncthreads();

      // ---- QK^T MFMA (3-term double-bf16) + fused mask/exp/pack -> Pw
      {
        bool dg = (t == g);
#pragma unroll
        for (int kb2 = 0; kb2 < 2; kb2++) {
          int kb = (w & 1) * 2 + kb2;
          f32x4 c = {0.f, 0.f, 0.f, 0.f};
#pragma unroll
          for (int ks2 = 0; ks2 < 2; ks2++) {
            bf16x8 ah = *(const bf16x8*)&Qb[qb * 16 + l15][ks2 * 32 + lhi * 8];
            bf16x8 al = *(const bf16x8*)&Ql[qb * 16 + l15][ks2 * 32 + lhi * 8];
            bf16x8 bh = *(const bf16x8*)&Kb[kb * 16 + l15][ks2 * 32 + lhi * 8];
            bf16x8 bl = *(const bf16x8*)&Kl[kb * 16 + l15][ks2 * 32 + lhi * 8];
            c = __builtin_amdgcn_mfma_f32_16x16x32_bf16(al, bh, c, 0, 0, 0);
            c = __builtin_amdgcn_mfma_f32_16x16x32_bf16(ah, bl, c, 0, 0, 0);
            c = __builtin_amdgcn_mfma_f32_16x16x32_bf16(ah, bh, c, 0, 0, 0);
          }
          int colc = kb * 16 + l15;
#pragma unroll
          for (int r = 0; r < 4; r++) {
            int row = qb * 16 + lhi * 4 + r;
            float wgt = (dg && colc > row) ? 0.f : __expf(c[r] - mbr4[r]);
            lp[r] += wgt;
            Pw[row][colc] = fpair(wgt);
          }
        }
      }
      __syncthreads();

      // ---- PV MFMA: frag f = w*2+fi: q-block f>>2 (= qb), d-block f&3
#pragma unroll
      for (int fi = 0; fi < 2; fi++) {
        int f = w * 2 + fi;
        int d4 = f & 3;
#pragma unroll
        for (int c4 = 0; c4 < 4; c4++) {
          bf16x8 af = *(const bf16x8*)&Pw[qb * 16 + l15][c4 * 16 + lhi * 4];
          int row = d4 * 16 + l15;
          int rswz = ((row >> 3) & 7) << 2;
          union { uint4 q; unsigned int u[4]; bf16x8 v; } bb, bs;
          bb.q = *(const uint4*)&VA[row][(c4 * 16 + lhi * 4) ^ rswz];
          oacc[fi] = __builtin_amdgcn_mfma_f32_16x16x32_bf16(af, bb.v, oacc[fi], 0, 0, 0);
#pragma unroll
          for (int j = 0; j < 4; j++)
            bs.u[j] = ror16(bb.u[j]);
          oacc[fi] = __builtin_amdgcn_mfma_f32_16x16x32_bf16(af, bs.v, oacc[fi], 0, 0, 0);
        }
      }
      __syncthreads();
    }

    // ---- l: reduce lp over the 16 l15 lanes (once per phase), publish per wave
#pragma unroll
    for (int r = 0; r < 4; r++) {
      lp[r] += __shfl_xor(lp[r], 1);
      lp[r] += __shfl_xor(lp[r], 2);
      lp[r] += __shfl_xor(lp[r], 4);
      lp[r] += __shfl_xor(lp[r], 8);
    }
    if (l15 == 0) {
#pragma unroll
      for (int r = 0; r < 4; r++) lsh[w][lhi * 4 + r] = lp[r];
    }
    __syncthreads();

    // ---- O epilogue: combine the two col-half waves' l, normalize, store
#pragma unroll
    for (int fi = 0; fi < 2; fi++) {
      int f = w * 2 + fi;
      int d4 = f & 3;
#pragma unroll
      for (int r = 0; r < 4; r++) {
        int idx = lhi * 4 + r;
        float lt = lsh[qb * 2][idx] + lsh[qb * 2 + 1][idx];
        float inv = 1.f / lt;
        int qrow = qb * 16 + idx;
        O[bh_base + (long long)(qlo + qrow) * H + d4 * 16 + l15] = oacc[fi][r] * inv;
      }
    }
    __syncthreads();                 // LDS reuse safe for next phase
  }
}

// ---------------- rmsnorm2 + router (argmax, fp64) + act_quant ----------------

__global__ __launch_bounds__(256) void k_rms2_router(
    const float* X2, const float* lnw, const float* rw,
    int8_t* xq, double* xsd, int* eidx) {
  __shared__ double tmp[4];
  __shared__ double xn[1024];
  __shared__ double logits[8];
  int t = blockIdx.x, tid = threadIdx.x;
  float4 xv = ((const float4*)(X2 + (long long)t * H))[tid];
  double x0 = xv.x, x1 = xv.y, x2 = xv.z, x3 = xv.w;
  double ss = x0 * x0 + x1 * x1 + x2 * x2 + x3 * x3;
  ss = bredd(ss, 0, tmp);
  double r = 1.0 / sqrt(ss * (1.0 / 1024.0) + 1e-5);
  float4 wv = ((const float4*)lnw)[tid];
  double n0 = x0 * r * wv.x, n1 = x1 * r * wv.y, n2 = x2 * r * wv.z, n3 = x3 * r * wv.w;
  xn[tid * 4 + 0] = n0; xn[tid * 4 + 1] = n1;
  xn[tid * 4 + 2] = n2; xn[tid * 4 + 3] = n3;
  double ma = fmax(fmax(fabs(n0), fabs(n1)), fmax(fabs(n2), fabs(n3)));
  ma = bredd(ma, 1, tmp);  // contains syncthreads -> xn visible
  double s = 127.0 / fmax(ma, 1e-5);
  ((int*)xq)[t * 256 + tid] = qpackd(n0, n1, n2, n3, s);
  if (tid == 0) xsd[t] = s;
  if (tid < 64) {
    int e = tid >> 3, i = tid & 7;
    const float* wr = rw + e * 1024;
    double p = 0.0;
    for (int h = i; h < 1024; h += 8) p += xn[h] * (double)wr[h];
    p += __shfl_xor(p, 1);
    p += __shfl_xor(p, 2);
    p += __shfl_xor(p, 4);
    if (i == 0) logits[e] = p;
  }
  __syncthreads();
  if (tid == 0) {
    double best = logits[0];
    int bi = 0;
    for (int e = 1; e < 8; e++)
      if (logits[e] > best) { best = logits[e]; bi = e; }
    eidx[t] = bi;
  }
}

// ---------------- MoE routing: group tokens by expert into padded 64-slot tiles ----
// meta[0] = ntile; meta[1+i] = expert of tile i. tokidx[slot] = token or -1 (pad).

__global__ __launch_bounds__(256) void k_route(const int* __restrict__ eidx,
                                               int* __restrict__ meta,
                                               int* __restrict__ tokidx) {
  __shared__ int cnt[8], pb[9], cur[8];
  int tid = threadIdx.x;
  if (tid < 8) cnt[tid] = 0;
  __syncthreads();
  for (int t = tid; t < NTOK; t += 256) atomicAdd(&cnt[eidx[t]], 1);
  __syncthreads();
  if (tid == 0) {
    pb[0] = 0;
    int nt = 0;
    for (int e = 0; e < 8; e++) {
      int tiles = (cnt[e] + 63) >> 6;
      for (int i = 0; i < tiles; i++) meta[1 + nt + i] = e;
      nt += tiles;
      pb[e + 1] = pb[e] + tiles * 64;
      cur[e] = pb[e];
    }
    meta[0] = nt;
  }
  __syncthreads();
  for (int s = tid; s < 4608; s += 256) tokidx[s] = -1;
  __syncthreads();
  for (int t = tid; t < NTOK; t += 256) {
    int e = eidx[t];
    int s = atomicAdd(&cur[e], 1);
    tokidx[s] = t;
  }
}

// ---------------- MoE gate+up GEMM via MFMA -> hh (fused relu(g)^2*u) ----------

__global__ __launch_bounds__(256) void k_moe_gu(
    const int8_t* __restrict__ Xq, const double* __restrict__ xsd,
    const int8_t* __restrict__ qw, const double* __restrict__ wsd,
    const int* __restrict__ meta, const int* __restrict__ tokidx,
    float* __restrict__ hhbuf) {
  __shared__ i32x4 Xs[4][64];
  __shared__ i32x4 Wg[4][128];
  __shared__ i32x4 Wu[4][128];
  __shared__ double invg[64], invu[64];
  int tile = blockIdx.y;
  if (tile >= meta[0]) return;
  int e = meta[1 + tile];
  int n0 = blockIdx.x * 128;
  int s0 = tile * 64;
  int tid = threadIdx.x;
  int w = tid >> 6, lane = tid & 63;
  int lrow = lane & 31, lk = lane >> 5;
  const int8_t* Gg = qw + ((long long)(4 + e) << 20);
  const int8_t* Ug = qw + ((long long)(12 + e) << 20);
  int xrow = tid >> 2, xkc = tid & 3;
  int tokr = tokidx[s0 + xrow];
  if (tokr < 0) tokr = 0;
  i32x16 accg[2], accu[2];
#pragma unroll
  for (int i = 0; i < 2; i++)
#pragma unroll
    for (int r = 0; r < 16; r++) { accg[i][r] = 0; accu[i][r] = 0; }

  for (int k0 = 0; k0 < 1024; k0 += 64) {
    Xs[xkc][xrow] = *(const i32x4*)(Xq + (long long)tokr * 1024 + k0 + xkc * 16);
#pragma unroll
    for (int i = 0; i < 2; i++) {
      int u = tid * 2 + i;                 // 0..511
      int row = u >> 2, kc = u & 3;
      Wg[kc][row] = *(const i32x4*)(Gg + (long long)(n0 + row) * 1024 + k0 + kc * 16);
      Wu[kc][row] = *(const i32x4*)(Ug + (long long)(n0 + row) * 1024 + k0 + kc * 16);
    }
    __syncthreads();
#pragma unroll
    for (int ks = 0; ks < 2; ks++) {
      i32x4 a0 = Xs[ks * 2 + lk][lrow];
      i32x4 a1 = Xs[ks * 2 + lk][32 + lrow];
      i32x4 bg = Wg[ks * 2 + lk][w * 32 + lrow];
      i32x4 bu = Wu[ks * 2 + lk][w * 32 + lrow];
      accg[0] = mfma_i8(a0, bg, accg[0]);
      accg[1] = mfma_i8(a1, bg, accg[1]);
      accu[0] = mfma_i8(a0, bu, accu[0]);
      accu[1] = mfma_i8(a1, bu, accu[1]);
    }
    __syncthreads();
  }

  double swg = wsd[4 + e], swu = wsd[12 + e];
  if (tid < 64) {
    int tk = tokidx[s0 + tid];
    double xs = (tk < 0) ? 1.0 : xsd[tk];
    invg[tid] = 1.0 / (xs * swg);
    invu[tid] = 1.0 / (xs * swu);
  }
  __syncthreads();
  int n = n0 + w * 32 + lrow;
#pragma unroll
  for (int i = 0; i < 2; i++) {
#pragma unroll
    for (int r = 0; r < 16; r++) {
      int sl = i * 32 + (r & 3) + 8 * (r >> 2) + 4 * lk;
      int s = s0 + sl;
      int tok = tokidx[s];
      if (tok < 0) continue;
      double g = (double)accg[i][r] * invg[sl];
      double uu = (double)accu[i][r] * invu[sl];
      double rg = fmax(g, 0.0);
      hhbuf[(long long)s * DDIM + n] = (float)(rg * rg * uu);
    }
  }
}

// ---------------- act_quant over hh slot rows ----------------

__global__ __launch_bounds__(256) void k_hh_actq(
    const float* __restrict__ hhbuf, const int* __restrict__ meta,
    const int* __restrict__ tokidx, int8_t* __restrict__ hq,
    double* __restrict__ hsd) {
  __shared__ double tmp[4];
  int s = blockIdx.x;
  if (s >= meta[0] * 64) return;
  int tid = threadIdx.x;
  int tok = tokidx[s];
  if (tok < 0) {
    ((int*)hq)[s * 256 + tid] = 0;
    if (tid == 0) hsd[s] = 1.0;
    return;
  }
  float4 xv = ((const float4*)(hhbuf + (long long)s * DDIM))[tid];
  double x0 = xv.x, x1 = xv.y, x2 = xv.z, x3 = xv.w;
  double ma = fmax(fmax(fabs(x0), fabs(x1)), fmax(fabs(x2), fabs(x3)));
  ma = bredd(ma, 1, tmp);
  double sc = 127.0 / fmax(ma, 1e-5);
  ((int*)hq)[s * 256 + tid] = qpackd(x0, x1, x2, x3, sc);
  if (tid == 0) hsd[s] = sc;
}

// ---------------- MoE down GEMM via MFMA + residual -> out (scatter) ------------

__global__ __launch_bounds__(256) void k_moe_down(
    const int8_t* __restrict__ hq, const double* __restrict__ hsd,
    const int8_t* __restrict__ qw, const double* __restrict__ wsd,
    const int* __restrict__ meta, const int* __restrict__ tokidx,
    const float* __restrict__ x2, float* __restrict__ out) {
  __shared__ i32x4 Xs[4][64];
  __shared__ i32x4 Ws[4][128];
  __shared__ double invd[64];
  int tile = blockIdx.y;
  if (tile >= meta[0]) return;
  int e = meta[1 + tile];
  int n0 = blockIdx.x * 128;
  int s0 = tile * 64;
  int tid = threadIdx.x;
  int w = tid >> 6, lane = tid & 63;
  int lrow = lane & 31, lk = lane >> 5;
  const int8_t* Wp = qw + ((long long)(20 + e) << 20);
  int xrow = tid >> 2, xkc = tid & 3;
  i32x16 acc[2];
#pragma unroll
  for (int i = 0; i < 2; i++)
#pragma unroll
    for (int r = 0; r < 16; r++) acc[i][r] = 0;

  for (int k0 = 0; k0 < 1024; k0 += 64) {
    Xs[xkc][xrow] = *(const i32x4*)(hq + (long long)(s0 + xrow) * 1024 + k0 + xkc * 16);
#pragma unroll
    for (int i = 0; i < 2; i++) {
      int u = tid * 2 + i;
      int row = u >> 2, kc = u & 3;
      Ws[kc][row] = *(const i32x4*)(Wp + (long long)(n0 + row) * 1024 + k0 + kc * 16);
    }
    __syncthreads();
#pragma unroll
    for (int ks = 0; ks < 2; ks++) {
      i32x4 a0 = Xs[ks * 2 + lk][lrow];
      i32x4 a1 = Xs[ks * 2 + lk][32 + lrow];
      i32x4 b  = Ws[ks * 2 + lk][w * 32 + lrow];
      acc[0] = mfma_i8(a0, b, acc[0]);
      acc[1] = mfma_i8(a1, b, acc[1]);
    }
    __syncthreads();
  }

  double sw = wsd[20 + e];
  if (tid < 64) invd[tid] = 1.0 / (hsd[s0 + tid] * sw);
  __syncthreads();
  int n = n0 + w * 32 + lrow;
#pragma unroll
  for (int i = 0; i < 2; i++) {
#pragma unroll
    for (int r = 0; r < 16; r++) {
      int sl = i * 32 + (r & 3) + 8 * (r >> 2) + 4 * lk;
      int s = s0 + sl;
      int tok = tokidx[s];
      if (tok < 0) continue;
      out[(long long)tok * H + n] =
          (float)((double)x2[(long long)tok * H + n] + (double)acc[i][r] * invd[sl]);
    }
  }
}

// ---------------- launch ----------------
// ws layout (bytes):
//   0        partial double[28*1024] (224 KB)
//   229376   wsd double[28]
//   229600   xsd double[4096] (32 KB)
//   262368   eidx int[4096] (16 KB)
//   278752   Mk float[32]
//   278912   meta int[128]  (ntile + tile_e)
//   279424   tokidx int[4608] (18 KB)
//   297856   hsd double[4608] (36.9 KB)
//   1MB      qw int8: 28 x 1MB
//   29MB     xq int8 4MB
//   33MB     qbuf fp32 16MB (q -> attn out h); later hhbuf f32 [4544][1024] (18.6MB, 33..51.6)
//   49MB     kbuf fp32 16MB (k; dead after attn)
//   52MB     hq int8 [4544][1024] (4.65MB, 52..56.7)   <- inside dead kbuf region
//   65MB     vbuf fp32 16MB (v -> x2 residual)

extern "C" void kernel_launch(void* const* d_in, const int* in_sizes, int n_in,
                              void* d_out, int out_size, void* d_ws, size_t ws_size,
                              hipStream_t stream) {
  const float* x   = (const float*)d_in[0];
  const float* qw_ = (const float*)d_in[1];
  const float* kw_ = (const float*)d_in[2];
  const float* vw_ = (const float*)d_in[3];
  const float* ow_ = (const float*)d_in[4];
  const float* ln1 = (const float*)d_in[5];
  const float* ln2 = (const float*)d_in[6];
  const float* rw  = (const float*)d_in[7];
  const float* gw  = (const float*)d_in[8];
  const float* uw  = (const float*)d_in[9];
  const float* dw  = (const float*)d_in[10];
  float* out = (float*)d_out;

  uint8_t* ws = (uint8_t*)d_ws;
  double* partial = (double*)ws;
  double* wsd    = (double*)(ws + 229376);
  double* xsd    = (double*)(ws + 229600);
  int*    eidx   = (int*)(ws + 262368);
  float*  Mk     = (float*)(ws + 278752);
  int*    meta   = (int*)(ws + 278912);
  int*    tokidx = (int*)(ws + 279424);
  double* hsd    = (double*)(ws + 297856);
  int8_t* qw     = (int8_t*)(ws + (1ull << 20));
  int8_t* xq     = (int8_t*)(ws + (29ull << 20));
  float*  qbuf   = (float*)(ws + (33ull << 20));
  float*  hhbuf  = (float*)(ws + (33ull << 20));   // aliases qbuf (dead by then)
  float*  kbuf   = (float*)(ws + (49ull << 20));
  int8_t* hq     = (int8_t*)(ws + (52ull << 20));  // inside dead kbuf region
  float*  vbuf   = (float*)(ws + (65ull << 20));

  // weight quantization (deterministic fp64 scales)
  k_absum<<<28 * 1024, 256, 0, stream>>>(qw_, kw_, vw_, ow_, gw, uw, dw, partial);
  k_wscale<<<28, 256, 0, stream>>>(partial, wsd);
  k_quantw<<<28 * 1024, 256, 0, stream>>>(qw_, kw_, vw_, ow_, gw, uw, dw, wsd, qw);

  // attention input: rmsnorm + act_quant
  k_rms1<<<NTOK, 256, 0, stream>>>(x, ln1, xq, xsd);
  // q/k/v projections fused into one launch (3 blocks/CU -> latency hiding)
  k_gemm3<<<dim3(8, 32, 3), 256, 0, stream>>>(xq, xsd, qw, wsd, qbuf, kbuf, vbuf);
  // causal flash attention (pair-exact full-MFMA, fused softmax in QK dump)
  k_knorm<<<32, 256, 0, stream>>>(kbuf, Mk);
  k_attn<<<dim3(512), 512, 0, stream>>>(qbuf, kbuf, vbuf, qbuf, Mk);
  // o projection with residual: x2 = x + bitlinear(h, o_w) -> vbuf
  k_actq<<<NTOK, 256, 0, stream>>>(qbuf, xq, xsd);
  k_gemm<<<dim3(8, 32), 256, 0, stream>>>(xq, xsd, qw + (3 << 20), wsd, 3, x, vbuf);
  // MoE: rmsnorm2 + router argmax + act_quant, then expert-gathered GEMMs
  k_rms2_router<<<NTOK, 256, 0, stream>>>(vbuf, ln2, rw, xq, xsd, eidx);
  k_route<<<1, 256, 0, stream>>>(eidx, meta, tokidx);
  k_moe_gu<<<dim3(8, 71), 256, 0, stream>>>(xq, xsd, qw, wsd, meta, tokidx, hhbuf);
  k_hh_actq<<<4544, 256, 0, stream>>>(hhbuf, meta, tokidx, hq, hsd);
  k_moe_down<<<dim3(8, 71), 256, 0, stream>>>(hq, hsd, qw, wsd, meta, tokidx, vbuf, out);
}

// Round 11
// 489.996 us; speedup vs baseline: 2.9005x; 1.0157x over previous
//
#include <hip/hip_runtime.h>
#include <stdint.h>
#include <math.h>

// Problem constants
#define NTOK 4096   // B*S
#define H    1024
#define NHEAD 16
#define HD   64
#define SEQ  2048
#define NE   8
#define DDIM 1024

typedef __attribute__((ext_vector_type(4)))  int i32x4;
typedef __attribute__((ext_vector_type(16))) int i32x16;
typedef __attribute__((ext_vector_type(8)))  short bf16x8;
typedef __attribute__((ext_vector_type(4)))  float f32x4;

// ---------------- helpers ----------------

__device__ __forceinline__ i32x16 mfma_i8(i32x4 a, i32x4 b, i32x16 c) {
  return __builtin_amdgcn_mfma_i32_32x32x32_i8(a, b, c, 0, 0, 0);
}

// float -> bf16 round-to-nearest-even (finite inputs)
__device__ __forceinline__ unsigned int f2bf(float f) {
  unsigned int u = __float_as_uint(f);
  return (u + 0x7fffu + ((u >> 16) & 1u)) >> 16;
}
__device__ __forceinline__ float bf2f(unsigned int b) {
  return __uint_as_float(b << 16);
}
// pack hi-parts of (a,b) into return, lo-parts (residual bf16) into lo
__device__ __forceinline__ unsigned int f2bf2hl(float a, float b, unsigned int& lo) {
  unsigned int ha = f2bf(a), hb = f2bf(b);
  lo = f2bf(a - bf2f(ha)) | (f2bf(b - bf2f(hb)) << 16);
  return ha | (hb << 16);
}
// pack double-bf16 pair of one float: low ushort = hi, high ushort = lo
__device__ __forceinline__ unsigned int fpair(float a) {
  unsigned int hi = f2bf(a);
  unsigned int lo = f2bf(a - bf2f(hi));
  return hi | (lo << 16);
}
__device__ __forceinline__ unsigned int ror16(unsigned int x) {
  return (x >> 16) | (x << 16);
}

// 256-thread block reduce (double). op=0 sum, op=1 max. tmp: __shared__ double[4]
__device__ __forceinline__ double bredd(double v, int op, double* tmp) {
#pragma unroll
  for (int o = 32; o; o >>= 1) {
    double w = __shfl_xor(v, o);
    v = op ? fmax(v, w) : v + w;
  }
  int wid = threadIdx.x >> 6;
  if ((threadIdx.x & 63) == 0) tmp[wid] = v;
  __syncthreads();
  double r = op ? fmax(fmax(tmp[0], tmp[1]), fmax(tmp[2], tmp[3]))
                : (tmp[0] + tmp[1] + tmp[2] + tmp[3]);
  __syncthreads();
  return r;
}

// quantize 4 doubles to packed int8 with double scale (round-half-even like jnp.round)
__device__ __forceinline__ int qpackd(double n0, double n1, double n2, double n3, double s) {
  int a = (int)fmin(fmax(rint(n0 * s), -128.0), 127.0);
  int b = (int)fmin(fmax(rint(n1 * s), -128.0), 127.0);
  int c = (int)fmin(fmax(rint(n2 * s), -128.0), 127.0);
  int d = (int)fmin(fmax(rint(n3 * s), -128.0), 127.0);
  return (a & 255) | ((b & 255) << 8) | ((c & 255) << 16) | ((d & 255) << 24);
}

// map flat tensor id (0..27, each 1M elems) -> source pointer
__device__ __forceinline__ const float* wsrc(int tensor,
    const float* qw_, const float* kw_, const float* vw_, const float* ow_,
    const float* gw_, const float* uw_, const float* dw_) {
  if (tensor < 4) return tensor == 0 ? qw_ : tensor == 1 ? kw_ : tensor == 2 ? vw_ : ow_;
  if (tensor < 12) return gw_ + ((long long)(tensor - 4) << 20);
  if (tensor < 20) return uw_ + ((long long)(tensor - 12) << 20);
  return dw_ + ((long long)(tensor - 20) << 20);
}

// ---------------- weight quantization (fp64 scale, deterministic) ----------------

__global__ __launch_bounds__(256) void k_absum(
    const float* qw_, const float* kw_, const float* vw_, const float* ow_,
    const float* gw_, const float* uw_, const float* dw_, double* partial) {
  __shared__ double tmp[4];
  int tensor = blockIdx.x >> 10;
  int j = ((blockIdx.x & 1023) << 10) + threadIdx.x * 4;
  const float* src = wsrc(tensor, qw_, kw_, vw_, ow_, gw_, uw_, dw_);
  float4 w = *(const float4*)(src + j);
  double v = fabs((double)w.x) + fabs((double)w.y) + fabs((double)w.z) + fabs((double)w.w);
  v = bredd(v, 0, tmp);
  if (threadIdx.x == 0) partial[blockIdx.x] = v;
}

__global__ __launch_bounds__(256) void k_wscale(const double* partial, double* wsd) {
  __shared__ double tmp[4];
  int tensor = blockIdx.x;
  const double* p = partial + (tensor << 10);
  int i = threadIdx.x * 4;
  double v = p[i] + p[i + 1] + p[i + 2] + p[i + 3];
  v = bredd(v, 0, tmp);
  if (threadIdx.x == 0) wsd[tensor] = 1.0 / fmax(v * (1.0 / 1048576.0), 1e-5);
}

__global__ __launch_bounds__(256) void k_quantw(
    const float* qw_, const float* kw_, const float* vw_, const float* ow_,
    const float* gw_, const float* uw_, const float* dw_,
    const double* wsd, int8_t* qw) {
  int tensor = blockIdx.x >> 10;
  int j = ((blockIdx.x & 1023) << 10) + threadIdx.x * 4;
  const float* src = wsrc(tensor, qw_, kw_, vw_, ow_, gw_, uw_, dw_);
  double s = wsd[tensor];
  float4 w = *(const float4*)(src + j);
  int a = (int)fmin(fmax(rint((double)w.x * s), -1.0), 1.0);
  int b = (int)fmin(fmax(rint((double)w.y * s), -1.0), 1.0);
  int c = (int)fmin(fmax(rint((double)w.z * s), -1.0), 1.0);
  int d = (int)fmin(fmax(rint((double)w.w * s), -1.0), 1.0);
  ((int*)qw)[(tensor << 18) + (j >> 2)] =
      (a & 255) | ((b & 255) << 8) | ((c & 255) << 16) | ((d & 255) << 24);
}

// ---------------- rmsnorm + act_quant (attention input), fp64 decisions ----------------

__global__ __launch_bounds__(256) void k_rms1(const float* X, const float* lnw,
                                              int8_t* xq, double* xsd) {
  __shared__ double tmp[4];
  int t = blockIdx.x, tid = threadIdx.x;
  float4 xv = ((const float4*)(X + (long long)t * H))[tid];
  double x0 = xv.x, x1 = xv.y, x2 = xv.z, x3 = xv.w;
  double ss = x0 * x0 + x1 * x1 + x2 * x2 + x3 * x3;
  ss = bredd(ss, 0, tmp);
  double r = 1.0 / sqrt(ss * (1.0 / 1024.0) + 1e-5);
  float4 wv = ((const float4*)lnw)[tid];
  double n0 = x0 * r * wv.x, n1 = x1 * r * wv.y, n2 = x2 * r * wv.z, n3 = x3 * r * wv.w;
  double ma = fmax(fmax(fabs(n0), fabs(n1)), fmax(fabs(n2), fabs(n3)));
  ma = bredd(ma, 1, tmp);
  double s = 127.0 / fmax(ma, 1e-5);
  ((int*)xq)[t * 256 + tid] = qpackd(n0, n1, n2, n3, s);
  if (tid == 0) xsd[t] = s;
}

// act_quant only (rows of 1024 floats), fp64 decisions
__global__ __launch_bounds__(256) void k_actq(const float* X, int8_t* xq, double* xsd) {
  __shared__ double tmp[4];
  int t = blockIdx.x, tid = threadIdx.x;
  float4 xv = ((const float4*)(X + (long long)t * H))[tid];
  double x0 = xv.x, x1 = xv.y, x2 = xv.z, x3 = xv.w;
  double ma = fmax(fmax(fabs(x0), fabs(x1)), fmax(fabs(x2), fabs(x3)));
  ma = bredd(ma, 1, tmp);
  double s = 127.0 / fmax(ma, 1e-5);
  ((int*)xq)[t * 256 + tid] = qpackd(x0, x1, x2, x3, s);
  if (tid == 0) xsd[t] = s;
}

// ---------------- int8 GEMM via MFMA: out[t,n] = res[t,n] + acc/(xs[t]*sw) -------
// BM=128 BN=128 BK=64. 4 waves 2x2; wave tile 64x64 = 2x2 mfma_i32_32x32x32_i8.
// Per-row fp64 inv hoisted to LDS (128 divides/block vs 8192) - bit-identical.

__global__ __launch_bounds__(256) void k_gemm(
    const int8_t* __restrict__ Xq, const double* __restrict__ xsd,
    const int8_t* __restrict__ W, const double* __restrict__ wsd, int widx,
    const float* __restrict__ residual, float* __restrict__ out) {
  __shared__ i32x4 Xs[4][128];
  __shared__ i32x4 Ws[4][128];
  __shared__ double invs[128];
  int tid = threadIdx.x;
  int t0 = blockIdx.y * 128, n0 = blockIdx.x * 128;
  int w = tid >> 6, lane = tid & 63;
  int wm = w >> 1, wn = w & 1;
  int lrow = lane & 31, lk = lane >> 5;
  i32x16 acc[2][2];
#pragma unroll
  for (int i = 0; i < 2; i++)
#pragma unroll
    for (int j = 0; j < 2; j++)
#pragma unroll
      for (int r = 0; r < 16; r++) acc[i][j][r] = 0;

  for (int k0 = 0; k0 < 1024; k0 += 64) {
#pragma unroll
    for (int i = 0; i < 2; i++) {
      int u = tid * 2 + i;                 // 0..511
      int row = u >> 2, kc = u & 3;
      Xs[kc][row] = *(const i32x4*)(Xq + (long long)(t0 + row) * 1024 + k0 + kc * 16);
      Ws[kc][row] = *(const i32x4*)(W  + (long long)(n0 + row) * 1024 + k0 + kc * 16);
    }
    __syncthreads();
#pragma unroll
    for (int ks = 0; ks < 2; ks++) {
      i32x4 a0 = Xs[ks * 2 + lk][wm * 64 + lrow];
      i32x4 a1 = Xs[ks * 2 + lk][wm * 64 + 32 + lrow];
      i32x4 b0 = Ws[ks * 2 + lk][wn * 64 + lrow];
      i32x4 b1 = Ws[ks * 2 + lk][wn * 64 + 32 + lrow];
      acc[0][0] = mfma_i8(a0, b0, acc[0][0]);
      acc[0][1] = mfma_i8(a0, b1, acc[0][1]);
      acc[1][0] = mfma_i8(a1, b0, acc[1][0]);
      acc[1][1] = mfma_i8(a1, b1, acc[1][1]);
    }
    __syncthreads();
  }

  double sw = wsd[widx];
  if (tid < 128) invs[tid] = 1.0 / (xsd[t0 + tid] * sw);
  __syncthreads();
#pragma unroll
  for (int i = 0; i < 2; i++) {
#pragma unroll
    for (int r = 0; r < 16; r++) {
      int rloc = wm * 64 + i * 32 + (r & 3) + 8 * (r >> 2) + 4 * lk;
      int trow = t0 + rloc;
      double inv = invs[rloc];
#pragma unroll
      for (int j = 0; j < 2; j++) {
        int n = n0 + wn * 64 + j * 32 + lrow;
        double v = (double)acc[i][j][r] * inv;
        if (residual) v += (double)residual[(long long)trow * H + n];
        out[(long long)trow * H + n] = (float)v;
      }
    }
  }
}

// k_gemm3 (R17): fused q/k/v projections writing ATTENTION-NATIVE formats:
//   z==0 (q): fp32 qbuf (for |q| bound reads; later overwritten by attn O)
//   z==1 (k): SPLIT double-bf16 planes Kh/Kl (ushort) - exactly the values
//             k_attn used to compute per-tile via f2bf2hl
//   z==2 (v): interleaved pair words Vp (uint32, fpair) - ditto
// Moves ~90 VALU ops/thread/tile OUT of k_attn's hot loop (and the ~16x
// per-(b,head) recompute redundancy). LDS contents in attn are bit-identical.

__global__ __launch_bounds__(256) void k_gemm3(
    const int8_t* __restrict__ Xq, const double* __restrict__ xsd,
    const int8_t* __restrict__ qw, const double* __restrict__ wsd,
    float* __restrict__ outq, unsigned short* __restrict__ Kh,
    unsigned short* __restrict__ Kl, unsigned int* __restrict__ Vp) {
  __shared__ i32x4 Xs[4][128];
  __shared__ i32x4 Ws[4][128];
  __shared__ double invs[128];
  int z = blockIdx.z;
  const int8_t* W = qw + ((long long)z << 20);
  int tid = threadIdx.x;
  int t0 = blockIdx.y * 128, n0 = blockIdx.x * 128;
  int w = tid >> 6, lane = tid & 63;
  int wm = w >> 1, wn = w & 1;
  int lrow = lane & 31, lk = lane >> 5;
  i32x16 acc[2][2];
#pragma unroll
  for (int i = 0; i < 2; i++)
#pragma unroll
    for (int j = 0; j < 2; j++)
#pragma unroll
      for (int r = 0; r < 16; r++) acc[i][j][r] = 0;

  for (int k0 = 0; k0 < 1024; k0 += 64) {
#pragma unroll
    for (int i = 0; i < 2; i++) {
      int u = tid * 2 + i;
      int row = u >> 2, kc = u & 3;
      Xs[kc][row] = *(const i32x4*)(Xq + (long long)(t0 + row) * 1024 + k0 + kc * 16);
      Ws[kc][row] = *(const i32x4*)(W  + (long long)(n0 + row) * 1024 + k0 + kc * 16);
    }
    __syncthreads();
#pragma unroll
    for (int ks = 0; ks < 2; ks++) {
      i32x4 a0 = Xs[ks * 2 + lk][wm * 64 + lrow];
      i32x4 a1 = Xs[ks * 2 + lk][wm * 64 + 32 + lrow];
      i32x4 b0 = Ws[ks * 2 + lk][wn * 64 + lrow];
      i32x4 b1 = Ws[ks * 2 + lk][wn * 64 + 32 + lrow];
      acc[0][0] = mfma_i8(a0, b0, acc[0][0]);
      acc[0][1] = mfma_i8(a0, b1, acc[0][1]);
      acc[1][0] = mfma_i8(a1, b0, acc[1][0]);
      acc[1][1] = mfma_i8(a1, b1, acc[1][1]);
    }
    __syncthreads();
  }

  double sw = wsd[z];
  if (tid < 128) invs[tid] = 1.0 / (xsd[t0 + tid] * sw);
  __syncthreads();
#pragma unroll
  for (int i = 0; i < 2; i++) {
#pragma unroll
    for (int r = 0; r < 16; r++) {
      int rloc = wm * 64 + i * 32 + (r & 3) + 8 * (r >> 2) + 4 * lk;
      long long base = (long long)(t0 + rloc) * H;
      double inv = invs[rloc];
#pragma unroll
      for (int j = 0; j < 2; j++) {
        int n = n0 + wn * 64 + j * 32 + lrow;
        float vf = (float)((double)acc[i][j][r] * inv);
        long long idx = base + n;
        if (z == 0) {
          outq[idx] = vf;
        } else if (z == 1) {
          unsigned int h = f2bf(vf);
          unsigned int l = f2bf(vf - bf2f(h));
          Kh[idx] = (unsigned short)h;
          Kl[idx] = (unsigned short)l;
        } else {
          Vp[idx] = fpair(vf);
        }
      }
    }
  }
}

// ---------------- attention ----------------
// k_knorm: per-(b,head) max key L2-norm from packed Kh/Kl (reconstruct h+l).
// Mk differs from fp32 version by ~2^-17 rel; mb shifts per-row uniformly and
// cancels in the l-normalization.

__global__ __launch_bounds__(256) void k_knorm(const unsigned short* __restrict__ Kh,
                                               const unsigned short* __restrict__ Kl,
                                               float* __restrict__ Mk) {
  __shared__ float tmp[4];
  int bh = blockIdx.x;          // b*16 + head
  int b = bh >> 4, head = bh & 15;
  int tid = threadIdx.x;
  float mx = 0.f;
  for (int key = tid; key < SEQ; key += 256) {
    long long base = ((long long)(b * SEQ + key)) * H + head * HD;
    const uint4* hq4 = (const uint4*)(Kh + base);
    const uint4* lq4 = (const uint4*)(Kl + base);
    float s = 0.f;
#pragma unroll
    for (int i = 0; i < 8; i++) {         // 8 x (8 ushorts) = 64 elems
      uint4 hu = hq4[i], lu = lq4[i];
      const unsigned int hw[4] = {hu.x, hu.y, hu.z, hu.w};
      const unsigned int lw[4] = {lu.x, lu.y, lu.z, lu.w};
#pragma unroll
      for (int j = 0; j < 4; j++) {
        float v0 = bf2f(hw[j] & 0xffffu) + bf2f(lw[j] & 0xffffu);
        float v1 = bf2f(hw[j] >> 16)     + bf2f(lw[j] >> 16);
        s += v0 * v0 + v1 * v1;
      }
    }
    mx = fmaxf(mx, s);
  }
#pragma unroll
  for (int o = 32; o; o >>= 1) mx = fmaxf(mx, __shfl_xor(mx, o));
  if ((tid & 63) == 0) tmp[tid >> 6] = mx;
  __syncthreads();
  if (tid == 0)
    Mk[bh] = sqrtf(fmaxf(fmaxf(tmp[0], tmp[1]), fmaxf(tmp[2], tmp[3])));
}

// k_attn (R17): R16 + PRE-PACKED K/V operands. K staged by pure uint4 copy from
// Kh/Kl planes; V staged by uint4 copy from Vp pair-words (swizzled scatter
// unchanged). Zero format-conversion VALU in the per-tile loop (was ~90
// ops/thread/tile, recomputed ~16x per (b,head) across q-tile blocks).
// Q path unchanged (fp32 qbuf; conversion once per phase, amortized).
// All LDS contents bit-identical to R16. Fused softmax in QK C-dump, pair-exact
// PV MFMA, register l-partials, swizzled VA - all unchanged from R16/R15.

__global__ __launch_bounds__(512, 4) void k_attn(
    const float* __restrict__ Q, const unsigned short* __restrict__ KH,
    const unsigned short* __restrict__ KL, const unsigned int* __restrict__ VP,
    float* __restrict__ O, const float* __restrict__ Mk) {
  __shared__ unsigned short Qb[64][72];     // Q bf16 hi (x0.125)
  __shared__ unsigned short Ql[64][72];     // Q bf16 lo
  __shared__ unsigned short Kb[64][72];     // K bf16 hi
  __shared__ unsigned short Kl[64][72];     // K bf16 lo
  __shared__ unsigned int   VA[64][76];     // V^T pairs, col-swizzled
  __shared__ unsigned int   Pw[64][76];     // softmax weight pairs
  __shared__ float mbs[64];
  __shared__ float lsh[8][16];
  int i = blockIdx.x;
  int hb = (i & 7) | (((i >> 3) & 3) << 3);
  int p  = ((i >> 5) & 7) | (((i >> 8) & 1) << 3);
  int head = hb & 15, b = hb >> 4;
  int tid = threadIdx.x;
  int w = tid >> 6, lane = tid & 63;
  int quad = lane >> 2, dp = lane & 3;
  int d0 = dp << 4;
  int l15 = lane & 15, lhi = lane >> 4;
  int qh = w >> 2, ks = w & 3;
  long long bh_base = ((long long)b * SEQ) * H + head * HD;
  float mkv = Mk[b * 16 + head];

  int srow = tid >> 3;               // staging row 0..63
  int sd = (tid & 7) << 3;           // staging elem offset 0,8,..,56
  int vswz = (tid & 7) << 2;         // V^T staging column swizzle

  int qb = w >> 1;                   // wave's q-block (QK and PV epilogue)

  for (int ph = 0; ph < 2; ph++) {
    int g = ph ? (31 - p) : p;
    int qlo = g * 64;

    // stage Q tile as double-bf16 (x0.125), once per phase
    {
      const float* qg = Q + bh_base + (long long)(qlo + srow) * H + sd;
      float4 a = *(const float4*)qg;
      float4 c = *(const float4*)(qg + 4);
      uint4 phh, pll;
      phh.x = f2bf2hl(a.x * 0.125f, a.y * 0.125f, pll.x);
      phh.y = f2bf2hl(a.z * 0.125f, a.w * 0.125f, pll.y);
      phh.z = f2bf2hl(c.x * 0.125f, c.y * 0.125f, pll.z);
      phh.w = f2bf2hl(c.z * 0.125f, c.w * 0.125f, pll.w);
      *(uint4*)&Qb[srow][sd] = phh;
      *(uint4*)&Ql[srow][sd] = pll;
    }

    // fixed bound mb = 0.125*|q|*max|k| into mbs[] (ks==0 waves cover all rows)
    if (ks == 0) {
      int j0 = qh * 32 + quad * 2;
#pragma unroll
      for (int qq = 0; qq < 2; qq++) {
        int j = j0 + qq;
        const float4* qp_ = (const float4*)(Q + bh_base + (long long)(qlo + j) * H + d0);
        float ss = 0.f;
#pragma unroll
        for (int i2 = 0; i2 < 4; i2++) {
          float4 t = qp_[i2];
          ss += t.x * t.x + t.y * t.y + t.z * t.z + t.w * t.w;
        }
        ss += __shfl_xor(ss, 1);
        ss += __shfl_xor(ss, 2);
        if (dp == 0) mbs[j] = 0.125f * sqrtf(ss) * mkv;
      }
    }

    float lp[4] = {0.f, 0.f, 0.f, 0.f};
    f32x4 oacc[2];
#pragma unroll
    for (int fi = 0; fi < 2; fi++)
#pragma unroll
      for (int r = 0; r < 4; r++) oacc[fi][r] = 0.f;

    __syncthreads();   // Qb/Ql/mbs visible

    // hoist this lane's row bounds (invariant across tiles)
    float mbr4[4];
#pragma unroll
    for (int r = 0; r < 4; r++) mbr4[r] = mbs[qb * 16 + lhi * 4 + r];

    for (int t = 0; t <= g; t++) {
      // ---- stage K and V^T: PURE COPY from pre-packed planes
      {
        long long idx = bh_base + (long long)(t * 64 + srow) * H + sd;
        *(uint4*)&Kb[srow][sd] = *(const uint4*)(KH + idx);
        *(uint4*)&Kl[srow][sd] = *(const uint4*)(KL + idx);
        const uint4* vg = (const uint4*)(VP + idx);
        uint4 va = vg[0], vb = vg[1];
        int col = srow ^ vswz;
        VA[sd + 0][col] = va.x;
        VA[sd + 1][col] = va.y;
        VA[sd + 2][col] = va.z;
        VA[sd + 3][col] = va.w;
        VA[sd + 4][col] = vb.x;
        VA[sd + 5][col] = vb.y;
        VA[sd + 6][col] = vb.z;
        VA[sd + 7][col] = vb.w;
      }
      __syncthreads();

      // ---- QK^T MFMA (3-term double-bf16) + fused mask/exp/pack -> Pw
      {
        bool dg = (t == g);
#pragma unroll
        for (int kb2 = 0; kb2 < 2; kb2++) {
          int kb = (w & 1) * 2 + kb2;
          f32x4 c = {0.f, 0.f, 0.f, 0.f};
#pragma unroll
          for (int ks2 = 0; ks2 < 2; ks2++) {
            bf16x8 ah = *(const bf16x8*)&Qb[qb * 16 + l15][ks2 * 32 + lhi * 8];
            bf16x8 al = *(const bf16x8*)&Ql[qb * 16 + l15][ks2 * 32 + lhi * 8];
            bf16x8 bh = *(const bf16x8*)&Kb[kb * 16 + l15][ks2 * 32 + lhi * 8];
            bf16x8 bl = *(const bf16x8*)&Kl[kb * 16 + l15][ks2 * 32 + lhi * 8];
            c = __builtin_amdgcn_mfma_f32_16x16x32_bf16(al, bh, c, 0, 0, 0);
            c = __builtin_amdgcn_mfma_f32_16x16x32_bf16(ah, bl, c, 0, 0, 0);
            c = __builtin_amdgcn_mfma_f32_16x16x32_bf16(ah, bh, c, 0, 0, 0);
          }
          int colc = kb * 16 + l15;
#pragma unroll
          for (int r = 0; r < 4; r++) {
            int row = qb * 16 + lhi * 4 + r;
            float wgt = (dg && colc > row) ? 0.f : __expf(c[r] - mbr4[r]);
            lp[r] += wgt;
            Pw[row][colc] = fpair(wgt);
          }
        }
      }
      __syncthreads();

      // ---- PV MFMA: frag f = w*2+fi: q-block f>>2 (= qb), d-block f&3
#pragma unroll
      for (int fi = 0; fi < 2; fi++) {
        int f = w * 2 + fi;
        int d4 = f & 3;
#pragma unroll
        for (int c4 = 0; c4 < 4; c4++) {
          bf16x8 af = *(const bf16x8*)&Pw[qb * 16 + l15][c4 * 16 + lhi * 4];
          int row = d4 * 16 + l15;
          int rswz = ((row >> 3) & 7) << 2;
          union { uint4 q; unsigned int u[4]; bf16x8 v; } bb, bs;
          bb.q = *(const uint4*)&VA[row][(c4 * 16 + lhi * 4) ^ rswz];
          oacc[fi] = __builtin_amdgcn_mfma_f32_16x16x32_bf16(af, bb.v, oacc[fi], 0, 0, 0);
#pragma unroll
          for (int j = 0; j < 4; j++)
            bs.u[j] = ror16(bb.u[j]);
          oacc[fi] = __builtin_amdgcn_mfma_f32_16x16x32_bf16(af, bs.v, oacc[fi], 0, 0, 0);
        }
      }
      __syncthreads();
    }

    // ---- l: reduce lp over the 16 l15 lanes (once per phase), publish per wave
#pragma unroll
    for (int r = 0; r < 4; r++) {
      lp[r] += __shfl_xor(lp[r], 1);
      lp[r] += __shfl_xor(lp[r], 2);
      lp[r] += __shfl_xor(lp[r], 4);
      lp[r] += __shfl_xor(lp[r], 8);
    }
    if (l15 == 0) {
#pragma unroll
      for (int r = 0; r < 4; r++) lsh[w][lhi * 4 + r] = lp[r];
    }
    __syncthreads();

    // ---- O epilogue: combine the two col-half waves' l, normalize, store
#pragma unroll
    for (int fi = 0; fi < 2; fi++) {
      int f = w * 2 + fi;
      int d4 = f & 3;
#pragma unroll
      for (int r = 0; r < 4; r++) {
        int idx = lhi * 4 + r;
        float lt = lsh[qb * 2][idx] + lsh[qb * 2 + 1][idx];
        float inv = 1.f / lt;
        int qrow = qb * 16 + idx;
        O[bh_base + (long long)(qlo + qrow) * H + d4 * 16 + l15] = oacc[fi][r] * inv;
      }
    }
    __syncthreads();                 // LDS reuse safe for next phase
  }
}

// ---------------- rmsnorm2 + router (argmax, fp64) + act_quant ----------------

__global__ __launch_bounds__(256) void k_rms2_router(
    const float* X2, const float* lnw, const float* rw,
    int8_t* xq, double* xsd, int* eidx) {
  __shared__ double tmp[4];
  __shared__ double xn[1024];
  __shared__ double logits[8];
  int t = blockIdx.x, tid = threadIdx.x;
  float4 xv = ((const float4*)(X2 + (long long)t * H))[tid];
  double x0 = xv.x, x1 = xv.y, x2 = xv.z, x3 = xv.w;
  double ss = x0 * x0 + x1 * x1 + x2 * x2 + x3 * x3;
  ss = bredd(ss, 0, tmp);
  double r = 1.0 / sqrt(ss * (1.0 / 1024.0) + 1e-5);
  float4 wv = ((const float4*)lnw)[tid];
  double n0 = x0 * r * wv.x, n1 = x1 * r * wv.y, n2 = x2 * r * wv.z, n3 = x3 * r * wv.w;
  xn[tid * 4 + 0] = n0; xn[tid * 4 + 1] = n1;
  xn[tid * 4 + 2] = n2; xn[tid * 4 + 3] = n3;
  double ma = fmax(fmax(fabs(n0), fabs(n1)), fmax(fabs(n2), fabs(n3)));
  ma = bredd(ma, 1, tmp);  // contains syncthreads -> xn visible
  double s = 127.0 / fmax(ma, 1e-5);
  ((int*)xq)[t * 256 + tid] = qpackd(n0, n1, n2, n3, s);
  if (tid == 0) xsd[t] = s;
  if (tid < 64) {
    int e = tid >> 3, i = tid & 7;
    const float* wr = rw + e * 1024;
    double p = 0.0;
    for (int h = i; h < 1024; h += 8) p += xn[h] * (double)wr[h];
    p += __shfl_xor(p, 1);
    p += __shfl_xor(p, 2);
    p += __shfl_xor(p, 4);
    if (i == 0) logits[e] = p;
  }
  __syncthreads();
  if (tid == 0) {
    double best = logits[0];
    int bi = 0;
    for (int e = 1; e < 8; e++)
      if (logits[e] > best) { best = logits[e]; bi = e; }
    eidx[t] = bi;
  }
}

// ---------------- MoE routing: group tokens by expert into padded 64-slot tiles ----
// meta[0] = ntile; meta[1+i] = expert of tile i. tokidx[slot] = token or -1 (pad).

__global__ __launch_bounds__(256) void k_route(const int* __restrict__ eidx,
                                               int* __restrict__ meta,
                                               int* __restrict__ tokidx) {
  __shared__ int cnt[8], pb[9], cur[8];
  int tid = threadIdx.x;
  if (tid < 8) cnt[tid] = 0;
  __syncthreads();
  for (int t = tid; t < NTOK; t += 256) atomicAdd(&cnt[eidx[t]], 1);
  __syncthreads();
  if (tid == 0) {
    pb[0] = 0;
    int nt = 0;
    for (int e = 0; e < 8; e++) {
      int tiles = (cnt[e] + 63) >> 6;
      for (int i = 0; i < tiles; i++) meta[1 + nt + i] = e;
      nt += tiles;
      pb[e + 1] = pb[e] + tiles * 64;
      cur[e] = pb[e];
    }
    meta[0] = nt;
  }
  __syncthreads();
  for (int s = tid; s < 4608; s += 256) tokidx[s] = -1;
  __syncthreads();
  for (int t = tid; t < NTOK; t += 256) {
    int e = eidx[t];
    int s = atomicAdd(&cur[e], 1);
    tokidx[s] = t;
  }
}

// ---------------- MoE gate+up GEMM via MFMA -> hh (fused relu(g)^2*u) ----------

__global__ __launch_bounds__(256) void k_moe_gu(
    const int8_t* __restrict__ Xq, const double* __restrict__ xsd,
    const int8_t* __restrict__ qw, const double* __restrict__ wsd,
    const int* __restrict__ meta, const int* __restrict__ tokidx,
    float* __restrict__ hhbuf) {
  __shared__ i32x4 Xs[4][64];
  __shared__ i32x4 Wg[4][128];
  __shared__ i32x4 Wu[4][128];
  __shared__ double invg[64], invu[64];
  int tile = blockIdx.y;
  if (tile >= meta[0]) return;
  int e = meta[1 + tile];
  int n0 = blockIdx.x * 128;
  int s0 = tile * 64;
  int tid = threadIdx.x;
  int w = tid >> 6, lane = tid & 63;
  int lrow = lane & 31, lk = lane >> 5;
  const int8_t* Gg = qw + ((long long)(4 + e) << 20);
  const int8_t* Ug = qw + ((long long)(12 + e) << 20);
  int xrow = tid >> 2, xkc = tid & 3;
  int tokr = tokidx[s0 + xrow];
  if (tokr < 0) tokr = 0;
  i32x16 accg[2], accu[2];
#pragma unroll
  for (int i = 0; i < 2; i++)
#pragma unroll
    for (int r = 0; r < 16; r++) { accg[i][r] = 0; accu[i][r] = 0; }

  for (int k0 = 0; k0 < 1024; k0 += 64) {
    Xs[xkc][xrow] = *(const i32x4*)(Xq + (long long)tokr * 1024 + k0 + xkc * 16);
#pragma unroll
    for (int i = 0; i < 2; i++) {
      int u = tid * 2 + i;                 // 0..511
      int row = u >> 2, kc = u & 3;
      Wg[kc][row] = *(const i32x4*)(Gg + (long long)(n0 + row) * 1024 + k0 + kc * 16);
      Wu[kc][row] = *(const i32x4*)(Ug + (long long)(n0 + row) * 1024 + k0 + kc * 16);
    }
    __syncthreads();
#pragma unroll
    for (int ks = 0; ks < 2; ks++) {
      i32x4 a0 = Xs[ks * 2 + lk][lrow];
      i32x4 a1 = Xs[ks * 2 + lk][32 + lrow];
      i32x4 bg = Wg[ks * 2 + lk][w * 32 + lrow];
      i32x4 bu = Wu[ks * 2 + lk][w * 32 + lrow];
      accg[0] = mfma_i8(a0, bg, accg[0]);
      accg[1] = mfma_i8(a1, bg, accg[1]);
      accu[0] = mfma_i8(a0, bu, accu[0]);
      accu[1] = mfma_i8(a1, bu, accu[1]);
    }
    __syncthreads();
  }

  double swg = wsd[4 + e], swu = wsd[12 + e];
  if (tid < 64) {
    int tk = tokidx[s0 + tid];
    double xs = (tk < 0) ? 1.0 : xsd[tk];
    invg[tid] = 1.0 / (xs * swg);
    invu[tid] = 1.0 / (xs * swu);
  }
  __syncthreads();
  int n = n0 + w * 32 + lrow;
#pragma unroll
  for (int i = 0; i < 2; i++) {
#pragma unroll
    for (int r = 0; r < 16; r++) {
      int sl = i * 32 + (r & 3) + 8 * (r >> 2) + 4 * lk;
      int s = s0 + sl;
      int tok = tokidx[s];
      if (tok < 0) continue;
      double g = (double)accg[i][r] * invg[sl];
      double uu = (double)accu[i][r] * invu[sl];
      double rg = fmax(g, 0.0);
      hhbuf[(long long)s * DDIM + n] = (float)(rg * rg * uu);
    }
  }
}

// ---------------- act_quant over hh slot rows ----------------

__global__ __launch_bounds__(256) void k_hh_actq(
    const float* __restrict__ hhbuf, const int* __restrict__ meta,
    const int* __restrict__ tokidx, int8_t* __restrict__ hq,
    double* __restrict__ hsd) {
  __shared__ double tmp[4];
  int s = blockIdx.x;
  if (s >= meta[0] * 64) return;
  int tid = threadIdx.x;
  int tok = tokidx[s];
  if (tok < 0) {
    ((int*)hq)[s * 256 + tid] = 0;
    if (tid == 0) hsd[s] = 1.0;
    return;
  }
  float4 xv = ((const float4*)(hhbuf + (long long)s * DDIM))[tid];
  double x0 = xv.x, x1 = xv.y, x2 = xv.z, x3 = xv.w;
  double ma = fmax(fmax(fabs(x0), fabs(x1)), fmax(fabs(x2), fabs(x3)));
  ma = bredd(ma, 1, tmp);
  double sc = 127.0 / fmax(ma, 1e-5);
  ((int*)hq)[s * 256 + tid] = qpackd(x0, x1, x2, x3, sc);
  if (tid == 0) hsd[s] = sc;
}

// ---------------- MoE down GEMM via MFMA + residual -> out (scatter) ------------

__global__ __launch_bounds__(256) void k_moe_down(
    const int8_t* __restrict__ hq, const double* __restrict__ hsd,
    const int8_t* __restrict__ qw, const double* __restrict__ wsd,
    const int* __restrict__ meta, const int* __restrict__ tokidx,
    const float* __restrict__ x2, float* __restrict__ out) {
  __shared__ i32x4 Xs[4][64];
  __shared__ i32x4 Ws[4][128];
  __shared__ double invd[64];
  int tile = blockIdx.y;
  if (tile >= meta[0]) return;
  int e = meta[1 + tile];
  int n0 = blockIdx.x * 128;
  int s0 = tile * 64;
  int tid = threadIdx.x;
  int w = tid >> 6, lane = tid & 63;
  int lrow = lane & 31, lk = lane >> 5;
  const int8_t* Wp = qw + ((long long)(20 + e) << 20);
  int xrow = tid >> 2, xkc = tid & 3;
  i32x16 acc[2];
#pragma unroll
  for (int i = 0; i < 2; i++)
#pragma unroll
    for (int r = 0; r < 16; r++) acc[i][r] = 0;

  for (int k0 = 0; k0 < 1024; k0 += 64) {
    Xs[xkc][xrow] = *(const i32x4*)(hq + (long long)(s0 + xrow) * 1024 + k0 + xkc * 16);
#pragma unroll
    for (int i = 0; i < 2; i++) {
      int u = tid * 2 + i;
      int row = u >> 2, kc = u & 3;
      Ws[kc][row] = *(const i32x4*)(Wp + (long long)(n0 + row) * 1024 + k0 + kc * 16);
    }
    __syncthreads();
#pragma unroll
    for (int ks = 0; ks < 2; ks++) {
      i32x4 a0 = Xs[ks * 2 + lk][lrow];
      i32x4 a1 = Xs[ks * 2 + lk][32 + lrow];
      i32x4 b  = Ws[ks * 2 + lk][w * 32 + lrow];
      acc[0] = mfma_i8(a0, b, acc[0]);
      acc[1] = mfma_i8(a1, b, acc[1]);
    }
    __syncthreads();
  }

  double sw = wsd[20 + e];
  if (tid < 64) invd[tid] = 1.0 / (hsd[s0 + tid] * sw);
  __syncthreads();
  int n = n0 + w * 32 + lrow;
#pragma unroll
  for (int i = 0; i < 2; i++) {
#pragma unroll
    for (int r = 0; r < 16; r++) {
      int sl = i * 32 + (r & 3) + 8 * (r >> 2) + 4 * lk;
      int s = s0 + sl;
      int tok = tokidx[s];
      if (tok < 0) continue;
      out[(long long)tok * H + n] =
          (float)((double)x2[(long long)tok * H + n] + (double)acc[i][r] * invd[sl]);
    }
  }
}

// ---------------- launch ----------------
// ws layout (bytes):
//   0        partial double[28*1024] (224 KB)
//   229376   wsd double[28]
//   229600   xsd double[4096] (32 KB)
//   262368   eidx int[4096] (16 KB)
//   278752   Mk float[32]
//   278912   meta int[128]  (ntile + tile_e)
//   279424   tokidx int[4608] (18 KB)
//   297856   hsd double[4608] (36.9 KB)
//   1MB      qw int8: 28 x 1MB
//   29MB     xq int8 4MB
//   33MB     qbuf fp32 16MB (q -> attn out h); later hhbuf f32 [4544][1024] (18.6MB, 33..51.6)
//   49MB     Kh ushort 8MB (dead after attn); hq int8 @52..56.7 later (inside)
//   57MB     Kl ushort 8MB (dead after attn)
//   65MB     Vp uint32 16MB (dead after attn); x2 fp32 written here by o-proj
extern "C" void kernel_launch(void* const* d_in, const int* in_sizes, int n_in,
                              void* d_out, int out_size, void* d_ws, size_t ws_size,
                              hipStream_t stream) {
  const float* x   = (const float*)d_in[0];
  const float* qw_ = (const float*)d_in[1];
  const float* kw_ = (const float*)d_in[2];
  const float* vw_ = (const float*)d_in[3];
  const float* ow_ = (const float*)d_in[4];
  const float* ln1 = (const float*)d_in[5];
  const float* ln2 = (const float*)d_in[6];
  const float* rw  = (const float*)d_in[7];
  const float* gw  = (const float*)d_in[8];
  const float* uw  = (const float*)d_in[9];
  const float* dw  = (const float*)d_in[10];
  float* out = (float*)d_out;

  uint8_t* ws = (uint8_t*)d_ws;
  double* partial = (double*)ws;
  double* wsd    = (double*)(ws + 229376);
  double* xsd    = (double*)(ws + 229600);
  int*    eidx   = (int*)(ws + 262368);
  float*  Mk     = (float*)(ws + 278752);
  int*    meta   = (int*)(ws + 278912);
  int*    tokidx = (int*)(ws + 279424);
  double* hsd    = (double*)(ws + 297856);
  int8_t* qw     = (int8_t*)(ws + (1ull << 20));
  int8_t* xq     = (int8_t*)(ws + (29ull << 20));
  float*  qbuf   = (float*)(ws + (33ull << 20));
  float*  hhbuf  = (float*)(ws + (33ull << 20));   // aliases qbuf (dead by then)
  unsigned short* Kh = (unsigned short*)(ws + (49ull << 20));
  unsigned short* Kl = (unsigned short*)(ws + (57ull << 20));
  int8_t* hq     = (int8_t*)(ws + (52ull << 20));  // inside dead Kh region (post-attn)
  unsigned int* Vp = (unsigned int*)(ws + (65ull << 20));
  float*  vbuf   = (float*)(ws + (65ull << 20));   // x2 overwrites dead Vp post-attn

  // weight quantization (deterministic fp64 scales)
  k_absum<<<28 * 1024, 256, 0, stream>>>(qw_, kw_, vw_, ow_, gw, uw, dw, partial);
  k_wscale<<<28, 256, 0, stream>>>(partial, wsd);
  k_quantw<<<28 * 1024, 256, 0, stream>>>(qw_, kw_, vw_, ow_, gw, uw, dw, wsd, qw);

  // attention input: rmsnorm + act_quant
  k_rms1<<<NTOK, 256, 0, stream>>>(x, ln1, xq, xsd);
  // q/k/v projections fused; k/v written in attention-native packed formats
  k_gemm3<<<dim3(8, 32, 3), 256, 0, stream>>>(xq, xsd, qw, wsd, qbuf, Kh, Kl, Vp);
  // causal flash attention (pre-packed K/V, fused softmax, pair-exact PV)
  k_knorm<<<32, 256, 0, stream>>>(Kh, Kl, Mk);
  k_attn<<<dim3(512), 512, 0, stream>>>(qbuf, Kh, Kl, Vp, qbuf, Mk);
  // o projection with residual: x2 = x + bitlinear(h, o_w) -> vbuf
  k_actq<<<NTOK, 256, 0, stream>>>(qbuf, xq, xsd);
  k_gemm<<<dim3(8, 32), 256, 0, stream>>>(xq, xsd, qw + (3 << 20), wsd, 3, x, vbuf);
  // MoE: rmsnorm2 + router argmax + act_quant, then expert-gathered GEMMs
  k_rms2_router<<<NTOK, 256, 0, stream>>>(vbuf, ln2, rw, xq, xsd, eidx);
  k_route<<<1, 256, 0, stream>>>(eidx, meta, tokidx);
  k_moe_gu<<<dim3(8, 71), 256, 0, stream>>>(xq, xsd, qw, wsd, meta, tokidx, hhbuf);
  k_hh_actq<<<4544, 256, 0, stream>>>(hhbuf, meta, tokidx, hq, hsd);
  k_moe_down<<<dim3(8, 71), 256, 0, stream>>>(hq, hsd, qw, wsd, meta, tokidx, vbuf, out);
}

// Round 12
// 463.490 us; speedup vs baseline: 3.0664x; 1.0572x over previous
//
#include <hip/hip_runtime.h>
#include <stdint.h>
#include <math.h>

// Problem constants
#define NTOK 4096   // B*S
#define H    1024
#define NHEAD 16
#define HD   64
#define SEQ  2048
#define NE   8
#define DDIM 1024

typedef __attribute__((ext_vector_type(4)))  int i32x4;
typedef __attribute__((ext_vector_type(16))) int i32x16;
typedef __attribute__((ext_vector_type(8)))  short bf16x8;
typedef __attribute__((ext_vector_type(4)))  float f32x4;

// ---------------- helpers ----------------

__device__ __forceinline__ i32x16 mfma_i8(i32x4 a, i32x4 b, i32x16 c) {
  return __builtin_amdgcn_mfma_i32_32x32x32_i8(a, b, c, 0, 0, 0);
}

// float -> bf16 round-to-nearest-even (finite inputs)
__device__ __forceinline__ unsigned int f2bf(float f) {
  unsigned int u = __float_as_uint(f);
  return (u + 0x7fffu + ((u >> 16) & 1u)) >> 16;
}
__device__ __forceinline__ float bf2f(unsigned int b) {
  return __uint_as_float(b << 16);
}
// pack hi-parts of (a,b) into return, lo-parts (residual bf16) into lo
__device__ __forceinline__ unsigned int f2bf2hl(float a, float b, unsigned int& lo) {
  unsigned int ha = f2bf(a), hb = f2bf(b);
  lo = f2bf(a - bf2f(ha)) | (f2bf(b - bf2f(hb)) << 16);
  return ha | (hb << 16);
}
// pack double-bf16 pair of one float: low ushort = hi, high ushort = lo
__device__ __forceinline__ unsigned int fpair(float a) {
  unsigned int hi = f2bf(a);
  unsigned int lo = f2bf(a - bf2f(hi));
  return hi | (lo << 16);
}
__device__ __forceinline__ unsigned int ror16(unsigned int x) {
  return (x >> 16) | (x << 16);
}

// 256-thread block reduce (double). op=0 sum, op=1 max. tmp: __shared__ double[4]
__device__ __forceinline__ double bredd(double v, int op, double* tmp) {
#pragma unroll
  for (int o = 32; o; o >>= 1) {
    double w = __shfl_xor(v, o);
    v = op ? fmax(v, w) : v + w;
  }
  int wid = threadIdx.x >> 6;
  if ((threadIdx.x & 63) == 0) tmp[wid] = v;
  __syncthreads();
  double r = op ? fmax(fmax(tmp[0], tmp[1]), fmax(tmp[2], tmp[3]))
                : (tmp[0] + tmp[1] + tmp[2] + tmp[3]);
  __syncthreads();
  return r;
}

// quantize 4 doubles to packed int8 with double scale (round-half-even like jnp.round)
__device__ __forceinline__ int qpackd(double n0, double n1, double n2, double n3, double s) {
  int a = (int)fmin(fmax(rint(n0 * s), -128.0), 127.0);
  int b = (int)fmin(fmax(rint(n1 * s), -128.0), 127.0);
  int c = (int)fmin(fmax(rint(n2 * s), -128.0), 127.0);
  int d = (int)fmin(fmax(rint(n3 * s), -128.0), 127.0);
  return (a & 255) | ((b & 255) << 8) | ((c & 255) << 16) | ((d & 255) << 24);
}

// map flat tensor id (0..27, each 1M elems) -> source pointer
__device__ __forceinline__ const float* wsrc(int tensor,
    const float* qw_, const float* kw_, const float* vw_, const float* ow_,
    const float* gw_, const float* uw_, const float* dw_) {
  if (tensor < 4) return tensor == 0 ? qw_ : tensor == 1 ? kw_ : tensor == 2 ? vw_ : ow_;
  if (tensor < 12) return gw_ + ((long long)(tensor - 4) << 20);
  if (tensor < 20) return uw_ + ((long long)(tensor - 12) << 20);
  return dw_ + ((long long)(tensor - 20) << 20);
}

// ---------------- weight quantization (fp64 scale, deterministic) ----------------

__global__ __launch_bounds__(256) void k_absum(
    const float* qw_, const float* kw_, const float* vw_, const float* ow_,
    const float* gw_, const float* uw_, const float* dw_, double* partial) {
  __shared__ double tmp[4];
  int tensor = blockIdx.x >> 10;
  int j = ((blockIdx.x & 1023) << 10) + threadIdx.x * 4;
  const float* src = wsrc(tensor, qw_, kw_, vw_, ow_, gw_, uw_, dw_);
  float4 w = *(const float4*)(src + j);
  double v = fabs((double)w.x) + fabs((double)w.y) + fabs((double)w.z) + fabs((double)w.w);
  v = bredd(v, 0, tmp);
  if (threadIdx.x == 0) partial[blockIdx.x] = v;
}

__global__ __launch_bounds__(256) void k_wscale(const double* partial, double* wsd) {
  __shared__ double tmp[4];
  int tensor = blockIdx.x;
  const double* p = partial + (tensor << 10);
  int i = threadIdx.x * 4;
  double v = p[i] + p[i + 1] + p[i + 2] + p[i + 3];
  v = bredd(v, 0, tmp);
  if (threadIdx.x == 0) wsd[tensor] = 1.0 / fmax(v * (1.0 / 1048576.0), 1e-5);
}

__global__ __launch_bounds__(256) void k_quantw(
    const float* qw_, const float* kw_, const float* vw_, const float* ow_,
    const float* gw_, const float* uw_, const float* dw_,
    const double* wsd, int8_t* qw) {
  int tensor = blockIdx.x >> 10;
  int j = ((blockIdx.x & 1023) << 10) + threadIdx.x * 4;
  const float* src = wsrc(tensor, qw_, kw_, vw_, ow_, gw_, uw_, dw_);
  double s = wsd[tensor];
  float4 w = *(const float4*)(src + j);
  int a = (int)fmin(fmax(rint((double)w.x * s), -1.0), 1.0);
  int b = (int)fmin(fmax(rint((double)w.y * s), -1.0), 1.0);
  int c = (int)fmin(fmax(rint((double)w.z * s), -1.0), 1.0);
  int d = (int)fmin(fmax(rint((double)w.w * s), -1.0), 1.0);
  ((int*)qw)[(tensor << 18) + (j >> 2)] =
      (a & 255) | ((b & 255) << 8) | ((c & 255) << 16) | ((d & 255) << 24);
}

// ---------------- rmsnorm + act_quant (attention input), fp64 decisions ----------------

__global__ __launch_bounds__(256) void k_rms1(const float* X, const float* lnw,
                                              int8_t* xq, double* xsd) {
  __shared__ double tmp[4];
  int t = blockIdx.x, tid = threadIdx.x;
  float4 xv = ((const float4*)(X + (long long)t * H))[tid];
  double x0 = xv.x, x1 = xv.y, x2 = xv.z, x3 = xv.w;
  double ss = x0 * x0 + x1 * x1 + x2 * x2 + x3 * x3;
  ss = bredd(ss, 0, tmp);
  double r = 1.0 / sqrt(ss * (1.0 / 1024.0) + 1e-5);
  float4 wv = ((const float4*)lnw)[tid];
  double n0 = x0 * r * wv.x, n1 = x1 * r * wv.y, n2 = x2 * r * wv.z, n3 = x3 * r * wv.w;
  double ma = fmax(fmax(fabs(n0), fabs(n1)), fmax(fabs(n2), fabs(n3)));
  ma = bredd(ma, 1, tmp);
  double s = 127.0 / fmax(ma, 1e-5);
  ((int*)xq)[t * 256 + tid] = qpackd(n0, n1, n2, n3, s);
  if (tid == 0) xsd[t] = s;
}

// act_quant only (rows of 1024 floats), fp64 decisions
__global__ __launch_bounds__(256) void k_actq(const float* X, int8_t* xq, double* xsd) {
  __shared__ double tmp[4];
  int t = blockIdx.x, tid = threadIdx.x;
  float4 xv = ((const float4*)(X + (long long)t * H))[tid];
  double x0 = xv.x, x1 = xv.y, x2 = xv.z, x3 = xv.w;
  double ma = fmax(fmax(fabs(x0), fabs(x1)), fmax(fabs(x2), fabs(x3)));
  ma = bredd(ma, 1, tmp);
  double s = 127.0 / fmax(ma, 1e-5);
  ((int*)xq)[t * 256 + tid] = qpackd(x0, x1, x2, x3, s);
  if (tid == 0) xsd[t] = s;
}

// ---------------- int8 GEMM via MFMA (o-proj): out = res + acc/(xs*sw) ----------
// R18: BM=64 BN=128 BK=64 -> 512 blocks = 2/CU (was 256 = 1/CU, no overlap).
// 4 waves: wave = 64t x 32n, acc[2] row-halves. Integer-exact, same epilogue.

__global__ __launch_bounds__(256) void k_gemm(
    const int8_t* __restrict__ Xq, const double* __restrict__ xsd,
    const int8_t* __restrict__ W, const double* __restrict__ wsd, int widx,
    const float* __restrict__ residual, float* __restrict__ out) {
  __shared__ i32x4 Xs[4][64];
  __shared__ i32x4 Ws[4][128];
  __shared__ double invs[64];
  int tid = threadIdx.x;
  int t0 = blockIdx.y * 64, n0 = blockIdx.x * 128;
  int w = tid >> 6, lane = tid & 63;
  int lrow = lane & 31, lk = lane >> 5;
  int xrow = tid >> 2, xkc = tid & 3;
  i32x16 acc[2];
#pragma unroll
  for (int i = 0; i < 2; i++)
#pragma unroll
    for (int r = 0; r < 16; r++) acc[i][r] = 0;

  for (int k0 = 0; k0 < 1024; k0 += 64) {
    Xs[xkc][xrow] = *(const i32x4*)(Xq + (long long)(t0 + xrow) * 1024 + k0 + xkc * 16);
#pragma unroll
    for (int i = 0; i < 2; i++) {
      int u = tid * 2 + i;
      int row = u >> 2, kc = u & 3;
      Ws[kc][row] = *(const i32x4*)(W + (long long)(n0 + row) * 1024 + k0 + kc * 16);
    }
    __syncthreads();
#pragma unroll
    for (int ks = 0; ks < 2; ks++) {
      i32x4 a0 = Xs[ks * 2 + lk][lrow];
      i32x4 a1 = Xs[ks * 2 + lk][32 + lrow];
      i32x4 b  = Ws[ks * 2 + lk][w * 32 + lrow];
      acc[0] = mfma_i8(a0, b, acc[0]);
      acc[1] = mfma_i8(a1, b, acc[1]);
    }
    __syncthreads();
  }

  double sw = wsd[widx];
  if (tid < 64) invs[tid] = 1.0 / (xsd[t0 + tid] * sw);
  __syncthreads();
  int n = n0 + w * 32 + lrow;
#pragma unroll
  for (int i = 0; i < 2; i++) {
#pragma unroll
    for (int r = 0; r < 16; r++) {
      int rl = i * 32 + (r & 3) + 8 * (r >> 2) + 4 * lk;
      int trow = t0 + rl;
      double v = (double)acc[i][r] * invs[rl];
      if (residual) v += (double)residual[(long long)trow * H + n];
      out[(long long)trow * H + n] = (float)v;
    }
  }
}

// k_gemm3 (R17): fused q/k/v projections writing ATTENTION-NATIVE formats:
//   z==0 (q): fp32 qbuf; z==1 (k): split double-bf16 planes Kh/Kl;
//   z==2 (v): interleaved pair words Vp (fpair).

__global__ __launch_bounds__(256) void k_gemm3(
    const int8_t* __restrict__ Xq, const double* __restrict__ xsd,
    const int8_t* __restrict__ qw, const double* __restrict__ wsd,
    float* __restrict__ outq, unsigned short* __restrict__ Kh,
    unsigned short* __restrict__ Kl, unsigned int* __restrict__ Vp) {
  __shared__ i32x4 Xs[4][128];
  __shared__ i32x4 Ws[4][128];
  __shared__ double invs[128];
  int z = blockIdx.z;
  const int8_t* W = qw + ((long long)z << 20);
  int tid = threadIdx.x;
  int t0 = blockIdx.y * 128, n0 = blockIdx.x * 128;
  int w = tid >> 6, lane = tid & 63;
  int wm = w >> 1, wn = w & 1;
  int lrow = lane & 31, lk = lane >> 5;
  i32x16 acc[2][2];
#pragma unroll
  for (int i = 0; i < 2; i++)
#pragma unroll
    for (int j = 0; j < 2; j++)
#pragma unroll
      for (int r = 0; r < 16; r++) acc[i][j][r] = 0;

  for (int k0 = 0; k0 < 1024; k0 += 64) {
#pragma unroll
    for (int i = 0; i < 2; i++) {
      int u = tid * 2 + i;
      int row = u >> 2, kc = u & 3;
      Xs[kc][row] = *(const i32x4*)(Xq + (long long)(t0 + row) * 1024 + k0 + kc * 16);
      Ws[kc][row] = *(const i32x4*)(W  + (long long)(n0 + row) * 1024 + k0 + kc * 16);
    }
    __syncthreads();
#pragma unroll
    for (int ks = 0; ks < 2; ks++) {
      i32x4 a0 = Xs[ks * 2 + lk][wm * 64 + lrow];
      i32x4 a1 = Xs[ks * 2 + lk][wm * 64 + 32 + lrow];
      i32x4 b0 = Ws[ks * 2 + lk][wn * 64 + lrow];
      i32x4 b1 = Ws[ks * 2 + lk][wn * 64 + 32 + lrow];
      acc[0][0] = mfma_i8(a0, b0, acc[0][0]);
      acc[0][1] = mfma_i8(a0, b1, acc[0][1]);
      acc[1][0] = mfma_i8(a1, b0, acc[1][0]);
      acc[1][1] = mfma_i8(a1, b1, acc[1][1]);
    }
    __syncthreads();
  }

  double sw = wsd[z];
  if (tid < 128) invs[tid] = 1.0 / (xsd[t0 + tid] * sw);
  __syncthreads();
#pragma unroll
  for (int i = 0; i < 2; i++) {
#pragma unroll
    for (int r = 0; r < 16; r++) {
      int rloc = wm * 64 + i * 32 + (r & 3) + 8 * (r >> 2) + 4 * lk;
      long long base = (long long)(t0 + rloc) * H;
      double inv = invs[rloc];
#pragma unroll
      for (int j = 0; j < 2; j++) {
        int n = n0 + wn * 64 + j * 32 + lrow;
        float vf = (float)((double)acc[i][j][r] * inv);
        long long idx = base + n;
        if (z == 0) {
          outq[idx] = vf;
        } else if (z == 1) {
          unsigned int h = f2bf(vf);
          unsigned int l = f2bf(vf - bf2f(h));
          Kh[idx] = (unsigned short)h;
          Kl[idx] = (unsigned short)l;
        } else {
          Vp[idx] = fpair(vf);
        }
      }
    }
  }
}

// ---------------- attention ----------------
// k_knorm: per-(b,head) max key L2-norm from packed Kh/Kl (reconstruct h+l).

__global__ __launch_bounds__(256) void k_knorm(const unsigned short* __restrict__ Kh,
                                               const unsigned short* __restrict__ Kl,
                                               float* __restrict__ Mk) {
  __shared__ float tmp[4];
  int bh = blockIdx.x;          // b*16 + head
  int b = bh >> 4, head = bh & 15;
  int tid = threadIdx.x;
  float mx = 0.f;
  for (int key = tid; key < SEQ; key += 256) {
    long long base = ((long long)(b * SEQ + key)) * H + head * HD;
    const uint4* hq4 = (const uint4*)(Kh + base);
    const uint4* lq4 = (const uint4*)(Kl + base);
    float s = 0.f;
#pragma unroll
    for (int i = 0; i < 8; i++) {         // 8 x (8 ushorts) = 64 elems
      uint4 hu = hq4[i], lu = lq4[i];
      const unsigned int hw[4] = {hu.x, hu.y, hu.z, hu.w};
      const unsigned int lw[4] = {lu.x, lu.y, lu.z, lu.w};
#pragma unroll
      for (int j = 0; j < 4; j++) {
        float v0 = bf2f(hw[j] & 0xffffu) + bf2f(lw[j] & 0xffffu);
        float v1 = bf2f(hw[j] >> 16)     + bf2f(lw[j] >> 16);
        s += v0 * v0 + v1 * v1;
      }
    }
    mx = fmaxf(mx, s);
  }
#pragma unroll
  for (int o = 32; o; o >>= 1) mx = fmaxf(mx, __shfl_xor(mx, o));
  if ((tid & 63) == 0) tmp[tid >> 6] = mx;
  __syncthreads();
  if (tid == 0)
    Mk[bh] = sqrtf(fmaxf(fmaxf(tmp[0], tmp[1]), fmaxf(tmp[2], tmp[3])));
}

// k_attn (R18): R17 + (a) Q MFMA frags hoisted into REGISTERS once per phase
// (Qb/Ql are tile-invariant: -4 b128 LDS reads/thread/tile, ~13% of LDS
// traffic; +16 VGPR, still within 4-wave/SIMD budget), (b) PV restructured
// c4-outer/fi-inner so the Pw A-frag is read once per c4 (guaranteed, not
// compiler-dependent), (c) s_setprio(1) around both MFMA clusters (waves here
// have role diversity across barrier phases - T5's favorable regime).
// All arithmetic bit-identical to R17.

__global__ __launch_bounds__(512, 4) void k_attn(
    const float* __restrict__ Q, const unsigned short* __restrict__ KH,
    const unsigned short* __restrict__ KL, const unsigned int* __restrict__ VP,
    float* __restrict__ O, const float* __restrict__ Mk) {
  __shared__ unsigned short Qb[64][72];     // Q bf16 hi (x0.125)
  __shared__ unsigned short Ql[64][72];     // Q bf16 lo
  __shared__ unsigned short Kb[64][72];     // K bf16 hi
  __shared__ unsigned short Kl[64][72];     // K bf16 lo
  __shared__ unsigned int   VA[64][76];     // V^T pairs, col-swizzled
  __shared__ unsigned int   Pw[64][76];     // softmax weight pairs
  __shared__ float mbs[64];
  __shared__ float lsh[8][16];
  int i = blockIdx.x;
  int hb = (i & 7) | (((i >> 3) & 3) << 3);
  int p  = ((i >> 5) & 7) | (((i >> 8) & 1) << 3);
  int head = hb & 15, b = hb >> 4;
  int tid = threadIdx.x;
  int w = tid >> 6, lane = tid & 63;
  int quad = lane >> 2, dp = lane & 3;
  int d0 = dp << 4;
  int l15 = lane & 15, lhi = lane >> 4;
  int qh = w >> 2, ks = w & 3;
  long long bh_base = ((long long)b * SEQ) * H + head * HD;
  float mkv = Mk[b * 16 + head];

  int srow = tid >> 3;               // staging row 0..63
  int sd = (tid & 7) << 3;           // staging elem offset 0,8,..,56
  int vswz = (tid & 7) << 2;         // V^T staging column swizzle

  int qb = w >> 1;                   // wave's q-block (QK and PV epilogue)

  for (int ph = 0; ph < 2; ph++) {
    int g = ph ? (31 - p) : p;
    int qlo = g * 64;

    // stage Q tile as double-bf16 (x0.125), once per phase
    {
      const float* qg = Q + bh_base + (long long)(qlo + srow) * H + sd;
      float4 a = *(const float4*)qg;
      float4 c = *(const float4*)(qg + 4);
      uint4 phh, pll;
      phh.x = f2bf2hl(a.x * 0.125f, a.y * 0.125f, pll.x);
      phh.y = f2bf2hl(a.z * 0.125f, a.w * 0.125f, pll.y);
      phh.z = f2bf2hl(c.x * 0.125f, c.y * 0.125f, pll.z);
      phh.w = f2bf2hl(c.z * 0.125f, c.w * 0.125f, pll.w);
      *(uint4*)&Qb[srow][sd] = phh;
      *(uint4*)&Ql[srow][sd] = pll;
    }

    // fixed bound mb = 0.125*|q|*max|k| into mbs[] (ks==0 waves cover all rows)
    if (ks == 0) {
      int j0 = qh * 32 + quad * 2;
#pragma unroll
      for (int qq = 0; qq < 2; qq++) {
        int j = j0 + qq;
        const float4* qp_ = (const float4*)(Q + bh_base + (long long)(qlo + j) * H + d0);
        float ss = 0.f;
#pragma unroll
        for (int i2 = 0; i2 < 4; i2++) {
          float4 t = qp_[i2];
          ss += t.x * t.x + t.y * t.y + t.z * t.z + t.w * t.w;
        }
        ss += __shfl_xor(ss, 1);
        ss += __shfl_xor(ss, 2);
        if (dp == 0) mbs[j] = 0.125f * sqrtf(ss) * mkv;
      }
    }

    float lp[4] = {0.f, 0.f, 0.f, 0.f};
    f32x4 oacc[2];
#pragma unroll
    for (int fi = 0; fi < 2; fi++)
#pragma unroll
      for (int r = 0; r < 4; r++) oacc[fi][r] = 0.f;

    __syncthreads();   // Qb/Ql/mbs visible

    // hoist this lane's Q frags (tile-invariant) + row bounds to registers
    bf16x8 qah[2], qal[2];
#pragma unroll
    for (int ks2 = 0; ks2 < 2; ks2++) {
      qah[ks2] = *(const bf16x8*)&Qb[qb * 16 + l15][ks2 * 32 + lhi * 8];
      qal[ks2] = *(const bf16x8*)&Ql[qb * 16 + l15][ks2 * 32 + lhi * 8];
    }
    float mbr4[4];
#pragma unroll
    for (int r = 0; r < 4; r++) mbr4[r] = mbs[qb * 16 + lhi * 4 + r];

    for (int t = 0; t <= g; t++) {
      // ---- stage K and V^T: PURE COPY from pre-packed planes
      {
        long long idx = bh_base + (long long)(t * 64 + srow) * H + sd;
        *(uint4*)&Kb[srow][sd] = *(const uint4*)(KH + idx);
        *(uint4*)&Kl[srow][sd] = *(const uint4*)(KL + idx);
        const uint4* vg = (const uint4*)(VP + idx);
        uint4 va = vg[0], vb = vg[1];
        int col = srow ^ vswz;
        VA[sd + 0][col] = va.x;
        VA[sd + 1][col] = va.y;
        VA[sd + 2][col] = va.z;
        VA[sd + 3][col] = va.w;
        VA[sd + 4][col] = vb.x;
        VA[sd + 5][col] = vb.y;
        VA[sd + 6][col] = vb.z;
        VA[sd + 7][col] = vb.w;
      }
      __syncthreads();

      // ---- QK^T MFMA (3-term double-bf16, reg A) + fused mask/exp/pack -> Pw
      {
        bool dg = (t == g);
#pragma unroll
        for (int kb2 = 0; kb2 < 2; kb2++) {
          int kb = (w & 1) * 2 + kb2;
          f32x4 c = {0.f, 0.f, 0.f, 0.f};
          __builtin_amdgcn_s_setprio(1);
#pragma unroll
          for (int ks2 = 0; ks2 < 2; ks2++) {
            bf16x8 bh = *(const bf16x8*)&Kb[kb * 16 + l15][ks2 * 32 + lhi * 8];
            bf16x8 bl = *(const bf16x8*)&Kl[kb * 16 + l15][ks2 * 32 + lhi * 8];
            c = __builtin_amdgcn_mfma_f32_16x16x32_bf16(qal[ks2], bh, c, 0, 0, 0);
            c = __builtin_amdgcn_mfma_f32_16x16x32_bf16(qah[ks2], bl, c, 0, 0, 0);
            c = __builtin_amdgcn_mfma_f32_16x16x32_bf16(qah[ks2], bh, c, 0, 0, 0);
          }
          __builtin_amdgcn_s_setprio(0);
          int colc = kb * 16 + l15;
#pragma unroll
          for (int r = 0; r < 4; r++) {
            int row = qb * 16 + lhi * 4 + r;
            float wgt = (dg && colc > row) ? 0.f : __expf(c[r] - mbr4[r]);
            lp[r] += wgt;
            Pw[row][colc] = fpair(wgt);
          }
        }
      }
      __syncthreads();

      // ---- PV MFMA: c4 outer (A-frag read once), fi inner (d-block)
      __builtin_amdgcn_s_setprio(1);
#pragma unroll
      for (int c4 = 0; c4 < 4; c4++) {
        bf16x8 af = *(const bf16x8*)&Pw[qb * 16 + l15][c4 * 16 + lhi * 4];
#pragma unroll
        for (int fi = 0; fi < 2; fi++) {
          int d4 = (w * 2 + fi) & 3;
          int row = d4 * 16 + l15;
          int rswz = ((row >> 3) & 7) << 2;
          union { uint4 q; unsigned int u[4]; bf16x8 v; } bb, bs;
          bb.q = *(const uint4*)&VA[row][(c4 * 16 + lhi * 4) ^ rswz];
          oacc[fi] = __builtin_amdgcn_mfma_f32_16x16x32_bf16(af, bb.v, oacc[fi], 0, 0, 0);
#pragma unroll
          for (int j = 0; j < 4; j++)
            bs.u[j] = ror16(bb.u[j]);
          oacc[fi] = __builtin_amdgcn_mfma_f32_16x16x32_bf16(af, bs.v, oacc[fi], 0, 0, 0);
        }
      }
      __builtin_amdgcn_s_setprio(0);
      __syncthreads();
    }

    // ---- l: reduce lp over the 16 l15 lanes (once per phase), publish per wave
#pragma unroll
    for (int r = 0; r < 4; r++) {
      lp[r] += __shfl_xor(lp[r], 1);
      lp[r] += __shfl_xor(lp[r], 2);
      lp[r] += __shfl_xor(lp[r], 4);
      lp[r] += __shfl_xor(lp[r], 8);
    }
    if (l15 == 0) {
#pragma unroll
      for (int r = 0; r < 4; r++) lsh[w][lhi * 4 + r] = lp[r];
    }
    __syncthreads();

    // ---- O epilogue: combine the two col-half waves' l, normalize, store
#pragma unroll
    for (int fi = 0; fi < 2; fi++) {
      int f = w * 2 + fi;
      int d4 = f & 3;
#pragma unroll
      for (int r = 0; r < 4; r++) {
        int idx = lhi * 4 + r;
        float lt = lsh[qb * 2][idx] + lsh[qb * 2 + 1][idx];
        float inv = 1.f / lt;
        int qrow = qb * 16 + idx;
        O[bh_base + (long long)(qlo + qrow) * H + d4 * 16 + l15] = oacc[fi][r] * inv;
      }
    }
    __syncthreads();                 // LDS reuse safe for next phase
  }
}

// ---------------- rmsnorm2 + router (argmax, fp64) + act_quant ----------------

__global__ __launch_bounds__(256) void k_rms2_router(
    const float* X2, const float* lnw, const float* rw,
    int8_t* xq, double* xsd, int* eidx) {
  __shared__ double tmp[4];
  __shared__ double xn[1024];
  __shared__ double logits[8];
  int t = blockIdx.x, tid = threadIdx.x;
  float4 xv = ((const float4*)(X2 + (long long)t * H))[tid];
  double x0 = xv.x, x1 = xv.y, x2 = xv.z, x3 = xv.w;
  double ss = x0 * x0 + x1 * x1 + x2 * x2 + x3 * x3;
  ss = bredd(ss, 0, tmp);
  double r = 1.0 / sqrt(ss * (1.0 / 1024.0) + 1e-5);
  float4 wv = ((const float4*)lnw)[tid];
  double n0 = x0 * r * wv.x, n1 = x1 * r * wv.y, n2 = x2 * r * wv.z, n3 = x3 * r * wv.w;
  xn[tid * 4 + 0] = n0; xn[tid * 4 + 1] = n1;
  xn[tid * 4 + 2] = n2; xn[tid * 4 + 3] = n3;
  double ma = fmax(fmax(fabs(n0), fabs(n1)), fmax(fabs(n2), fabs(n3)));
  ma = bredd(ma, 1, tmp);  // contains syncthreads -> xn visible
  double s = 127.0 / fmax(ma, 1e-5);
  ((int*)xq)[t * 256 + tid] = qpackd(n0, n1, n2, n3, s);
  if (tid == 0) xsd[t] = s;
  if (tid < 64) {
    int e = tid >> 3, i = tid & 7;
    const float* wr = rw + e * 1024;
    double p = 0.0;
    for (int h = i; h < 1024; h += 8) p += xn[h] * (double)wr[h];
    p += __shfl_xor(p, 1);
    p += __shfl_xor(p, 2);
    p += __shfl_xor(p, 4);
    if (i == 0) logits[e] = p;
  }
  __syncthreads();
  if (tid == 0) {
    double best = logits[0];
    int bi = 0;
    for (int e = 1; e < 8; e++)
      if (logits[e] > best) { best = logits[e]; bi = e; }
    eidx[t] = bi;
  }
}

// ---------------- MoE routing: group tokens by expert into padded 64-slot tiles ----
// meta[0] = ntile; meta[1+i] = expert of tile i. tokidx[slot] = token or -1 (pad).

__global__ __launch_bounds__(256) void k_route(const int* __restrict__ eidx,
                                               int* __restrict__ meta,
                                               int* __restrict__ tokidx) {
  __shared__ int cnt[8], pb[9], cur[8];
  int tid = threadIdx.x;
  if (tid < 8) cnt[tid] = 0;
  __syncthreads();
  for (int t = tid; t < NTOK; t += 256) atomicAdd(&cnt[eidx[t]], 1);
  __syncthreads();
  if (tid == 0) {
    pb[0] = 0;
    int nt = 0;
    for (int e = 0; e < 8; e++) {
      int tiles = (cnt[e] + 63) >> 6;
      for (int i = 0; i < tiles; i++) meta[1 + nt + i] = e;
      nt += tiles;
      pb[e + 1] = pb[e] + tiles * 64;
      cur[e] = pb[e];
    }
    meta[0] = nt;
  }
  __syncthreads();
  for (int s = tid; s < 4608; s += 256) tokidx[s] = -1;
  __syncthreads();
  for (int t = tid; t < NTOK; t += 256) {
    int e = eidx[t];
    int s = atomicAdd(&cur[e], 1);
    tokidx[s] = t;
  }
}

// ---------------- MoE gate+up GEMM via MFMA -> hh (fused relu(g)^2*u) ----------

__global__ __launch_bounds__(256) void k_moe_gu(
    const int8_t* __restrict__ Xq, const double* __restrict__ xsd,
    const int8_t* __restrict__ qw, const double* __restrict__ wsd,
    const int* __restrict__ meta, const int* __restrict__ tokidx,
    float* __restrict__ hhbuf) {
  __shared__ i32x4 Xs[4][64];
  __shared__ i32x4 Wg[4][128];
  __shared__ i32x4 Wu[4][128];
  __shared__ double invg[64], invu[64];
  int tile = blockIdx.y;
  if (tile >= meta[0]) return;
  int e = meta[1 + tile];
  int n0 = blockIdx.x * 128;
  int s0 = tile * 64;
  int tid = threadIdx.x;
  int w = tid >> 6, lane = tid & 63;
  int lrow = lane & 31, lk = lane >> 5;
  const int8_t* Gg = qw + ((long long)(4 + e) << 20);
  const int8_t* Ug = qw + ((long long)(12 + e) << 20);
  int xrow = tid >> 2, xkc = tid & 3;
  int tokr = tokidx[s0 + xrow];
  if (tokr < 0) tokr = 0;
  i32x16 accg[2], accu[2];
#pragma unroll
  for (int i = 0; i < 2; i++)
#pragma unroll
    for (int r = 0; r < 16; r++) { accg[i][r] = 0; accu[i][r] = 0; }

  for (int k0 = 0; k0 < 1024; k0 += 64) {
    Xs[xkc][xrow] = *(const i32x4*)(Xq + (long long)tokr * 1024 + k0 + xkc * 16);
#pragma unroll
    for (int i = 0; i < 2; i++) {
      int u = tid * 2 + i;                 // 0..511
      int row = u >> 2, kc = u & 3;
      Wg[kc][row] = *(const i32x4*)(Gg + (long long)(n0 + row) * 1024 + k0 + kc * 16);
      Wu[kc][row] = *(const i32x4*)(Ug + (long long)(n0 + row) * 1024 + k0 + kc * 16);
    }
    __syncthreads();
#pragma unroll
    for (int ks = 0; ks < 2; ks++) {
      i32x4 a0 = Xs[ks * 2 + lk][lrow];
      i32x4 a1 = Xs[ks * 2 + lk][32 + lrow];
      i32x4 bg = Wg[ks * 2 + lk][w * 32 + lrow];
      i32x4 bu = Wu[ks * 2 + lk][w * 32 + lrow];
      accg[0] = mfma_i8(a0, bg, accg[0]);
      accg[1] = mfma_i8(a1, bg, accg[1]);
      accu[0] = mfma_i8(a0, bu, accu[0]);
      accu[1] = mfma_i8(a1, bu, accu[1]);
    }
    __syncthreads();
  }

  double swg = wsd[4 + e], swu = wsd[12 + e];
  if (tid < 64) {
    int tk = tokidx[s0 + tid];
    double xs = (tk < 0) ? 1.0 : xsd[tk];
    invg[tid] = 1.0 / (xs * swg);
    invu[tid] = 1.0 / (xs * swu);
  }
  __syncthreads();
  int n = n0 + w * 32 + lrow;
#pragma unroll
  for (int i = 0; i < 2; i++) {
#pragma unroll
    for (int r = 0; r < 16; r++) {
      int sl = i * 32 + (r & 3) + 8 * (r >> 2) + 4 * lk;
      int s = s0 + sl;
      int tok = tokidx[s];
      if (tok < 0) continue;
      double g = (double)accg[i][r] * invg[sl];
      double uu = (double)accu[i][r] * invu[sl];
      double rg = fmax(g, 0.0);
      hhbuf[(long long)s * DDIM + n] = (float)(rg * rg * uu);
    }
  }
}

// ---------------- act_quant over hh slot rows ----------------

__global__ __launch_bounds__(256) void k_hh_actq(
    const float* __restrict__ hhbuf, const int* __restrict__ meta,
    const int* __restrict__ tokidx, int8_t* __restrict__ hq,
    double* __restrict__ hsd) {
  __shared__ double tmp[4];
  int s = blockIdx.x;
  if (s >= meta[0] * 64) return;
  int tid = threadIdx.x;
  int tok = tokidx[s];
  if (tok < 0) {
    ((int*)hq)[s * 256 + tid] = 0;
    if (tid == 0) hsd[s] = 1.0;
    return;
  }
  float4 xv = ((const float4*)(hhbuf + (long long)s * DDIM))[tid];
  double x0 = xv.x, x1 = xv.y, x2 = xv.z, x3 = xv.w;
  double ma = fmax(fmax(fabs(x0), fabs(x1)), fmax(fabs(x2), fabs(x3)));
  ma = bredd(ma, 1, tmp);
  double sc = 127.0 / fmax(ma, 1e-5);
  ((int*)hq)[s * 256 + tid] = qpackd(x0, x1, x2, x3, sc);
  if (tid == 0) hsd[s] = sc;
}

// ---------------- MoE down GEMM via MFMA + residual -> out (scatter) ------------

__global__ __launch_bounds__(256) void k_moe_down(
    const int8_t* __restrict__ hq, const double* __restrict__ hsd,
    const int8_t* __restrict__ qw, const double* __restrict__ wsd,
    const int* __restrict__ meta, const int* __restrict__ tokidx,
    const float* __restrict__ x2, float* __restrict__ out) {
  __shared__ i32x4 Xs[4][64];
  __shared__ i32x4 Ws[4][128];
  __shared__ double invd[64];
  int tile = blockIdx.y;
  if (tile >= meta[0]) return;
  int e = meta[1 + tile];
  int n0 = blockIdx.x * 128;
  int s0 = tile * 64;
  int tid = threadIdx.x;
  int w = tid >> 6, lane = tid & 63;
  int lrow = lane & 31, lk = lane >> 5;
  const int8_t* Wp = qw + ((long long)(20 + e) << 20);
  int xrow = tid >> 2, xkc = tid & 3;
  i32x16 acc[2];
#pragma unroll
  for (int i = 0; i < 2; i++)
#pragma unroll
    for (int r = 0; r < 16; r++) acc[i][r] = 0;

  for (int k0 = 0; k0 < 1024; k0 += 64) {
    Xs[xkc][xrow] = *(const i32x4*)(hq + (long long)(s0 + xrow) * 1024 + k0 + xkc * 16);
#pragma unroll
    for (int i = 0; i < 2; i++) {
      int u = tid * 2 + i;
      int row = u >> 2, kc = u & 3;
      Ws[kc][row] = *(const i32x4*)(Wp + (long long)(n0 + row) * 1024 + k0 + kc * 16);
    }
    __syncthreads();
#pragma unroll
    for (int ks = 0; ks < 2; ks++) {
      i32x4 a0 = Xs[ks * 2 + lk][lrow];
      i32x4 a1 = Xs[ks * 2 + lk][32 + lrow];
      i32x4 b  = Ws[ks * 2 + lk][w * 32 + lrow];
      acc[0] = mfma_i8(a0, b, acc[0]);
      acc[1] = mfma_i8(a1, b, acc[1]);
    }
    __syncthreads();
  }

  double sw = wsd[20 + e];
  if (tid < 64) invd[tid] = 1.0 / (hsd[s0 + tid] * sw);
  __syncthreads();
  int n = n0 + w * 32 + lrow;
#pragma unroll
  for (int i = 0; i < 2; i++) {
#pragma unroll
    for (int r = 0; r < 16; r++) {
      int sl = i * 32 + (r & 3) + 8 * (r >> 2) + 4 * lk;
      int s = s0 + sl;
      int tok = tokidx[s];
      if (tok < 0) continue;
      out[(long long)tok * H + n] =
          (float)((double)x2[(long long)tok * H + n] + (double)acc[i][r] * invd[sl]);
    }
  }
}

// ---------------- launch ----------------
// ws layout (bytes):
//   0        partial double[28*1024] (224 KB)
//   229376   wsd double[28]
//   229600   xsd double[4096] (32 KB)
//   262368   eidx int[4096] (16 KB)
//   278752   Mk float[32]
//   278912   meta int[128]  (ntile + tile_e)
//   279424   tokidx int[4608] (18 KB)
//   297856   hsd double[4608] (36.9 KB)
//   1MB      qw int8: 28 x 1MB
//   29MB     xq int8 4MB
//   33MB     qbuf fp32 16MB (q -> attn out h); later hhbuf f32 [4544][1024] (18.6MB, 33..51.6)
//   49MB     Kh ushort 8MB (dead after attn); hq int8 @52..56.7 later (inside)
//   57MB     Kl ushort 8MB (dead after attn)
//   65MB     Vp uint32 16MB (dead after attn); x2 fp32 written here by o-proj
extern "C" void kernel_launch(void* const* d_in, const int* in_sizes, int n_in,
                              void* d_out, int out_size, void* d_ws, size_t ws_size,
                              hipStream_t stream) {
  const float* x   = (const float*)d_in[0];
  const float* qw_ = (const float*)d_in[1];
  const float* kw_ = (const float*)d_in[2];
  const float* vw_ = (const float*)d_in[3];
  const float* ow_ = (const float*)d_in[4];
  const float* ln1 = (const float*)d_in[5];
  const float* ln2 = (const float*)d_in[6];
  const float* rw  = (const float*)d_in[7];
  const float* gw  = (const float*)d_in[8];
  const float* uw  = (const float*)d_in[9];
  const float* dw  = (const float*)d_in[10];
  float* out = (float*)d_out;

  uint8_t* ws = (uint8_t*)d_ws;
  double* partial = (double*)ws;
  double* wsd    = (double*)(ws + 229376);
  double* xsd    = (double*)(ws + 229600);
  int*    eidx   = (int*)(ws + 262368);
  float*  Mk     = (float*)(ws + 278752);
  int*    meta   = (int*)(ws + 278912);
  int*    tokidx = (int*)(ws + 279424);
  double* hsd    = (double*)(ws + 297856);
  int8_t* qw     = (int8_t*)(ws + (1ull << 20));
  int8_t* xq     = (int8_t*)(ws + (29ull << 20));
  float*  qbuf   = (float*)(ws + (33ull << 20));
  float*  hhbuf  = (float*)(ws + (33ull << 20));   // aliases qbuf (dead by then)
  unsigned short* Kh = (unsigned short*)(ws + (49ull << 20));
  unsigned short* Kl = (unsigned short*)(ws + (57ull << 20));
  int8_t* hq     = (int8_t*)(ws + (52ull << 20));  // inside dead Kh region (post-attn)
  unsigned int* Vp = (unsigned int*)(ws + (65ull << 20));
  float*  vbuf   = (float*)(ws + (65ull << 20));   // x2 overwrites dead Vp post-attn

  // weight quantization (deterministic fp64 scales)
  k_absum<<<28 * 1024, 256, 0, stream>>>(qw_, kw_, vw_, ow_, gw, uw, dw, partial);
  k_wscale<<<28, 256, 0, stream>>>(partial, wsd);
  k_quantw<<<28 * 1024, 256, 0, stream>>>(qw_, kw_, vw_, ow_, gw, uw, dw, wsd, qw);

  // attention input: rmsnorm + act_quant
  k_rms1<<<NTOK, 256, 0, stream>>>(x, ln1, xq, xsd);
  // q/k/v projections fused; k/v written in attention-native packed formats
  k_gemm3<<<dim3(8, 32, 3), 256, 0, stream>>>(xq, xsd, qw, wsd, qbuf, Kh, Kl, Vp);
  // causal flash attention (pre-packed K/V, reg-Q frags, fused softmax)
  k_knorm<<<32, 256, 0, stream>>>(Kh, Kl, Mk);
  k_attn<<<dim3(512), 512, 0, stream>>>(qbuf, Kh, Kl, Vp, qbuf, Mk);
  // o projection with residual: x2 = x + bitlinear(h, o_w) -> vbuf (BM=64, 2/CU)
  k_actq<<<NTOK, 256, 0, stream>>>(qbuf, xq, xsd);
  k_gemm<<<dim3(8, 64), 256, 0, stream>>>(xq, xsd, qw + (3 << 20), wsd, 3, x, vbuf);
  // MoE: rmsnorm2 + router argmax + act_quant, then expert-gathered GEMMs
  k_rms2_router<<<NTOK, 256, 0, stream>>>(vbuf, ln2, rw, xq, xsd, eidx);
  k_route<<<1, 256, 0, stream>>>(eidx, meta, tokidx);
  k_moe_gu<<<dim3(8, 71), 256, 0, stream>>>(xq, xsd, qw, wsd, meta, tokidx, hhbuf);
  k_hh_actq<<<4544, 256, 0, stream>>>(hhbuf, meta, tokidx, hq, hsd);
  k_moe_down<<<dim3(8, 71), 256, 0, stream>>>(hq, hsd, qw, wsd, meta, tokidx, vbuf, out);
}

// Round 13
// 458.973 us; speedup vs baseline: 3.0966x; 1.0098x over previous
//
#include <hip/hip_runtime.h>
#include <stdint.h>
#include <math.h>

// Problem constants
#define NTOK 4096   // B*S
#define H    1024
#define NHEAD 16
#define HD   64
#define SEQ  2048
#define NE   8
#define DDIM 1024

typedef __attribute__((ext_vector_type(4)))  int i32x4;
typedef __attribute__((ext_vector_type(16))) int i32x16;
typedef __attribute__((ext_vector_type(8)))  short bf16x8;
typedef __attribute__((ext_vector_type(4)))  float f32x4;

#define LOG2E 1.4426950408889634f

// ---------------- helpers ----------------

__device__ __forceinline__ i32x16 mfma_i8(i32x4 a, i32x4 b, i32x16 c) {
  return __builtin_amdgcn_mfma_i32_32x32x32_i8(a, b, c, 0, 0, 0);
}

// float -> bf16 round-to-nearest-even (finite inputs)
__device__ __forceinline__ unsigned int f2bf(float f) {
  unsigned int u = __float_as_uint(f);
  return (u + 0x7fffu + ((u >> 16) & 1u)) >> 16;
}
__device__ __forceinline__ float bf2f(unsigned int b) {
  return __uint_as_float(b << 16);
}
// pack hi-parts of (a,b) into return, lo-parts (residual bf16) into lo
__device__ __forceinline__ unsigned int f2bf2hl(float a, float b, unsigned int& lo) {
  unsigned int ha = f2bf(a), hb = f2bf(b);
  lo = f2bf(a - bf2f(ha)) | (f2bf(b - bf2f(hb)) << 16);
  return ha | (hb << 16);
}
// pack double-bf16 pair of one float: low ushort = hi, high ushort = lo
__device__ __forceinline__ unsigned int fpair(float a) {
  unsigned int hi = f2bf(a);
  unsigned int lo = f2bf(a - bf2f(hi));
  return hi | (lo << 16);
}
__device__ __forceinline__ unsigned int ror16(unsigned int x) {
  return (x >> 16) | (x << 16);
}

// 256-thread block reduce (double). op=0 sum, op=1 max. tmp: __shared__ double[4]
__device__ __forceinline__ double bredd(double v, int op, double* tmp) {
#pragma unroll
  for (int o = 32; o; o >>= 1) {
    double w = __shfl_xor(v, o);
    v = op ? fmax(v, w) : v + w;
  }
  int wid = threadIdx.x >> 6;
  if ((threadIdx.x & 63) == 0) tmp[wid] = v;
  __syncthreads();
  double r = op ? fmax(fmax(tmp[0], tmp[1]), fmax(tmp[2], tmp[3]))
                : (tmp[0] + tmp[1] + tmp[2] + tmp[3]);
  __syncthreads();
  return r;
}

// quantize 4 doubles to packed int8 with double scale (round-half-even like jnp.round)
__device__ __forceinline__ int qpackd(double n0, double n1, double n2, double n3, double s) {
  int a = (int)fmin(fmax(rint(n0 * s), -128.0), 127.0);
  int b = (int)fmin(fmax(rint(n1 * s), -128.0), 127.0);
  int c = (int)fmin(fmax(rint(n2 * s), -128.0), 127.0);
  int d = (int)fmin(fmax(rint(n3 * s), -128.0), 127.0);
  return (a & 255) | ((b & 255) << 8) | ((c & 255) << 16) | ((d & 255) << 24);
}

// map flat tensor id (0..27, each 1M elems) -> source pointer
__device__ __forceinline__ const float* wsrc(int tensor,
    const float* qw_, const float* kw_, const float* vw_, const float* ow_,
    const float* gw_, const float* uw_, const float* dw_) {
  if (tensor < 4) return tensor == 0 ? qw_ : tensor == 1 ? kw_ : tensor == 2 ? vw_ : ow_;
  if (tensor < 12) return gw_ + ((long long)(tensor - 4) << 20);
  if (tensor < 20) return uw_ + ((long long)(tensor - 12) << 20);
  return dw_ + ((long long)(tensor - 20) << 20);
}

// ---------------- weight quantization (fp64 scale, deterministic) ----------------

__global__ __launch_bounds__(256) void k_absum(
    const float* qw_, const float* kw_, const float* vw_, const float* ow_,
    const float* gw_, const float* uw_, const float* dw_, double* partial) {
  __shared__ double tmp[4];
  int tensor = blockIdx.x >> 10;
  int j = ((blockIdx.x & 1023) << 10) + threadIdx.x * 4;
  const float* src = wsrc(tensor, qw_, kw_, vw_, ow_, gw_, uw_, dw_);
  float4 w = *(const float4*)(src + j);
  double v = fabs((double)w.x) + fabs((double)w.y) + fabs((double)w.z) + fabs((double)w.w);
  v = bredd(v, 0, tmp);
  if (threadIdx.x == 0) partial[blockIdx.x] = v;
}

__global__ __launch_bounds__(256) void k_wscale(const double* partial, double* wsd) {
  __shared__ double tmp[4];
  int tensor = blockIdx.x;
  const double* p = partial + (tensor << 10);
  int i = threadIdx.x * 4;
  double v = p[i] + p[i + 1] + p[i + 2] + p[i + 3];
  v = bredd(v, 0, tmp);
  if (threadIdx.x == 0) wsd[tensor] = 1.0 / fmax(v * (1.0 / 1048576.0), 1e-5);
}

__global__ __launch_bounds__(256) void k_quantw(
    const float* qw_, const float* kw_, const float* vw_, const float* ow_,
    const float* gw_, const float* uw_, const float* dw_,
    const double* wsd, int8_t* qw) {
  int tensor = blockIdx.x >> 10;
  int j = ((blockIdx.x & 1023) << 10) + threadIdx.x * 4;
  const float* src = wsrc(tensor, qw_, kw_, vw_, ow_, gw_, uw_, dw_);
  double s = wsd[tensor];
  float4 w = *(const float4*)(src + j);
  int a = (int)fmin(fmax(rint((double)w.x * s), -1.0), 1.0);
  int b = (int)fmin(fmax(rint((double)w.y * s), -1.0), 1.0);
  int c = (int)fmin(fmax(rint((double)w.z * s), -1.0), 1.0);
  int d = (int)fmin(fmax(rint((double)w.w * s), -1.0), 1.0);
  ((int*)qw)[(tensor << 18) + (j >> 2)] =
      (a & 255) | ((b & 255) << 8) | ((c & 255) << 16) | ((d & 255) << 24);
}

// ---------------- rmsnorm + act_quant (attention input), fp64 decisions ----------------

__global__ __launch_bounds__(256) void k_rms1(const float* X, const float* lnw,
                                              int8_t* xq, double* xsd) {
  __shared__ double tmp[4];
  int t = blockIdx.x, tid = threadIdx.x;
  float4 xv = ((const float4*)(X + (long long)t * H))[tid];
  double x0 = xv.x, x1 = xv.y, x2 = xv.z, x3 = xv.w;
  double ss = x0 * x0 + x1 * x1 + x2 * x2 + x3 * x3;
  ss = bredd(ss, 0, tmp);
  double r = 1.0 / sqrt(ss * (1.0 / 1024.0) + 1e-5);
  float4 wv = ((const float4*)lnw)[tid];
  double n0 = x0 * r * wv.x, n1 = x1 * r * wv.y, n2 = x2 * r * wv.z, n3 = x3 * r * wv.w;
  double ma = fmax(fmax(fabs(n0), fabs(n1)), fmax(fabs(n2), fabs(n3)));
  ma = bredd(ma, 1, tmp);
  double s = 127.0 / fmax(ma, 1e-5);
  ((int*)xq)[t * 256 + tid] = qpackd(n0, n1, n2, n3, s);
  if (tid == 0) xsd[t] = s;
}

// act_quant only (rows of 1024 floats), fp64 decisions
__global__ __launch_bounds__(256) void k_actq(const float* X, int8_t* xq, double* xsd) {
  __shared__ double tmp[4];
  int t = blockIdx.x, tid = threadIdx.x;
  float4 xv = ((const float4*)(X + (long long)t * H))[tid];
  double x0 = xv.x, x1 = xv.y, x2 = xv.z, x3 = xv.w;
  double ma = fmax(fmax(fabs(x0), fabs(x1)), fmax(fabs(x2), fabs(x3)));
  ma = bredd(ma, 1, tmp);
  double s = 127.0 / fmax(ma, 1e-5);
  ((int*)xq)[t * 256 + tid] = qpackd(x0, x1, x2, x3, s);
  if (tid == 0) xsd[t] = s;
}

// ---------------- int8 GEMM via MFMA (o-proj): out = res + acc/(xs*sw) ----------
// BM=64 BN=128 BK=64 -> 512 blocks = 2/CU. Integer-exact.

__global__ __launch_bounds__(256) void k_gemm(
    const int8_t* __restrict__ Xq, const double* __restrict__ xsd,
    const int8_t* __restrict__ W, const double* __restrict__ wsd, int widx,
    const float* __restrict__ residual, float* __restrict__ out) {
  __shared__ i32x4 Xs[4][64];
  __shared__ i32x4 Ws[4][128];
  __shared__ double invs[64];
  int tid = threadIdx.x;
  int t0 = blockIdx.y * 64, n0 = blockIdx.x * 128;
  int w = tid >> 6, lane = tid & 63;
  int lrow = lane & 31, lk = lane >> 5;
  int xrow = tid >> 2, xkc = tid & 3;
  i32x16 acc[2];
#pragma unroll
  for (int i = 0; i < 2; i++)
#pragma unroll
    for (int r = 0; r < 16; r++) acc[i][r] = 0;

  for (int k0 = 0; k0 < 1024; k0 += 64) {
    Xs[xkc][xrow] = *(const i32x4*)(Xq + (long long)(t0 + xrow) * 1024 + k0 + xkc * 16);
#pragma unroll
    for (int i = 0; i < 2; i++) {
      int u = tid * 2 + i;
      int row = u >> 2, kc = u & 3;
      Ws[kc][row] = *(const i32x4*)(W + (long long)(n0 + row) * 1024 + k0 + kc * 16);
    }
    __syncthreads();
#pragma unroll
    for (int ks = 0; ks < 2; ks++) {
      i32x4 a0 = Xs[ks * 2 + lk][lrow];
      i32x4 a1 = Xs[ks * 2 + lk][32 + lrow];
      i32x4 b  = Ws[ks * 2 + lk][w * 32 + lrow];
      acc[0] = mfma_i8(a0, b, acc[0]);
      acc[1] = mfma_i8(a1, b, acc[1]);
    }
    __syncthreads();
  }

  double sw = wsd[widx];
  if (tid < 64) invs[tid] = 1.0 / (xsd[t0 + tid] * sw);
  __syncthreads();
  int n = n0 + w * 32 + lrow;
#pragma unroll
  for (int i = 0; i < 2; i++) {
#pragma unroll
    for (int r = 0; r < 16; r++) {
      int rl = i * 32 + (r & 3) + 8 * (r >> 2) + 4 * lk;
      int trow = t0 + rl;
      double v = (double)acc[i][r] * invs[rl];
      if (residual) v += (double)residual[(long long)trow * H + n];
      out[(long long)trow * H + n] = (float)v;
    }
  }
}

// k_gemm3: fused q/k/v projections writing ATTENTION-NATIVE formats:
//   z==0 (q): fp32 qbuf; z==1 (k): split double-bf16 planes Kh/Kl;
//   z==2 (v): interleaved pair words Vp (fpair).

__global__ __launch_bounds__(256) void k_gemm3(
    const int8_t* __restrict__ Xq, const double* __restrict__ xsd,
    const int8_t* __restrict__ qw, const double* __restrict__ wsd,
    float* __restrict__ outq, unsigned short* __restrict__ Kh,
    unsigned short* __restrict__ Kl, unsigned int* __restrict__ Vp) {
  __shared__ i32x4 Xs[4][128];
  __shared__ i32x4 Ws[4][128];
  __shared__ double invs[128];
  int z = blockIdx.z;
  const int8_t* W = qw + ((long long)z << 20);
  int tid = threadIdx.x;
  int t0 = blockIdx.y * 128, n0 = blockIdx.x * 128;
  int w = tid >> 6, lane = tid & 63;
  int wm = w >> 1, wn = w & 1;
  int lrow = lane & 31, lk = lane >> 5;
  i32x16 acc[2][2];
#pragma unroll
  for (int i = 0; i < 2; i++)
#pragma unroll
    for (int j = 0; j < 2; j++)
#pragma unroll
      for (int r = 0; r < 16; r++) acc[i][j][r] = 0;

  for (int k0 = 0; k0 < 1024; k0 += 64) {
#pragma unroll
    for (int i = 0; i < 2; i++) {
      int u = tid * 2 + i;
      int row = u >> 2, kc = u & 3;
      Xs[kc][row] = *(const i32x4*)(Xq + (long long)(t0 + row) * 1024 + k0 + kc * 16);
      Ws[kc][row] = *(const i32x4*)(W  + (long long)(n0 + row) * 1024 + k0 + kc * 16);
    }
    __syncthreads();
#pragma unroll
    for (int ks = 0; ks < 2; ks++) {
      i32x4 a0 = Xs[ks * 2 + lk][wm * 64 + lrow];
      i32x4 a1 = Xs[ks * 2 + lk][wm * 64 + 32 + lrow];
      i32x4 b0 = Ws[ks * 2 + lk][wn * 64 + lrow];
      i32x4 b1 = Ws[ks * 2 + lk][wn * 64 + 32 + lrow];
      acc[0][0] = mfma_i8(a0, b0, acc[0][0]);
      acc[0][1] = mfma_i8(a0, b1, acc[0][1]);
      acc[1][0] = mfma_i8(a1, b0, acc[1][0]);
      acc[1][1] = mfma_i8(a1, b1, acc[1][1]);
    }
    __syncthreads();
  }

  double sw = wsd[z];
  if (tid < 128) invs[tid] = 1.0 / (xsd[t0 + tid] * sw);
  __syncthreads();
#pragma unroll
  for (int i = 0; i < 2; i++) {
#pragma unroll
    for (int r = 0; r < 16; r++) {
      int rloc = wm * 64 + i * 32 + (r & 3) + 8 * (r >> 2) + 4 * lk;
      long long base = (long long)(t0 + rloc) * H;
      double inv = invs[rloc];
#pragma unroll
      for (int j = 0; j < 2; j++) {
        int n = n0 + wn * 64 + j * 32 + lrow;
        float vf = (float)((double)acc[i][j][r] * inv);
        long long idx = base + n;
        if (z == 0) {
          outq[idx] = vf;
        } else if (z == 1) {
          unsigned int h = f2bf(vf);
          unsigned int l = f2bf(vf - bf2f(h));
          Kh[idx] = (unsigned short)h;
          Kl[idx] = (unsigned short)l;
        } else {
          Vp[idx] = fpair(vf);
        }
      }
    }
  }
}

// ---------------- attention ----------------
// k_knorm: per-(b,head) max key L2-norm from packed Kh/Kl (reconstruct h+l).

__global__ __launch_bounds__(256) void k_knorm(const unsigned short* __restrict__ Kh,
                                               const unsigned short* __restrict__ Kl,
                                               float* __restrict__ Mk) {
  __shared__ float tmp[4];
  int bh = blockIdx.x;          // b*16 + head
  int b = bh >> 4, head = bh & 15;
  int tid = threadIdx.x;
  float mx = 0.f;
  for (int key = tid; key < SEQ; key += 256) {
    long long base = ((long long)(b * SEQ + key)) * H + head * HD;
    const uint4* hq4 = (const uint4*)(Kh + base);
    const uint4* lq4 = (const uint4*)(Kl + base);
    float s = 0.f;
#pragma unroll
    for (int i = 0; i < 8; i++) {         // 8 x (8 ushorts) = 64 elems
      uint4 hu = hq4[i], lu = lq4[i];
      const unsigned int hw[4] = {hu.x, hu.y, hu.z, hu.w};
      const unsigned int lw[4] = {lu.x, lu.y, lu.z, lu.w};
#pragma unroll
      for (int j = 0; j < 4; j++) {
        float v0 = bf2f(hw[j] & 0xffffu) + bf2f(lw[j] & 0xffffu);
        float v1 = bf2f(hw[j] >> 16)     + bf2f(lw[j] >> 16);
        s += v0 * v0 + v1 * v1;
      }
    }
    mx = fmaxf(mx, s);
  }
#pragma unroll
  for (int o = 32; o; o >>= 1) mx = fmaxf(mx, __shfl_xor(mx, o));
  if ((tid & 63) == 0) tmp[tid >> 6] = mx;
  __syncthreads();
  if (tid == 0)
    Mk[bh] = sqrtf(fmaxf(fmaxf(tmp[0], tmp[1]), fmaxf(tmp[2], tmp[3])));
}

// k_attn (R19): R18 + (a) ASYNC-STAGE (T14): next tile's K/V global loads issued
// right after the staging barrier into registers (+16 VGPR); their ~200-900cy
// latency hides under the QK+PV phases, and the staging phase shrinks to pure
// reg->LDS writes. (b) exp2 fold: Q staged at scale 0.125*log2e and mbs scaled
// by log2e, so the weight is v_exp_f32 direct (exp2f) - drops the per-exp mul.
// Math equivalent within the established ~2^-17 pair class.

__global__ __launch_bounds__(512, 4) void k_attn(
    const float* __restrict__ Q, const unsigned short* __restrict__ KH,
    const unsigned short* __restrict__ KL, const unsigned int* __restrict__ VP,
    float* __restrict__ O, const float* __restrict__ Mk) {
  __shared__ unsigned short Qb[64][72];     // Q bf16 hi (x0.125*log2e)
  __shared__ unsigned short Ql[64][72];     // Q bf16 lo
  __shared__ unsigned short Kb[64][72];     // K bf16 hi
  __shared__ unsigned short Kl[64][72];     // K bf16 lo
  __shared__ unsigned int   VA[64][76];     // V^T pairs, col-swizzled
  __shared__ unsigned int   Pw[64][76];     // softmax weight pairs
  __shared__ float mbs[64];
  __shared__ float lsh[8][16];
  int i = blockIdx.x;
  int hb = (i & 7) | (((i >> 3) & 3) << 3);
  int p  = ((i >> 5) & 7) | (((i >> 8) & 1) << 3);
  int head = hb & 15, b = hb >> 4;
  int tid = threadIdx.x;
  int w = tid >> 6, lane = tid & 63;
  int quad = lane >> 2, dp = lane & 3;
  int d0 = dp << 4;
  int l15 = lane & 15, lhi = lane >> 4;
  int qh = w >> 2, ks = w & 3;
  long long bh_base = ((long long)b * SEQ) * H + head * HD;
  float mkv = Mk[b * 16 + head];

  int srow = tid >> 3;               // staging row 0..63
  int sd = (tid & 7) << 3;           // staging elem offset 0,8,..,56
  int vswz = (tid & 7) << 2;         // V^T staging column swizzle

  int qb = w >> 1;                   // wave's q-block (QK and PV epilogue)

  const float qscale = 0.125f * LOG2E;

  for (int ph = 0; ph < 2; ph++) {
    int g = ph ? (31 - p) : p;
    int qlo = g * 64;

    // stage Q tile as double-bf16 (x0.125*log2e), once per phase
    {
      const float* qg = Q + bh_base + (long long)(qlo + srow) * H + sd;
      float4 a = *(const float4*)qg;
      float4 c = *(const float4*)(qg + 4);
      uint4 phh, pll;
      phh.x = f2bf2hl(a.x * qscale, a.y * qscale, pll.x);
      phh.y = f2bf2hl(a.z * qscale, a.w * qscale, pll.y);
      phh.z = f2bf2hl(c.x * qscale, c.y * qscale, pll.z);
      phh.w = f2bf2hl(c.z * qscale, c.w * qscale, pll.w);
      *(uint4*)&Qb[srow][sd] = phh;
      *(uint4*)&Ql[srow][sd] = pll;
    }

    // fixed bound mb = log2e*0.125*|q|*max|k| into mbs[] (ks==0 waves)
    if (ks == 0) {
      int j0 = qh * 32 + quad * 2;
#pragma unroll
      for (int qq = 0; qq < 2; qq++) {
        int j = j0 + qq;
        const float4* qp_ = (const float4*)(Q + bh_base + (long long)(qlo + j) * H + d0);
        float ss = 0.f;
#pragma unroll
        for (int i2 = 0; i2 < 4; i2++) {
          float4 t = qp_[i2];
          ss += t.x * t.x + t.y * t.y + t.z * t.z + t.w * t.w;
        }
        ss += __shfl_xor(ss, 1);
        ss += __shfl_xor(ss, 2);
        if (dp == 0) mbs[j] = qscale * sqrtf(ss) * mkv;
      }
    }

    float lp[4] = {0.f, 0.f, 0.f, 0.f};
    f32x4 oacc[2];
#pragma unroll
    for (int fi = 0; fi < 2; fi++)
#pragma unroll
      for (int r = 0; r < 4; r++) oacc[fi][r] = 0.f;

    __syncthreads();   // Qb/Ql/mbs visible

    // hoist this lane's Q frags (tile-invariant) + row bounds to registers
    bf16x8 qah[2], qal[2];
#pragma unroll
    for (int ks2 = 0; ks2 < 2; ks2++) {
      qah[ks2] = *(const bf16x8*)&Qb[qb * 16 + l15][ks2 * 32 + lhi * 8];
      qal[ks2] = *(const bf16x8*)&Ql[qb * 16 + l15][ks2 * 32 + lhi * 8];
    }
    float mbr4[4];
#pragma unroll
    for (int r = 0; r < 4; r++) mbr4[r] = mbs[qb * 16 + lhi * 4 + r];

    // prefetch tile 0 K/V into registers (T14 async-stage)
    uint4 kh_r, kl_r, vp_r0, vp_r1;
    {
      long long idx = bh_base + (long long)(srow) * H + sd;
      kh_r = *(const uint4*)(KH + idx);
      kl_r = *(const uint4*)(KL + idx);
      const uint4* vg = (const uint4*)(VP + idx);
      vp_r0 = vg[0];
      vp_r1 = vg[1];
    }

    for (int t = 0; t <= g; t++) {
      // ---- staging phase: pure reg -> LDS writes
      {
        *(uint4*)&Kb[srow][sd] = kh_r;
        *(uint4*)&Kl[srow][sd] = kl_r;
        int col = srow ^ vswz;
        VA[sd + 0][col] = vp_r0.x;
        VA[sd + 1][col] = vp_r0.y;
        VA[sd + 2][col] = vp_r0.z;
        VA[sd + 3][col] = vp_r0.w;
        VA[sd + 4][col] = vp_r1.x;
        VA[sd + 5][col] = vp_r1.y;
        VA[sd + 6][col] = vp_r1.z;
        VA[sd + 7][col] = vp_r1.w;
      }
      __syncthreads();

      // issue next tile's loads now; latency hides under QK+PV
      if (t < g) {
        long long idx = bh_base + (long long)((t + 1) * 64 + srow) * H + sd;
        kh_r = *(const uint4*)(KH + idx);
        kl_r = *(const uint4*)(KL + idx);
        const uint4* vg = (const uint4*)(VP + idx);
        vp_r0 = vg[0];
        vp_r1 = vg[1];
      }

      // ---- QK^T MFMA (3-term double-bf16, reg A) + fused mask/exp2/pack -> Pw
      {
        bool dg = (t == g);
#pragma unroll
        for (int kb2 = 0; kb2 < 2; kb2++) {
          int kb = (w & 1) * 2 + kb2;
          f32x4 c = {0.f, 0.f, 0.f, 0.f};
          __builtin_amdgcn_s_setprio(1);
#pragma unroll
          for (int ks2 = 0; ks2 < 2; ks2++) {
            bf16x8 bh = *(const bf16x8*)&Kb[kb * 16 + l15][ks2 * 32 + lhi * 8];
            bf16x8 bl = *(const bf16x8*)&Kl[kb * 16 + l15][ks2 * 32 + lhi * 8];
            c = __builtin_amdgcn_mfma_f32_16x16x32_bf16(qal[ks2], bh, c, 0, 0, 0);
            c = __builtin_amdgcn_mfma_f32_16x16x32_bf16(qah[ks2], bl, c, 0, 0, 0);
            c = __builtin_amdgcn_mfma_f32_16x16x32_bf16(qah[ks2], bh, c, 0, 0, 0);
          }
          __builtin_amdgcn_s_setprio(0);
          int colc = kb * 16 + l15;
#pragma unroll
          for (int r = 0; r < 4; r++) {
            int row = qb * 16 + lhi * 4 + r;
            float wgt = (dg && colc > row) ? 0.f
                        : __builtin_amdgcn_exp2f(c[r] - mbr4[r]);
            lp[r] += wgt;
            Pw[row][colc] = fpair(wgt);
          }
        }
      }
      __syncthreads();

      // ---- PV MFMA: c4 outer (A-frag read once), fi inner (d-block)
      __builtin_amdgcn_s_setprio(1);
#pragma unroll
      for (int c4 = 0; c4 < 4; c4++) {
        bf16x8 af = *(const bf16x8*)&Pw[qb * 16 + l15][c4 * 16 + lhi * 4];
#pragma unroll
        for (int fi = 0; fi < 2; fi++) {
          int d4 = (w * 2 + fi) & 3;
          int row = d4 * 16 + l15;
          int rswz = ((row >> 3) & 7) << 2;
          union { uint4 q; unsigned int u[4]; bf16x8 v; } bb, bs;
          bb.q = *(const uint4*)&VA[row][(c4 * 16 + lhi * 4) ^ rswz];
          oacc[fi] = __builtin_amdgcn_mfma_f32_16x16x32_bf16(af, bb.v, oacc[fi], 0, 0, 0);
#pragma unroll
          for (int j = 0; j < 4; j++)
            bs.u[j] = ror16(bb.u[j]);
          oacc[fi] = __builtin_amdgcn_mfma_f32_16x16x32_bf16(af, bs.v, oacc[fi], 0, 0, 0);
        }
      }
      __builtin_amdgcn_s_setprio(0);
      __syncthreads();
    }

    // ---- l: reduce lp over the 16 l15 lanes (once per phase), publish per wave
#pragma unroll
    for (int r = 0; r < 4; r++) {
      lp[r] += __shfl_xor(lp[r], 1);
      lp[r] += __shfl_xor(lp[r], 2);
      lp[r] += __shfl_xor(lp[r], 4);
      lp[r] += __shfl_xor(lp[r], 8);
    }
    if (l15 == 0) {
#pragma unroll
      for (int r = 0; r < 4; r++) lsh[w][lhi * 4 + r] = lp[r];
    }
    __syncthreads();

    // ---- O epilogue: combine the two col-half waves' l, normalize, store
#pragma unroll
    for (int fi = 0; fi < 2; fi++) {
      int f = w * 2 + fi;
      int d4 = f & 3;
#pragma unroll
      for (int r = 0; r < 4; r++) {
        int idx = lhi * 4 + r;
        float lt = lsh[qb * 2][idx] + lsh[qb * 2 + 1][idx];
        float inv = 1.f / lt;
        int qrow = qb * 16 + idx;
        O[bh_base + (long long)(qlo + qrow) * H + d4 * 16 + l15] = oacc[fi][r] * inv;
      }
    }
    __syncthreads();                 // LDS reuse safe for next phase
  }
}

// ---------------- rmsnorm2 + router (argmax, fp64) + act_quant ----------------

__global__ __launch_bounds__(256) void k_rms2_router(
    const float* X2, const float* lnw, const float* rw,
    int8_t* xq, double* xsd, int* eidx) {
  __shared__ double tmp[4];
  __shared__ double xn[1024];
  __shared__ double logits[8];
  int t = blockIdx.x, tid = threadIdx.x;
  float4 xv = ((const float4*)(X2 + (long long)t * H))[tid];
  double x0 = xv.x, x1 = xv.y, x2 = xv.z, x3 = xv.w;
  double ss = x0 * x0 + x1 * x1 + x2 * x2 + x3 * x3;
  ss = bredd(ss, 0, tmp);
  double r = 1.0 / sqrt(ss * (1.0 / 1024.0) + 1e-5);
  float4 wv = ((const float4*)lnw)[tid];
  double n0 = x0 * r * wv.x, n1 = x1 * r * wv.y, n2 = x2 * r * wv.z, n3 = x3 * r * wv.w;
  xn[tid * 4 + 0] = n0; xn[tid * 4 + 1] = n1;
  xn[tid * 4 + 2] = n2; xn[tid * 4 + 3] = n3;
  double ma = fmax(fmax(fabs(n0), fabs(n1)), fmax(fabs(n2), fabs(n3)));
  ma = bredd(ma, 1, tmp);  // contains syncthreads -> xn visible
  double s = 127.0 / fmax(ma, 1e-5);
  ((int*)xq)[t * 256 + tid] = qpackd(n0, n1, n2, n3, s);
  if (tid == 0) xsd[t] = s;
  if (tid < 64) {
    int e = tid >> 3, i = tid & 7;
    const float* wr = rw + e * 1024;
    double p = 0.0;
    for (int h = i; h < 1024; h += 8) p += xn[h] * (double)wr[h];
    p += __shfl_xor(p, 1);
    p += __shfl_xor(p, 2);
    p += __shfl_xor(p, 4);
    if (i == 0) logits[e] = p;
  }
  __syncthreads();
  if (tid == 0) {
    double best = logits[0];
    int bi = 0;
    for (int e = 1; e < 8; e++)
      if (logits[e] > best) { best = logits[e]; bi = e; }
    eidx[t] = bi;
  }
}

// ---------------- MoE routing: group tokens by expert into padded 64-slot tiles ----
// meta[0] = ntile; meta[1+i] = expert of tile i. tokidx[slot] = token or -1 (pad).

__global__ __launch_bounds__(256) void k_route(const int* __restrict__ eidx,
                                               int* __restrict__ meta,
                                               int* __restrict__ tokidx) {
  __shared__ int cnt[8], pb[9], cur[8];
  int tid = threadIdx.x;
  if (tid < 8) cnt[tid] = 0;
  __syncthreads();
  for (int t = tid; t < NTOK; t += 256) atomicAdd(&cnt[eidx[t]], 1);
  __syncthreads();
  if (tid == 0) {
    pb[0] = 0;
    int nt = 0;
    for (int e = 0; e < 8; e++) {
      int tiles = (cnt[e] + 63) >> 6;
      for (int i = 0; i < tiles; i++) meta[1 + nt + i] = e;
      nt += tiles;
      pb[e + 1] = pb[e] + tiles * 64;
      cur[e] = pb[e];
    }
    meta[0] = nt;
  }
  __syncthreads();
  for (int s = tid; s < 4608; s += 256) tokidx[s] = -1;
  __syncthreads();
  for (int t = tid; t < NTOK; t += 256) {
    int e = eidx[t];
    int s = atomicAdd(&cur[e], 1);
    tokidx[s] = t;
  }
}

// ---------------- MoE gate+up GEMM via MFMA -> hh (fused relu(g)^2*u) ----------

__global__ __launch_bounds__(256) void k_moe_gu(
    const int8_t* __restrict__ Xq, const double* __restrict__ xsd,
    const int8_t* __restrict__ qw, const double* __restrict__ wsd,
    const int* __restrict__ meta, const int* __restrict__ tokidx,
    float* __restrict__ hhbuf) {
  __shared__ i32x4 Xs[4][64];
  __shared__ i32x4 Wg[4][128];
  __shared__ i32x4 Wu[4][128];
  __shared__ double invg[64], invu[64];
  int tile = blockIdx.y;
  if (tile >= meta[0]) return;
  int e = meta[1 + tile];
  int n0 = blockIdx.x * 128;
  int s0 = tile * 64;
  int tid = threadIdx.x;
  int w = tid >> 6, lane = tid & 63;
  int lrow = lane & 31, lk = lane >> 5;
  const int8_t* Gg = qw + ((long long)(4 + e) << 20);
  const int8_t* Ug = qw + ((long long)(12 + e) << 20);
  int xrow = tid >> 2, xkc = tid & 3;
  int tokr = tokidx[s0 + xrow];
  if (tokr < 0) tokr = 0;
  i32x16 accg[2], accu[2];
#pragma unroll
  for (int i = 0; i < 2; i++)
#pragma unroll
    for (int r = 0; r < 16; r++) { accg[i][r] = 0; accu[i][r] = 0; }

  for (int k0 = 0; k0 < 1024; k0 += 64) {
    Xs[xkc][xrow] = *(const i32x4*)(Xq + (long long)tokr * 1024 + k0 + xkc * 16);
#pragma unroll
    for (int i = 0; i < 2; i++) {
      int u = tid * 2 + i;                 // 0..511
      int row = u >> 2, kc = u & 3;
      Wg[kc][row] = *(const i32x4*)(Gg + (long long)(n0 + row) * 1024 + k0 + kc * 16);
      Wu[kc][row] = *(const i32x4*)(Ug + (long long)(n0 + row) * 1024 + k0 + kc * 16);
    }
    __syncthreads();
#pragma unroll
    for (int ks = 0; ks < 2; ks++) {
      i32x4 a0 = Xs[ks * 2 + lk][lrow];
      i32x4 a1 = Xs[ks * 2 + lk][32 + lrow];
      i32x4 bg = Wg[ks * 2 + lk][w * 32 + lrow];
      i32x4 bu = Wu[ks * 2 + lk][w * 32 + lrow];
      accg[0] = mfma_i8(a0, bg, accg[0]);
      accg[1] = mfma_i8(a1, bg, accg[1]);
      accu[0] = mfma_i8(a0, bu, accu[0]);
      accu[1] = mfma_i8(a1, bu, accu[1]);
    }
    __syncthreads();
  }

  double swg = wsd[4 + e], swu = wsd[12 + e];
  if (tid < 64) {
    int tk = tokidx[s0 + tid];
    double xs = (tk < 0) ? 1.0 : xsd[tk];
    invg[tid] = 1.0 / (xs * swg);
    invu[tid] = 1.0 / (xs * swu);
  }
  __syncthreads();
  int n = n0 + w * 32 + lrow;
#pragma unroll
  for (int i = 0; i < 2; i++) {
#pragma unroll
    for (int r = 0; r < 16; r++) {
      int sl = i * 32 + (r & 3) + 8 * (r >> 2) + 4 * lk;
      int s = s0 + sl;
      int tok = tokidx[s];
      if (tok < 0) continue;
      double g = (double)accg[i][r] * invg[sl];
      double uu = (double)accu[i][r] * invu[sl];
      double rg = fmax(g, 0.0);
      hhbuf[(long long)s * DDIM + n] = (float)(rg * rg * uu);
    }
  }
}

// ---------------- act_quant over hh slot rows ----------------

__global__ __launch_bounds__(256) void k_hh_actq(
    const float* __restrict__ hhbuf, const int* __restrict__ meta,
    const int* __restrict__ tokidx, int8_t* __restrict__ hq,
    double* __restrict__ hsd) {
  __shared__ double tmp[4];
  int s = blockIdx.x;
  if (s >= meta[0] * 64) return;
  int tid = threadIdx.x;
  int tok = tokidx[s];
  if (tok < 0) {
    ((int*)hq)[s * 256 + tid] = 0;
    if (tid == 0) hsd[s] = 1.0;
    return;
  }
  float4 xv = ((const float4*)(hhbuf + (long long)s * DDIM))[tid];
  double x0 = xv.x, x1 = xv.y, x2 = xv.z, x3 = xv.w;
  double ma = fmax(fmax(fabs(x0), fabs(x1)), fmax(fabs(x2), fabs(x3)));
  ma = bredd(ma, 1, tmp);
  double sc = 127.0 / fmax(ma, 1e-5);
  ((int*)hq)[s * 256 + tid] = qpackd(x0, x1, x2, x3, sc);
  if (tid == 0) hsd[s] = sc;
}

// ---------------- MoE down GEMM via MFMA + residual -> out (scatter) ------------

__global__ __launch_bounds__(256) void k_moe_down(
    const int8_t* __restrict__ hq, const double* __restrict__ hsd,
    const int8_t* __restrict__ qw, const double* __restrict__ wsd,
    const int* __restrict__ meta, const int* __restrict__ tokidx,
    const float* __restrict__ x2, float* __restrict__ out) {
  __shared__ i32x4 Xs[4][64];
  __shared__ i32x4 Ws[4][128];
  __shared__ double invd[64];
  int tile = blockIdx.y;
  if (tile >= meta[0]) return;
  int e = meta[1 + tile];
  int n0 = blockIdx.x * 128;
  int s0 = tile * 64;
  int tid = threadIdx.x;
  int w = tid >> 6, lane = tid & 63;
  int lrow = lane & 31, lk = lane >> 5;
  const int8_t* Wp = qw + ((long long)(20 + e) << 20);
  int xrow = tid >> 2, xkc = tid & 3;
  i32x16 acc[2];
#pragma unroll
  for (int i = 0; i < 2; i++)
#pragma unroll
    for (int r = 0; r < 16; r++) acc[i][r] = 0;

  for (int k0 = 0; k0 < 1024; k0 += 64) {
    Xs[xkc][xrow] = *(const i32x4*)(hq + (long long)(s0 + xrow) * 1024 + k0 + xkc * 16);
#pragma unroll
    for (int i = 0; i < 2; i++) {
      int u = tid * 2 + i;
      int row = u >> 2, kc = u & 3;
      Ws[kc][row] = *(const i32x4*)(Wp + (long long)(n0 + row) * 1024 + k0 + kc * 16);
    }
    __syncthreads();
#pragma unroll
    for (int ks = 0; ks < 2; ks++) {
      i32x4 a0 = Xs[ks * 2 + lk][lrow];
      i32x4 a1 = Xs[ks * 2 + lk][32 + lrow];
      i32x4 b  = Ws[ks * 2 + lk][w * 32 + lrow];
      acc[0] = mfma_i8(a0, b, acc[0]);
      acc[1] = mfma_i8(a1, b, acc[1]);
    }
    __syncthreads();
  }

  double sw = wsd[20 + e];
  if (tid < 64) invd[tid] = 1.0 / (hsd[s0 + tid] * sw);
  __syncthreads();
  int n = n0 + w * 32 + lrow;
#pragma unroll
  for (int i = 0; i < 2; i++) {
#pragma unroll
    for (int r = 0; r < 16; r++) {
      int sl = i * 32 + (r & 3) + 8 * (r >> 2) + 4 * lk;
      int s = s0 + sl;
      int tok = tokidx[s];
      if (tok < 0) continue;
      out[(long long)tok * H + n] =
          (float)((double)x2[(long long)tok * H + n] + (double)acc[i][r] * invd[sl]);
    }
  }
}

// ---------------- launch ----------------
// ws layout (bytes):
//   0        partial double[28*1024] (224 KB)
//   229376   wsd double[28]
//   229600   xsd double[4096] (32 KB)
//   262368   eidx int[4096] (16 KB)
//   278752   Mk float[32]
//   278912   meta int[128]  (ntile + tile_e)
//   279424   tokidx int[4608] (18 KB)
//   297856   hsd double[4608] (36.9 KB)
//   1MB      qw int8: 28 x 1MB
//   29MB     xq int8 4MB
//   33MB     qbuf fp32 16MB (q -> attn out h); later hhbuf f32 [4544][1024] (18.6MB, 33..51.6)
//   49MB     Kh ushort 8MB (dead after attn); hq int8 @52..56.7 later (inside)
//   57MB     Kl ushort 8MB (dead after attn)
//   65MB     Vp uint32 16MB (dead after attn); x2 fp32 written here by o-proj
extern "C" void kernel_launch(void* const* d_in, const int* in_sizes, int n_in,
                              void* d_out, int out_size, void* d_ws, size_t ws_size,
                              hipStream_t stream) {
  const float* x   = (const float*)d_in[0];
  const float* qw_ = (const float*)d_in[1];
  const float* kw_ = (const float*)d_in[2];
  const float* vw_ = (const float*)d_in[3];
  const float* ow_ = (const float*)d_in[4];
  const float* ln1 = (const float*)d_in[5];
  const float* ln2 = (const float*)d_in[6];
  const float* rw  = (const float*)d_in[7];
  const float* gw  = (const float*)d_in[8];
  const float* uw  = (const float*)d_in[9];
  const float* dw  = (const float*)d_in[10];
  float* out = (float*)d_out;

  uint8_t* ws = (uint8_t*)d_ws;
  double* partial = (double*)ws;
  double* wsd    = (double*)(ws + 229376);
  double* xsd    = (double*)(ws + 229600);
  int*    eidx   = (int*)(ws + 262368);
  float*  Mk     = (float*)(ws + 278752);
  int*    meta   = (int*)(ws + 278912);
  int*    tokidx = (int*)(ws + 279424);
  double* hsd    = (double*)(ws + 297856);
  int8_t* qw     = (int8_t*)(ws + (1ull << 20));
  int8_t* xq     = (int8_t*)(ws + (29ull << 20));
  float*  qbuf   = (float*)(ws + (33ull << 20));
  float*  hhbuf  = (float*)(ws + (33ull << 20));   // aliases qbuf (dead by then)
  unsigned short* Kh = (unsigned short*)(ws + (49ull << 20));
  unsigned short* Kl = (unsigned short*)(ws + (57ull << 20));
  int8_t* hq     = (int8_t*)(ws + (52ull << 20));  // inside dead Kh region (post-attn)
  unsigned int* Vp = (unsigned int*)(ws + (65ull << 20));
  float*  vbuf   = (float*)(ws + (65ull << 20));   // x2 overwrites dead Vp post-attn

  // weight quantization (deterministic fp64 scales)
  k_absum<<<28 * 1024, 256, 0, stream>>>(qw_, kw_, vw_, ow_, gw, uw, dw, partial);
  k_wscale<<<28, 256, 0, stream>>>(partial, wsd);
  k_quantw<<<28 * 1024, 256, 0, stream>>>(qw_, kw_, vw_, ow_, gw, uw, dw, wsd, qw);

  // attention input: rmsnorm + act_quant
  k_rms1<<<NTOK, 256, 0, stream>>>(x, ln1, xq, xsd);
  // q/k/v projections fused; k/v written in attention-native packed formats
  k_gemm3<<<dim3(8, 32, 3), 256, 0, stream>>>(xq, xsd, qw, wsd, qbuf, Kh, Kl, Vp);
  // causal flash attention (async-stage prefetch, exp2 softmax, pair-exact PV)
  k_knorm<<<32, 256, 0, stream>>>(Kh, Kl, Mk);
  k_attn<<<dim3(512), 512, 0, stream>>>(qbuf, Kh, Kl, Vp, qbuf, Mk);
  // o projection with residual: x2 = x + bitlinear(h, o_w) -> vbuf (BM=64, 2/CU)
  k_actq<<<NTOK, 256, 0, stream>>>(qbuf, xq, xsd);
  k_gemm<<<dim3(8, 64), 256, 0, stream>>>(xq, xsd, qw + (3 << 20), wsd, 3, x, vbuf);
  // MoE: rmsnorm2 + router argmax + act_quant, then expert-gathered GEMMs
  k_rms2_router<<<NTOK, 256, 0, stream>>>(vbuf, ln2, rw, xq, xsd, eidx);
  k_route<<<1, 256, 0, stream>>>(eidx, meta, tokidx);
  k_moe_gu<<<dim3(8, 71), 256, 0, stream>>>(xq, xsd, qw, wsd, meta, tokidx, hhbuf);
  k_hh_actq<<<4544, 256, 0, stream>>>(hhbuf, meta, tokidx, hq, hsd);
  k_moe_down<<<dim3(8, 71), 256, 0, stream>>>(hq, hsd, qw, wsd, meta, tokidx, vbuf, out);
}